// Round 1
// baseline (24236.316 us; speedup 1.0000x reference)
//
#include <hip/hip_runtime.h>

#define N_NODES 100000
#define N_EDGES 1600000
#define C1 262144              // 64^3 cells after pool1
#define C2 4096                // 16^3 cells after pool2
#define E2 (N_EDGES + C1)      // 1,862,144 edges at level 1/2 (with self loops)

__device__ __forceinline__ void amaxf(float* p, float v) {
    atomicMax(reinterpret_cast<int*>(p), __float_as_int(v));
}

// Graph conv: msg = [f_src ; pos_src - pos_dst] @ W, max-aggregated at dst.
// Aggregation buffer must be zero-initialized; the subsequent relu is folded in
// (negatives lose to the 0 init under signed-int max on float bits).
// LEVEL 0: positions from nodes[] array, ids direct.
// LEVEL 1: ids are 64^3 cell ids; positions are the integer cell coords.
// LEVEL 2: ids are 64^3 cell ids; remap to 16^3 analytically (coord>>2).
template<int CIN, int COUT, int LEVEL>
__global__ __launch_bounds__(256)
void gconv_k(const int* __restrict__ edges, int nE, int rowStride,
             const float* __restrict__ nodes,
             const float* __restrict__ feats,
             const float* __restrict__ W,
             float* __restrict__ agg)
{
    __shared__ float sW[(CIN + 3) * COUT];
    for (int i = threadIdx.x; i < (CIN + 3) * COUT; i += 256) sW[i] = W[i];
    __syncthreads();

    int e = blockIdx.x * 256 + threadIdx.x;
    if (e >= nE) return;
    int src = edges[e];
    int dst = edges[rowStride + e];

    float px, py, pz;
    if (LEVEL == 0) {
        px = nodes[3 * src]     - nodes[3 * dst];
        py = nodes[3 * src + 1] - nodes[3 * dst + 1];
        pz = nodes[3 * src + 2] - nodes[3 * dst + 2];
    } else if (LEVEL == 1) {
        px = (float)((src >> 12)       - (dst >> 12));
        py = (float)(((src >> 6) & 63) - ((dst >> 6) & 63));
        pz = (float)((src & 63)        - (dst & 63));
    } else { // LEVEL == 2
        int sx = src >> 12, sy = (src >> 6) & 63, sz = src & 63;
        int dx = dst >> 12, dy = (dst >> 6) & 63, dz = dst & 63;
        px = (float)((sx >> 2) - (dx >> 2));
        py = (float)((sy >> 2) - (dy >> 2));
        pz = (float)((sz >> 2) - (dz >> 2));
        src = ((sx >> 2) * 16 + (sy >> 2)) * 16 + (sz >> 2);
        dst = ((dx >> 2) * 16 + (dy >> 2)) * 16 + (dz >> 2);
    }

    float out[COUT];
    #pragma unroll
    for (int j = 0; j < COUT; ++j)
        out[j] = px * sW[(CIN + 0) * COUT + j]
               + py * sW[(CIN + 1) * COUT + j]
               + pz * sW[(CIN + 2) * COUT + j];
    for (int k = 0; k < CIN; ++k) {
        float f = feats[(size_t)src * CIN + k];
        #pragma unroll
        for (int j = 0; j < COUT; ++j)
            out[j] += f * sW[k * COUT + j];
    }

    float* ap = agg + (size_t)dst * COUT;
    #pragma unroll
    for (int j = 0; j < COUT; ++j) amaxf(ap + j, out[j]);
}

// Voxel pool 1: node coords -> 64^3 cell id; max-pool 16 channels; record cid.
__global__ __launch_bounds__(256)
void pool1_k(const float* __restrict__ nodes, const float* __restrict__ f,
             int* __restrict__ cid1, float* __restrict__ nf)
{
    int i = blockIdx.x * 256 + threadIdx.x;
    if (i >= N_NODES) return;
    int cx = min(max((int)floorf(nodes[3 * i]     * 0.25f), 0), 63);
    int cy = min(max((int)floorf(nodes[3 * i + 1] * 0.25f), 0), 63);
    int cz = min(max((int)floorf(nodes[3 * i + 2] * 0.25f), 0), 63);
    int c = (cx * 64 + cy) * 64 + cz;
    cid1[i] = c;
    float* ap = nf + (size_t)c * 16;
    const float* fp = f + (size_t)i * 16;
    #pragma unroll
    for (int ch = 0; ch < 16; ++ch) amaxf(ap + ch, fp[ch]);
}

// Remap original edges through cid1 and append one self loop per 64^3 cell.
__global__ __launch_bounds__(256)
void remap1_k(const int* __restrict__ edges, const int* __restrict__ cid1,
              int* __restrict__ e1)
{
    int i = blockIdx.x * 256 + threadIdx.x;
    if (i >= E2) return;
    if (i < N_EDGES) {
        e1[i]      = cid1[edges[i]];
        e1[E2 + i] = cid1[edges[N_EDGES + i]];
    } else {
        int c = i - N_EDGES;
        e1[i] = c; e1[E2 + i] = c;
    }
}

// Voxel pool 2: 64^3 cells -> 16^3 cells (analytic), 32 channels.
__global__ __launch_bounds__(256)
void pool2_k(const float* __restrict__ g, float* __restrict__ nf)
{
    int i = blockIdx.x * 256 + threadIdx.x;
    if (i >= C1) return;
    int x = i >> 12, y = (i >> 6) & 63, z = i & 63;
    int c = ((x >> 2) * 16 + (y >> 2)) * 16 + (z >> 2);
    float* ap = nf + (size_t)c * 32;
    const float* gp = g + (size_t)i * 32;
    #pragma unroll
    for (int ch = 0; ch < 32; ++ch) amaxf(ap + ch, gp[ch]);
}

// Output pool: 16^3 cells -> 4^3 = 64 cells (analytic), 64 channels.
__global__ __launch_bounds__(256)
void outpool_k(const float* __restrict__ g, float* __restrict__ xo)
{
    int i = blockIdx.x * 256 + threadIdx.x;
    if (i >= C2) return;
    int x = i >> 8, y = (i >> 4) & 15, z = i & 15;
    int c = ((x >> 2) * 4 + (y >> 2)) * 4 + (z >> 2);
    float* ap = xo + (size_t)c * 64;
    const float* gp = g + (size_t)i * 64;
    #pragma unroll
    for (int ch = 0; ch < 64; ++ch) amaxf(ap + ch, gp[ch]);
}

// Final linear: out[j] = sum_i xo[i] * Wl[i,j] + bl[j].  One wave per output.
__global__ __launch_bounds__(64)
void linear_k(const float* __restrict__ xo, const float* __restrict__ Wl,
              const float* __restrict__ bl, float* __restrict__ out)
{
    int j = blockIdx.x;
    float s = 0.f;
    for (int i = threadIdx.x; i < 4096; i += 64)
        s += xo[i] * Wl[(size_t)i * 100 + j];
    #pragma unroll
    for (int off = 32; off; off >>= 1) s += __shfl_down(s, off);
    if (threadIdx.x == 0) out[j] = s + bl[j];
}

extern "C" void kernel_launch(void* const* d_in, const int* in_sizes, int n_in,
                              void* d_out, int out_size, void* d_ws, size_t ws_size,
                              hipStream_t stream) {
    const float* nodes    = (const float*)d_in[0];
    const float* features = (const float*)d_in[1];
    const int*   edges    = (const int*)d_in[2];
    const float* W1 = (const float*)d_in[3];
    const float* W2 = (const float*)d_in[4];
    const float* W3 = (const float*)d_in[5];
    const float* W4 = (const float*)d_in[6];
    const float* W5 = (const float*)d_in[7];
    const float* W6 = (const float*)d_in[8];
    const float* W7 = (const float*)d_in[9];
    const float* Wl = (const float*)d_in[10];
    const float* bl = (const float*)d_in[11];
    float* out = (float*)d_out;

    // Workspace layout (all offsets 256B-aligned). Zeroed region first.
    char* ws = (char*)d_ws;
    size_t off = 0;
    auto alloc = [&](size_t bytes) { void* p = ws + off; off = (off + bytes + 255) & ~(size_t)255; return p; };
    float* f1  = (float*)alloc((size_t)N_NODES * 8  * 4);   // gconv1 out
    float* f2  = (float*)alloc((size_t)N_NODES * 16 * 4);   // gconv2 out
    float* nf1 = (float*)alloc((size_t)C1 * 16 * 4);        // pool1 out
    float* g3  = (float*)alloc((size_t)C1 * 32 * 4);        // gconv3 out
    float* g4  = (float*)alloc((size_t)C1 * 32 * 4);        // gconv4 out
    float* nf2 = (float*)alloc((size_t)C2 * 32 * 4);        // pool2 out
    float* g5  = (float*)alloc((size_t)C2 * 64 * 4);        // gconv5 out
    float* g6  = (float*)alloc((size_t)C2 * 64 * 4);        // gconv6 out
    float* g7  = (float*)alloc((size_t)C2 * 64 * 4);        // gconv7 out
    float* xo  = (float*)alloc((size_t)64 * 64 * 4);        // output pool
    size_t zero_bytes = off;                                // everything above needs 0-init
    int*   cid1 = (int*)alloc((size_t)N_NODES * 4);
    int*   e1   = (int*)alloc((size_t)2 * E2 * 4);
    if (ws_size < off) return;  // insufficient scratch — cannot proceed

    hipMemsetAsync(d_ws, 0, zero_bytes, stream);

    const int gE  = (N_EDGES + 255) / 256;
    const int gE2 = (E2 + 255) / 256;
    const int gN  = (N_NODES + 255) / 256;

    gconv_k<1, 8, 0><<<gE, 256, 0, stream>>>(edges, N_EDGES, N_EDGES, nodes, features, W1, f1);
    gconv_k<8, 16, 0><<<gE, 256, 0, stream>>>(edges, N_EDGES, N_EDGES, nodes, f1, W2, f2);
    pool1_k<<<gN, 256, 0, stream>>>(nodes, f2, cid1, nf1);
    remap1_k<<<gE2, 256, 0, stream>>>(edges, cid1, e1);
    gconv_k<16, 32, 1><<<gE2, 256, 0, stream>>>(e1, E2, E2, nullptr, nf1, W3, g3);
    gconv_k<32, 32, 1><<<gE2, 256, 0, stream>>>(e1, E2, E2, nullptr, g3, W4, g4);
    pool2_k<<<(C1 + 255) / 256, 256, 0, stream>>>(g4, nf2);
    gconv_k<32, 64, 2><<<gE2, 256, 0, stream>>>(e1, E2, E2, nullptr, nf2, W5, g5);
    gconv_k<64, 64, 2><<<gE2, 256, 0, stream>>>(e1, E2, E2, nullptr, g5, W6, g6);
    gconv_k<64, 64, 2><<<gE2, 256, 0, stream>>>(e1, E2, E2, nullptr, g6, W7, g7);
    outpool_k<<<(C2 + 255) / 256, 256, 0, stream>>>(g7, xo);
    linear_k<<<100, 64, 0, stream>>>(xo, Wl, bl, out);
}

// Round 2
// 1214.607 us; speedup vs baseline: 19.9540x; 19.9540x over previous
//
#include <hip/hip_runtime.h>

#define NN 100000      // nodes
#define NE 1600000     // edges
#define C1 262144      // 64^3 cells
#define C2 4096        // 16^3 cells

// ---------------- cell id of each node ----------------
__global__ __launch_bounds__(256)
void cid_k(const float* __restrict__ nodes, int* __restrict__ cid) {
    int i = blockIdx.x * 256 + threadIdx.x;
    if (i >= NN) return;
    int cx = min(max((int)floorf(nodes[3 * i]     * 0.25f), 0), 63);
    int cy = min(max((int)floorf(nodes[3 * i + 1] * 0.25f), 0), 63);
    int cz = min(max((int)floorf(nodes[3 * i + 2] * 0.25f), 0), 63);
    cid[i] = (cx * 64 + cy) * 64 + cz;
}

// ---------------- CSR build: histogram / scan / scatter ----------------
// MODE 0: edges keyed by dst node, value = src node
// MODE 1: edges keyed by cid[dst],  value = cid[src]
// MODE 2: nodes keyed by cid[i],    value = i
template<int MODE>
__global__ __launch_bounds__(256)
void hist_k(const int* __restrict__ src, const int* __restrict__ dst,
            const int* __restrict__ cid, int n, int* __restrict__ cnt) {
    int e = blockIdx.x * 256 + threadIdx.x;
    if (e >= n) return;
    int key = (MODE == 0) ? dst[e] : (MODE == 1) ? cid[dst[e]] : cid[e];
    atomicAdd(&cnt[key], 1);
}

template<int MODE>
__global__ __launch_bounds__(256)
void scatter_k(const int* __restrict__ src, const int* __restrict__ dst,
               const int* __restrict__ cid, int n,
               const int* __restrict__ offs, int* __restrict__ cnt,
               int* __restrict__ out) {
    int e = blockIdx.x * 256 + threadIdx.x;
    if (e >= n) return;
    int key, val;
    if (MODE == 0)      { key = dst[e];      val = src[e]; }
    else if (MODE == 1) { key = cid[dst[e]]; val = cid[src[e]]; }
    else                { key = cid[e];      val = e; }
    int pos = offs[key] + atomicAdd(&cnt[key], -1) - 1;  // order-free; max is commutative
    out[pos] = val;
}

// exclusive scan, 1024 elems per block (256 thr x 4)
__global__ __launch_bounds__(256)
void scan1_k(const int* __restrict__ cnt, int n, int* __restrict__ offs,
             int* __restrict__ bsum) {
    __shared__ int ws[4];
    int t = threadIdx.x, lane = t & 63, w = t >> 6;
    int base = blockIdx.x * 1024 + t * 4;
    int v[4]; int s = 0;
    #pragma unroll
    for (int i = 0; i < 4; ++i) { v[i] = (base + i < n) ? cnt[base + i] : 0; s += v[i]; }
    int sc = s;
    #pragma unroll
    for (int off = 1; off < 64; off <<= 1) {
        int o = __shfl_up(sc, off);
        if (lane >= off) sc += o;
    }
    if (lane == 63) ws[w] = sc;
    __syncthreads();
    int wbase = 0;
    for (int i = 0; i < w; ++i) wbase += ws[i];
    int run = wbase + sc - s;   // exclusive prefix of this thread
    #pragma unroll
    for (int i = 0; i < 4; ++i) { if (base + i < n) offs[base + i] = run; run += v[i]; }
    if (t == 255) bsum[blockIdx.x] = wbase + sc;  // block total
}

__global__ void scan2_k(int* __restrict__ bsum, int nb) {
    if (threadIdx.x != 0) return;
    int acc = 0;
    for (int i = 0; i < nb; ++i) { int t = bsum[i]; bsum[i] = acc; acc += t; }
    bsum[nb] = acc;
}

__global__ __launch_bounds__(256)
void scan3_k(int* __restrict__ offs, int n, const int* __restrict__ bsum, int nb) {
    int i = blockIdx.x * 256 + threadIdx.x;
    if (i < n) offs[i] += bsum[i >> 10];
    else if (i == n) offs[n] = bsum[nb];
}

// ---------------- per-node transform: h = f @ W_f + pos @ W_p ----------------
// LEVEL 0: pos from nodes[]; LEVEL 1: 64^3 cell coords; LEVEL 2: 16^3 cell coords
template<int CI, int CO, int LEVEL>
__global__ __launch_bounds__(256)
void xform_k(int n, const float* __restrict__ nodes, const float* __restrict__ f,
             const float* __restrict__ W, float* __restrict__ h) {
    __shared__ float sW[(CI + 3) * CO];
    for (int i = threadIdx.x; i < (CI + 3) * CO; i += 256) sW[i] = W[i];
    __syncthreads();
    int gid = blockIdx.x * 256 + threadIdx.x;
    int i = gid / CO, ch = gid - i * CO;
    if (i >= n) return;
    float px, py, pz;
    if (LEVEL == 0) { px = nodes[3 * i]; py = nodes[3 * i + 1]; pz = nodes[3 * i + 2]; }
    else if (LEVEL == 1) { px = (float)(i >> 12); py = (float)((i >> 6) & 63); pz = (float)(i & 63); }
    else { px = (float)(i >> 8); py = (float)((i >> 4) & 15); pz = (float)(i & 15); }
    float s = px * sW[CI * CO + ch] + py * sW[(CI + 1) * CO + ch] + pz * sW[(CI + 2) * CO + ch];
    for (int k = 0; k < CI; ++k) s += f[(size_t)i * CI + k] * sW[k * CO + ch];
    h[(size_t)i * CO + ch] = s;
}

// ---------------- gather aggregation (atomic-free) ----------------
// out[d] = max(c_d, max_{src in CSR[d]} h[src]) - c_d   (== relu'd gconv, empty -> 0)
template<int CO>
__global__ __launch_bounds__(256)
void gatherL0_k(int n, const float* __restrict__ nodes, const float* __restrict__ h,
                const float* __restrict__ Wpos, const int* __restrict__ offs,
                const int* __restrict__ srcs, float* __restrict__ out) {
    __shared__ float sW[3 * CO];
    for (int i = threadIdx.x; i < 3 * CO; i += 256) sW[i] = Wpos[i];
    __syncthreads();
    int gid = blockIdx.x * 256 + threadIdx.x;
    int d = gid / CO, ch = gid - d * CO;
    if (d >= n) return;
    float c = nodes[3 * d] * sW[ch] + nodes[3 * d + 1] * sW[CO + ch] + nodes[3 * d + 2] * sW[2 * CO + ch];
    float m = c;                        // no self-loop at level 0; empty -> 0
    int e0 = offs[d], e1 = offs[d + 1];
    for (int t = e0; t < e1; ++t) m = fmaxf(m, h[(size_t)srcs[t] * CO + ch]);
    out[(size_t)d * CO + ch] = m - c;
}

template<int CO>
__global__ __launch_bounds__(256)
void gatherL1_k(const float* __restrict__ h, const float* __restrict__ Wpos,
                const int* __restrict__ offs, const int* __restrict__ srcs,
                float* __restrict__ out) {
    __shared__ float sW[3 * CO];
    for (int i = threadIdx.x; i < 3 * CO; i += 256) sW[i] = Wpos[i];
    __syncthreads();
    int gid = blockIdx.x * 256 + threadIdx.x;
    int d = gid / CO, ch = gid - d * CO;
    if (d >= C1) return;
    float px = (float)(d >> 12), py = (float)((d >> 6) & 63), pz = (float)(d & 63);
    float c = px * sW[ch] + py * sW[CO + ch] + pz * sW[2 * CO + ch];
    float m = fmaxf(c, h[(size_t)d * CO + ch]);   // self-loop
    int e0 = offs[d], e1 = offs[d + 1];
    for (int t = e0; t < e1; ++t) m = fmaxf(m, h[(size_t)srcs[t] * CO + ch]);
    out[(size_t)d * CO + ch] = m - c;
}

// level-2 gconv: per 16^3 cell, aggregate over its 64 children's level-1 in-edges
// (edges parent-mapped on the fly; self-loops folded into the init). h is [4096][64].
__global__ __launch_bounds__(256)
void gconvL2_k(const float* __restrict__ h, const float* __restrict__ Wpos,
               const int* __restrict__ offs, const int* __restrict__ srcs,
               float* __restrict__ out) {
    __shared__ float red[4][64];
    __shared__ float sW[3 * 64];
    int t = threadIdx.x, lane = t & 63, w = t >> 6;
    if (t < 192) sW[t] = Wpos[t];
    __syncthreads();
    int d2 = blockIdx.x;
    int x2 = d2 >> 8, y2 = (d2 >> 4) & 15, z2 = d2 & 15;
    float m = -1e30f;
    for (int ci = 0; ci < 16; ++ci) {
        int tc = w * 16 + ci;
        int i = tc >> 4, j = (tc >> 2) & 3, k = tc & 3;
        int d1 = ((x2 * 4 + i) * 64 + (y2 * 4 + j)) * 64 + (z2 * 4 + k);
        int e0 = offs[d1], e1 = offs[d1 + 1];
        for (int q = e0; q < e1; ++q) {
            int s1 = srcs[q];
            int p = (((s1 >> 12) >> 2) * 16 + (((s1 >> 6) & 63) >> 2)) * 16 + ((s1 & 63) >> 2);
            m = fmaxf(m, h[(size_t)p * 64 + lane]);
        }
    }
    red[w][lane] = m;
    __syncthreads();
    if (w == 0) {
        float c = x2 * sW[lane] + y2 * sW[64 + lane] + z2 * sW[128 + lane];
        float mm = fmaxf(fmaxf(red[0][lane], red[1][lane]), fmaxf(red[2][lane], red[3][lane]));
        mm = fmaxf(mm, fmaxf(c, h[(size_t)d2 * 64 + lane]));   // self-loops + empty
        out[(size_t)d2 * 64 + lane] = mm - c;
    }
}

// ---------------- pools ----------------
__global__ __launch_bounds__(256)
void pool1g_k(const float* __restrict__ f2, const int* __restrict__ offs,
              const int* __restrict__ nidx, float* __restrict__ nf1) {
    int gid = blockIdx.x * 256 + threadIdx.x;
    int cell = gid >> 4, ch = gid & 15;
    if (cell >= C1) return;
    float m = 0.f;                       // f2 >= 0 (post-relu); empty -> 0
    int e0 = offs[cell], e1 = offs[cell + 1];
    for (int t = e0; t < e1; ++t) m = fmaxf(m, f2[(size_t)nidx[t] * 16 + ch]);
    nf1[(size_t)cell * 16 + ch] = m;
}

__global__ __launch_bounds__(256)
void pool2_k(const float* __restrict__ g4, float* __restrict__ nf2) {
    int gid = blockIdx.x * 256 + threadIdx.x;
    int d2 = gid >> 5, ch = gid & 31;
    if (d2 >= C2) return;
    int x2 = d2 >> 8, y2 = (d2 >> 4) & 15, z2 = d2 & 15;
    float m = 0.f;
    for (int tc = 0; tc < 64; ++tc) {
        int i = tc >> 4, j = (tc >> 2) & 3, k = tc & 3;
        int d1 = ((x2 * 4 + i) * 64 + (y2 * 4 + j)) * 64 + (z2 * 4 + k);
        m = fmaxf(m, g4[(size_t)d1 * 32 + ch]);
    }
    nf2[(size_t)d2 * 32 + ch] = m;
}

__global__ __launch_bounds__(256)
void outpool_k(const float* __restrict__ g7, float* __restrict__ xo) {
    int gid = blockIdx.x * 256 + threadIdx.x;
    if (gid >= 64 * 64) return;
    int oc = gid >> 6, ch = gid & 63;
    int cx = oc >> 4, cy = (oc >> 2) & 3, cz = oc & 3;
    float m = 0.f;
    for (int tc = 0; tc < 64; ++tc) {
        int i = tc >> 4, j = (tc >> 2) & 3, k = tc & 3;
        int d2 = ((cx * 4 + i) * 16 + (cy * 4 + j)) * 16 + (cz * 4 + k);
        m = fmaxf(m, g7[(size_t)d2 * 64 + ch]);
    }
    xo[(size_t)oc * 64 + ch] = m;
}

__global__ __launch_bounds__(64)
void linear_k(const float* __restrict__ xo, const float* __restrict__ Wl,
              const float* __restrict__ bl, float* __restrict__ out) {
    int j = blockIdx.x;
    float s = 0.f;
    for (int i = threadIdx.x; i < 4096; i += 64) s += xo[i] * Wl[(size_t)i * 100 + j];
    #pragma unroll
    for (int off = 32; off; off >>= 1) s += __shfl_down(s, off);
    if (threadIdx.x == 0) out[j] = s + bl[j];
}

extern "C" void kernel_launch(void* const* d_in, const int* in_sizes, int n_in,
                              void* d_out, int out_size, void* d_ws, size_t ws_size,
                              hipStream_t stream) {
    (void)in_sizes; (void)n_in; (void)out_size;
    const float* nodes = (const float*)d_in[0];
    const float* feats = (const float*)d_in[1];
    const int*   edges = (const int*)d_in[2];
    const int*   esrc  = edges;
    const int*   edst  = edges + NE;
    const float* W1 = (const float*)d_in[3];
    const float* W2 = (const float*)d_in[4];
    const float* W3 = (const float*)d_in[5];
    const float* W4 = (const float*)d_in[6];
    const float* W5 = (const float*)d_in[7];
    const float* W6 = (const float*)d_in[8];
    const float* W7 = (const float*)d_in[9];
    const float* Wl = (const float*)d_in[10];
    const float* bl = (const float*)d_in[11];
    float* out = (float*)d_out;

    char* ws = (char*)d_ws;
    size_t off = 0;
    auto alloc = [&](size_t bytes) { void* p = ws + off; off = (off + bytes + 255) & ~(size_t)255; return p; };
    int*   cnt   = (int*)alloc((size_t)(C1 + 1) * 4);   // shared counter buf (zeroed once; scatter re-zeroes)
    int*   bsum  = (int*)alloc(260 * 4);
    int*   cid   = (int*)alloc((size_t)NN * 4);
    int*   offs0 = (int*)alloc((size_t)(NN + 1) * 4);
    int*   srcs0 = (int*)alloc((size_t)NE * 4);
    int*   offsN = (int*)alloc((size_t)(C1 + 1) * 4);
    int*   nidx  = (int*)alloc((size_t)NN * 4);
    int*   offs1 = (int*)alloc((size_t)(C1 + 1) * 4);
    int*   srcs1 = (int*)alloc((size_t)NE * 4);
    float* A     = (float*)alloc((size_t)C1 * 32 * 4);  // 32 MB: {h1,f1,h2,f2} then h3/h4
    float* B     = (float*)alloc((size_t)C1 * 32 * 4);  // 32 MB: {nf1} then g3/g4
    float* nf2   = (float*)alloc((size_t)C2 * 32 * 4);
    float* h5    = (float*)alloc((size_t)C2 * 64 * 4);
    float* g5    = (float*)alloc((size_t)C2 * 64 * 4);
    float* h6    = (float*)alloc((size_t)C2 * 64 * 4);
    float* g6    = (float*)alloc((size_t)C2 * 64 * 4);
    float* h7    = (float*)alloc((size_t)C2 * 64 * 4);
    float* g7    = (float*)alloc((size_t)C2 * 64 * 4);
    float* xo    = (float*)alloc((size_t)64 * 64 * 4);
    if (ws_size < off) return;

    float* h1 = A;
    float* f1 = A + (size_t)NN * 8;
    float* h2 = A + (size_t)NN * 16;
    float* f2 = A + (size_t)NN * 32;
    float* h3 = A, *h4 = A;
    float* nf1 = B;
    float* g3 = B, *g4 = B;

    hipMemsetAsync(cnt, 0, (size_t)(C1 + 1) * 4, stream);

    auto gr = [](long long n) { return (int)((n + 255) / 256); };
    const int nbN  = (NN + 1023) / 1024;   // scan blocks for N-sized arrays
    const int nbC1 = (C1 + 1023) / 1024;

    cid_k<<<gr(NN), 256, 0, stream>>>(nodes, cid);

    // CSR0: edges by dst node
    hist_k<0><<<gr(NE), 256, 0, stream>>>(esrc, edst, cid, NE, cnt);
    scan1_k<<<nbN, 256, 0, stream>>>(cnt, NN, offs0, bsum);
    scan2_k<<<1, 64, 0, stream>>>(bsum, nbN);
    scan3_k<<<gr(NN + 1), 256, 0, stream>>>(offs0, NN, bsum, nbN);
    scatter_k<0><<<gr(NE), 256, 0, stream>>>(esrc, edst, cid, NE, offs0, cnt, srcs0);

    // CSRn: nodes by cell
    hist_k<2><<<gr(NN), 256, 0, stream>>>(nullptr, nullptr, cid, NN, cnt);
    scan1_k<<<nbC1, 256, 0, stream>>>(cnt, C1, offsN, bsum);
    scan2_k<<<1, 64, 0, stream>>>(bsum, nbC1);
    scan3_k<<<gr(C1 + 1), 256, 0, stream>>>(offsN, C1, bsum, nbC1);
    scatter_k<2><<<gr(NN), 256, 0, stream>>>(nullptr, nullptr, cid, NN, offsN, cnt, nidx);

    // CSR1: edges by dst cell (srcs stored pre-remapped to cells)
    hist_k<1><<<gr(NE), 256, 0, stream>>>(esrc, edst, cid, NE, cnt);
    scan1_k<<<nbC1, 256, 0, stream>>>(cnt, C1, offs1, bsum);
    scan2_k<<<1, 64, 0, stream>>>(bsum, nbC1);
    scan3_k<<<gr(C1 + 1), 256, 0, stream>>>(offs1, C1, bsum, nbC1);
    scatter_k<1><<<gr(NE), 256, 0, stream>>>(esrc, edst, cid, NE, offs1, cnt, srcs1);

    // level 0
    xform_k<1, 8, 0><<<gr((long long)NN * 8), 256, 0, stream>>>(NN, nodes, feats, W1, h1);
    gatherL0_k<8><<<gr((long long)NN * 8), 256, 0, stream>>>(NN, nodes, h1, W1 + 1 * 8, offs0, srcs0, f1);
    xform_k<8, 16, 0><<<gr((long long)NN * 16), 256, 0, stream>>>(NN, nodes, f1, W2, h2);
    gatherL0_k<16><<<gr((long long)NN * 16), 256, 0, stream>>>(NN, nodes, h2, W2 + 8 * 16, offs0, srcs0, f2);
    pool1g_k<<<gr((long long)C1 * 16), 256, 0, stream>>>(f2, offsN, nidx, nf1);

    // level 1
    xform_k<16, 32, 1><<<gr((long long)C1 * 32), 256, 0, stream>>>(C1, nullptr, nf1, W3, h3);
    gatherL1_k<32><<<gr((long long)C1 * 32), 256, 0, stream>>>(h3, W3 + 16 * 32, offs1, srcs1, g3);
    xform_k<32, 32, 1><<<gr((long long)C1 * 32), 256, 0, stream>>>(C1, nullptr, g3, W4, h4);
    gatherL1_k<32><<<gr((long long)C1 * 32), 256, 0, stream>>>(h4, W4 + 32 * 32, offs1, srcs1, g4);
    pool2_k<<<gr((long long)C2 * 32), 256, 0, stream>>>(g4, nf2);

    // level 2
    xform_k<32, 64, 2><<<gr((long long)C2 * 64), 256, 0, stream>>>(C2, nullptr, nf2, W5, h5);
    gconvL2_k<<<C2, 256, 0, stream>>>(h5, W5 + 32 * 64, offs1, srcs1, g5);
    xform_k<64, 64, 2><<<gr((long long)C2 * 64), 256, 0, stream>>>(C2, nullptr, g5, W6, h6);
    gconvL2_k<<<C2, 256, 0, stream>>>(h6, W6 + 64 * 64, offs1, srcs1, g6);
    xform_k<64, 64, 2><<<gr((long long)C2 * 64), 256, 0, stream>>>(C2, nullptr, g6, W7, h7);
    gconvL2_k<<<C2, 256, 0, stream>>>(h7, W7 + 64 * 64, offs1, srcs1, g7);

    outpool_k<<<16, 256, 0, stream>>>(g7, xo);
    linear_k<<<100, 64, 0, stream>>>(xo, Wl, bl, out);
}

// Round 3
// 1157.494 us; speedup vs baseline: 20.9386x; 1.0493x over previous
//
#include <hip/hip_runtime.h>

#define NN 100000      // nodes
#define NE 1600000     // edges
#define C1 262144      // 64^3 cells
#define C2 4096        // 16^3 cells

// ---------------- cid of each node + node histogram (fused) ----------------
__global__ __launch_bounds__(256)
void cidhist_k(const float* __restrict__ nodes, int* __restrict__ cid,
               int* __restrict__ cntN) {
    int i = blockIdx.x * 256 + threadIdx.x;
    if (i >= NN) return;
    int cx = min(max((int)floorf(nodes[3 * i]     * 0.25f), 0), 63);
    int cy = min(max((int)floorf(nodes[3 * i + 1] * 0.25f), 0), 63);
    int cz = min(max((int)floorf(nodes[3 * i + 2] * 0.25f), 0), 63);
    int c = (cx * 64 + cy) * 64 + cz;
    cid[i] = c;
    atomicAdd(&cntN[c], 1);
}

// ---------------- edge histogram: both keyspaces in one pass ----------------
__global__ __launch_bounds__(256)
void ehist_k(const int* __restrict__ edst, const int* __restrict__ cid,
             int* __restrict__ cnt0, int* __restrict__ cnt1) {
    int e = blockIdx.x * 256 + threadIdx.x;
    if (e >= NE) return;
    int dst = edst[e];
    atomicAdd(&cnt0[dst], 1);
    atomicAdd(&cnt1[cid[dst]], 1);
}

// ---------------- exclusive scan: 1024/block, then 1-block fixup ----------------
__global__ __launch_bounds__(256)
void scan1_k(const int* __restrict__ cnt, int n, int* __restrict__ offs,
             int* __restrict__ bsum) {
    __shared__ int ws[4];
    int t = threadIdx.x, lane = t & 63, w = t >> 6;
    int base = blockIdx.x * 1024 + t * 4;
    int v[4]; int s = 0;
    #pragma unroll
    for (int i = 0; i < 4; ++i) { v[i] = (base + i < n) ? cnt[base + i] : 0; s += v[i]; }
    int sc = s;
    #pragma unroll
    for (int off = 1; off < 64; off <<= 1) {
        int o = __shfl_up(sc, off);
        if (lane >= off) sc += o;
    }
    if (lane == 63) ws[w] = sc;
    __syncthreads();
    int wbase = 0;
    for (int i = 0; i < w; ++i) wbase += ws[i];
    int run = wbase + sc - s;
    #pragma unroll
    for (int i = 0; i < 4; ++i) { if (base + i < n) offs[base + i] = run; run += v[i]; }
    if (t == 255) bsum[blockIdx.x] = wbase + sc;
}

// one block, nb <= 256: exclusive-scan bsum in place, bsum[nb] = total
__global__ __launch_bounds__(256)
void scan2_k(int* __restrict__ bsum, int nb) {
    __shared__ int ws[4];
    int t = threadIdx.x, lane = t & 63, w = t >> 6;
    int v = (t < nb) ? bsum[t] : 0;
    int sc = v;
    #pragma unroll
    for (int off = 1; off < 64; off <<= 1) {
        int o = __shfl_up(sc, off);
        if (lane >= off) sc += o;
    }
    if (lane == 63) ws[w] = sc;
    __syncthreads();
    int wbase = 0;
    for (int i = 0; i < w; ++i) wbase += ws[i];
    if (t < nb) bsum[t] = wbase + sc - v;
    if (t == 255) bsum[nb] = ws[0] + ws[1] + ws[2] + ws[3];
}

__global__ __launch_bounds__(256)
void scan3_k(int* __restrict__ offs, int n, const int* __restrict__ bsum, int nb) {
    int i = blockIdx.x * 256 + threadIdx.x;
    if (i < n) offs[i] += bsum[i >> 10];
    else if (i == n) offs[n] = bsum[nb];
}

// ---------------- fused edge scatter: both CSRs in one pass ----------------
__global__ __launch_bounds__(256)
void escatter_k(const int* __restrict__ esrc, const int* __restrict__ edst,
                const int* __restrict__ cid,
                const int* __restrict__ offs0, int* __restrict__ cnt0, int* __restrict__ srcs0,
                const int* __restrict__ offs1, int* __restrict__ cnt1, int* __restrict__ srcs1) {
    int e = blockIdx.x * 256 + threadIdx.x;
    if (e >= NE) return;
    int src = esrc[e], dst = edst[e];
    int p0 = offs0[dst] + atomicAdd(&cnt0[dst], -1) - 1;   // order-free: max is commutative
    srcs0[p0] = src;
    int cd = cid[dst], cs = cid[src];
    int p1 = offs1[cd] + atomicAdd(&cnt1[cd], -1) - 1;
    srcs1[p1] = cs;
}

__global__ __launch_bounds__(256)
void nscatter_k(const int* __restrict__ cid, const int* __restrict__ offsN,
                int* __restrict__ cntN, int* __restrict__ nidx) {
    int i = blockIdx.x * 256 + threadIdx.x;
    if (i >= NN) return;
    int c = cid[i];
    int pos = offsN[c] + atomicAdd(&cntN[c], -1) - 1;
    nidx[pos] = i;
}

// ---------------- per-node transform: h = f @ W_f + pos @ W_p ----------------
template<int CI, int CO, int LEVEL>
__global__ __launch_bounds__(256)
void xform_k(int n, const float* __restrict__ nodes, const float* __restrict__ f,
             const float* __restrict__ W, float* __restrict__ h) {
    __shared__ float sW[(CI + 3) * CO];
    for (int i = threadIdx.x; i < (CI + 3) * CO; i += 256) sW[i] = W[i];
    __syncthreads();
    int gid = blockIdx.x * 256 + threadIdx.x;
    int i = gid / CO, ch = gid - i * CO;
    if (i >= n) return;
    float px, py, pz;
    if (LEVEL == 0) { px = nodes[3 * i]; py = nodes[3 * i + 1]; pz = nodes[3 * i + 2]; }
    else if (LEVEL == 1) { px = (float)(i >> 12); py = (float)((i >> 6) & 63); pz = (float)(i & 63); }
    else { px = (float)(i >> 8); py = (float)((i >> 4) & 15); pz = (float)(i & 15); }
    float s = px * sW[CI * CO + ch] + py * sW[(CI + 1) * CO + ch] + pz * sW[(CI + 2) * CO + ch];
    for (int k = 0; k < CI; ++k) s += f[(size_t)i * CI + k] * sW[k * CO + ch];
    h[(size_t)i * CO + ch] = s;
}

// ---------------- gather aggregation (atomic-free) ----------------
template<int CO>
__global__ __launch_bounds__(256)
void gatherL0_k(int n, const float* __restrict__ nodes, const float* __restrict__ h,
                const float* __restrict__ Wpos, const int* __restrict__ offs,
                const int* __restrict__ srcs, float* __restrict__ out) {
    __shared__ float sW[3 * CO];
    for (int i = threadIdx.x; i < 3 * CO; i += 256) sW[i] = Wpos[i];
    __syncthreads();
    int gid = blockIdx.x * 256 + threadIdx.x;
    int d = gid / CO, ch = gid - d * CO;
    if (d >= n) return;
    float c = nodes[3 * d] * sW[ch] + nodes[3 * d + 1] * sW[CO + ch] + nodes[3 * d + 2] * sW[2 * CO + ch];
    float m = c;                        // no self-loop at level 0; empty -> 0
    int e0 = offs[d], e1 = offs[d + 1];
    for (int t = e0; t < e1; ++t) m = fmaxf(m, h[(size_t)srcs[t] * CO + ch]);
    out[(size_t)d * CO + ch] = m - c;
}

template<int CO>
__global__ __launch_bounds__(256)
void gatherL1_k(const float* __restrict__ h, const float* __restrict__ Wpos,
                const int* __restrict__ offs, const int* __restrict__ srcs,
                float* __restrict__ out) {
    __shared__ float sW[3 * CO];
    for (int i = threadIdx.x; i < 3 * CO; i += 256) sW[i] = Wpos[i];
    __syncthreads();
    int gid = blockIdx.x * 256 + threadIdx.x;
    int d = gid / CO, ch = gid - d * CO;
    if (d >= C1) return;
    float px = (float)(d >> 12), py = (float)((d >> 6) & 63), pz = (float)(d & 63);
    float c = px * sW[ch] + py * sW[CO + ch] + pz * sW[2 * CO + ch];
    float m = fmaxf(c, h[(size_t)d * CO + ch]);   // self-loop
    int e0 = offs[d], e1 = offs[d + 1];
    for (int t = e0; t < e1; ++t) m = fmaxf(m, h[(size_t)srcs[t] * CO + ch]);
    out[(size_t)d * CO + ch] = m - c;
}

// level-2 step A: per level-1 cell, max over in-edges of h[parent(src)]. wave = one cell.
__global__ __launch_bounds__(256)
void gatherL2a_k(const float* __restrict__ h, const int* __restrict__ offs,
                 const int* __restrict__ srcs, float* __restrict__ m1) {
    int gid = blockIdx.x * 256 + threadIdx.x;   // C1*64 threads exactly
    int d1 = gid >> 6, ch = gid & 63;
    float m = -1e30f;
    int e0 = offs[d1], e1 = offs[d1 + 1];
    for (int t = e0; t < e1; ++t) {
        int s1 = srcs[t];
        int p = ((s1 >> 14) * 16 + (((s1 >> 6) & 63) >> 2)) * 16 + ((s1 & 63) >> 2);
        m = fmaxf(m, h[(size_t)p * 64 + ch]);
    }
    m1[gid] = m;
}

// level-2 step B: reduce 64 analytic children, add self-loop + pos term.
__global__ __launch_bounds__(256)
void gconvL2b_k(const float* __restrict__ m1, const float* __restrict__ h,
                const float* __restrict__ Wpos, float* __restrict__ out) {
    int gid = blockIdx.x * 256 + threadIdx.x;   // C2*64 threads exactly
    int d2 = gid >> 6, ch = gid & 63;
    int x2 = d2 >> 8, y2 = (d2 >> 4) & 15, z2 = d2 & 15;
    float mm = -1e30f;
    #pragma unroll
    for (int i = 0; i < 4; ++i)
        #pragma unroll
        for (int j = 0; j < 4; ++j)
            #pragma unroll
            for (int k = 0; k < 4; ++k) {
                int d1 = ((x2 * 4 + i) * 64 + (y2 * 4 + j)) * 64 + (z2 * 4 + k);
                mm = fmaxf(mm, m1[(size_t)d1 * 64 + ch]);
            }
    float c = x2 * Wpos[ch] + y2 * Wpos[64 + ch] + z2 * Wpos[128 + ch];
    mm = fmaxf(mm, fmaxf(c, h[gid]));            // self-loops (all children's) + empty
    out[gid] = mm - c;
}

// ---------------- pools ----------------
__global__ __launch_bounds__(256)
void pool1g_k(const float* __restrict__ f2, const int* __restrict__ offs,
              const int* __restrict__ nidx, float* __restrict__ nf1) {
    int gid = blockIdx.x * 256 + threadIdx.x;
    int cell = gid >> 4, ch = gid & 15;
    if (cell >= C1) return;
    float m = 0.f;                       // f2 >= 0 (post-relu); empty -> 0
    int e0 = offs[cell], e1 = offs[cell + 1];
    for (int t = e0; t < e1; ++t) m = fmaxf(m, f2[(size_t)nidx[t] * 16 + ch]);
    nf1[(size_t)cell * 16 + ch] = m;
}

__global__ __launch_bounds__(256)
void pool2_k(const float* __restrict__ g4, float* __restrict__ nf2) {
    int gid = blockIdx.x * 256 + threadIdx.x;
    int d2 = gid >> 5, ch = gid & 31;
    if (d2 >= C2) return;
    int x2 = d2 >> 8, y2 = (d2 >> 4) & 15, z2 = d2 & 15;
    float m = 0.f;
    #pragma unroll
    for (int i = 0; i < 4; ++i)
        #pragma unroll
        for (int j = 0; j < 4; ++j)
            #pragma unroll
            for (int k = 0; k < 4; ++k) {
                int d1 = ((x2 * 4 + i) * 64 + (y2 * 4 + j)) * 64 + (z2 * 4 + k);
                m = fmaxf(m, g4[(size_t)d1 * 32 + ch]);
            }
    nf2[(size_t)d2 * 32 + ch] = m;
}

__global__ __launch_bounds__(256)
void outpool_k(const float* __restrict__ g7, float* __restrict__ xo) {
    int gid = blockIdx.x * 256 + threadIdx.x;
    if (gid >= 64 * 64) return;
    int oc = gid >> 6, ch = gid & 63;
    int cx = oc >> 4, cy = (oc >> 2) & 3, cz = oc & 3;
    float m = 0.f;
    for (int tc = 0; tc < 64; ++tc) {
        int i = tc >> 4, j = (tc >> 2) & 3, k = tc & 3;
        int d2 = ((cx * 4 + i) * 16 + (cy * 4 + j)) * 16 + (cz * 4 + k);
        m = fmaxf(m, g7[(size_t)d2 * 64 + ch]);
    }
    xo[(size_t)oc * 64 + ch] = m;
}

__global__ __launch_bounds__(64)
void linear_k(const float* __restrict__ xo, const float* __restrict__ Wl,
              const float* __restrict__ bl, float* __restrict__ out) {
    int j = blockIdx.x;
    float s = 0.f;
    for (int i = threadIdx.x; i < 4096; i += 64) s += xo[i] * Wl[(size_t)i * 100 + j];
    #pragma unroll
    for (int off = 32; off; off >>= 1) s += __shfl_down(s, off);
    if (threadIdx.x == 0) out[j] = s + bl[j];
}

extern "C" void kernel_launch(void* const* d_in, const int* in_sizes, int n_in,
                              void* d_out, int out_size, void* d_ws, size_t ws_size,
                              hipStream_t stream) {
    (void)in_sizes; (void)n_in; (void)out_size;
    const float* nodes = (const float*)d_in[0];
    const float* feats = (const float*)d_in[1];
    const int*   edges = (const int*)d_in[2];
    const int*   esrc  = edges;
    const int*   edst  = edges + NE;
    const float* W1 = (const float*)d_in[3];
    const float* W2 = (const float*)d_in[4];
    const float* W3 = (const float*)d_in[5];
    const float* W4 = (const float*)d_in[6];
    const float* W5 = (const float*)d_in[7];
    const float* W6 = (const float*)d_in[8];
    const float* W7 = (const float*)d_in[9];
    const float* Wl = (const float*)d_in[10];
    const float* bl = (const float*)d_in[11];
    float* out = (float*)d_out;

    char* ws = (char*)d_ws;
    size_t off = 0;
    auto alloc = [&](size_t bytes) { void* p = ws + off; off = (off + bytes + 255) & ~(size_t)255; return p; };
    // counters first (one contiguous memset); scatters restore them to zero each call
    int*   cnt0  = (int*)alloc((size_t)(NN + 1) * 4);
    int*   cnt1  = (int*)alloc((size_t)(C1 + 1) * 4);
    int*   cntN  = (int*)alloc((size_t)(C1 + 1) * 4);
    size_t cnt_bytes = off;
    int*   bsum  = (int*)alloc(260 * 4);
    int*   cid   = (int*)alloc((size_t)NN * 4);
    int*   offs0 = (int*)alloc((size_t)(NN + 1) * 4);
    int*   srcs0 = (int*)alloc((size_t)NE * 4);
    int*   offsN = (int*)alloc((size_t)(C1 + 1) * 4);
    int*   nidx  = (int*)alloc((size_t)NN * 4);
    int*   offs1 = (int*)alloc((size_t)(C1 + 1) * 4);
    int*   srcs1 = (int*)alloc((size_t)NE * 4);
    float* A     = (float*)alloc((size_t)C1 * 32 * 4);  // 32MB; A+B contiguous -> m1 (64MB)
    float* B     = (float*)alloc((size_t)C1 * 32 * 4);  // 32MB
    float* nf2   = (float*)alloc((size_t)C2 * 32 * 4);
    float* h5    = (float*)alloc((size_t)C2 * 64 * 4);
    float* g5    = (float*)alloc((size_t)C2 * 64 * 4);
    float* h6    = (float*)alloc((size_t)C2 * 64 * 4);
    float* g6    = (float*)alloc((size_t)C2 * 64 * 4);
    float* h7    = (float*)alloc((size_t)C2 * 64 * 4);
    float* g7    = (float*)alloc((size_t)C2 * 64 * 4);
    float* xo    = (float*)alloc((size_t)64 * 64 * 4);
    if (ws_size < off) return;

    float* h1 = A;                      // [NN][8]
    float* f1 = A + (size_t)NN * 8;     // [NN][8]
    float* h2 = A + (size_t)NN * 16;    // [NN][16]
    float* f2 = A + (size_t)NN * 32;    // [NN][16]
    float* h3 = A, *h4 = A;             // [C1][32] (level-0 bufs dead by then)
    float* nf1 = B;                     // [C1][16]
    float* g3 = B, *g4 = B;             // [C1][32] (nf1/g3 dead when overwritten)
    float* m1 = A;                      // [C1][64] = 64MB spanning A+B (both dead post-pool2)

    hipMemsetAsync(cnt0, 0, cnt_bytes, stream);

    auto gr = [](long long n) { return (int)((n + 255) / 256); };
    const int nbN  = (NN + 1023) / 1024;   // 98
    const int nbC1 = (C1 + 1023) / 1024;   // 256

    // ---- CSR builds (fused) ----
    cidhist_k<<<gr(NN), 256, 0, stream>>>(nodes, cid, cntN);
    ehist_k<<<gr(NE), 256, 0, stream>>>(edst, cid, cnt0, cnt1);

    scan1_k<<<nbN, 256, 0, stream>>>(cnt0, NN, offs0, bsum);
    scan2_k<<<1, 256, 0, stream>>>(bsum, nbN);
    scan3_k<<<gr(NN + 1), 256, 0, stream>>>(offs0, NN, bsum, nbN);

    scan1_k<<<nbC1, 256, 0, stream>>>(cnt1, C1, offs1, bsum);
    scan2_k<<<1, 256, 0, stream>>>(bsum, nbC1);
    scan3_k<<<gr(C1 + 1), 256, 0, stream>>>(offs1, C1, bsum, nbC1);

    scan1_k<<<nbC1, 256, 0, stream>>>(cntN, C1, offsN, bsum);
    scan2_k<<<1, 256, 0, stream>>>(bsum, nbC1);
    scan3_k<<<gr(C1 + 1), 256, 0, stream>>>(offsN, C1, bsum, nbC1);

    escatter_k<<<gr(NE), 256, 0, stream>>>(esrc, edst, cid, offs0, cnt0, srcs0, offs1, cnt1, srcs1);
    nscatter_k<<<gr(NN), 256, 0, stream>>>(cid, offsN, cntN, nidx);

    // ---- level 0 ----
    xform_k<1, 8, 0><<<gr((long long)NN * 8), 256, 0, stream>>>(NN, nodes, feats, W1, h1);
    gatherL0_k<8><<<gr((long long)NN * 8), 256, 0, stream>>>(NN, nodes, h1, W1 + 1 * 8, offs0, srcs0, f1);
    xform_k<8, 16, 0><<<gr((long long)NN * 16), 256, 0, stream>>>(NN, nodes, f1, W2, h2);
    gatherL0_k<16><<<gr((long long)NN * 16), 256, 0, stream>>>(NN, nodes, h2, W2 + 8 * 16, offs0, srcs0, f2);
    pool1g_k<<<gr((long long)C1 * 16), 256, 0, stream>>>(f2, offsN, nidx, nf1);

    // ---- level 1 ----
    xform_k<16, 32, 1><<<gr((long long)C1 * 32), 256, 0, stream>>>(C1, nullptr, nf1, W3, h3);
    gatherL1_k<32><<<gr((long long)C1 * 32), 256, 0, stream>>>(h3, W3 + 16 * 32, offs1, srcs1, g3);
    xform_k<32, 32, 1><<<gr((long long)C1 * 32), 256, 0, stream>>>(C1, nullptr, g3, W4, h4);
    gatherL1_k<32><<<gr((long long)C1 * 32), 256, 0, stream>>>(h4, W4 + 32 * 32, offs1, srcs1, g4);
    pool2_k<<<gr((long long)C2 * 32), 256, 0, stream>>>(g4, nf2);

    // ---- level 2 (A+B now free -> m1) ----
    xform_k<32, 64, 2><<<gr((long long)C2 * 64), 256, 0, stream>>>(C2, nullptr, nf2, W5, h5);
    gatherL2a_k<<<(C1 * 64) / 256, 256, 0, stream>>>(h5, offs1, srcs1, m1);
    gconvL2b_k<<<(C2 * 64) / 256, 256, 0, stream>>>(m1, h5, W5 + 32 * 64, g5);
    xform_k<64, 64, 2><<<gr((long long)C2 * 64), 256, 0, stream>>>(C2, nullptr, g5, W6, h6);
    gatherL2a_k<<<(C1 * 64) / 256, 256, 0, stream>>>(h6, offs1, srcs1, m1);
    gconvL2b_k<<<(C2 * 64) / 256, 256, 0, stream>>>(m1, h6, W6 + 64 * 64, g6);
    xform_k<64, 64, 2><<<gr((long long)C2 * 64), 256, 0, stream>>>(C2, nullptr, g6, W7, h7);
    gatherL2a_k<<<(C1 * 64) / 256, 256, 0, stream>>>(h7, offs1, srcs1, m1);
    gconvL2b_k<<<(C2 * 64) / 256, 256, 0, stream>>>(m1, h7, W7 + 64 * 64, g7);

    outpool_k<<<16, 256, 0, stream>>>(g7, xo);
    linear_k<<<100, 64, 0, stream>>>(xo, Wl, bl, out);
}

// Round 4
// 1131.704 us; speedup vs baseline: 21.4158x; 1.0228x over previous
//
#include <hip/hip_runtime.h>

#define NN 100000      // nodes
#define NE 1600000     // edges
#define C1 262144      // 64^3 cells
#define C2 4096        // 16^3 cells
#define NJ (NN + C1)   // joint scan length
#define NOCC_MAX NN    // occupied cells <= nodes

// ---------------- cid of each node + node-per-cell histogram ----------------
__global__ __launch_bounds__(256)
void cidhist_k(const float* __restrict__ nodes, int* __restrict__ cid,
               int* __restrict__ cntN) {
    int i = blockIdx.x * 256 + threadIdx.x;
    if (i >= NN) return;
    int cx = min(max((int)floorf(nodes[3 * i]     * 0.25f), 0), 63);
    int cy = min(max((int)floorf(nodes[3 * i + 1] * 0.25f), 0), 63);
    int cz = min(max((int)floorf(nodes[3 * i + 2] * 0.25f), 0), 63);
    int c = (cx * 64 + cy) * 64 + cz;
    cid[i] = c;
    atomicAdd(&cntN[c], 1);
}

// ---------------- edge histogram by dst node ----------------
__global__ __launch_bounds__(256)
void ehist_k(const int* __restrict__ edst, int* __restrict__ cnt0) {
    int e = blockIdx.x * 256 + threadIdx.x;
    if (e >= NE) return;
    atomicAdd(&cnt0[edst[e]], 1);
}

// ---------------- joint exclusive scan: 2048/block ----------------
__global__ __launch_bounds__(256)
void scan1_k(const int* __restrict__ cnt, int n, int* __restrict__ offs,
             int* __restrict__ bsum) {
    __shared__ int ws[4];
    int t = threadIdx.x, lane = t & 63, w = t >> 6;
    long long base = (long long)blockIdx.x * 2048 + t * 8;
    int v[8]; int s = 0;
    #pragma unroll
    for (int i = 0; i < 8; ++i) { v[i] = (base + i < n) ? cnt[base + i] : 0; s += v[i]; }
    int sc = s;
    #pragma unroll
    for (int off = 1; off < 64; off <<= 1) {
        int o = __shfl_up(sc, off);
        if (lane >= off) sc += o;
    }
    if (lane == 63) ws[w] = sc;
    __syncthreads();
    int wbase = 0;
    for (int i = 0; i < w; ++i) wbase += ws[i];
    int run = wbase + sc - s;
    #pragma unroll
    for (int i = 0; i < 8; ++i) { if (base + i < n) offs[base + i] = run; run += v[i]; }
    if (t == 255) bsum[blockIdx.x] = wbase + sc;
}

__global__ __launch_bounds__(256)
void scan2_k(int* __restrict__ bsum, int nb) {   // one block, nb <= 256
    __shared__ int ws[4];
    int t = threadIdx.x, lane = t & 63, w = t >> 6;
    int v = (t < nb) ? bsum[t] : 0;
    int sc = v;
    #pragma unroll
    for (int off = 1; off < 64; off <<= 1) {
        int o = __shfl_up(sc, off);
        if (lane >= off) sc += o;
    }
    if (lane == 63) ws[w] = sc;
    __syncthreads();
    int wbase = 0;
    for (int i = 0; i < w; ++i) wbase += ws[i];
    if (t < nb) bsum[t] = wbase + sc - v;
    if (t == 255) bsum[nb] = ws[0] + ws[1] + ws[2] + ws[3];
}

__global__ __launch_bounds__(256)
void scan3_k(int* __restrict__ offs, int n, const int* __restrict__ bsum, int nb) {
    int i = blockIdx.x * 256 + threadIdx.x;
    if (i < n) offs[i] += bsum[i >> 11];
    else if (i == n) offs[n] = bsum[nb];
}

// ---------------- scatters ----------------
__global__ __launch_bounds__(256)
void escatter_k(const int* __restrict__ esrc, const int* __restrict__ edst,
                const int* __restrict__ offs0, int* __restrict__ cnt0,
                int* __restrict__ srcs0) {
    int e = blockIdx.x * 256 + threadIdx.x;
    if (e >= NE) return;
    int src = esrc[e], dst = edst[e];
    int p0 = offs0[dst] + atomicAdd(&cnt0[dst], -1) - 1;   // order-free: max is commutative
    srcs0[p0] = src;
}

__global__ __launch_bounds__(256)
void nscatter_k(const int* __restrict__ cid, const int* __restrict__ offsN,
                int* __restrict__ cntN, int* __restrict__ nidx) {
    int i = blockIdx.x * 256 + threadIdx.x;
    if (i >= NN) return;
    int c = cid[i];
    int pos = offsN[c] - NE + atomicAdd(&cntN[c], -1) - 1;  // offsN biased by NE (joint scan)
    nidx[pos] = i;
}

// ---------------- occupied-cell list (wave-aggregated append) ----------------
__global__ __launch_bounds__(256)
void oclist_k(const int* __restrict__ offsN, int* __restrict__ oclist,
              int* __restrict__ ocount) {
    int c = blockIdx.x * 256 + threadIdx.x;     // grid covers C1 exactly
    bool occ = offsN[c + 1] > offsN[c];
    unsigned long long b = __ballot(occ);
    int lane = threadIdx.x & 63;
    int cnt = __popcll(b);
    if (cnt == 0) return;
    int base = 0;
    if (lane == 0) base = atomicAdd(ocount, cnt);
    base = __shfl(base, 0);
    if (occ) {
        int pre = __popcll(b & ((1ull << lane) - 1));
        oclist[base + pre] = c;
    }
}

// ---------------- level 0: h = f @ W_f + pos @ W_p ----------------
template<int CI, int CO>
__global__ __launch_bounds__(256)
void xform0_k(const float* __restrict__ nodes, const float* __restrict__ f,
              const float* __restrict__ W, float* __restrict__ h) {
    __shared__ float sW[(CI + 3) * CO];
    for (int i = threadIdx.x; i < (CI + 3) * CO; i += 256) sW[i] = W[i];
    __syncthreads();
    int gid = blockIdx.x * 256 + threadIdx.x;
    int i = gid / CO, ch = gid - i * CO;
    if (i >= NN) return;
    float s = nodes[3 * i] * sW[CI * CO + ch] + nodes[3 * i + 1] * sW[(CI + 1) * CO + ch]
            + nodes[3 * i + 2] * sW[(CI + 2) * CO + ch];
    #pragma unroll
    for (int k = 0; k < CI; ++k) s += f[(size_t)i * CI + k] * sW[k * CO + ch];
    h[(size_t)i * CO + ch] = s;
}

template<int CO>
__global__ __launch_bounds__(256)
void gatherL0_k(const float* __restrict__ nodes, const float* __restrict__ h,
                const float* __restrict__ Wpos, const int* __restrict__ offs,
                const int* __restrict__ srcs, float* __restrict__ out) {
    __shared__ float sW[3 * CO];
    for (int i = threadIdx.x; i < 3 * CO; i += 256) sW[i] = Wpos[i];
    __syncthreads();
    int gid = blockIdx.x * 256 + threadIdx.x;
    int d = gid / CO, ch = gid - d * CO;
    if (d >= NN) return;
    float c = nodes[3 * d] * sW[ch] + nodes[3 * d + 1] * sW[CO + ch] + nodes[3 * d + 2] * sW[2 * CO + ch];
    float m = c;                        // no self-loop at level 0; empty -> 0
    int e0 = offs[d], e1 = offs[d + 1];
    for (int t = e0; t < e1; ++t) m = fmaxf(m, h[(size_t)srcs[t] * CO + ch]);
    out[(size_t)d * CO + ch] = m - c;
}

// ---------------- level 1 (occupied cells only) ----------------
__global__ __launch_bounds__(256)
void pool1c_k(const float* __restrict__ f2, const int* __restrict__ offsN,
              const int* __restrict__ nidx, const int* __restrict__ oclist,
              const int* __restrict__ ocount, float* __restrict__ nf1c) {
    int gid = blockIdx.x * 256 + threadIdx.x;
    int j = gid >> 4, ch = gid & 15;
    if (j >= *ocount) return;
    int d = oclist[j];
    float m = 0.f;                       // f2 >= 0 (post-relu)
    int e0 = offsN[d] - NE, e1 = offsN[d + 1] - NE;
    for (int t = e0; t < e1; ++t) m = fmaxf(m, f2[(size_t)nidx[t] * 16 + ch]);
    nf1c[(size_t)j * 16 + ch] = m;
}

// h[cell] = f @ W_f + pos @ W_p over occupied cells. INC: input compact [j][CI], else dense [cell][CI].
template<int CI, bool INC>
__global__ __launch_bounds__(256)
void xformL1_k(const float* __restrict__ fin, const float* __restrict__ W,
               const int* __restrict__ oclist, const int* __restrict__ ocount,
               float* __restrict__ h) {
    __shared__ float sW[(CI + 3) * 32];
    for (int i = threadIdx.x; i < (CI + 3) * 32; i += 256) sW[i] = W[i];
    __syncthreads();
    int gid = blockIdx.x * 256 + threadIdx.x;
    int j = gid >> 5, ch = gid & 31;
    if (j >= *ocount) return;
    int d = oclist[j];
    const float* f = INC ? fin + (size_t)j * CI : fin + (size_t)d * CI;
    float px = (float)(d >> 12), py = (float)((d >> 6) & 63), pz = (float)(d & 63);
    float s = px * sW[CI * 32 + ch] + py * sW[(CI + 1) * 32 + ch] + pz * sW[(CI + 2) * 32 + ch];
    #pragma unroll
    for (int k = 0; k < CI; ++k) s += f[k] * sW[k * 32 + ch];
    h[(size_t)d * 32 + ch] = s;
}

// gather over occupied dst cells: nodes-in-cell -> their in-edges -> cid[src]
__global__ __launch_bounds__(256)
void gatherL1_k(const float* __restrict__ h, const float* __restrict__ Wpos,
                const int* __restrict__ offsN, const int* __restrict__ nidx,
                const int* __restrict__ offs0, const int* __restrict__ srcs0,
                const int* __restrict__ cid,
                const int* __restrict__ oclist, const int* __restrict__ ocount,
                float* __restrict__ g) {
    __shared__ float sW[3 * 32];
    for (int i = threadIdx.x; i < 96; i += 256) sW[i] = Wpos[i];
    __syncthreads();
    int gid = blockIdx.x * 256 + threadIdx.x;
    int j = gid >> 5, ch = gid & 31;
    if (j >= *ocount) return;
    int d = oclist[j];
    float px = (float)(d >> 12), py = (float)((d >> 6) & 63), pz = (float)(d & 63);
    float c = px * sW[ch] + py * sW[32 + ch] + pz * sW[64 + ch];
    float m = fmaxf(c, h[(size_t)d * 32 + ch]);            // self-loop
    int n0 = offsN[d] - NE, n1 = offsN[d + 1] - NE;
    for (int nt = n0; nt < n1; ++nt) {
        int n = nidx[nt];
        int e0 = offs0[n], e1 = offs0[n + 1];
        for (int t = e0; t < e1; ++t) {
            int cs = cid[srcs0[t]];
            m = fmaxf(m, h[(size_t)cs * 32 + ch]);
        }
    }
    g[(size_t)d * 32 + ch] = m - c;
}

// ---------------- level 2 (block per 16^3 cell) ----------------
// fused pool2 (64 children max, 32ch) + xform -> h5 (64ch)
__global__ __launch_bounds__(256)
void pool2x_k(const float* __restrict__ g4, const float* __restrict__ W5,
              float* __restrict__ h5) {
    __shared__ float part[8][32];
    __shared__ float nf2row[32];
    int d2 = blockIdx.x, tid = threadIdx.x;
    int x2 = d2 >> 8, y2 = (d2 >> 4) & 15, z2 = d2 & 15;
    int ch = tid & 31, grp = tid >> 5;                 // 8 grps x 8 children
    float m = 0.f;
    #pragma unroll
    for (int cc = 0; cc < 8; ++cc) {
        int child = grp * 8 + cc;
        int i = child >> 4, jj = (child >> 2) & 3, k = child & 3;
        int d1 = ((x2 * 4 + i) * 64 + (y2 * 4 + jj)) * 64 + (z2 * 4 + k);
        m = fmaxf(m, g4[(size_t)d1 * 32 + ch]);
    }
    part[grp][ch] = m;
    __syncthreads();
    if (tid < 32) {
        float mm = part[0][tid];
        #pragma unroll
        for (int g = 1; g < 8; ++g) mm = fmaxf(mm, part[g][tid]);
        nf2row[tid] = mm;
    }
    __syncthreads();
    if (tid < 64) {
        float s = x2 * W5[32 * 64 + tid] + y2 * W5[33 * 64 + tid] + z2 * W5[34 * 64 + tid];
        #pragma unroll
        for (int k = 0; k < 32; ++k) s += nf2row[k] * W5[k * 64 + tid];
        h5[(size_t)d2 * 64 + tid] = s;
    }
}

// fused level-2 gconv (+ optional next xform). One block per d2.
template<bool FUSE, bool WRITE_G>
__global__ __launch_bounds__(256)
void gconvL2_k(const float* __restrict__ h, const float* __restrict__ Wpos,
               const int* __restrict__ offsN, const int* __restrict__ nidx,
               const int* __restrict__ offs0, const int* __restrict__ srcs0,
               const int* __restrict__ cid,
               const float* __restrict__ Wn,           // (64+3)x64, if FUSE
               float* __restrict__ gout, float* __restrict__ hnext) {
    __shared__ float red[4][64];
    __shared__ float grow[64];
    int d2 = blockIdx.x, tid = threadIdx.x;
    int x2 = d2 >> 8, y2 = (d2 >> 4) & 15, z2 = d2 & 15;
    int ch = tid & 63, grp = tid >> 6;                 // 4 grps x 16 children
    float m = -1e30f;
    for (int cc = 0; cc < 16; ++cc) {
        int child = grp * 16 + cc;
        int i = child >> 4, jj = (child >> 2) & 3, k = child & 3;
        int d1 = ((x2 * 4 + i) * 64 + (y2 * 4 + jj)) * 64 + (z2 * 4 + k);
        int n0 = offsN[d1] - NE, n1 = offsN[d1 + 1] - NE;
        for (int nt = n0; nt < n1; ++nt) {
            int n = nidx[nt];
            int e0 = offs0[n], e1 = offs0[n + 1];
            for (int t = e0; t < e1; ++t) {
                int cs = cid[srcs0[t]];
                int p = ((cs >> 14) << 8) | (((cs >> 8) & 15) << 4) | ((cs >> 2) & 15);
                m = fmaxf(m, h[(size_t)p * 64 + ch]);
            }
        }
    }
    red[grp][ch] = m;
    __syncthreads();
    if (grp == 0) {
        float mm = fmaxf(fmaxf(red[0][ch], red[1][ch]), fmaxf(red[2][ch], red[3][ch]));
        float c = x2 * Wpos[ch] + y2 * Wpos[64 + ch] + z2 * Wpos[128 + ch];
        mm = fmaxf(mm, fmaxf(c, h[(size_t)d2 * 64 + ch]));   // self-loops (every cell has one)
        float g = mm - c;
        if (WRITE_G) gout[(size_t)d2 * 64 + ch] = g;
        if (FUSE) grow[ch] = g;
    }
    if (FUSE) {
        __syncthreads();
        if (tid < 64) {
            float s = x2 * Wn[64 * 64 + tid] + y2 * Wn[65 * 64 + tid] + z2 * Wn[66 * 64 + tid];
            #pragma unroll
            for (int k = 0; k < 64; ++k) s += grow[k] * Wn[k * 64 + tid];
            hnext[(size_t)d2 * 64 + tid] = s;
        }
    }
}

// ---------------- output pool + linear ----------------
__global__ __launch_bounds__(256)
void outpool_k(const float* __restrict__ g7, float* __restrict__ xo) {
    int gid = blockIdx.x * 256 + threadIdx.x;
    if (gid >= 64 * 64) return;
    int oc = gid >> 6, ch = gid & 63;
    int cx = oc >> 4, cy = (oc >> 2) & 3, cz = oc & 3;
    float m = 0.f;
    for (int tc = 0; tc < 64; ++tc) {
        int i = tc >> 4, j = (tc >> 2) & 3, k = tc & 3;
        int d2 = ((cx * 4 + i) * 16 + (cy * 4 + j)) * 16 + (cz * 4 + k);
        m = fmaxf(m, g7[(size_t)d2 * 64 + ch]);
    }
    xo[(size_t)oc * 64 + ch] = m;
}

__global__ __launch_bounds__(64)
void linear_k(const float* __restrict__ xo, const float* __restrict__ Wl,
              const float* __restrict__ bl, float* __restrict__ out) {
    int j = blockIdx.x;
    float s = 0.f;
    for (int i = threadIdx.x; i < 4096; i += 64) s += xo[i] * Wl[(size_t)i * 100 + j];
    #pragma unroll
    for (int off = 32; off; off >>= 1) s += __shfl_down(s, off);
    if (threadIdx.x == 0) out[j] = s + bl[j];
}

extern "C" void kernel_launch(void* const* d_in, const int* in_sizes, int n_in,
                              void* d_out, int out_size, void* d_ws, size_t ws_size,
                              hipStream_t stream) {
    (void)in_sizes; (void)n_in; (void)out_size;
    const float* nodes = (const float*)d_in[0];
    const float* feats = (const float*)d_in[1];
    const int*   edges = (const int*)d_in[2];
    const int*   esrc  = edges;
    const int*   edst  = edges + NE;
    const float* W1 = (const float*)d_in[3];
    const float* W2 = (const float*)d_in[4];
    const float* W3 = (const float*)d_in[5];
    const float* W4 = (const float*)d_in[6];
    const float* W5 = (const float*)d_in[7];
    const float* W6 = (const float*)d_in[8];
    const float* W7 = (const float*)d_in[9];
    const float* Wl = (const float*)d_in[10];
    const float* bl = (const float*)d_in[11];
    float* out = (float*)d_out;

    char* ws = (char*)d_ws;
    size_t off = 0;
    auto alloc = [&](size_t bytes) { void* p = ws + off; off = (off + bytes + 255) & ~(size_t)255; return p; };
    // zero-region 1: joint counters + ocount
    int*   cntJ   = (int*)alloc((size_t)NJ * 4);        // [cnt0(NN); cntN(C1)]
    int*   ocount = (int*)alloc(4);
    size_t cnt_bytes = off;
    int*   bsum  = (int*)alloc(260 * 4);
    int*   cid   = (int*)alloc((size_t)NN * 4);
    int*   offsJ = (int*)alloc((size_t)(NJ + 1) * 4);   // [offs0(NN); offsN(C1); total]
    int*   srcs0 = (int*)alloc((size_t)NE * 4);
    int*   nidx  = (int*)alloc((size_t)NN * 4);
    int*   oclist= (int*)alloc((size_t)NOCC_MAX * 4);
    float* nf1c  = (float*)alloc((size_t)NOCC_MAX * 16 * 4);
    float* A     = (float*)alloc((size_t)C1 * 32 * 4);  // 32MB: {h1,f1,h2,f2} then h3/h4 (occupied rows)
    float* B     = (float*)alloc((size_t)C1 * 32 * 4);  // 32MB: g3/g4 (zero-region 2)
    float* h5    = (float*)alloc((size_t)C2 * 64 * 4);
    float* h6    = (float*)alloc((size_t)C2 * 64 * 4);
    float* h7    = (float*)alloc((size_t)C2 * 64 * 4);
    float* g7    = (float*)alloc((size_t)C2 * 64 * 4);
    float* xo    = (float*)alloc((size_t)64 * 64 * 4);
    if (ws_size < off) return;

    int* cnt0  = cntJ;
    int* cntN  = cntJ + NN;
    int* offs0 = offsJ;
    int* offsN = offsJ + NN;     // values biased by +NE (joint scan); kernels subtract

    float* h1 = A;                      // [NN][8]
    float* f1 = A + (size_t)NN * 8;
    float* h2 = A + (size_t)NN * 16;    // [NN][16]
    float* f2 = A + (size_t)NN * 32;
    float* h3 = A, *h4 = A;             // [C1][32], occupied rows only
    float* g3 = B, *g4 = B;             // [C1][32], empty rows stay 0 from memset

    hipMemsetAsync(cntJ, 0, cnt_bytes, stream);
    hipMemsetAsync(B, 0, (size_t)C1 * 32 * 4, stream);

    auto gr = [](long long n) { return (int)((n + 255) / 256); };
    const int nbJ = (NJ + 2047) / 2048;   // 177

    // ---- CSR build (CSR0 + node-by-cell only) ----
    cidhist_k<<<gr(NN), 256, 0, stream>>>(nodes, cid, cntN);
    ehist_k<<<gr(NE), 256, 0, stream>>>(edst, cnt0);
    scan1_k<<<nbJ, 256, 0, stream>>>(cntJ, NJ, offsJ, bsum);
    scan2_k<<<1, 256, 0, stream>>>(bsum, nbJ);
    scan3_k<<<gr(NJ + 1), 256, 0, stream>>>(offsJ, NJ, bsum, nbJ);
    escatter_k<<<gr(NE), 256, 0, stream>>>(esrc, edst, offs0, cnt0, srcs0);
    nscatter_k<<<gr(NN), 256, 0, stream>>>(cid, offsN, cntN, nidx);
    oclist_k<<<C1 / 256, 256, 0, stream>>>(offsN, oclist, ocount);

    // ---- level 0 ----
    xform0_k<1, 8><<<gr((long long)NN * 8), 256, 0, stream>>>(nodes, feats, W1, h1);
    gatherL0_k<8><<<gr((long long)NN * 8), 256, 0, stream>>>(nodes, h1, W1 + 1 * 8, offs0, srcs0, f1);
    xform0_k<8, 16><<<gr((long long)NN * 16), 256, 0, stream>>>(nodes, f1, W2, h2);
    gatherL0_k<16><<<gr((long long)NN * 16), 256, 0, stream>>>(nodes, h2, W2 + 8 * 16, offs0, srcs0, f2);

    // ---- level 1 (occupied cells only) ----
    const int gO16 = gr((long long)NOCC_MAX * 16);
    const int gO32 = gr((long long)NOCC_MAX * 32);
    pool1c_k<<<gO16, 256, 0, stream>>>(f2, offsN, nidx, oclist, ocount, nf1c);
    xformL1_k<16, true><<<gO32, 256, 0, stream>>>(nf1c, W3, oclist, ocount, h3);
    gatherL1_k<<<gO32, 256, 0, stream>>>(h3, W3 + 16 * 32, offsN, nidx, offs0, srcs0, cid, oclist, ocount, g3);
    xformL1_k<32, false><<<gO32, 256, 0, stream>>>(g3, W4, oclist, ocount, h4);
    gatherL1_k<<<gO32, 256, 0, stream>>>(h4, W4 + 32 * 32, offsN, nidx, offs0, srcs0, cid, oclist, ocount, g4);

    // ---- level 2 (block per 16^3 cell, fully fused) ----
    pool2x_k<<<C2, 256, 0, stream>>>(g4, W5, h5);
    gconvL2_k<true,  false><<<C2, 256, 0, stream>>>(h5, W5 + 32 * 64, offsN, nidx, offs0, srcs0, cid, W6, nullptr, h6);
    gconvL2_k<true,  false><<<C2, 256, 0, stream>>>(h6, W6 + 64 * 64, offsN, nidx, offs0, srcs0, cid, W7, nullptr, h7);
    gconvL2_k<false, true ><<<C2, 256, 0, stream>>>(h7, W7 + 64 * 64, offsN, nidx, offs0, srcs0, cid, nullptr, g7, nullptr);

    outpool_k<<<16, 256, 0, stream>>>(g7, xo);
    linear_k<<<100, 64, 0, stream>>>(xo, Wl, bl, out);
}

// Round 5
// 834.914 us; speedup vs baseline: 29.0285x; 1.3555x over previous
//
#include <hip/hip_runtime.h>

#define NN 100000      // nodes
#define NE 1600000     // edges
#define C1 262144      // 64^3 cells
#define C2 4096        // 16^3 cells
#define NJ (NN + C1)   // joint scan length
#define NOCC_MAX NN    // occupied cells <= nodes

__device__ __forceinline__ int parent2(int c) {   // 64^3 cell id -> 16^3 cell id
    return ((c >> 14) << 8) | (((c >> 8) & 15) << 4) | ((c >> 2) & 15);
}

// ---------------- cid of each node + node-per-cell histogram ----------------
__global__ __launch_bounds__(256)
void cidhist_k(const float* __restrict__ nodes, int* __restrict__ cid,
               int* __restrict__ cntN) {
    int i = blockIdx.x * 256 + threadIdx.x;
    if (i >= NN) return;
    int cx = min(max((int)floorf(nodes[3 * i]     * 0.25f), 0), 63);
    int cy = min(max((int)floorf(nodes[3 * i + 1] * 0.25f), 0), 63);
    int cz = min(max((int)floorf(nodes[3 * i + 2] * 0.25f), 0), 63);
    int c = (cx * 64 + cy) * 64 + cz;
    cid[i] = c;
    atomicAdd(&cntN[c], 1);
}

// ---------------- edge histogram by dst node ----------------
__global__ __launch_bounds__(256)
void ehist_k(const int* __restrict__ edst, int* __restrict__ cnt0) {
    int e = blockIdx.x * 256 + threadIdx.x;
    if (e >= NE) return;
    atomicAdd(&cnt0[edst[e]], 1);
}

// ---------------- level-2 connectivity bitmask: mask[d2] has bit s2 set ----------------
__global__ __launch_bounds__(256)
void bmask_k(const int* __restrict__ esrc, const int* __restrict__ edst,
             const int* __restrict__ cid, unsigned long long* __restrict__ mask) {
    int e = blockIdx.x * 256 + threadIdx.x;
    if (e >= NE) return;
    int s2 = parent2(cid[esrc[e]]);
    int d2 = parent2(cid[edst[e]]);
    atomicOr(&mask[(size_t)d2 * 64 + (s2 >> 6)], 1ull << (s2 & 63));
}

// ---------------- joint exclusive scan: 2048/block ----------------
__global__ __launch_bounds__(256)
void scan1_k(const int* __restrict__ cnt, int n, int* __restrict__ offs,
             int* __restrict__ bsum) {
    __shared__ int ws[4];
    int t = threadIdx.x, lane = t & 63, w = t >> 6;
    long long base = (long long)blockIdx.x * 2048 + t * 8;
    int v[8]; int s = 0;
    #pragma unroll
    for (int i = 0; i < 8; ++i) { v[i] = (base + i < n) ? cnt[base + i] : 0; s += v[i]; }
    int sc = s;
    #pragma unroll
    for (int off = 1; off < 64; off <<= 1) {
        int o = __shfl_up(sc, off);
        if (lane >= off) sc += o;
    }
    if (lane == 63) ws[w] = sc;
    __syncthreads();
    int wbase = 0;
    for (int i = 0; i < w; ++i) wbase += ws[i];
    int run = wbase + sc - s;
    #pragma unroll
    for (int i = 0; i < 8; ++i) { if (base + i < n) offs[base + i] = run; run += v[i]; }
    if (t == 255) bsum[blockIdx.x] = wbase + sc;
}

__global__ __launch_bounds__(256)
void scan2_k(int* __restrict__ bsum, int nb) {   // one block, nb <= 256
    __shared__ int ws[4];
    int t = threadIdx.x, lane = t & 63, w = t >> 6;
    int v = (t < nb) ? bsum[t] : 0;
    int sc = v;
    #pragma unroll
    for (int off = 1; off < 64; off <<= 1) {
        int o = __shfl_up(sc, off);
        if (lane >= off) sc += o;
    }
    if (lane == 63) ws[w] = sc;
    __syncthreads();
    int wbase = 0;
    for (int i = 0; i < w; ++i) wbase += ws[i];
    if (t < nb) bsum[t] = wbase + sc - v;
    if (t == 255) bsum[nb] = ws[0] + ws[1] + ws[2] + ws[3];
}

__global__ __launch_bounds__(256)
void scan3_k(int* __restrict__ offs, int n, const int* __restrict__ bsum, int nb) {
    int i = blockIdx.x * 256 + threadIdx.x;
    if (i < n) offs[i] += bsum[i >> 11];
    else if (i == n) offs[n] = bsum[nb];
}

// ---------------- scatters ----------------
__global__ __launch_bounds__(256)
void escatter_k(const int* __restrict__ esrc, const int* __restrict__ edst,
                const int* __restrict__ offs0, int* __restrict__ cnt0,
                int* __restrict__ srcs0) {
    int e = blockIdx.x * 256 + threadIdx.x;
    if (e >= NE) return;
    int src = esrc[e], dst = edst[e];
    int p0 = offs0[dst] + atomicAdd(&cnt0[dst], -1) - 1;   // order-free: max is commutative
    srcs0[p0] = src;
}

// csrc0[t] = cid[srcs0[t]] (coalesced; removes one hop from gatherL1's chain)
__global__ __launch_bounds__(256)
void csrc_k(const int* __restrict__ srcs0, const int* __restrict__ cid,
            int* __restrict__ csrc0) {
    int t = blockIdx.x * 256 + threadIdx.x;
    if (t >= NE) return;
    csrc0[t] = cid[srcs0[t]];
}

__global__ __launch_bounds__(256)
void nscatter_k(const int* __restrict__ cid, const int* __restrict__ offsN,
                int* __restrict__ cntN, int* __restrict__ nidx) {
    int i = blockIdx.x * 256 + threadIdx.x;
    if (i >= NN) return;
    int c = cid[i];
    int pos = offsN[c] - NE + atomicAdd(&cntN[c], -1) - 1;  // offsN biased by NE (joint scan)
    nidx[pos] = i;
}

// ---------------- occupied-cell list (wave-aggregated append) ----------------
__global__ __launch_bounds__(256)
void oclist_k(const int* __restrict__ offsN, int* __restrict__ oclist,
              int* __restrict__ ocount) {
    int c = blockIdx.x * 256 + threadIdx.x;     // grid covers C1 exactly
    bool occ = offsN[c + 1] > offsN[c];
    unsigned long long b = __ballot(occ);
    int lane = threadIdx.x & 63;
    int cnt = __popcll(b);
    if (cnt == 0) return;
    int base = 0;
    if (lane == 0) base = atomicAdd(ocount, cnt);
    base = __shfl(base, 0);
    if (occ) {
        int pre = __popcll(b & ((1ull << lane) - 1));
        oclist[base + pre] = c;
    }
}

// ---------------- level 0: h = f @ W_f + pos @ W_p ----------------
template<int CI, int CO>
__global__ __launch_bounds__(256)
void xform0_k(const float* __restrict__ nodes, const float* __restrict__ f,
              const float* __restrict__ W, float* __restrict__ h) {
    __shared__ float sW[(CI + 3) * CO];
    for (int i = threadIdx.x; i < (CI + 3) * CO; i += 256) sW[i] = W[i];
    __syncthreads();
    int gid = blockIdx.x * 256 + threadIdx.x;
    int i = gid / CO, ch = gid - i * CO;
    if (i >= NN) return;
    float s = nodes[3 * i] * sW[CI * CO + ch] + nodes[3 * i + 1] * sW[(CI + 1) * CO + ch]
            + nodes[3 * i + 2] * sW[(CI + 2) * CO + ch];
    #pragma unroll
    for (int k = 0; k < CI; ++k) s += f[(size_t)i * CI + k] * sW[k * CO + ch];
    h[(size_t)i * CO + ch] = s;
}

template<int CO>
__global__ __launch_bounds__(256)
void gatherL0_k(const float* __restrict__ nodes, const float* __restrict__ h,
                const float* __restrict__ Wpos, const int* __restrict__ offs,
                const int* __restrict__ srcs, float* __restrict__ out) {
    __shared__ float sW[3 * CO];
    for (int i = threadIdx.x; i < 3 * CO; i += 256) sW[i] = Wpos[i];
    __syncthreads();
    int gid = blockIdx.x * 256 + threadIdx.x;
    int d = gid / CO, ch = gid - d * CO;
    if (d >= NN) return;
    float c = nodes[3 * d] * sW[ch] + nodes[3 * d + 1] * sW[CO + ch] + nodes[3 * d + 2] * sW[2 * CO + ch];
    float m = c;                        // no self-loop at level 0; empty -> 0
    int e0 = offs[d], e1 = offs[d + 1];
    for (int t = e0; t < e1; ++t) m = fmaxf(m, h[(size_t)srcs[t] * CO + ch]);
    out[(size_t)d * CO + ch] = m - c;
}

// ---------------- level 1 (occupied cells only) ----------------
__global__ __launch_bounds__(256)
void pool1c_k(const float* __restrict__ f2, const int* __restrict__ offsN,
              const int* __restrict__ nidx, const int* __restrict__ oclist,
              const int* __restrict__ ocount, float* __restrict__ nf1c) {
    int gid = blockIdx.x * 256 + threadIdx.x;
    int j = gid >> 4, ch = gid & 15;
    if (j >= *ocount) return;
    int d = oclist[j];
    float m = 0.f;                       // f2 >= 0 (post-relu)
    int e0 = offsN[d] - NE, e1 = offsN[d + 1] - NE;
    for (int t = e0; t < e1; ++t) m = fmaxf(m, f2[(size_t)nidx[t] * 16 + ch]);
    nf1c[(size_t)j * 16 + ch] = m;
}

// h[cell] = f @ W_f + pos @ W_p over occupied cells. INC: input compact [j][CI], else dense [cell][CI].
template<int CI, bool INC>
__global__ __launch_bounds__(256)
void xformL1_k(const float* __restrict__ fin, const float* __restrict__ W,
               const int* __restrict__ oclist, const int* __restrict__ ocount,
               float* __restrict__ h) {
    __shared__ float sW[(CI + 3) * 32];
    for (int i = threadIdx.x; i < (CI + 3) * 32; i += 256) sW[i] = W[i];
    __syncthreads();
    int gid = blockIdx.x * 256 + threadIdx.x;
    int j = gid >> 5, ch = gid & 31;
    if (j >= *ocount) return;
    int d = oclist[j];
    const float* f = INC ? fin + (size_t)j * CI : fin + (size_t)d * CI;
    float px = (float)(d >> 12), py = (float)((d >> 6) & 63), pz = (float)(d & 63);
    float s = px * sW[CI * 32 + ch] + py * sW[(CI + 1) * 32 + ch] + pz * sW[(CI + 2) * 32 + ch];
    #pragma unroll
    for (int k = 0; k < CI; ++k) s += f[k] * sW[k * 32 + ch];
    h[(size_t)d * 32 + ch] = s;
}

// gather over occupied dst cells: nodes-in-cell -> their in-edges -> csrc0 (src cell)
__global__ __launch_bounds__(256)
void gatherL1_k(const float* __restrict__ h, const float* __restrict__ Wpos,
                const int* __restrict__ offsN, const int* __restrict__ nidx,
                const int* __restrict__ offs0, const int* __restrict__ csrc0,
                const int* __restrict__ oclist, const int* __restrict__ ocount,
                float* __restrict__ g) {
    __shared__ float sW[3 * 32];
    for (int i = threadIdx.x; i < 96; i += 256) sW[i] = Wpos[i];
    __syncthreads();
    int gid = blockIdx.x * 256 + threadIdx.x;
    int j = gid >> 5, ch = gid & 31;
    if (j >= *ocount) return;
    int d = oclist[j];
    float px = (float)(d >> 12), py = (float)((d >> 6) & 63), pz = (float)(d & 63);
    float c = px * sW[ch] + py * sW[32 + ch] + pz * sW[64 + ch];
    float m = fmaxf(c, h[(size_t)d * 32 + ch]);            // self-loop
    int n0 = offsN[d] - NE, n1 = offsN[d + 1] - NE;
    for (int nt = n0; nt < n1; ++nt) {
        int n = nidx[nt];
        int e0 = offs0[n], e1 = offs0[n + 1];
        for (int t = e0; t < e1; ++t)
            m = fmaxf(m, h[(size_t)csrc0[t] * 32 + ch]);
    }
    g[(size_t)d * 32 + ch] = m - c;
}

// ---------------- level 2 (block per 16^3 cell) ----------------
// fused pool2 (64 children max, 32ch) + xform -> h5 (64ch)
__global__ __launch_bounds__(256)
void pool2x_k(const float* __restrict__ g4, const float* __restrict__ W5,
              float* __restrict__ h5) {
    __shared__ float part[8][32];
    __shared__ float nf2row[32];
    int d2 = blockIdx.x, tid = threadIdx.x;
    int x2 = d2 >> 8, y2 = (d2 >> 4) & 15, z2 = d2 & 15;
    int ch = tid & 31, grp = tid >> 5;                 // 8 grps x 8 children
    float m = 0.f;
    #pragma unroll
    for (int cc = 0; cc < 8; ++cc) {
        int child = grp * 8 + cc;
        int i = child >> 4, jj = (child >> 2) & 3, k = child & 3;
        int d1 = ((x2 * 4 + i) * 64 + (y2 * 4 + jj)) * 64 + (z2 * 4 + k);
        m = fmaxf(m, g4[(size_t)d1 * 32 + ch]);
    }
    part[grp][ch] = m;
    __syncthreads();
    if (tid < 32) {
        float mm = part[0][tid];
        #pragma unroll
        for (int g = 1; g < 8; ++g) mm = fmaxf(mm, part[g][tid]);
        nf2row[tid] = mm;
    }
    __syncthreads();
    if (tid < 64) {
        float s = x2 * W5[32 * 64 + tid] + y2 * W5[33 * 64 + tid] + z2 * W5[34 * 64 + tid];
        #pragma unroll
        for (int k = 0; k < 32; ++k) s += nf2row[k] * W5[k * 64 + tid];
        h5[(size_t)d2 * 64 + tid] = s;
    }
}

// level-2 gconv via bitmask scan (+ optional fused next xform). One block per d2.
template<bool FUSE, bool WRITE_G>
__global__ __launch_bounds__(256)
void gconvL2_k(const float* __restrict__ h, const float* __restrict__ Wpos,
               const unsigned long long* __restrict__ mask,
               const float* __restrict__ Wn,           // (64+3)x64, if FUSE
               float* __restrict__ gout, float* __restrict__ hnext) {
    __shared__ float red[4][64];
    __shared__ float grow[64];
    int d2 = blockIdx.x, tid = threadIdx.x;
    int x2 = d2 >> 8, y2 = (d2 >> 4) & 15, z2 = d2 & 15;
    int ch = tid & 63, grp = tid >> 6;                 // 4 waves x 16 mask words
    const unsigned long long* mrow = mask + (size_t)d2 * 64;
    float m = -1e30f;
    #pragma unroll 4
    for (int wi = grp * 16; wi < grp * 16 + 16; ++wi) {
        unsigned long long wb = mrow[wi];
        while (wb) {
            int b = __builtin_ctzll(wb);
            wb &= wb - 1;
            m = fmaxf(m, h[((size_t)(wi * 64 + b)) * 64 + ch]);
        }
    }
    red[grp][ch] = m;
    __syncthreads();
    if (grp == 0) {
        float mm = fmaxf(fmaxf(red[0][ch], red[1][ch]), fmaxf(red[2][ch], red[3][ch]));
        float c = x2 * Wpos[ch] + y2 * Wpos[64 + ch] + z2 * Wpos[128 + ch];
        mm = fmaxf(mm, fmaxf(c, h[(size_t)d2 * 64 + ch]));   // self-loop (every cell) + empty
        float g = mm - c;
        if (WRITE_G) gout[(size_t)d2 * 64 + ch] = g;
        if (FUSE) grow[ch] = g;
    }
    if (FUSE) {
        __syncthreads();
        if (tid < 64) {
            float s = x2 * Wn[64 * 64 + tid] + y2 * Wn[65 * 64 + tid] + z2 * Wn[66 * 64 + tid];
            #pragma unroll
            for (int k = 0; k < 64; ++k) s += grow[k] * Wn[k * 64 + tid];
            hnext[(size_t)d2 * 64 + tid] = s;
        }
    }
}

// ---------------- output pool + linear ----------------
__global__ __launch_bounds__(256)
void outpool_k(const float* __restrict__ g7, float* __restrict__ xo) {
    int gid = blockIdx.x * 256 + threadIdx.x;
    if (gid >= 64 * 64) return;
    int oc = gid >> 6, ch = gid & 63;
    int cx = oc >> 4, cy = (oc >> 2) & 3, cz = oc & 3;
    float m = 0.f;
    for (int tc = 0; tc < 64; ++tc) {
        int i = tc >> 4, j = (tc >> 2) & 3, k = tc & 3;
        int d2 = ((cx * 4 + i) * 16 + (cy * 4 + j)) * 16 + (cz * 4 + k);
        m = fmaxf(m, g7[(size_t)d2 * 64 + ch]);
    }
    xo[(size_t)oc * 64 + ch] = m;
}

__global__ __launch_bounds__(64)
void linear_k(const float* __restrict__ xo, const float* __restrict__ Wl,
              const float* __restrict__ bl, float* __restrict__ out) {
    int j = blockIdx.x;
    float s = 0.f;
    for (int i = threadIdx.x; i < 4096; i += 64) s += xo[i] * Wl[(size_t)i * 100 + j];
    #pragma unroll
    for (int off = 32; off; off >>= 1) s += __shfl_down(s, off);
    if (threadIdx.x == 0) out[j] = s + bl[j];
}

extern "C" void kernel_launch(void* const* d_in, const int* in_sizes, int n_in,
                              void* d_out, int out_size, void* d_ws, size_t ws_size,
                              hipStream_t stream) {
    (void)in_sizes; (void)n_in; (void)out_size;
    const float* nodes = (const float*)d_in[0];
    const float* feats = (const float*)d_in[1];
    const int*   edges = (const int*)d_in[2];
    const int*   esrc  = edges;
    const int*   edst  = edges + NE;
    const float* W1 = (const float*)d_in[3];
    const float* W2 = (const float*)d_in[4];
    const float* W3 = (const float*)d_in[5];
    const float* W4 = (const float*)d_in[6];
    const float* W5 = (const float*)d_in[7];
    const float* W6 = (const float*)d_in[8];
    const float* W7 = (const float*)d_in[9];
    const float* Wl = (const float*)d_in[10];
    const float* bl = (const float*)d_in[11];
    float* out = (float*)d_out;

    char* ws = (char*)d_ws;
    size_t off = 0;
    auto alloc = [&](size_t bytes) { void* p = ws + off; off = (off + bytes + 255) & ~(size_t)255; return p; };
    // zero-region 1: joint counters + ocount
    int*   cntJ   = (int*)alloc((size_t)NJ * 4);        // [cnt0(NN); cntN(C1)]
    int*   ocount = (int*)alloc(4);
    size_t cnt_bytes = off;
    int*   bsum  = (int*)alloc(260 * 4);
    int*   cid   = (int*)alloc((size_t)NN * 4);
    int*   offsJ = (int*)alloc((size_t)(NJ + 1) * 4);   // [offs0(NN); offsN(C1); total]
    int*   srcs0 = (int*)alloc((size_t)NE * 4);
    int*   csrc0 = (int*)alloc((size_t)NE * 4);
    int*   nidx  = (int*)alloc((size_t)NN * 4);
    int*   oclist= (int*)alloc((size_t)NOCC_MAX * 4);
    float* nf1c  = (float*)alloc((size_t)NOCC_MAX * 16 * 4);
    float* A     = (float*)alloc((size_t)C1 * 32 * 4);  // 32MB: {h1,f1,h2,f2} then h3/h4 (occupied rows)
    // zero-region 2 (contiguous): B (g3/g4) + mask
    float* B     = (float*)alloc((size_t)C1 * 32 * 4);  // 32MB
    unsigned long long* mask = (unsigned long long*)alloc((size_t)C2 * 64 * 8);  // 2MB
    size_t zero2_bytes = (size_t)C1 * 32 * 4 + (size_t)C2 * 64 * 8;
    float* h5    = (float*)alloc((size_t)C2 * 64 * 4);
    float* h6    = (float*)alloc((size_t)C2 * 64 * 4);
    float* h7    = (float*)alloc((size_t)C2 * 64 * 4);
    float* g7    = (float*)alloc((size_t)C2 * 64 * 4);
    float* xo    = (float*)alloc((size_t)64 * 64 * 4);
    if (ws_size < off) return;

    int* cnt0  = cntJ;
    int* cntN  = cntJ + NN;
    int* offs0 = offsJ;
    int* offsN = offsJ + NN;     // values biased by +NE (joint scan); kernels subtract

    float* h1 = A;                      // [NN][8]
    float* f1 = A + (size_t)NN * 8;
    float* h2 = A + (size_t)NN * 16;    // [NN][16]
    float* f2 = A + (size_t)NN * 32;
    float* h3 = A, *h4 = A;             // [C1][32], occupied rows only (srcs are always occupied)
    float* g3 = B, *g4 = B;             // [C1][32], empty rows stay 0 from memset (pool2x reads dense)

    hipMemsetAsync(cntJ, 0, cnt_bytes, stream);
    hipMemsetAsync(B, 0, zero2_bytes, stream);

    auto gr = [](long long n) { return (int)((n + 255) / 256); };
    const int nbJ = (NJ + 2047) / 2048;   // 177

    // ---- CSR build (CSR0 + node-by-cell) + L2 bitmask ----
    cidhist_k<<<gr(NN), 256, 0, stream>>>(nodes, cid, cntN);
    ehist_k<<<gr(NE), 256, 0, stream>>>(edst, cnt0);
    bmask_k<<<gr(NE), 256, 0, stream>>>(esrc, edst, cid, mask);
    scan1_k<<<nbJ, 256, 0, stream>>>(cntJ, NJ, offsJ, bsum);
    scan2_k<<<1, 256, 0, stream>>>(bsum, nbJ);
    scan3_k<<<gr(NJ + 1), 256, 0, stream>>>(offsJ, NJ, bsum, nbJ);
    escatter_k<<<gr(NE), 256, 0, stream>>>(esrc, edst, offs0, cnt0, srcs0);
    csrc_k<<<gr(NE), 256, 0, stream>>>(srcs0, cid, csrc0);
    nscatter_k<<<gr(NN), 256, 0, stream>>>(cid, offsN, cntN, nidx);
    oclist_k<<<C1 / 256, 256, 0, stream>>>(offsN, oclist, ocount);

    // ---- level 0 ----
    xform0_k<1, 8><<<gr((long long)NN * 8), 256, 0, stream>>>(nodes, feats, W1, h1);
    gatherL0_k<8><<<gr((long long)NN * 8), 256, 0, stream>>>(nodes, h1, W1 + 1 * 8, offs0, srcs0, f1);
    xform0_k<8, 16><<<gr((long long)NN * 16), 256, 0, stream>>>(nodes, f1, W2, h2);
    gatherL0_k<16><<<gr((long long)NN * 16), 256, 0, stream>>>(nodes, h2, W2 + 8 * 16, offs0, srcs0, f2);

    // ---- level 1 (occupied cells only) ----
    const int gO16 = gr((long long)NOCC_MAX * 16);
    const int gO32 = gr((long long)NOCC_MAX * 32);
    pool1c_k<<<gO16, 256, 0, stream>>>(f2, offsN, nidx, oclist, ocount, nf1c);
    xformL1_k<16, true><<<gO32, 256, 0, stream>>>(nf1c, W3, oclist, ocount, h3);
    gatherL1_k<<<gO32, 256, 0, stream>>>(h3, W3 + 16 * 32, offsN, nidx, offs0, csrc0, oclist, ocount, g3);
    xformL1_k<32, false><<<gO32, 256, 0, stream>>>(g3, W4, oclist, ocount, h4);
    gatherL1_k<<<gO32, 256, 0, stream>>>(h4, W4 + 32 * 32, offsN, nidx, offs0, csrc0, oclist, ocount, g4);

    // ---- level 2 (block per 16^3 cell, bitmask-driven, fused) ----
    pool2x_k<<<C2, 256, 0, stream>>>(g4, W5, h5);
    gconvL2_k<true,  false><<<C2, 256, 0, stream>>>(h5, W5 + 32 * 64, mask, W6, nullptr, h6);
    gconvL2_k<true,  false><<<C2, 256, 0, stream>>>(h6, W6 + 64 * 64, mask, W7, nullptr, h7);
    gconvL2_k<false, true ><<<C2, 256, 0, stream>>>(h7, W7 + 64 * 64, mask, nullptr, g7, nullptr);

    outpool_k<<<16, 256, 0, stream>>>(g7, xo);
    linear_k<<<100, 64, 0, stream>>>(xo, Wl, bl, out);
}

// Round 6
// 713.385 us; speedup vs baseline: 33.9737x; 1.1704x over previous
//
#include <hip/hip_runtime.h>

#define NN 100000      // nodes
#define NE 1600000     // edges
#define C1 262144      // 64^3 cells
#define C2 4096        // 16^3 cells
#define NB 391         // dst-node buckets of 256 (ceil(NN/256))
#define PA_EDGES 8192
#define PA_IT (PA_EDGES / 256)

__device__ __forceinline__ int parent2(int c) {   // 64^3 cell id -> 16^3 cell id
    return ((c >> 14) << 8) | (((c >> 8) & 15) << 4) | ((c >> 2) & 15);
}

// ---------------- cid of each node + node-per-cell histogram ----------------
__global__ __launch_bounds__(256)
void cidhist_k(const float* __restrict__ nodes, int* __restrict__ cid,
               int* __restrict__ cntN) {
    int i = blockIdx.x * 256 + threadIdx.x;
    if (i >= NN) return;
    int cx = min(max((int)floorf(nodes[3 * i]     * 0.25f), 0), 63);
    int cy = min(max((int)floorf(nodes[3 * i + 1] * 0.25f), 0), 63);
    int cz = min(max((int)floorf(nodes[3 * i + 2] * 0.25f), 0), 63);
    int c = (cx * 64 + cy) * 64 + cz;
    cid[i] = c;
    atomicAdd(&cntN[c], 1);
}

// ---------------- occupied-cell list + cell->compact-index map ----------------
__global__ __launch_bounds__(256)
void oclist_k(const int* __restrict__ cntN, int* __restrict__ oclist,
              int* __restrict__ jmap, int* __restrict__ ocount) {
    int c = blockIdx.x * 256 + threadIdx.x;     // grid covers C1 exactly
    bool occ = cntN[c] > 0;
    unsigned long long b = __ballot(occ);
    int lane = threadIdx.x & 63;
    int cnt = __popcll(b);
    int base = 0;
    if (cnt) {
        if (lane == 0) base = atomicAdd(ocount, cnt);
        base = __shfl(base, 0);
    }
    int pre = __popcll(b & ((1ull << lane) - 1));
    int j = occ ? base + pre : -1;
    jmap[c] = j;
    if (occ) oclist[j] = c;
}

// ---------------- bucket histogram (LDS pre-aggregated) ----------------
__global__ __launch_bounds__(256)
void bhist_k(const int* __restrict__ edst, int* __restrict__ btot) {
    __shared__ int h[NB];
    int tid = threadIdx.x;
    for (int i = tid; i < NB; i += 256) h[i] = 0;
    __syncthreads();
    int base = blockIdx.x * PA_EDGES;
    for (int i = 0; i < PA_IT; ++i) {
        int e = base + i * 256 + tid;
        if (e < NE) atomicAdd(&h[edst[e] >> 8], 1);
    }
    __syncthreads();
    for (int i = tid; i < NB; i += 256) if (h[i]) atomicAdd(&btot[i], h[i]);
}

// one block: exclusive scan of NB bucket totals -> bbase[NB+1]; copy to cursor
__global__ __launch_bounds__(256)
void scanB_k(const int* __restrict__ btot, int* __restrict__ bbase,
             int* __restrict__ cursor) {
    __shared__ int ws[4];
    int t = threadIdx.x, lane = t & 63, w = t >> 6;
    int i0 = 2 * t, i1 = 2 * t + 1;
    int v0 = (i0 < NB) ? btot[i0] : 0;
    int v1 = (i1 < NB) ? btot[i1] : 0;
    int s = v0 + v1, sc = s;
    #pragma unroll
    for (int off = 1; off < 64; off <<= 1) { int o = __shfl_up(sc, off); if (lane >= off) sc += o; }
    if (lane == 63) ws[w] = sc;
    __syncthreads();
    int wb = 0;
    for (int q = 0; q < w; ++q) wb += ws[q];
    int P = wb + sc - s;
    if (i0 <= NB) { bbase[i0] = P;      if (i0 < NB) cursor[i0] = P; }
    if (i1 <= NB) { bbase[i1] = P + v0; if (i1 < NB) cursor[i1] = P + v0; }
}

// ---------------- cell scan (offsN over C1): 2048/block ----------------
__global__ __launch_bounds__(256)
void scan1_k(const int* __restrict__ cnt, int n, int* __restrict__ offs,
             int* __restrict__ bsum) {
    __shared__ int ws[4];
    int t = threadIdx.x, lane = t & 63, w = t >> 6;
    int base = blockIdx.x * 2048 + t * 8;
    int v[8]; int s = 0;
    #pragma unroll
    for (int i = 0; i < 8; ++i) { v[i] = (base + i < n) ? cnt[base + i] : 0; s += v[i]; }
    int sc = s;
    #pragma unroll
    for (int off = 1; off < 64; off <<= 1) { int o = __shfl_up(sc, off); if (lane >= off) sc += o; }
    if (lane == 63) ws[w] = sc;
    __syncthreads();
    int wbase = 0;
    for (int i = 0; i < w; ++i) wbase += ws[i];
    int run = wbase + sc - s;
    #pragma unroll
    for (int i = 0; i < 8; ++i) { if (base + i < n) offs[base + i] = run; run += v[i]; }
    if (t == 255) bsum[blockIdx.x] = wbase + sc;
}

__global__ __launch_bounds__(256)
void scan2_k(int* __restrict__ bsum, int nb) {   // one block, nb <= 256
    __shared__ int ws[4];
    int t = threadIdx.x, lane = t & 63, w = t >> 6;
    int v = (t < nb) ? bsum[t] : 0;
    int sc = v;
    #pragma unroll
    for (int off = 1; off < 64; off <<= 1) { int o = __shfl_up(sc, off); if (lane >= off) sc += o; }
    if (lane == 63) ws[w] = sc;
    __syncthreads();
    int wbase = 0;
    for (int i = 0; i < w; ++i) wbase += ws[i];
    if (t < nb) bsum[t] = wbase + sc - v;
    if (t == 255) bsum[nb] = ws[0] + ws[1] + ws[2] + ws[3];
}

__global__ __launch_bounds__(256)
void scan3_k(int* __restrict__ offs, int n, const int* __restrict__ bsum, int nb) {
    int i = blockIdx.x * 256 + threadIdx.x;
    if (i < n) offs[i] += bsum[i >> 11];
    else if (i == n) offs[n] = bsum[nb];
}

// ---------------- pass A: partition edges into bucket-contiguous pair buffer ----------------
__global__ __launch_bounds__(256)
void passA_k(const int* __restrict__ esrc, const int* __restrict__ edst,
             int* __restrict__ cursor, int2* __restrict__ ebuf) {
    __shared__ int hist[NB];
    __shared__ int lofs[NB + 1];
    __shared__ int gbase[NB];
    __shared__ int cnt2[NB];
    __shared__ int2 stage[PA_EDGES];             // 64KB
    __shared__ unsigned short sbid[PA_EDGES];    // 16KB
    __shared__ int ws[4];
    int tid = threadIdx.x, lane = tid & 63, w = tid >> 6;
    for (int i = tid; i < NB; i += 256) { hist[i] = 0; cnt2[i] = 0; }
    __syncthreads();
    int base = blockIdx.x * PA_EDGES;
    for (int i = 0; i < PA_IT; ++i) {
        int e = base + i * 256 + tid;
        if (e < NE) atomicAdd(&hist[edst[e] >> 8], 1);
    }
    __syncthreads();
    // exclusive scan hist -> lofs (2 per thread)
    int i0 = 2 * tid, i1 = 2 * tid + 1;
    int v0 = (i0 < NB) ? hist[i0] : 0;
    int v1 = (i1 < NB) ? hist[i1] : 0;
    int s = v0 + v1, sc = s;
    #pragma unroll
    for (int off = 1; off < 64; off <<= 1) { int o = __shfl_up(sc, off); if (lane >= off) sc += o; }
    if (lane == 63) ws[w] = sc;
    __syncthreads();
    int wb = 0;
    for (int q = 0; q < w; ++q) wb += ws[q];
    int P = wb + sc - s;
    if (i0 <= NB) lofs[i0] = P;
    if (i1 <= NB) lofs[i1] = P + v0;
    __syncthreads();
    // reserve global bucket space
    for (int b = tid; b < NB; b += 256) {
        int c = hist[b];
        gbase[b] = c ? atomicAdd(&cursor[b], c) : 0;
    }
    __syncthreads();
    // place into LDS stage (bucket-sorted within block)
    for (int i = 0; i < PA_IT; ++i) {
        int e = base + i * 256 + tid;
        if (e < NE) {
            int d = edst[e], b = d >> 8;
            int p = lofs[b] + atomicAdd(&cnt2[b], 1);
            stage[p] = make_int2(esrc[e], d);
            sbid[p] = (unsigned short)b;
        }
    }
    __syncthreads();
    // write out: consecutive slots of a bucket -> consecutive global addrs
    int nval = min(PA_EDGES, NE - base);
    for (int k = tid; k < nval; k += 256) {
        int b = sbid[k];
        ebuf[gbase[b] + (k - lofs[b])] = stage[k];
    }
}

// ---------------- pass B: per-bucket final scatter; derives offs0; fuses csrc + mask ----------------
__global__ __launch_bounds__(256)
void passB_k(const int2* __restrict__ ebuf, const int* __restrict__ bbase,
             const int* __restrict__ cid, const int* __restrict__ jmap,
             int* __restrict__ offs0, int* __restrict__ srcs0, int* __restrict__ csrc0,
             unsigned long long* __restrict__ mask) {
    __shared__ int cnt[256];
    __shared__ int pos[256];
    __shared__ int cidD[256];
    __shared__ int ws[4];
    int b = blockIdx.x, tid = threadIdx.x, lane = tid & 63, w = tid >> 6;
    int d0 = b << 8;
    int range = min(256, NN - d0);
    cnt[tid] = 0;
    if (tid < range) cidD[tid] = cid[d0 + tid];
    __syncthreads();
    int r0 = bbase[b], r1 = bbase[b + 1];
    for (int k = r0 + tid; k < r1; k += 256) atomicAdd(&cnt[ebuf[k].y & 255], 1);
    __syncthreads();
    int v = cnt[tid], sc = v;
    #pragma unroll
    for (int off = 1; off < 64; off <<= 1) { int o = __shfl_up(sc, off); if (lane >= off) sc += o; }
    if (lane == 63) ws[w] = sc;
    __syncthreads();
    int wb = 0;
    for (int q = 0; q < w; ++q) wb += ws[q];
    int rel = wb + sc - v;                        // exclusive per-node prefix
    if (tid < range) offs0[d0 + tid] = r0 + rel;
    if (tid == 0) offs0[min(d0 + 256, NN)] = r1;  // next bucket base (benign duplicate)
    pos[tid] = r0 + rel;
    __syncthreads();
    for (int k = r0 + tid; k < r1; k += 256) {
        int2 pr = ebuf[k];
        int di = pr.y & 255;
        int p = atomicAdd(&pos[di], 1);
        int cs = cid[pr.x];
        srcs0[p] = pr.x;
        csrc0[p] = jmap[cs];                      // compact j-index of src cell
        int d2 = parent2(cidD[di]);
        int s2 = parent2(cs);
        atomicOr(&mask[(size_t)d2 * 64 + (s2 >> 6)], 1ull << (s2 & 63));
    }
}

// ---------------- node-by-cell scatter ----------------
__global__ __launch_bounds__(256)
void nscatter_k(const int* __restrict__ cid, const int* __restrict__ offsN,
                int* __restrict__ cntN, int* __restrict__ nidx) {
    int i = blockIdx.x * 256 + threadIdx.x;
    if (i >= NN) return;
    int c = cid[i];
    int pos = offsN[c] + atomicAdd(&cntN[c], -1) - 1;
    nidx[pos] = i;
}

// ---------------- level 0: h = f @ W_f + pos @ W_p ----------------
template<int CI, int CO>
__global__ __launch_bounds__(256)
void xform0_k(const float* __restrict__ nodes, const float* __restrict__ f,
              const float* __restrict__ W, float* __restrict__ h) {
    __shared__ float sW[(CI + 3) * CO];
    for (int i = threadIdx.x; i < (CI + 3) * CO; i += 256) sW[i] = W[i];
    __syncthreads();
    int gid = blockIdx.x * 256 + threadIdx.x;
    int i = gid / CO, ch = gid - i * CO;
    if (i >= NN) return;
    float s = nodes[3 * i] * sW[CI * CO + ch] + nodes[3 * i + 1] * sW[(CI + 1) * CO + ch]
            + nodes[3 * i + 2] * sW[(CI + 2) * CO + ch];
    #pragma unroll
    for (int k = 0; k < CI; ++k) s += f[(size_t)i * CI + k] * sW[k * CO + ch];
    h[(size_t)i * CO + ch] = s;
}

template<int CO>
__global__ __launch_bounds__(256)
void gatherL0_k(const float* __restrict__ nodes, const float* __restrict__ h,
                const float* __restrict__ Wpos, const int* __restrict__ offs,
                const int* __restrict__ srcs, float* __restrict__ out) {
    __shared__ float sW[3 * CO];
    for (int i = threadIdx.x; i < 3 * CO; i += 256) sW[i] = Wpos[i];
    __syncthreads();
    int gid = blockIdx.x * 256 + threadIdx.x;
    int d = gid / CO, ch = gid - d * CO;
    if (d >= NN) return;
    float c = nodes[3 * d] * sW[ch] + nodes[3 * d + 1] * sW[CO + ch] + nodes[3 * d + 2] * sW[2 * CO + ch];
    float m = c;                        // no self-loop at level 0; empty -> 0
    int e0 = offs[d], e1 = offs[d + 1];
    for (int t = e0; t < e1; ++t) m = fmaxf(m, h[(size_t)srcs[t] * CO + ch]);
    out[(size_t)d * CO + ch] = m - c;
}

// ---------------- level 1 (compact over occupied cells) ----------------
__global__ __launch_bounds__(256)
void pool1c_k(const float* __restrict__ f2, const int* __restrict__ offsN,
              const int* __restrict__ nidx, const int* __restrict__ oclist,
              const int* __restrict__ ocount, float* __restrict__ nf1c) {
    int gid = blockIdx.x * 256 + threadIdx.x;
    int j = gid >> 4, ch = gid & 15;
    if (j >= *ocount) return;
    int d = oclist[j];
    float m = 0.f;                       // f2 >= 0 (post-relu)
    int e0 = offsN[d], e1 = offsN[d + 1];
    for (int t = e0; t < e1; ++t) m = fmaxf(m, f2[(size_t)nidx[t] * 16 + ch]);
    nf1c[(size_t)j * 16 + ch] = m;
}

template<int CI>
__global__ __launch_bounds__(256)
void xformL1_k(const float* __restrict__ fin, const float* __restrict__ W,
               const int* __restrict__ oclist, const int* __restrict__ ocount,
               float* __restrict__ h) {
    __shared__ float sW[(CI + 3) * 32];
    for (int i = threadIdx.x; i < (CI + 3) * 32; i += 256) sW[i] = W[i];
    __syncthreads();
    int gid = blockIdx.x * 256 + threadIdx.x;
    int j = gid >> 5, ch = gid & 31;
    if (j >= *ocount) return;
    int d = oclist[j];
    const float* f = fin + (size_t)j * CI;
    float px = (float)(d >> 12), py = (float)((d >> 6) & 63), pz = (float)(d & 63);
    float s = px * sW[CI * 32 + ch] + py * sW[(CI + 1) * 32 + ch] + pz * sW[(CI + 2) * 32 + ch];
    #pragma unroll
    for (int k = 0; k < CI; ++k) s += f[k] * sW[k * 32 + ch];
    h[(size_t)j * 32 + ch] = s;
}

// gather over occupied dst cells: nodes-in-cell -> their in-edges -> csrc0 (compact j)
__global__ __launch_bounds__(256)
void gatherL1_k(const float* __restrict__ h, const float* __restrict__ Wpos,
                const int* __restrict__ offsN, const int* __restrict__ nidx,
                const int* __restrict__ offs0, const int* __restrict__ csrc0,
                const int* __restrict__ oclist, const int* __restrict__ ocount,
                float* __restrict__ g) {
    __shared__ float sW[96];
    for (int i = threadIdx.x; i < 96; i += 256) sW[i] = Wpos[i];
    __syncthreads();
    int gid = blockIdx.x * 256 + threadIdx.x;
    int j = gid >> 5, ch = gid & 31;
    if (j >= *ocount) return;
    int d = oclist[j];
    float px = (float)(d >> 12), py = (float)((d >> 6) & 63), pz = (float)(d & 63);
    float c = px * sW[ch] + py * sW[32 + ch] + pz * sW[64 + ch];
    float m = fmaxf(c, h[(size_t)j * 32 + ch]);            // self-loop
    int n0 = offsN[d], n1 = offsN[d + 1];
    for (int nt = n0; nt < n1; ++nt) {
        int n = nidx[nt];
        int e0 = offs0[n], e1 = offs0[n + 1];
        for (int t = e0; t < e1; ++t)
            m = fmaxf(m, h[(size_t)csrc0[t] * 32 + ch]);
    }
    g[(size_t)j * 32 + ch] = m - c;
}

// ---------------- level 2 (block per 16^3 cell) ----------------
// fused pool2 (64 children via jmap, 32ch) + xform W5 -> h5 (64ch)
__global__ __launch_bounds__(256)
void pool2x_k(const float* __restrict__ Gc, const int* __restrict__ jmap,
              const float* __restrict__ W5, float* __restrict__ h5) {
    __shared__ float part[8][32];
    __shared__ float nf2row[32];
    int d2 = blockIdx.x, tid = threadIdx.x;
    int x2 = d2 >> 8, y2 = (d2 >> 4) & 15, z2 = d2 & 15;
    int ch = tid & 31, grp = tid >> 5;                 // 8 grps x 8 children
    float m = 0.f;
    #pragma unroll
    for (int cc = 0; cc < 8; ++cc) {
        int child = grp * 8 + cc;
        int i = child >> 4, jj = (child >> 2) & 3, k = child & 3;
        int d1 = ((x2 * 4 + i) * 64 + (y2 * 4 + jj)) * 64 + (z2 * 4 + k);
        int cj = jmap[d1];
        if (cj >= 0) m = fmaxf(m, Gc[(size_t)cj * 32 + ch]);
    }
    part[grp][ch] = m;
    __syncthreads();
    if (tid < 32) {
        float mm = part[0][tid];
        #pragma unroll
        for (int g = 1; g < 8; ++g) mm = fmaxf(mm, part[g][tid]);
        nf2row[tid] = mm;
    }
    __syncthreads();
    if (tid < 64) {
        float s = x2 * W5[32 * 64 + tid] + y2 * W5[33 * 64 + tid] + z2 * W5[34 * 64 + tid];
        #pragma unroll
        for (int k = 0; k < 32; ++k) s += nf2row[k] * W5[k * 64 + tid];
        h5[(size_t)d2 * 64 + tid] = s;
    }
}

// level-2 gconv via bitmask scan (+ optional fused next xform). One block per d2.
template<bool FUSE, bool WRITE_G>
__global__ __launch_bounds__(256)
void gconvL2_k(const float* __restrict__ h, const float* __restrict__ Wpos,
               const unsigned long long* __restrict__ mask,
               const float* __restrict__ Wn,           // (64+3)x64, if FUSE
               float* __restrict__ gout, float* __restrict__ hnext) {
    __shared__ float red[4][64];
    __shared__ float grow[64];
    int d2 = blockIdx.x, tid = threadIdx.x;
    int x2 = d2 >> 8, y2 = (d2 >> 4) & 15, z2 = d2 & 15;
    int ch = tid & 63, grp = tid >> 6;                 // 4 waves x 16 mask words
    const unsigned long long* mrow = mask + (size_t)d2 * 64;
    float m = -1e30f;
    #pragma unroll 4
    for (int wi = grp * 16; wi < grp * 16 + 16; ++wi) {
        unsigned long long wb = mrow[wi];
        while (wb) {
            int b = __builtin_ctzll(wb);
            wb &= wb - 1;
            m = fmaxf(m, h[((size_t)(wi * 64 + b)) * 64 + ch]);
        }
    }
    red[grp][ch] = m;
    __syncthreads();
    if (grp == 0) {
        float mm = fmaxf(fmaxf(red[0][ch], red[1][ch]), fmaxf(red[2][ch], red[3][ch]));
        float c = x2 * Wpos[ch] + y2 * Wpos[64 + ch] + z2 * Wpos[128 + ch];
        mm = fmaxf(mm, fmaxf(c, h[(size_t)d2 * 64 + ch]));   // self-loop + empty
        float g = mm - c;
        if (WRITE_G) gout[(size_t)d2 * 64 + ch] = g;
        if (FUSE) grow[ch] = g;
    }
    if (FUSE) {
        __syncthreads();
        if (tid < 64) {
            float s = x2 * Wn[64 * 64 + tid] + y2 * Wn[65 * 64 + tid] + z2 * Wn[66 * 64 + tid];
            #pragma unroll
            for (int k = 0; k < 64; ++k) s += grow[k] * Wn[k * 64 + tid];
            hnext[(size_t)d2 * 64 + tid] = s;
        }
    }
}

// ---------------- output pool + linear ----------------
__global__ __launch_bounds__(256)
void outpool_k(const float* __restrict__ g7, float* __restrict__ xo) {
    int gid = blockIdx.x * 256 + threadIdx.x;
    if (gid >= 64 * 64) return;
    int oc = gid >> 6, ch = gid & 63;
    int cx = oc >> 4, cy = (oc >> 2) & 3, cz = oc & 3;
    float m = 0.f;
    for (int tc = 0; tc < 64; ++tc) {
        int i = tc >> 4, j = (tc >> 2) & 3, k = tc & 3;
        int d2 = ((cx * 4 + i) * 16 + (cy * 4 + j)) * 16 + (cz * 4 + k);
        m = fmaxf(m, g7[(size_t)d2 * 64 + ch]);
    }
    xo[(size_t)oc * 64 + ch] = m;
}

__global__ __launch_bounds__(64)
void linear_k(const float* __restrict__ xo, const float* __restrict__ Wl,
              const float* __restrict__ bl, float* __restrict__ out) {
    int j = blockIdx.x;
    float s = 0.f;
    for (int i = threadIdx.x; i < 4096; i += 64) s += xo[i] * Wl[(size_t)i * 100 + j];
    #pragma unroll
    for (int off = 32; off; off >>= 1) s += __shfl_down(s, off);
    if (threadIdx.x == 0) out[j] = s + bl[j];
}

extern "C" void kernel_launch(void* const* d_in, const int* in_sizes, int n_in,
                              void* d_out, int out_size, void* d_ws, size_t ws_size,
                              hipStream_t stream) {
    (void)in_sizes; (void)n_in; (void)out_size;
    const float* nodes = (const float*)d_in[0];
    const float* feats = (const float*)d_in[1];
    const int*   edges = (const int*)d_in[2];
    const int*   esrc  = edges;
    const int*   edst  = edges + NE;
    const float* W1 = (const float*)d_in[3];
    const float* W2 = (const float*)d_in[4];
    const float* W3 = (const float*)d_in[5];
    const float* W4 = (const float*)d_in[6];
    const float* W5 = (const float*)d_in[7];
    const float* W6 = (const float*)d_in[8];
    const float* W7 = (const float*)d_in[9];
    const float* Wl = (const float*)d_in[10];
    const float* bl = (const float*)d_in[11];
    float* out = (float*)d_out;

    char* ws = (char*)d_ws;
    size_t off = 0;
    auto alloc = [&](size_t bytes) { void* p = ws + off; off = (off + bytes + 255) & ~(size_t)255; return p; };
    // zero region: cntN + ocount + btot + mask (one memset)
    int*   cntN   = (int*)alloc((size_t)C1 * 4);
    int*   ocount = (int*)alloc(4);
    int*   btot   = (int*)alloc((size_t)NB * 4);
    unsigned long long* mask = (unsigned long long*)alloc((size_t)C2 * 64 * 8);  // 2MB
    size_t zero_bytes = off;
    int*   bsum   = (int*)alloc(260 * 4);
    int*   bbase  = (int*)alloc((size_t)(NB + 1) * 4);
    int*   cursor = (int*)alloc((size_t)NB * 4);
    int*   cid    = (int*)alloc((size_t)NN * 4);
    int*   offsN  = (int*)alloc((size_t)(C1 + 1) * 4);
    int*   offs0  = (int*)alloc((size_t)(NN + 1) * 4);
    int*   srcs0  = (int*)alloc((size_t)NE * 4);
    int*   csrc0  = (int*)alloc((size_t)NE * 4);
    int2*  ebuf   = (int2*)alloc((size_t)NE * 8);
    int*   nidx   = (int*)alloc((size_t)NN * 4);
    int*   oclist = (int*)alloc((size_t)NN * 4);
    int*   jmap   = (int*)alloc((size_t)C1 * 4);
    float* nf1c   = (float*)alloc((size_t)NN * 16 * 4);
    float* A      = (float*)alloc((size_t)NN * 48 * 4);   // h1,f1,h2,f2
    float* Hc     = (float*)alloc((size_t)NN * 32 * 4);
    float* Gc     = (float*)alloc((size_t)NN * 32 * 4);
    float* h5     = (float*)alloc((size_t)C2 * 64 * 4);
    float* h6     = (float*)alloc((size_t)C2 * 64 * 4);
    float* h7     = (float*)alloc((size_t)C2 * 64 * 4);
    float* g7     = (float*)alloc((size_t)C2 * 64 * 4);
    float* xo     = (float*)alloc((size_t)64 * 64 * 4);
    if (ws_size < off) return;

    float* h1 = A;                      // [NN][8]
    float* f1 = A + (size_t)NN * 8;
    float* h2 = A + (size_t)NN * 16;    // [NN][16]
    float* f2 = A + (size_t)NN * 32;

    hipMemsetAsync(cntN, 0, zero_bytes, stream);

    auto gr = [](long long n) { return (int)((n + 255) / 256); };
    const int nbC1 = (C1 + 2047) / 2048;   // 128
    const int gPA  = (NE + PA_EDGES - 1) / PA_EDGES;  // 196

    // ---- connectivity build ----
    cidhist_k<<<gr(NN), 256, 0, stream>>>(nodes, cid, cntN);
    oclist_k<<<C1 / 256, 256, 0, stream>>>(cntN, oclist, jmap, ocount);
    bhist_k<<<gPA, 256, 0, stream>>>(edst, btot);
    scanB_k<<<1, 256, 0, stream>>>(btot, bbase, cursor);
    scan1_k<<<nbC1, 256, 0, stream>>>(cntN, C1, offsN, bsum);
    scan2_k<<<1, 256, 0, stream>>>(bsum, nbC1);
    scan3_k<<<gr(C1 + 1), 256, 0, stream>>>(offsN, C1, bsum, nbC1);
    passA_k<<<gPA, 256, 0, stream>>>(esrc, edst, cursor, ebuf);
    passB_k<<<NB, 256, 0, stream>>>(ebuf, bbase, cid, jmap, offs0, srcs0, csrc0, mask);
    nscatter_k<<<gr(NN), 256, 0, stream>>>(cid, offsN, cntN, nidx);

    // ---- level 0 ----
    xform0_k<1, 8><<<gr((long long)NN * 8), 256, 0, stream>>>(nodes, feats, W1, h1);
    gatherL0_k<8><<<gr((long long)NN * 8), 256, 0, stream>>>(nodes, h1, W1 + 1 * 8, offs0, srcs0, f1);
    xform0_k<8, 16><<<gr((long long)NN * 16), 256, 0, stream>>>(nodes, f1, W2, h2);
    gatherL0_k<16><<<gr((long long)NN * 16), 256, 0, stream>>>(nodes, h2, W2 + 8 * 16, offs0, srcs0, f2);

    // ---- level 1 (compact occupied cells) ----
    pool1c_k<<<gr((long long)NN * 16), 256, 0, stream>>>(f2, offsN, nidx, oclist, ocount, nf1c);
    xformL1_k<16><<<gr((long long)NN * 32), 256, 0, stream>>>(nf1c, W3, oclist, ocount, Hc);
    gatherL1_k<<<gr((long long)NN * 32), 256, 0, stream>>>(Hc, W3 + 16 * 32, offsN, nidx, offs0, csrc0, oclist, ocount, Gc);
    xformL1_k<32><<<gr((long long)NN * 32), 256, 0, stream>>>(Gc, W4, oclist, ocount, Hc);
    gatherL1_k<<<gr((long long)NN * 32), 256, 0, stream>>>(Hc, W4 + 32 * 32, offsN, nidx, offs0, csrc0, oclist, ocount, Gc);

    // ---- level 2 (block per 16^3 cell, bitmask-driven, fused) ----
    pool2x_k<<<C2, 256, 0, stream>>>(Gc, jmap, W5, h5);
    gconvL2_k<true,  false><<<C2, 256, 0, stream>>>(h5, W5 + 32 * 64, mask, W6, nullptr, h6);
    gconvL2_k<true,  false><<<C2, 256, 0, stream>>>(h6, W6 + 64 * 64, mask, W7, nullptr, h7);
    gconvL2_k<false, true ><<<C2, 256, 0, stream>>>(h7, W7 + 64 * 64, mask, nullptr, g7, nullptr);

    outpool_k<<<16, 256, 0, stream>>>(g7, xo);
    linear_k<<<100, 64, 0, stream>>>(xo, Wl, bl, out);
}

// Round 7
// 635.339 us; speedup vs baseline: 38.1471x; 1.1228x over previous
//
#include <hip/hip_runtime.h>

#define NN 100000      // nodes
#define NE 1600000     // edges
#define C1 262144      // 64^3 cells
#define C2 4096        // 16^3 cells
#define NB 391         // new-id dst buckets of 256 (ceil(NN/256))
#define PA_EDGES 8192
#define PA_IT (PA_EDGES / 256)

__device__ __forceinline__ int parent2(int c) {   // 64^3 cell id -> 16^3 cell id
    return ((c >> 14) << 8) | (((c >> 8) & 15) << 4) | ((c >> 2) & 15);
}

// ---------------- cid of each node + node-per-cell histogram ----------------
__global__ __launch_bounds__(256)
void cidhist_k(const float* __restrict__ nodes, int* __restrict__ cid,
               int* __restrict__ cntN) {
    int i = blockIdx.x * 256 + threadIdx.x;
    if (i >= NN) return;
    int cx = min(max((int)floorf(nodes[3 * i]     * 0.25f), 0), 63);
    int cy = min(max((int)floorf(nodes[3 * i + 1] * 0.25f), 0), 63);
    int cz = min(max((int)floorf(nodes[3 * i + 2] * 0.25f), 0), 63);
    int c = (cx * 64 + cy) * 64 + cz;
    cid[i] = c;
    atomicAdd(&cntN[c], 1);
}

// ---------------- occupied-cell list + cell->compact-index map ----------------
__global__ __launch_bounds__(256)
void oclist_k(const int* __restrict__ cntN, int* __restrict__ oclist,
              int* __restrict__ jmap, int* __restrict__ ocount) {
    int c = blockIdx.x * 256 + threadIdx.x;     // grid covers C1 exactly
    bool occ = cntN[c] > 0;
    unsigned long long b = __ballot(occ);
    int lane = threadIdx.x & 63;
    int cnt = __popcll(b);
    int base = 0;
    if (cnt) {
        if (lane == 0) base = atomicAdd(ocount, cnt);
        base = __shfl(base, 0);
    }
    int pre = __popcll(b & ((1ull << lane) - 1));
    int j = occ ? base + pre : -1;
    jmap[c] = j;
    if (occ) oclist[j] = c;
}

// ---------------- cell scan (offsN over C1): 2048/block ----------------
__global__ __launch_bounds__(256)
void scan1_k(const int* __restrict__ cnt, int n, int* __restrict__ offs,
             int* __restrict__ bsum) {
    __shared__ int ws[4];
    int t = threadIdx.x, lane = t & 63, w = t >> 6;
    int base = blockIdx.x * 2048 + t * 8;
    int v[8]; int s = 0;
    #pragma unroll
    for (int i = 0; i < 8; ++i) { v[i] = (base + i < n) ? cnt[base + i] : 0; s += v[i]; }
    int sc = s;
    #pragma unroll
    for (int off = 1; off < 64; off <<= 1) { int o = __shfl_up(sc, off); if (lane >= off) sc += o; }
    if (lane == 63) ws[w] = sc;
    __syncthreads();
    int wbase = 0;
    for (int i = 0; i < w; ++i) wbase += ws[i];
    int run = wbase + sc - s;
    #pragma unroll
    for (int i = 0; i < 8; ++i) { if (base + i < n) offs[base + i] = run; run += v[i]; }
    if (t == 255) bsum[blockIdx.x] = wbase + sc;
}

__global__ __launch_bounds__(256)
void scan2_k(int* __restrict__ bsum, int nb) {   // one block, nb <= 256
    __shared__ int ws[4];
    int t = threadIdx.x, lane = t & 63, w = t >> 6;
    int v = (t < nb) ? bsum[t] : 0;
    int sc = v;
    #pragma unroll
    for (int off = 1; off < 64; off <<= 1) { int o = __shfl_up(sc, off); if (lane >= off) sc += o; }
    if (lane == 63) ws[w] = sc;
    __syncthreads();
    int wbase = 0;
    for (int i = 0; i < w; ++i) wbase += ws[i];
    if (t < nb) bsum[t] = wbase + sc - v;
    if (t == 255) bsum[nb] = ws[0] + ws[1] + ws[2] + ws[3];
}

__global__ __launch_bounds__(256)
void scan3_k(int* __restrict__ offs, int n, const int* __restrict__ bsum, int nb) {
    int i = blockIdx.x * 256 + threadIdx.x;
    if (i < n) offs[i] += bsum[i >> 11];
    else if (i == n) offs[n] = bsum[nb];
}

// ---------------- node scatter: rank (new id) + nidx (old id by new id) ----------------
__global__ __launch_bounds__(256)
void nscatter_k(const int* __restrict__ cid, const int* __restrict__ offsN,
                int* __restrict__ cntN, int* __restrict__ rank, int* __restrict__ nidx) {
    int i = blockIdx.x * 256 + threadIdx.x;
    if (i >= NN) return;
    int c = cid[i];
    int pos = offsN[c] + atomicAdd(&cntN[c], -1) - 1;
    rank[i] = pos;
    nidx[pos] = i;
}

// ---------------- permute node data into new-id order ----------------
__global__ __launch_bounds__(256)
void permute_k(const int* __restrict__ nidx, const float* __restrict__ nodes,
               const float* __restrict__ feats, const int* __restrict__ cid,
               const int* __restrict__ jmap,
               float* __restrict__ pnodes, float* __restrict__ pfeat,
               int* __restrict__ cidP, int* __restrict__ jsrcP) {
    int d = blockIdx.x * 256 + threadIdx.x;
    if (d >= NN) return;
    int i = nidx[d];
    pnodes[3 * d]     = nodes[3 * i];
    pnodes[3 * d + 1] = nodes[3 * i + 1];
    pnodes[3 * d + 2] = nodes[3 * i + 2];
    pfeat[d] = feats[i];
    int c = cid[i];
    cidP[d] = c;
    jsrcP[d] = jmap[c];
}

// ---------------- bucket histogram over rank[dst] (LDS pre-aggregated) ----------------
__global__ __launch_bounds__(256)
void bhist_k(const int* __restrict__ edst, const int* __restrict__ rank,
             int* __restrict__ btot) {
    __shared__ int h[NB];
    int tid = threadIdx.x;
    for (int i = tid; i < NB; i += 256) h[i] = 0;
    __syncthreads();
    int base = blockIdx.x * PA_EDGES;
    for (int i = 0; i < PA_IT; ++i) {
        int e = base + i * 256 + tid;
        if (e < NE) atomicAdd(&h[rank[edst[e]] >> 8], 1);
    }
    __syncthreads();
    for (int i = tid; i < NB; i += 256) if (h[i]) atomicAdd(&btot[i], h[i]);
}

// one block: exclusive scan of NB bucket totals -> bbase[NB+1]; copy to cursor
__global__ __launch_bounds__(256)
void scanB_k(const int* __restrict__ btot, int* __restrict__ bbase,
             int* __restrict__ cursor) {
    __shared__ int ws[4];
    int t = threadIdx.x, lane = t & 63, w = t >> 6;
    int i0 = 2 * t, i1 = 2 * t + 1;
    int v0 = (i0 < NB) ? btot[i0] : 0;
    int v1 = (i1 < NB) ? btot[i1] : 0;
    int s = v0 + v1, sc = s;
    #pragma unroll
    for (int off = 1; off < 64; off <<= 1) { int o = __shfl_up(sc, off); if (lane >= off) sc += o; }
    if (lane == 63) ws[w] = sc;
    __syncthreads();
    int wb = 0;
    for (int q = 0; q < w; ++q) wb += ws[q];
    int P = wb + sc - s;
    if (i0 <= NB) { bbase[i0] = P;      if (i0 < NB) cursor[i0] = P; }
    if (i1 <= NB) { bbase[i1] = P + v0; if (i1 < NB) cursor[i1] = P + v0; }
}

// ---------------- pass A: partition (rank_src, rank_dst) pairs by dst bucket ----------------
__global__ __launch_bounds__(256)
void passA_k(const int* __restrict__ esrc, const int* __restrict__ edst,
             const int* __restrict__ rank, int* __restrict__ cursor,
             int2* __restrict__ ebuf) {
    __shared__ int hist[NB];
    __shared__ int lofs[NB + 1];
    __shared__ int gbase[NB];
    __shared__ int cnt2[NB];
    __shared__ int2 stage[PA_EDGES];             // 64KB
    __shared__ unsigned short sbid[PA_EDGES];    // 16KB
    __shared__ int ws[4];
    int tid = threadIdx.x, lane = tid & 63, w = tid >> 6;
    for (int i = tid; i < NB; i += 256) { hist[i] = 0; cnt2[i] = 0; }
    __syncthreads();
    int base = blockIdx.x * PA_EDGES;
    for (int i = 0; i < PA_IT; ++i) {
        int e = base + i * 256 + tid;
        if (e < NE) atomicAdd(&hist[rank[edst[e]] >> 8], 1);
    }
    __syncthreads();
    int i0 = 2 * tid, i1 = 2 * tid + 1;
    int v0 = (i0 < NB) ? hist[i0] : 0;
    int v1 = (i1 < NB) ? hist[i1] : 0;
    int s = v0 + v1, sc = s;
    #pragma unroll
    for (int off = 1; off < 64; off <<= 1) { int o = __shfl_up(sc, off); if (lane >= off) sc += o; }
    if (lane == 63) ws[w] = sc;
    __syncthreads();
    int wb = 0;
    for (int q = 0; q < w; ++q) wb += ws[q];
    int P = wb + sc - s;
    if (i0 <= NB) lofs[i0] = P;
    if (i1 <= NB) lofs[i1] = P + v0;
    __syncthreads();
    for (int b = tid; b < NB; b += 256) {
        int c = hist[b];
        gbase[b] = c ? atomicAdd(&cursor[b], c) : 0;
    }
    __syncthreads();
    for (int i = 0; i < PA_IT; ++i) {
        int e = base + i * 256 + tid;
        if (e < NE) {
            int rd = rank[edst[e]], rs = rank[esrc[e]];
            int b = rd >> 8;
            int p = lofs[b] + atomicAdd(&cnt2[b], 1);
            stage[p] = make_int2(rs, rd);
            sbid[p] = (unsigned short)b;
        }
    }
    __syncthreads();
    int nval = min(PA_EDGES, NE - base);
    for (int k = tid; k < nval; k += 256) {
        int b = sbid[k];
        ebuf[gbase[b] + (k - lofs[b])] = stage[k];
    }
}

// ---------------- pass B: per-bucket final scatter; offs0 (new-id CSR); csrc + mask fused ----------------
__global__ __launch_bounds__(256)
void passB_k(const int2* __restrict__ ebuf, const int* __restrict__ bbase,
             const int* __restrict__ cidP, const int* __restrict__ jsrcP,
             int* __restrict__ offs0, int* __restrict__ srcs0, int* __restrict__ csrc0,
             unsigned long long* __restrict__ mask) {
    __shared__ int cnt[256];
    __shared__ int pos[256];
    __shared__ int d2D[256];
    __shared__ int ws[4];
    int b = blockIdx.x, tid = threadIdx.x, lane = tid & 63, w = tid >> 6;
    int d0 = b << 8;
    int range = min(256, NN - d0);
    cnt[tid] = 0;
    if (tid < range) d2D[tid] = parent2(cidP[d0 + tid]);
    __syncthreads();
    int r0 = bbase[b], r1 = bbase[b + 1];
    for (int k = r0 + tid; k < r1; k += 256) atomicAdd(&cnt[ebuf[k].y & 255], 1);
    __syncthreads();
    int v = cnt[tid], sc = v;
    #pragma unroll
    for (int off = 1; off < 64; off <<= 1) { int o = __shfl_up(sc, off); if (lane >= off) sc += o; }
    if (lane == 63) ws[w] = sc;
    __syncthreads();
    int wb = 0;
    for (int q = 0; q < w; ++q) wb += ws[q];
    int rel = wb + sc - v;                        // exclusive per-dst prefix
    if (tid < range) offs0[d0 + tid] = r0 + rel;
    if (tid == 0) offs0[min(d0 + 256, NN)] = r1;  // benign duplicate of next base
    pos[tid] = r0 + rel;
    __syncthreads();
    for (int k = r0 + tid; k < r1; k += 256) {
        int2 pr = ebuf[k];
        int di = pr.y & 255;
        int p = atomicAdd(&pos[di], 1);
        int rs = pr.x;
        srcs0[p] = rs;
        csrc0[p] = jsrcP[rs];
        int s2 = parent2(cidP[rs]);
        atomicOr(&mask[(size_t)d2D[di] * 64 + (s2 >> 6)], 1ull << (s2 & 63));
    }
}

// ---------------- level 0: h = f @ W_f + pos @ W_p (new-id space) ----------------
template<int CI, int CO>
__global__ __launch_bounds__(256)
void xform0_k(const float* __restrict__ pnodes, const float* __restrict__ f,
              const float* __restrict__ W, float* __restrict__ h) {
    __shared__ float sW[(CI + 3) * CO];
    for (int i = threadIdx.x; i < (CI + 3) * CO; i += 256) sW[i] = W[i];
    __syncthreads();
    int gid = blockIdx.x * 256 + threadIdx.x;
    int i = gid / CO, ch = gid - i * CO;
    if (i >= NN) return;
    float s = pnodes[3 * i] * sW[CI * CO + ch] + pnodes[3 * i + 1] * sW[(CI + 1) * CO + ch]
            + pnodes[3 * i + 2] * sW[(CI + 2) * CO + ch];
    #pragma unroll
    for (int k = 0; k < CI; ++k) s += f[(size_t)i * CI + k] * sW[k * CO + ch];
    h[(size_t)i * CO + ch] = s;
}

template<int CO>
__global__ __launch_bounds__(256)
void gatherL0_k(const float* __restrict__ pnodes, const float* __restrict__ h,
                const float* __restrict__ Wpos, const int* __restrict__ offs,
                const int* __restrict__ srcs, float* __restrict__ out) {
    __shared__ float sW[3 * CO];
    for (int i = threadIdx.x; i < 3 * CO; i += 256) sW[i] = Wpos[i];
    __syncthreads();
    int gid = blockIdx.x * 256 + threadIdx.x;
    int d = gid / CO, ch = gid - d * CO;
    if (d >= NN) return;
    float c = pnodes[3 * d] * sW[ch] + pnodes[3 * d + 1] * sW[CO + ch] + pnodes[3 * d + 2] * sW[2 * CO + ch];
    float m = c;                        // no self-loop at level 0; empty -> 0
    int e0 = offs[d], e1 = offs[d + 1];
    int t = e0;
    for (; t + 4 <= e1; t += 4) {
        int s0 = srcs[t], s1 = srcs[t + 1], s2 = srcs[t + 2], s3 = srcs[t + 3];
        float v0 = h[(size_t)s0 * CO + ch], v1 = h[(size_t)s1 * CO + ch];
        float v2 = h[(size_t)s2 * CO + ch], v3 = h[(size_t)s3 * CO + ch];
        m = fmaxf(fmaxf(m, fmaxf(v0, v1)), fmaxf(v2, v3));
    }
    for (; t < e1; ++t) m = fmaxf(m, h[(size_t)srcs[t] * CO + ch]);
    out[(size_t)d * CO + ch] = m - c;
}

// ---------------- level 1 (compact over occupied cells; contiguous node ranges) ----------------
__global__ __launch_bounds__(256)
void pool1c_k(const float* __restrict__ f2, const int* __restrict__ offsN,
              const int* __restrict__ oclist, const int* __restrict__ ocount,
              float* __restrict__ nf1c) {
    int gid = blockIdx.x * 256 + threadIdx.x;
    int j = gid >> 4, ch = gid & 15;
    if (j >= *ocount) return;
    int d = oclist[j];
    float m = 0.f;                       // f2 >= 0 (post-relu)
    int n0 = offsN[d], n1 = offsN[d + 1];
    for (int n = n0; n < n1; ++n) m = fmaxf(m, f2[(size_t)n * 16 + ch]);
    nf1c[(size_t)j * 16 + ch] = m;
}

template<int CI>
__global__ __launch_bounds__(256)
void xformL1_k(const float* __restrict__ fin, const float* __restrict__ W,
               const int* __restrict__ oclist, const int* __restrict__ ocount,
               float* __restrict__ h) {
    __shared__ float sW[(CI + 3) * 32];
    for (int i = threadIdx.x; i < (CI + 3) * 32; i += 256) sW[i] = W[i];
    __syncthreads();
    int gid = blockIdx.x * 256 + threadIdx.x;
    int j = gid >> 5, ch = gid & 31;
    if (j >= *ocount) return;
    int d = oclist[j];
    const float* f = fin + (size_t)j * CI;
    float px = (float)(d >> 12), py = (float)((d >> 6) & 63), pz = (float)(d & 63);
    float s = px * sW[CI * 32 + ch] + py * sW[(CI + 1) * 32 + ch] + pz * sW[(CI + 2) * 32 + ch];
    #pragma unroll
    for (int k = 0; k < CI; ++k) s += f[k] * sW[k * 32 + ch];
    h[(size_t)j * 32 + ch] = s;
}

// flat gather over occupied dst cells: one contiguous edge range per cell
__global__ __launch_bounds__(256)
void gatherL1_k(const float* __restrict__ h, const float* __restrict__ Wpos,
                const int* __restrict__ offsN, const int* __restrict__ offs0,
                const int* __restrict__ csrc0,
                const int* __restrict__ oclist, const int* __restrict__ ocount,
                float* __restrict__ g) {
    __shared__ float sW[96];
    for (int i = threadIdx.x; i < 96; i += 256) sW[i] = Wpos[i];
    __syncthreads();
    int gid = blockIdx.x * 256 + threadIdx.x;
    int j = gid >> 5, ch = gid & 31;
    if (j >= *ocount) return;
    int d = oclist[j];
    float px = (float)(d >> 12), py = (float)((d >> 6) & 63), pz = (float)(d & 63);
    float c = px * sW[ch] + py * sW[32 + ch] + pz * sW[64 + ch];
    float m = fmaxf(c, h[(size_t)j * 32 + ch]);            // self-loop
    int e0 = offs0[offsN[d]], e1 = offs0[offsN[d + 1]];
    int t = e0;
    for (; t + 4 <= e1; t += 4) {
        int s0 = csrc0[t], s1 = csrc0[t + 1], s2 = csrc0[t + 2], s3 = csrc0[t + 3];
        float v0 = h[(size_t)s0 * 32 + ch], v1 = h[(size_t)s1 * 32 + ch];
        float v2 = h[(size_t)s2 * 32 + ch], v3 = h[(size_t)s3 * 32 + ch];
        m = fmaxf(fmaxf(m, fmaxf(v0, v1)), fmaxf(v2, v3));
    }
    for (; t < e1; ++t) m = fmaxf(m, h[(size_t)csrc0[t] * 32 + ch]);
    g[(size_t)j * 32 + ch] = m - c;
}

// ---------------- level 2 (block per 16^3 cell) ----------------
__global__ __launch_bounds__(256)
void pool2x_k(const float* __restrict__ Gc, const int* __restrict__ jmap,
              const float* __restrict__ W5, float* __restrict__ h5) {
    __shared__ float part[8][32];
    __shared__ float nf2row[32];
    int d2 = blockIdx.x, tid = threadIdx.x;
    int x2 = d2 >> 8, y2 = (d2 >> 4) & 15, z2 = d2 & 15;
    int ch = tid & 31, grp = tid >> 5;                 // 8 grps x 8 children
    float m = 0.f;
    #pragma unroll
    for (int cc = 0; cc < 8; ++cc) {
        int child = grp * 8 + cc;
        int i = child >> 4, jj = (child >> 2) & 3, k = child & 3;
        int d1 = ((x2 * 4 + i) * 64 + (y2 * 4 + jj)) * 64 + (z2 * 4 + k);
        int cj = jmap[d1];
        if (cj >= 0) m = fmaxf(m, Gc[(size_t)cj * 32 + ch]);
    }
    part[grp][ch] = m;
    __syncthreads();
    if (tid < 32) {
        float mm = part[0][tid];
        #pragma unroll
        for (int g = 1; g < 8; ++g) mm = fmaxf(mm, part[g][tid]);
        nf2row[tid] = mm;
    }
    __syncthreads();
    if (tid < 64) {
        float s = x2 * W5[32 * 64 + tid] + y2 * W5[33 * 64 + tid] + z2 * W5[34 * 64 + tid];
        #pragma unroll
        for (int k = 0; k < 32; ++k) s += nf2row[k] * W5[k * 64 + tid];
        h5[(size_t)d2 * 64 + tid] = s;
    }
}

template<bool FUSE, bool WRITE_G>
__global__ __launch_bounds__(256)
void gconvL2_k(const float* __restrict__ h, const float* __restrict__ Wpos,
               const unsigned long long* __restrict__ mask,
               const float* __restrict__ Wn,           // (64+3)x64, if FUSE
               float* __restrict__ gout, float* __restrict__ hnext) {
    __shared__ float red[4][64];
    __shared__ float grow[64];
    int d2 = blockIdx.x, tid = threadIdx.x;
    int x2 = d2 >> 8, y2 = (d2 >> 4) & 15, z2 = d2 & 15;
    int ch = tid & 63, grp = tid >> 6;                 // 4 waves x 16 mask words
    const unsigned long long* mrow = mask + (size_t)d2 * 64;
    float m = -1e30f;
    #pragma unroll 4
    for (int wi = grp * 16; wi < grp * 16 + 16; ++wi) {
        unsigned long long wb = mrow[wi];
        while (wb) {
            int b = __builtin_ctzll(wb);
            wb &= wb - 1;
            m = fmaxf(m, h[((size_t)(wi * 64 + b)) * 64 + ch]);
        }
    }
    red[grp][ch] = m;
    __syncthreads();
    if (grp == 0) {
        float mm = fmaxf(fmaxf(red[0][ch], red[1][ch]), fmaxf(red[2][ch], red[3][ch]));
        float c = x2 * Wpos[ch] + y2 * Wpos[64 + ch] + z2 * Wpos[128 + ch];
        mm = fmaxf(mm, fmaxf(c, h[(size_t)d2 * 64 + ch]));   // self-loop + empty
        float g = mm - c;
        if (WRITE_G) gout[(size_t)d2 * 64 + ch] = g;
        if (FUSE) grow[ch] = g;
    }
    if (FUSE) {
        __syncthreads();
        if (tid < 64) {
            float s = x2 * Wn[64 * 64 + tid] + y2 * Wn[65 * 64 + tid] + z2 * Wn[66 * 64 + tid];
            #pragma unroll
            for (int k = 0; k < 64; ++k) s += grow[k] * Wn[k * 64 + tid];
            hnext[(size_t)d2 * 64 + tid] = s;
        }
    }
}

// ---------------- output pool + linear ----------------
__global__ __launch_bounds__(256)
void outpool_k(const float* __restrict__ g7, float* __restrict__ xo) {
    int gid = blockIdx.x * 256 + threadIdx.x;
    if (gid >= 64 * 64) return;
    int oc = gid >> 6, ch = gid & 63;
    int cx = oc >> 4, cy = (oc >> 2) & 3, cz = oc & 3;
    float m = 0.f;
    for (int tc = 0; tc < 64; ++tc) {
        int i = tc >> 4, j = (tc >> 2) & 3, k = tc & 3;
        int d2 = ((cx * 4 + i) * 16 + (cy * 4 + j)) * 16 + (cz * 4 + k);
        m = fmaxf(m, g7[(size_t)d2 * 64 + ch]);
    }
    xo[(size_t)oc * 64 + ch] = m;
}

__global__ __launch_bounds__(64)
void linear_k(const float* __restrict__ xo, const float* __restrict__ Wl,
              const float* __restrict__ bl, float* __restrict__ out) {
    int j = blockIdx.x;
    float s = 0.f;
    for (int i = threadIdx.x; i < 4096; i += 64) s += xo[i] * Wl[(size_t)i * 100 + j];
    #pragma unroll
    for (int off = 32; off; off >>= 1) s += __shfl_down(s, off);
    if (threadIdx.x == 0) out[j] = s + bl[j];
}

extern "C" void kernel_launch(void* const* d_in, const int* in_sizes, int n_in,
                              void* d_out, int out_size, void* d_ws, size_t ws_size,
                              hipStream_t stream) {
    (void)in_sizes; (void)n_in; (void)out_size;
    const float* nodes = (const float*)d_in[0];
    const float* feats = (const float*)d_in[1];
    const int*   edges = (const int*)d_in[2];
    const int*   esrc  = edges;
    const int*   edst  = edges + NE;
    const float* W1 = (const float*)d_in[3];
    const float* W2 = (const float*)d_in[4];
    const float* W3 = (const float*)d_in[5];
    const float* W4 = (const float*)d_in[6];
    const float* W5 = (const float*)d_in[7];
    const float* W6 = (const float*)d_in[8];
    const float* W7 = (const float*)d_in[9];
    const float* Wl = (const float*)d_in[10];
    const float* bl = (const float*)d_in[11];
    float* out = (float*)d_out;

    char* ws = (char*)d_ws;
    size_t off = 0;
    auto alloc = [&](size_t bytes) { void* p = ws + off; off = (off + bytes + 255) & ~(size_t)255; return p; };
    // zero region: cntN + ocount + btot + mask (one memset)
    int*   cntN   = (int*)alloc((size_t)C1 * 4);
    int*   ocount = (int*)alloc(4);
    int*   btot   = (int*)alloc((size_t)NB * 4);
    unsigned long long* mask = (unsigned long long*)alloc((size_t)C2 * 64 * 8);  // 2MB
    size_t zero_bytes = off;
    int*   bsum   = (int*)alloc(260 * 4);
    int*   bbase  = (int*)alloc((size_t)(NB + 1) * 4);
    int*   cursor = (int*)alloc((size_t)NB * 4);
    int*   cid    = (int*)alloc((size_t)NN * 4);
    int*   rank   = (int*)alloc((size_t)NN * 4);
    int*   nidx   = (int*)alloc((size_t)NN * 4);
    int*   offsN  = (int*)alloc((size_t)(C1 + 1) * 4);
    int*   offs0  = (int*)alloc((size_t)(NN + 1) * 4);
    int*   srcs0  = (int*)alloc((size_t)NE * 4);
    int*   csrc0  = (int*)alloc((size_t)NE * 4);
    int2*  ebuf   = (int2*)alloc((size_t)NE * 8);
    int*   oclist = (int*)alloc((size_t)NN * 4);
    int*   jmap   = (int*)alloc((size_t)C1 * 4);
    int*   cidP   = (int*)alloc((size_t)NN * 4);
    int*   jsrcP  = (int*)alloc((size_t)NN * 4);
    float* pnodes = (float*)alloc((size_t)NN * 3 * 4);
    float* pfeat  = (float*)alloc((size_t)NN * 4);
    float* nf1c   = (float*)alloc((size_t)NN * 16 * 4);
    float* A      = (float*)alloc((size_t)NN * 48 * 4);   // h1,f1,h2,f2
    float* Hc     = (float*)alloc((size_t)NN * 32 * 4);
    float* Gc     = (float*)alloc((size_t)NN * 32 * 4);
    float* h5     = (float*)alloc((size_t)C2 * 64 * 4);
    float* h6     = (float*)alloc((size_t)C2 * 64 * 4);
    float* h7     = (float*)alloc((size_t)C2 * 64 * 4);
    float* g7     = (float*)alloc((size_t)C2 * 64 * 4);
    float* xo     = (float*)alloc((size_t)64 * 64 * 4);
    if (ws_size < off) return;

    float* h1 = A;                      // [NN][8]
    float* f1 = A + (size_t)NN * 8;
    float* h2 = A + (size_t)NN * 16;    // [NN][16]
    float* f2 = A + (size_t)NN * 32;

    hipMemsetAsync(cntN, 0, zero_bytes, stream);

    auto gr = [](long long n) { return (int)((n + 255) / 256); };
    const int nbC1 = (C1 + 2047) / 2048;   // 128
    const int gPA  = (NE + PA_EDGES - 1) / PA_EDGES;  // 196

    // ---- connectivity build (new-id space) ----
    cidhist_k<<<gr(NN), 256, 0, stream>>>(nodes, cid, cntN);
    oclist_k<<<C1 / 256, 256, 0, stream>>>(cntN, oclist, jmap, ocount);
    scan1_k<<<nbC1, 256, 0, stream>>>(cntN, C1, offsN, bsum);
    scan2_k<<<1, 256, 0, stream>>>(bsum, nbC1);
    scan3_k<<<gr(C1 + 1), 256, 0, stream>>>(offsN, C1, bsum, nbC1);
    nscatter_k<<<gr(NN), 256, 0, stream>>>(cid, offsN, cntN, rank, nidx);
    permute_k<<<gr(NN), 256, 0, stream>>>(nidx, nodes, feats, cid, jmap, pnodes, pfeat, cidP, jsrcP);
    bhist_k<<<gPA, 256, 0, stream>>>(edst, rank, btot);
    scanB_k<<<1, 256, 0, stream>>>(btot, bbase, cursor);
    passA_k<<<gPA, 256, 0, stream>>>(esrc, edst, rank, cursor, ebuf);
    passB_k<<<NB, 256, 0, stream>>>(ebuf, bbase, cidP, jsrcP, offs0, srcs0, csrc0, mask);

    // ---- level 0 (new-id space) ----
    xform0_k<1, 8><<<gr((long long)NN * 8), 256, 0, stream>>>(pnodes, pfeat, W1, h1);
    gatherL0_k<8><<<gr((long long)NN * 8), 256, 0, stream>>>(pnodes, h1, W1 + 1 * 8, offs0, srcs0, f1);
    xform0_k<8, 16><<<gr((long long)NN * 16), 256, 0, stream>>>(pnodes, f1, W2, h2);
    gatherL0_k<16><<<gr((long long)NN * 16), 256, 0, stream>>>(pnodes, h2, W2 + 8 * 16, offs0, srcs0, f2);

    // ---- level 1 (compact occupied cells, flat edge ranges) ----
    pool1c_k<<<gr((long long)NN * 16), 256, 0, stream>>>(f2, offsN, oclist, ocount, nf1c);
    xformL1_k<16><<<gr((long long)NN * 32), 256, 0, stream>>>(nf1c, W3, oclist, ocount, Hc);
    gatherL1_k<<<gr((long long)NN * 32), 256, 0, stream>>>(Hc, W3 + 16 * 32, offsN, offs0, csrc0, oclist, ocount, Gc);
    xformL1_k<32><<<gr((long long)NN * 32), 256, 0, stream>>>(Gc, W4, oclist, ocount, Hc);
    gatherL1_k<<<gr((long long)NN * 32), 256, 0, stream>>>(Hc, W4 + 32 * 32, offsN, offs0, csrc0, oclist, ocount, Gc);

    // ---- level 2 (block per 16^3 cell, bitmask-driven, fused) ----
    pool2x_k<<<C2, 256, 0, stream>>>(Gc, jmap, W5, h5);
    gconvL2_k<true,  false><<<C2, 256, 0, stream>>>(h5, W5 + 32 * 64, mask, W6, nullptr, h6);
    gconvL2_k<true,  false><<<C2, 256, 0, stream>>>(h6, W6 + 64 * 64, mask, W7, nullptr, h7);
    gconvL2_k<false, true ><<<C2, 256, 0, stream>>>(h7, W7 + 64 * 64, mask, nullptr, g7, nullptr);

    outpool_k<<<16, 256, 0, stream>>>(g7, xo);
    linear_k<<<100, 64, 0, stream>>>(xo, Wl, bl, out);
}

// Round 8
// 603.306 us; speedup vs baseline: 40.1725x; 1.0531x over previous
//
#include <hip/hip_runtime.h>

#define NN 100000      // nodes
#define NE 1600000     // edges
#define C1 262144      // 64^3 cells
#define C2 4096        // 16^3 cells
#define BSH 7          // bucket shift (128 new-ids per bucket)
#define BSZ 128
#define NB 782         // ceil(NN/128)
#define PA_EDGES 8192
#define PA_IT (PA_EDGES / 256)

__device__ __forceinline__ int parent2(int c) {   // 64^3 cell id -> 16^3 cell id
    return ((c >> 14) << 8) | (((c >> 8) & 15) << 4) | ((c >> 2) & 15);
}

// ---------------- cid of each node + node-per-cell histogram ----------------
__global__ __launch_bounds__(256)
void cidhist_k(const float* __restrict__ nodes, int* __restrict__ cid,
               int* __restrict__ cntN) {
    int i = blockIdx.x * 256 + threadIdx.x;
    if (i >= NN) return;
    int cx = min(max((int)floorf(nodes[3 * i]     * 0.25f), 0), 63);
    int cy = min(max((int)floorf(nodes[3 * i + 1] * 0.25f), 0), 63);
    int cz = min(max((int)floorf(nodes[3 * i + 2] * 0.25f), 0), 63);
    int c = (cx * 64 + cy) * 64 + cz;
    cid[i] = c;
    atomicAdd(&cntN[c], 1);
}

// ---------------- occupied-cell list + cell->compact-index map ----------------
__global__ __launch_bounds__(256)
void oclist_k(const int* __restrict__ cntN, int* __restrict__ oclist,
              int* __restrict__ jmap, int* __restrict__ ocount) {
    int c = blockIdx.x * 256 + threadIdx.x;     // grid covers C1 exactly
    bool occ = cntN[c] > 0;
    unsigned long long b = __ballot(occ);
    int lane = threadIdx.x & 63;
    int cnt = __popcll(b);
    int base = 0;
    if (cnt) {
        if (lane == 0) base = atomicAdd(ocount, cnt);
        base = __shfl(base, 0);
    }
    int pre = __popcll(b & ((1ull << lane) - 1));
    int j = occ ? base + pre : -1;
    jmap[c] = j;
    if (occ) oclist[j] = c;
}

// ---------------- cell scan (offsN over C1): 2048/block ----------------
__global__ __launch_bounds__(256)
void scan1_k(const int* __restrict__ cnt, int n, int* __restrict__ offs,
             int* __restrict__ bsum) {
    __shared__ int ws[4];
    int t = threadIdx.x, lane = t & 63, w = t >> 6;
    int base = blockIdx.x * 2048 + t * 8;
    int v[8]; int s = 0;
    #pragma unroll
    for (int i = 0; i < 8; ++i) { v[i] = (base + i < n) ? cnt[base + i] : 0; s += v[i]; }
    int sc = s;
    #pragma unroll
    for (int off = 1; off < 64; off <<= 1) { int o = __shfl_up(sc, off); if (lane >= off) sc += o; }
    if (lane == 63) ws[w] = sc;
    __syncthreads();
    int wbase = 0;
    for (int i = 0; i < w; ++i) wbase += ws[i];
    int run = wbase + sc - s;
    #pragma unroll
    for (int i = 0; i < 8; ++i) { if (base + i < n) offs[base + i] = run; run += v[i]; }
    if (t == 255) bsum[blockIdx.x] = wbase + sc;
}

__global__ __launch_bounds__(256)
void scan2_k(int* __restrict__ bsum, int nb) {   // one block, nb <= 256
    __shared__ int ws[4];
    int t = threadIdx.x, lane = t & 63, w = t >> 6;
    int v = (t < nb) ? bsum[t] : 0;
    int sc = v;
    #pragma unroll
    for (int off = 1; off < 64; off <<= 1) { int o = __shfl_up(sc, off); if (lane >= off) sc += o; }
    if (lane == 63) ws[w] = sc;
    __syncthreads();
    int wbase = 0;
    for (int i = 0; i < w; ++i) wbase += ws[i];
    if (t < nb) bsum[t] = wbase + sc - v;
    if (t == 255) bsum[nb] = ws[0] + ws[1] + ws[2] + ws[3];
}

__global__ __launch_bounds__(256)
void scan3_k(int* __restrict__ offs, int n, const int* __restrict__ bsum, int nb) {
    int i = blockIdx.x * 256 + threadIdx.x;
    if (i < n) offs[i] += bsum[i >> 11];
    else if (i == n) offs[n] = bsum[nb];
}

// ---------------- node scatter: rank (new id) + nidx (old id by new id) ----------------
__global__ __launch_bounds__(256)
void nscatter_k(const int* __restrict__ cid, const int* __restrict__ offsN,
                int* __restrict__ cntN, int* __restrict__ rank, int* __restrict__ nidx) {
    int i = blockIdx.x * 256 + threadIdx.x;
    if (i >= NN) return;
    int c = cid[i];
    int pos = offsN[c] + atomicAdd(&cntN[c], -1) - 1;
    rank[i] = pos;
    nidx[pos] = i;
}

// ---------------- permute node data into new-id order ----------------
__global__ __launch_bounds__(256)
void permute_k(const int* __restrict__ nidx, const float* __restrict__ nodes,
               const float* __restrict__ feats, const int* __restrict__ cid,
               const int* __restrict__ jmap,
               float* __restrict__ pnodes, float* __restrict__ pfeat,
               int* __restrict__ cidP, int* __restrict__ jsrcP) {
    int d = blockIdx.x * 256 + threadIdx.x;
    if (d >= NN) return;
    int i = nidx[d];
    pnodes[3 * d]     = nodes[3 * i];
    pnodes[3 * d + 1] = nodes[3 * i + 1];
    pnodes[3 * d + 2] = nodes[3 * i + 2];
    pfeat[d] = feats[i];
    int c = cid[i];
    cidP[d] = c;
    jsrcP[d] = jmap[c];
}

// ---------------- bucket histogram over rank[dst] (LDS pre-aggregated) ----------------
__global__ __launch_bounds__(256)
void bhist_k(const int* __restrict__ edst, const int* __restrict__ rank,
             int* __restrict__ btot) {
    __shared__ int h[NB];
    int tid = threadIdx.x;
    for (int i = tid; i < NB; i += 256) h[i] = 0;
    __syncthreads();
    int base = blockIdx.x * PA_EDGES;
    for (int i = 0; i < PA_IT; ++i) {
        int e = base + i * 256 + tid;
        if (e < NE) atomicAdd(&h[rank[edst[e]] >> BSH], 1);
    }
    __syncthreads();
    for (int i = tid; i < NB; i += 256) if (h[i]) atomicAdd(&btot[i], h[i]);
}

// one block: exclusive scan of NB (<=1024) bucket totals -> bbase[NB+1]; copy to cursor
__global__ __launch_bounds__(256)
void scanB_k(const int* __restrict__ btot, int* __restrict__ bbase,
             int* __restrict__ cursor) {
    __shared__ int ws[4];
    int t = threadIdx.x, lane = t & 63, w = t >> 6;
    int i0 = 4 * t;
    int v[4]; int s = 0;
    #pragma unroll
    for (int q = 0; q < 4; ++q) { v[q] = (i0 + q < NB) ? btot[i0 + q] : 0; s += v[q]; }
    int sc = s;
    #pragma unroll
    for (int off = 1; off < 64; off <<= 1) { int o = __shfl_up(sc, off); if (lane >= off) sc += o; }
    if (lane == 63) ws[w] = sc;
    __syncthreads();
    int wb = 0;
    for (int q = 0; q < w; ++q) wb += ws[q];
    int run = wb + sc - s;
    #pragma unroll
    for (int q = 0; q < 4; ++q) {
        if (i0 + q <= NB) { bbase[i0 + q] = run; if (i0 + q < NB) cursor[i0 + q] = run; }
        run += v[q];
    }
}

// ---------------- pass A: partition (rank_src, rank_dst) pairs by dst bucket ----------------
__global__ __launch_bounds__(256)
void passA_k(const int* __restrict__ esrc, const int* __restrict__ edst,
             const int* __restrict__ rank, int* __restrict__ cursor,
             int2* __restrict__ ebuf) {
    __shared__ int hist[NB];
    __shared__ int lofs[NB + 1];
    __shared__ int gbase[NB];
    __shared__ int cnt2[NB];
    __shared__ int2 stage[PA_EDGES];             // 64KB
    __shared__ unsigned short sbid[PA_EDGES];    // 16KB
    __shared__ int ws[4];
    int tid = threadIdx.x, lane = tid & 63, w = tid >> 6;
    for (int i = tid; i < NB; i += 256) { hist[i] = 0; cnt2[i] = 0; }
    __syncthreads();
    int base = blockIdx.x * PA_EDGES;
    for (int i = 0; i < PA_IT; ++i) {
        int e = base + i * 256 + tid;
        if (e < NE) atomicAdd(&hist[rank[edst[e]] >> BSH], 1);
    }
    __syncthreads();
    // exclusive scan hist -> lofs (4 per thread)
    int i0 = 4 * tid;
    int v[4]; int s = 0;
    #pragma unroll
    for (int q = 0; q < 4; ++q) { v[q] = (i0 + q < NB) ? hist[i0 + q] : 0; s += v[q]; }
    int sc = s;
    #pragma unroll
    for (int off = 1; off < 64; off <<= 1) { int o = __shfl_up(sc, off); if (lane >= off) sc += o; }
    if (lane == 63) ws[w] = sc;
    __syncthreads();
    int wb = 0;
    for (int q = 0; q < w; ++q) wb += ws[q];
    int run = wb + sc - s;
    #pragma unroll
    for (int q = 0; q < 4; ++q) {
        if (i0 + q <= NB) lofs[i0 + q] = run;
        run += v[q];
    }
    __syncthreads();
    for (int b = tid; b < NB; b += 256) {
        int c = hist[b];
        gbase[b] = c ? atomicAdd(&cursor[b], c) : 0;
    }
    __syncthreads();
    for (int i = 0; i < PA_IT; ++i) {
        int e = base + i * 256 + tid;
        if (e < NE) {
            int rd = rank[edst[e]], rs = rank[esrc[e]];
            int b = rd >> BSH;
            int p = lofs[b] + atomicAdd(&cnt2[b], 1);
            stage[p] = make_int2(rs, rd);
            sbid[p] = (unsigned short)b;
        }
    }
    __syncthreads();
    int nval = min(PA_EDGES, NE - base);
    for (int k = tid; k < nval; k += 256) {
        int b = sbid[k];
        ebuf[gbase[b] + (k - lofs[b])] = stage[k];
    }
}

// ---------------- pass B: per-bucket final scatter; offs0 (new-id CSR); csrc fused ----------------
__global__ __launch_bounds__(256)
void passB_k(const int2* __restrict__ ebuf, const int* __restrict__ bbase,
             const int* __restrict__ jsrcP,
             int* __restrict__ offs0, int* __restrict__ srcs0, int* __restrict__ csrc0) {
    __shared__ int cnt[BSZ];
    __shared__ int pos[BSZ];
    __shared__ int ws[4];
    int b = blockIdx.x, tid = threadIdx.x, lane = tid & 63, w = tid >> 6;
    int d0 = b << BSH;
    int range = min(BSZ, NN - d0);
    if (tid < BSZ) cnt[tid] = 0;
    __syncthreads();
    int r0 = bbase[b], r1 = bbase[b + 1];
    for (int k = r0 + tid; k < r1; k += 256) atomicAdd(&cnt[ebuf[k].y & (BSZ - 1)], 1);
    __syncthreads();
    int v = (tid < BSZ) ? cnt[tid] : 0;
    int sc = v;
    #pragma unroll
    for (int off = 1; off < 64; off <<= 1) { int o = __shfl_up(sc, off); if (lane >= off) sc += o; }
    if (lane == 63) ws[w] = sc;
    __syncthreads();
    int wb = 0;
    for (int q = 0; q < w; ++q) wb += ws[q];
    int rel = wb + sc - v;                        // exclusive per-dst prefix
    if (tid < range) offs0[d0 + tid] = r0 + rel;
    if (tid == 0) offs0[min(d0 + BSZ, NN)] = r1;  // benign duplicate of next base
    if (tid < BSZ) pos[tid] = r0 + rel;
    __syncthreads();
    for (int k = r0 + tid; k < r1; k += 256) {
        int2 pr = ebuf[k];
        int di = pr.y & (BSZ - 1);
        int p = atomicAdd(&pos[di], 1);
        int rs = pr.x;
        srcs0[p] = rs;
        csrc0[p] = jsrcP[rs];
    }
}

// ---------------- level-2 mask: one block per d2, LDS bitmap ----------------
__global__ __launch_bounds__(256)
void mask_k(const int* __restrict__ offsN, const int* __restrict__ offs0,
            const int* __restrict__ csrc0, const int* __restrict__ oclist,
            unsigned long long* __restrict__ mask) {
    __shared__ unsigned long long words[64];
    int d2 = blockIdx.x, tid = threadIdx.x;
    if (tid < 64) words[tid] = 0;
    __syncthreads();
    int x2 = d2 >> 8, y2 = (d2 >> 4) & 15, z2 = d2 & 15;
    int child = tid >> 2, sub = tid & 3;         // 64 children x 4 threads
    int i = child >> 4, jj = (child >> 2) & 3, k = child & 3;
    int d1 = ((x2 * 4 + i) * 64 + (y2 * 4 + jj)) * 64 + (z2 * 4 + k);
    int e0 = offs0[offsN[d1]], e1 = offs0[offsN[d1 + 1]];
    for (int t = e0 + sub; t < e1; t += 4) {
        int c = oclist[csrc0[t]];
        int s2 = parent2(c);
        atomicOr(&words[s2 >> 6], 1ull << (s2 & 63));
    }
    __syncthreads();
    if (tid < 64) mask[(size_t)d2 * 64 + tid] = words[tid];
}

// ---------------- level 0: h = f @ W_f + pos @ W_p (new-id space) ----------------
template<int CI, int CO>
__global__ __launch_bounds__(256)
void xform0_k(const float* __restrict__ pnodes, const float* __restrict__ f,
              const float* __restrict__ W, float* __restrict__ h) {
    __shared__ float sW[(CI + 3) * CO];
    for (int i = threadIdx.x; i < (CI + 3) * CO; i += 256) sW[i] = W[i];
    __syncthreads();
    int gid = blockIdx.x * 256 + threadIdx.x;
    int i = gid / CO, ch = gid - i * CO;
    if (i >= NN) return;
    float s = pnodes[3 * i] * sW[CI * CO + ch] + pnodes[3 * i + 1] * sW[(CI + 1) * CO + ch]
            + pnodes[3 * i + 2] * sW[(CI + 2) * CO + ch];
    #pragma unroll
    for (int k = 0; k < CI; ++k) s += f[(size_t)i * CI + k] * sW[k * CO + ch];
    h[(size_t)i * CO + ch] = s;
}

template<int CO>
__global__ __launch_bounds__(256)
void gatherL0_k(const float* __restrict__ pnodes, const float* __restrict__ h,
                const float* __restrict__ Wpos, const int* __restrict__ offs,
                const int* __restrict__ srcs, float* __restrict__ out) {
    __shared__ float sW[3 * CO];
    for (int i = threadIdx.x; i < 3 * CO; i += 256) sW[i] = Wpos[i];
    __syncthreads();
    int gid = blockIdx.x * 256 + threadIdx.x;
    int d = gid / CO, ch = gid - d * CO;
    if (d >= NN) return;
    float c = pnodes[3 * d] * sW[ch] + pnodes[3 * d + 1] * sW[CO + ch] + pnodes[3 * d + 2] * sW[2 * CO + ch];
    float m = c;                        // no self-loop at level 0; empty -> 0
    int e0 = offs[d], e1 = offs[d + 1];
    int t = e0;
    for (; t + 4 <= e1; t += 4) {
        int s0 = srcs[t], s1 = srcs[t + 1], s2 = srcs[t + 2], s3 = srcs[t + 3];
        float v0 = h[(size_t)s0 * CO + ch], v1 = h[(size_t)s1 * CO + ch];
        float v2 = h[(size_t)s2 * CO + ch], v3 = h[(size_t)s3 * CO + ch];
        m = fmaxf(fmaxf(m, fmaxf(v0, v1)), fmaxf(v2, v3));
    }
    for (; t < e1; ++t) m = fmaxf(m, h[(size_t)srcs[t] * CO + ch]);
    out[(size_t)d * CO + ch] = m - c;
}

// ---------------- level 1 (compact over occupied cells; contiguous ranges) ----------------
__global__ __launch_bounds__(256)
void pool1c_k(const float* __restrict__ f2, const int* __restrict__ offsN,
              const int* __restrict__ oclist, const int* __restrict__ ocount,
              float* __restrict__ nf1c) {
    int gid = blockIdx.x * 256 + threadIdx.x;
    int j = gid >> 4, ch = gid & 15;
    if (j >= *ocount) return;
    int d = oclist[j];
    float m = 0.f;                       // f2 >= 0 (post-relu)
    int n0 = offsN[d], n1 = offsN[d + 1];
    for (int n = n0; n < n1; ++n) m = fmaxf(m, f2[(size_t)n * 16 + ch]);
    nf1c[(size_t)j * 16 + ch] = m;
}

template<int CI>
__global__ __launch_bounds__(256)
void xformL1_k(const float* __restrict__ fin, const float* __restrict__ W,
               const int* __restrict__ oclist, const int* __restrict__ ocount,
               float* __restrict__ h) {
    __shared__ float sW[(CI + 3) * 32];
    for (int i = threadIdx.x; i < (CI + 3) * 32; i += 256) sW[i] = W[i];
    __syncthreads();
    int gid = blockIdx.x * 256 + threadIdx.x;
    int j = gid >> 5, ch = gid & 31;
    if (j >= *ocount) return;
    int d = oclist[j];
    const float* f = fin + (size_t)j * CI;
    float px = (float)(d >> 12), py = (float)((d >> 6) & 63), pz = (float)(d & 63);
    float s = px * sW[CI * 32 + ch] + py * sW[(CI + 1) * 32 + ch] + pz * sW[(CI + 2) * 32 + ch];
    #pragma unroll
    for (int k = 0; k < CI; ++k) s += f[k] * sW[k * 32 + ch];
    h[(size_t)j * 32 + ch] = s;
}

// flat gather over occupied dst cells: one contiguous edge range per cell
__global__ __launch_bounds__(256)
void gatherL1_k(const float* __restrict__ h, const float* __restrict__ Wpos,
                const int* __restrict__ offsN, const int* __restrict__ offs0,
                const int* __restrict__ csrc0,
                const int* __restrict__ oclist, const int* __restrict__ ocount,
                float* __restrict__ g) {
    __shared__ float sW[96];
    for (int i = threadIdx.x; i < 96; i += 256) sW[i] = Wpos[i];
    __syncthreads();
    int gid = blockIdx.x * 256 + threadIdx.x;
    int j = gid >> 5, ch = gid & 31;
    if (j >= *ocount) return;
    int d = oclist[j];
    float px = (float)(d >> 12), py = (float)((d >> 6) & 63), pz = (float)(d & 63);
    float c = px * sW[ch] + py * sW[32 + ch] + pz * sW[64 + ch];
    float m = fmaxf(c, h[(size_t)j * 32 + ch]);            // self-loop
    int e0 = offs0[offsN[d]], e1 = offs0[offsN[d + 1]];
    int t = e0;
    for (; t + 4 <= e1; t += 4) {
        int s0 = csrc0[t], s1 = csrc0[t + 1], s2 = csrc0[t + 2], s3 = csrc0[t + 3];
        float v0 = h[(size_t)s0 * 32 + ch], v1 = h[(size_t)s1 * 32 + ch];
        float v2 = h[(size_t)s2 * 32 + ch], v3 = h[(size_t)s3 * 32 + ch];
        m = fmaxf(fmaxf(m, fmaxf(v0, v1)), fmaxf(v2, v3));
    }
    for (; t < e1; ++t) m = fmaxf(m, h[(size_t)csrc0[t] * 32 + ch]);
    g[(size_t)j * 32 + ch] = m - c;
}

// ---------------- level 2 (block per 16^3 cell) ----------------
__global__ __launch_bounds__(256)
void pool2x_k(const float* __restrict__ Gc, const int* __restrict__ jmap,
              const float* __restrict__ W5, float* __restrict__ h5) {
    __shared__ float part[8][32];
    __shared__ float nf2row[32];
    int d2 = blockIdx.x, tid = threadIdx.x;
    int x2 = d2 >> 8, y2 = (d2 >> 4) & 15, z2 = d2 & 15;
    int ch = tid & 31, grp = tid >> 5;                 // 8 grps x 8 children
    float m = 0.f;
    #pragma unroll
    for (int cc = 0; cc < 8; ++cc) {
        int child = grp * 8 + cc;
        int i = child >> 4, jj = (child >> 2) & 3, k = child & 3;
        int d1 = ((x2 * 4 + i) * 64 + (y2 * 4 + jj)) * 64 + (z2 * 4 + k);
        int cj = jmap[d1];
        if (cj >= 0) m = fmaxf(m, Gc[(size_t)cj * 32 + ch]);
    }
    part[grp][ch] = m;
    __syncthreads();
    if (tid < 32) {
        float mm = part[0][tid];
        #pragma unroll
        for (int g = 1; g < 8; ++g) mm = fmaxf(mm, part[g][tid]);
        nf2row[tid] = mm;
    }
    __syncthreads();
    if (tid < 64) {
        float s = x2 * W5[32 * 64 + tid] + y2 * W5[33 * 64 + tid] + z2 * W5[34 * 64 + tid];
        #pragma unroll
        for (int k = 0; k < 32; ++k) s += nf2row[k] * W5[k * 64 + tid];
        h5[(size_t)d2 * 64 + tid] = s;
    }
}

template<bool FUSE, bool WRITE_G>
__global__ __launch_bounds__(256)
void gconvL2_k(const float* __restrict__ h, const float* __restrict__ Wpos,
               const unsigned long long* __restrict__ mask,
               const float* __restrict__ Wn,           // (64+3)x64, if FUSE
               float* __restrict__ gout, float* __restrict__ hnext) {
    __shared__ float red[4][64];
    __shared__ float grow[64];
    int d2 = blockIdx.x, tid = threadIdx.x;
    int x2 = d2 >> 8, y2 = (d2 >> 4) & 15, z2 = d2 & 15;
    int ch = tid & 63, grp = tid >> 6;                 // 4 waves x 16 mask words
    const unsigned long long* mrow = mask + (size_t)d2 * 64;
    float m = -1e30f;
    #pragma unroll 4
    for (int wi = grp * 16; wi < grp * 16 + 16; ++wi) {
        unsigned long long wb = mrow[wi];
        while (wb) {
            int b = __builtin_ctzll(wb);
            wb &= wb - 1;
            m = fmaxf(m, h[((size_t)(wi * 64 + b)) * 64 + ch]);
        }
    }
    red[grp][ch] = m;
    __syncthreads();
    if (grp == 0) {
        float mm = fmaxf(fmaxf(red[0][ch], red[1][ch]), fmaxf(red[2][ch], red[3][ch]));
        float c = x2 * Wpos[ch] + y2 * Wpos[64 + ch] + z2 * Wpos[128 + ch];
        mm = fmaxf(mm, fmaxf(c, h[(size_t)d2 * 64 + ch]));   // self-loop + empty
        float g = mm - c;
        if (WRITE_G) gout[(size_t)d2 * 64 + ch] = g;
        if (FUSE) grow[ch] = g;
    }
    if (FUSE) {
        __syncthreads();
        if (tid < 64) {
            float s = x2 * Wn[64 * 64 + tid] + y2 * Wn[65 * 64 + tid] + z2 * Wn[66 * 64 + tid];
            #pragma unroll
            for (int k = 0; k < 64; ++k) s += grow[k] * Wn[k * 64 + tid];
            hnext[(size_t)d2 * 64 + tid] = s;
        }
    }
}

// ---------------- output pool + linear ----------------
__global__ __launch_bounds__(256)
void outpool_k(const float* __restrict__ g7, float* __restrict__ xo) {
    int gid = blockIdx.x * 256 + threadIdx.x;
    if (gid >= 64 * 64) return;
    int oc = gid >> 6, ch = gid & 63;
    int cx = oc >> 4, cy = (oc >> 2) & 3, cz = oc & 3;
    float m = 0.f;
    for (int tc = 0; tc < 64; ++tc) {
        int i = tc >> 4, j = (tc >> 2) & 3, k = tc & 3;
        int d2 = ((cx * 4 + i) * 16 + (cy * 4 + j)) * 16 + (cz * 4 + k);
        m = fmaxf(m, g7[(size_t)d2 * 64 + ch]);
    }
    xo[(size_t)oc * 64 + ch] = m;
}

__global__ __launch_bounds__(64)
void linear_k(const float* __restrict__ xo, const float* __restrict__ Wl,
              const float* __restrict__ bl, float* __restrict__ out) {
    int j = blockIdx.x;
    float s = 0.f;
    for (int i = threadIdx.x; i < 4096; i += 64) s += xo[i] * Wl[(size_t)i * 100 + j];
    #pragma unroll
    for (int off = 32; off; off >>= 1) s += __shfl_down(s, off);
    if (threadIdx.x == 0) out[j] = s + bl[j];
}

extern "C" void kernel_launch(void* const* d_in, const int* in_sizes, int n_in,
                              void* d_out, int out_size, void* d_ws, size_t ws_size,
                              hipStream_t stream) {
    (void)in_sizes; (void)n_in; (void)out_size;
    const float* nodes = (const float*)d_in[0];
    const float* feats = (const float*)d_in[1];
    const int*   edges = (const int*)d_in[2];
    const int*   esrc  = edges;
    const int*   edst  = edges + NE;
    const float* W1 = (const float*)d_in[3];
    const float* W2 = (const float*)d_in[4];
    const float* W3 = (const float*)d_in[5];
    const float* W4 = (const float*)d_in[6];
    const float* W5 = (const float*)d_in[7];
    const float* W6 = (const float*)d_in[8];
    const float* W7 = (const float*)d_in[9];
    const float* Wl = (const float*)d_in[10];
    const float* bl = (const float*)d_in[11];
    float* out = (float*)d_out;

    char* ws = (char*)d_ws;
    size_t off = 0;
    auto alloc = [&](size_t bytes) { void* p = ws + off; off = (off + bytes + 255) & ~(size_t)255; return p; };
    // zero region: cntN + ocount + btot (one memset; mask no longer needs zeroing)
    int*   cntN   = (int*)alloc((size_t)C1 * 4);
    int*   ocount = (int*)alloc(4);
    int*   btot   = (int*)alloc((size_t)NB * 4);
    size_t zero_bytes = off;
    unsigned long long* mask = (unsigned long long*)alloc((size_t)C2 * 64 * 8);  // 2MB
    int*   bsum   = (int*)alloc(260 * 4);
    int*   bbase  = (int*)alloc((size_t)(NB + 1) * 4);
    int*   cursor = (int*)alloc((size_t)NB * 4);
    int*   cid    = (int*)alloc((size_t)NN * 4);
    int*   rank   = (int*)alloc((size_t)NN * 4);
    int*   nidx   = (int*)alloc((size_t)NN * 4);
    int*   offsN  = (int*)alloc((size_t)(C1 + 1) * 4);
    int*   offs0  = (int*)alloc((size_t)(NN + 1) * 4);
    int*   srcs0  = (int*)alloc((size_t)NE * 4);
    int*   csrc0  = (int*)alloc((size_t)NE * 4);
    int2*  ebuf   = (int2*)alloc((size_t)NE * 8);
    int*   oclist = (int*)alloc((size_t)NN * 4);
    int*   jmap   = (int*)alloc((size_t)C1 * 4);
    int*   cidP   = (int*)alloc((size_t)NN * 4);
    int*   jsrcP  = (int*)alloc((size_t)NN * 4);
    float* pnodes = (float*)alloc((size_t)NN * 3 * 4);
    float* pfeat  = (float*)alloc((size_t)NN * 4);
    float* nf1c   = (float*)alloc((size_t)NN * 16 * 4);
    float* A      = (float*)alloc((size_t)NN * 48 * 4);   // h1,f1,h2,f2
    float* Hc     = (float*)alloc((size_t)NN * 32 * 4);
    float* Gc     = (float*)alloc((size_t)NN * 32 * 4);
    float* h5     = (float*)alloc((size_t)C2 * 64 * 4);
    float* h6     = (float*)alloc((size_t)C2 * 64 * 4);
    float* h7     = (float*)alloc((size_t)C2 * 64 * 4);
    float* g7     = (float*)alloc((size_t)C2 * 64 * 4);
    float* xo     = (float*)alloc((size_t)64 * 64 * 4);
    if (ws_size < off) return;

    float* h1 = A;                      // [NN][8]
    float* f1 = A + (size_t)NN * 8;
    float* h2 = A + (size_t)NN * 16;    // [NN][16]
    float* f2 = A + (size_t)NN * 32;

    hipMemsetAsync(cntN, 0, zero_bytes, stream);

    auto gr = [](long long n) { return (int)((n + 255) / 256); };
    const int nbC1 = (C1 + 2047) / 2048;   // 128
    const int gPA  = (NE + PA_EDGES - 1) / PA_EDGES;  // 196

    // ---- connectivity build (new-id space) ----
    cidhist_k<<<gr(NN), 256, 0, stream>>>(nodes, cid, cntN);
    oclist_k<<<C1 / 256, 256, 0, stream>>>(cntN, oclist, jmap, ocount);
    scan1_k<<<nbC1, 256, 0, stream>>>(cntN, C1, offsN, bsum);
    scan2_k<<<1, 256, 0, stream>>>(bsum, nbC1);
    scan3_k<<<gr(C1 + 1), 256, 0, stream>>>(offsN, C1, bsum, nbC1);
    nscatter_k<<<gr(NN), 256, 0, stream>>>(cid, offsN, cntN, rank, nidx);
    permute_k<<<gr(NN), 256, 0, stream>>>(nidx, nodes, feats, cid, jmap, pnodes, pfeat, cidP, jsrcP);
    bhist_k<<<gPA, 256, 0, stream>>>(edst, rank, btot);
    scanB_k<<<1, 256, 0, stream>>>(btot, bbase, cursor);
    passA_k<<<gPA, 256, 0, stream>>>(esrc, edst, rank, cursor, ebuf);
    passB_k<<<NB, 256, 0, stream>>>(ebuf, bbase, jsrcP, offs0, srcs0, csrc0);
    mask_k<<<C2, 256, 0, stream>>>(offsN, offs0, csrc0, oclist, mask);

    // ---- level 0 (new-id space) ----
    xform0_k<1, 8><<<gr((long long)NN * 8), 256, 0, stream>>>(pnodes, pfeat, W1, h1);
    gatherL0_k<8><<<gr((long long)NN * 8), 256, 0, stream>>>(pnodes, h1, W1 + 1 * 8, offs0, srcs0, f1);
    xform0_k<8, 16><<<gr((long long)NN * 16), 256, 0, stream>>>(pnodes, f1, W2, h2);
    gatherL0_k<16><<<gr((long long)NN * 16), 256, 0, stream>>>(pnodes, h2, W2 + 8 * 16, offs0, srcs0, f2);

    // ---- level 1 (compact occupied cells, flat edge ranges) ----
    pool1c_k<<<gr((long long)NN * 16), 256, 0, stream>>>(f2, offsN, oclist, ocount, nf1c);
    xformL1_k<16><<<gr((long long)NN * 32), 256, 0, stream>>>(nf1c, W3, oclist, ocount, Hc);
    gatherL1_k<<<gr((long long)NN * 32), 256, 0, stream>>>(Hc, W3 + 16 * 32, offsN, offs0, csrc0, oclist, ocount, Gc);
    xformL1_k<32><<<gr((long long)NN * 32), 256, 0, stream>>>(Gc, W4, oclist, ocount, Hc);
    gatherL1_k<<<gr((long long)NN * 32), 256, 0, stream>>>(Hc, W4 + 32 * 32, offsN, offs0, csrc0, oclist, ocount, Gc);

    // ---- level 2 (block per 16^3 cell, bitmask-driven, fused) ----
    pool2x_k<<<C2, 256, 0, stream>>>(Gc, jmap, W5, h5);
    gconvL2_k<true,  false><<<C2, 256, 0, stream>>>(h5, W5 + 32 * 64, mask, W6, nullptr, h6);
    gconvL2_k<true,  false><<<C2, 256, 0, stream>>>(h6, W6 + 64 * 64, mask, W7, nullptr, h7);
    gconvL2_k<false, true ><<<C2, 256, 0, stream>>>(h7, W7 + 64 * 64, mask, nullptr, g7, nullptr);

    outpool_k<<<16, 256, 0, stream>>>(g7, xo);
    linear_k<<<100, 64, 0, stream>>>(xo, Wl, bl, out);
}

// Round 9
// 560.143 us; speedup vs baseline: 43.2681x; 1.0771x over previous
//
#include <hip/hip_runtime.h>

#define NN 100000      // nodes
#define NE 1600000     // edges
#define C1 262144      // 64^3 cells
#define C2 4096        // 16^3 cells
#define BSH 7          // bucket shift (128 new-ids per bucket)
#define BSZ 128
#define NB 782         // ceil(NN/128)
#define PA_EDGES 8192
#define PA_IT (PA_EDGES / 256)

__device__ __forceinline__ int parent2(int c) {   // 64^3 cell id -> 16^3 cell id
    return ((c >> 14) << 8) | (((c >> 8) & 15) << 4) | ((c >> 2) & 15);
}

// ---------------- cid of each node + node-per-cell histogram ----------------
__global__ __launch_bounds__(256)
void cidhist_k(const float* __restrict__ nodes, int* __restrict__ cid,
               int* __restrict__ cntN) {
    int i = blockIdx.x * 256 + threadIdx.x;
    if (i >= NN) return;
    int cx = min(max((int)floorf(nodes[3 * i]     * 0.25f), 0), 63);
    int cy = min(max((int)floorf(nodes[3 * i + 1] * 0.25f), 0), 63);
    int cz = min(max((int)floorf(nodes[3 * i + 2] * 0.25f), 0), 63);
    int c = (cx * 64 + cy) * 64 + cz;
    cid[i] = c;
    atomicAdd(&cntN[c], 1);
}

// ---------------- occupied-cell list + cell->compact-index map ----------------
__global__ __launch_bounds__(256)
void oclist_k(const int* __restrict__ cntN, int* __restrict__ oclist,
              int* __restrict__ jmap, int* __restrict__ ocount) {
    int c = blockIdx.x * 256 + threadIdx.x;     // grid covers C1 exactly
    bool occ = cntN[c] > 0;
    unsigned long long b = __ballot(occ);
    int lane = threadIdx.x & 63;
    int cnt = __popcll(b);
    int base = 0;
    if (cnt) {
        if (lane == 0) base = atomicAdd(ocount, cnt);
        base = __shfl(base, 0);
    }
    int pre = __popcll(b & ((1ull << lane) - 1));
    int j = occ ? base + pre : -1;
    jmap[c] = j;
    if (occ) oclist[j] = c;
}

// ---------------- cell scan (offsN over C1): 2048/block ----------------
__global__ __launch_bounds__(256)
void scan1_k(const int* __restrict__ cnt, int n, int* __restrict__ offs,
             int* __restrict__ bsum) {
    __shared__ int ws[4];
    int t = threadIdx.x, lane = t & 63, w = t >> 6;
    int base = blockIdx.x * 2048 + t * 8;
    int v[8]; int s = 0;
    #pragma unroll
    for (int i = 0; i < 8; ++i) { v[i] = (base + i < n) ? cnt[base + i] : 0; s += v[i]; }
    int sc = s;
    #pragma unroll
    for (int off = 1; off < 64; off <<= 1) { int o = __shfl_up(sc, off); if (lane >= off) sc += o; }
    if (lane == 63) ws[w] = sc;
    __syncthreads();
    int wbase = 0;
    for (int i = 0; i < w; ++i) wbase += ws[i];
    int run = wbase + sc - s;
    #pragma unroll
    for (int i = 0; i < 8; ++i) { if (base + i < n) offs[base + i] = run; run += v[i]; }
    if (t == 255) bsum[blockIdx.x] = wbase + sc;
}

__global__ __launch_bounds__(256)
void scan2_k(int* __restrict__ bsum, int nb) {   // one block, nb <= 256
    __shared__ int ws[4];
    int t = threadIdx.x, lane = t & 63, w = t >> 6;
    int v = (t < nb) ? bsum[t] : 0;
    int sc = v;
    #pragma unroll
    for (int off = 1; off < 64; off <<= 1) { int o = __shfl_up(sc, off); if (lane >= off) sc += o; }
    if (lane == 63) ws[w] = sc;
    __syncthreads();
    int wbase = 0;
    for (int i = 0; i < w; ++i) wbase += ws[i];
    if (t < nb) bsum[t] = wbase + sc - v;
    if (t == 255) bsum[nb] = ws[0] + ws[1] + ws[2] + ws[3];
}

__global__ __launch_bounds__(256)
void scan3_k(int* __restrict__ offs, int n, const int* __restrict__ bsum, int nb) {
    int i = blockIdx.x * 256 + threadIdx.x;
    if (i < n) offs[i] += bsum[i >> 11];
    else if (i == n) offs[n] = bsum[nb];
}

// ---------------- node scatter: rank (new id) + nidx (old id by new id) ----------------
__global__ __launch_bounds__(256)
void nscatter_k(const int* __restrict__ cid, const int* __restrict__ offsN,
                int* __restrict__ cntN, int* __restrict__ rank, int* __restrict__ nidx) {
    int i = blockIdx.x * 256 + threadIdx.x;
    if (i >= NN) return;
    int c = cid[i];
    int pos = offsN[c] + atomicAdd(&cntN[c], -1) - 1;
    rank[i] = pos;
    nidx[pos] = i;
}

// ---------------- permute node data into new-id order ----------------
__global__ __launch_bounds__(256)
void permute_k(const int* __restrict__ nidx, const float* __restrict__ nodes,
               const float* __restrict__ feats, const int* __restrict__ cid,
               const int* __restrict__ jmap,
               float* __restrict__ pnodes, float* __restrict__ pfeat,
               int* __restrict__ cidP, int* __restrict__ jsrcP) {
    int d = blockIdx.x * 256 + threadIdx.x;
    if (d >= NN) return;
    int i = nidx[d];
    pnodes[3 * d]     = nodes[3 * i];
    pnodes[3 * d + 1] = nodes[3 * i + 1];
    pnodes[3 * d + 2] = nodes[3 * i + 2];
    pfeat[d] = feats[i];
    int c = cid[i];
    cidP[d] = c;
    jsrcP[d] = jmap[c];
}

// ---------------- bucket histogram over rank[dst] (LDS pre-aggregated) ----------------
__global__ __launch_bounds__(256)
void bhist_k(const int* __restrict__ edst, const int* __restrict__ rank,
             int* __restrict__ btot) {
    __shared__ int h[NB];
    int tid = threadIdx.x;
    for (int i = tid; i < NB; i += 256) h[i] = 0;
    __syncthreads();
    int base = blockIdx.x * PA_EDGES;
    for (int i = 0; i < PA_IT; ++i) {
        int e = base + i * 256 + tid;
        if (e < NE) atomicAdd(&h[rank[edst[e]] >> BSH], 1);
    }
    __syncthreads();
    for (int i = tid; i < NB; i += 256) if (h[i]) atomicAdd(&btot[i], h[i]);
}

// one block: exclusive scan of NB (<=1024) bucket totals -> bbase[NB+1]; copy to cursor
__global__ __launch_bounds__(256)
void scanB_k(const int* __restrict__ btot, int* __restrict__ bbase,
             int* __restrict__ cursor) {
    __shared__ int ws[4];
    int t = threadIdx.x, lane = t & 63, w = t >> 6;
    int i0 = 4 * t;
    int v[4]; int s = 0;
    #pragma unroll
    for (int q = 0; q < 4; ++q) { v[q] = (i0 + q < NB) ? btot[i0 + q] : 0; s += v[q]; }
    int sc = s;
    #pragma unroll
    for (int off = 1; off < 64; off <<= 1) { int o = __shfl_up(sc, off); if (lane >= off) sc += o; }
    if (lane == 63) ws[w] = sc;
    __syncthreads();
    int wb = 0;
    for (int q = 0; q < w; ++q) wb += ws[q];
    int run = wb + sc - s;
    #pragma unroll
    for (int q = 0; q < 4; ++q) {
        if (i0 + q <= NB) { bbase[i0 + q] = run; if (i0 + q < NB) cursor[i0 + q] = run; }
        run += v[q];
    }
}

// ---------------- pass A: partition (rank_src, rank_dst) pairs by dst bucket ----------------
__global__ __launch_bounds__(256)
void passA_k(const int* __restrict__ esrc, const int* __restrict__ edst,
             const int* __restrict__ rank, int* __restrict__ cursor,
             int2* __restrict__ ebuf) {
    __shared__ int hist[NB];
    __shared__ int lofs[NB + 1];
    __shared__ int gbase[NB];
    __shared__ int cnt2[NB];
    __shared__ int2 stage[PA_EDGES];             // 64KB
    __shared__ unsigned short sbid[PA_EDGES];    // 16KB
    __shared__ int ws[4];
    int tid = threadIdx.x, lane = tid & 63, w = tid >> 6;
    for (int i = tid; i < NB; i += 256) { hist[i] = 0; cnt2[i] = 0; }
    __syncthreads();
    int base = blockIdx.x * PA_EDGES;
    for (int i = 0; i < PA_IT; ++i) {
        int e = base + i * 256 + tid;
        if (e < NE) atomicAdd(&hist[rank[edst[e]] >> BSH], 1);
    }
    __syncthreads();
    // exclusive scan hist -> lofs (4 per thread)
    int i0 = 4 * tid;
    int v[4]; int s = 0;
    #pragma unroll
    for (int q = 0; q < 4; ++q) { v[q] = (i0 + q < NB) ? hist[i0 + q] : 0; s += v[q]; }
    int sc = s;
    #pragma unroll
    for (int off = 1; off < 64; off <<= 1) { int o = __shfl_up(sc, off); if (lane >= off) sc += o; }
    if (lane == 63) ws[w] = sc;
    __syncthreads();
    int wb = 0;
    for (int q = 0; q < w; ++q) wb += ws[q];
    int run = wb + sc - s;
    #pragma unroll
    for (int q = 0; q < 4; ++q) {
        if (i0 + q <= NB) lofs[i0 + q] = run;
        run += v[q];
    }
    __syncthreads();
    for (int b = tid; b < NB; b += 256) {
        int c = hist[b];
        gbase[b] = c ? atomicAdd(&cursor[b], c) : 0;
    }
    __syncthreads();
    for (int i = 0; i < PA_IT; ++i) {
        int e = base + i * 256 + tid;
        if (e < NE) {
            int rd = rank[edst[e]], rs = rank[esrc[e]];
            int b = rd >> BSH;
            int p = lofs[b] + atomicAdd(&cnt2[b], 1);
            stage[p] = make_int2(rs, rd);
            sbid[p] = (unsigned short)b;
        }
    }
    __syncthreads();
    int nval = min(PA_EDGES, NE - base);
    for (int k = tid; k < nval; k += 256) {
        int b = sbid[k];
        ebuf[gbase[b] + (k - lofs[b])] = stage[k];
    }
}

// ---------------- pass B: per-bucket final scatter; offs0 (new-id CSR); csrc fused ----------------
__global__ __launch_bounds__(256)
void passB_k(const int2* __restrict__ ebuf, const int* __restrict__ bbase,
             const int* __restrict__ jsrcP,
             int* __restrict__ offs0, int* __restrict__ srcs0, int* __restrict__ csrc0) {
    __shared__ int cnt[BSZ];
    __shared__ int pos[BSZ];
    __shared__ int ws[4];
    int b = blockIdx.x, tid = threadIdx.x, lane = tid & 63, w = tid >> 6;
    int d0 = b << BSH;
    int range = min(BSZ, NN - d0);
    if (tid < BSZ) cnt[tid] = 0;
    __syncthreads();
    int r0 = bbase[b], r1 = bbase[b + 1];
    for (int k = r0 + tid; k < r1; k += 256) atomicAdd(&cnt[ebuf[k].y & (BSZ - 1)], 1);
    __syncthreads();
    int v = (tid < BSZ) ? cnt[tid] : 0;
    int sc = v;
    #pragma unroll
    for (int off = 1; off < 64; off <<= 1) { int o = __shfl_up(sc, off); if (lane >= off) sc += o; }
    if (lane == 63) ws[w] = sc;
    __syncthreads();
    int wb = 0;
    for (int q = 0; q < w; ++q) wb += ws[q];
    int rel = wb + sc - v;                        // exclusive per-dst prefix
    if (tid < range) offs0[d0 + tid] = r0 + rel;
    if (tid == 0) offs0[min(d0 + BSZ, NN)] = r1;  // benign duplicate of next base
    if (tid < BSZ) pos[tid] = r0 + rel;
    __syncthreads();
    for (int k = r0 + tid; k < r1; k += 256) {
        int2 pr = ebuf[k];
        int di = pr.y & (BSZ - 1);
        int p = atomicAdd(&pos[di], 1);
        int rs = pr.x;
        srcs0[p] = rs;
        csrc0[p] = jsrcP[rs];
    }
}

// ---------------- level-2 adjacency list: LDS bitmap -> compact per-d2 src list ----------------
__global__ __launch_bounds__(256)
void masklist_k(const int* __restrict__ offsN, const int* __restrict__ offs0,
                const int* __restrict__ csrc0, const int* __restrict__ oclist,
                int* __restrict__ l2off, int* __restrict__ l2num,
                int* __restrict__ l2src, int* __restrict__ l2cursor) {
    __shared__ unsigned long long words[64];
    __shared__ int wpre[64];
    __shared__ int sbase;
    int d2 = blockIdx.x, tid = threadIdx.x;
    if (tid < 64) words[tid] = 0;
    __syncthreads();
    int x2 = d2 >> 8, y2 = (d2 >> 4) & 15, z2 = d2 & 15;
    int child = tid >> 2, sub = tid & 3;         // 64 children x 4 threads
    int i = child >> 4, jj = (child >> 2) & 3, k = child & 3;
    int d1 = ((x2 * 4 + i) * 64 + (y2 * 4 + jj)) * 64 + (z2 * 4 + k);
    int e0 = offs0[offsN[d1]], e1 = offs0[offsN[d1 + 1]];
    for (int t = e0 + sub; t < e1; t += 4) {
        int c = oclist[csrc0[t]];
        int s2 = parent2(c);
        atomicOr(&words[s2 >> 6], 1ull << (s2 & 63));
    }
    __syncthreads();
    if (tid < 64) {                                // wave 0 only
        int pc = __popcll(words[tid]);
        int sc = pc;
        #pragma unroll
        for (int off = 1; off < 64; off <<= 1) {
            int o = __shfl_up(sc, off);
            if (tid >= off) sc += o;
        }
        wpre[tid] = sc - pc;                       // exclusive prefix
        if (tid == 63) {
            l2num[d2] = sc;
            int bb = atomicAdd(l2cursor, sc);
            l2off[d2] = bb;
            sbase = bb;
        }
    }
    __syncthreads();
    if (tid < 64) {
        unsigned long long wb = words[tid];
        int p = sbase + wpre[tid];
        while (wb) {
            int b = __builtin_ctzll(wb);
            wb &= wb - 1;
            l2src[p++] = (tid << 6) | b;
        }
    }
}

// ---------------- level 0: h = f @ W_f + pos @ W_p (new-id space) ----------------
template<int CI, int CO>
__global__ __launch_bounds__(256)
void xform0_k(const float* __restrict__ pnodes, const float* __restrict__ f,
              const float* __restrict__ W, float* __restrict__ h) {
    __shared__ float sW[(CI + 3) * CO];
    for (int i = threadIdx.x; i < (CI + 3) * CO; i += 256) sW[i] = W[i];
    __syncthreads();
    int gid = blockIdx.x * 256 + threadIdx.x;
    int i = gid / CO, ch = gid - i * CO;
    if (i >= NN) return;
    float s = pnodes[3 * i] * sW[CI * CO + ch] + pnodes[3 * i + 1] * sW[(CI + 1) * CO + ch]
            + pnodes[3 * i + 2] * sW[(CI + 2) * CO + ch];
    #pragma unroll
    for (int k = 0; k < CI; ++k) s += f[(size_t)i * CI + k] * sW[k * CO + ch];
    h[(size_t)i * CO + ch] = s;
}

template<int CO>
__global__ __launch_bounds__(256)
void gatherL0_k(const float* __restrict__ pnodes, const float* __restrict__ h,
                const float* __restrict__ Wpos, const int* __restrict__ offs,
                const int* __restrict__ srcs, float* __restrict__ out) {
    __shared__ float sW[3 * CO];
    for (int i = threadIdx.x; i < 3 * CO; i += 256) sW[i] = Wpos[i];
    __syncthreads();
    int gid = blockIdx.x * 256 + threadIdx.x;
    int d = gid / CO, ch = gid - d * CO;
    if (d >= NN) return;
    float c = pnodes[3 * d] * sW[ch] + pnodes[3 * d + 1] * sW[CO + ch] + pnodes[3 * d + 2] * sW[2 * CO + ch];
    float m0 = c, m1 = c, m2 = c, m3 = c;        // no self-loop at level 0; empty -> 0
    int e0 = offs[d], e1 = offs[d + 1];
    int t = e0;
    for (; t + 4 <= e1; t += 4) {
        int s0 = srcs[t], s1 = srcs[t + 1], s2 = srcs[t + 2], s3 = srcs[t + 3];
        m0 = fmaxf(m0, h[(size_t)s0 * CO + ch]);
        m1 = fmaxf(m1, h[(size_t)s1 * CO + ch]);
        m2 = fmaxf(m2, h[(size_t)s2 * CO + ch]);
        m3 = fmaxf(m3, h[(size_t)s3 * CO + ch]);
    }
    for (; t < e1; ++t) m0 = fmaxf(m0, h[(size_t)srcs[t] * CO + ch]);
    float m = fmaxf(fmaxf(m0, m1), fmaxf(m2, m3));
    out[(size_t)d * CO + ch] = m - c;
}

// ---------------- level 1: fused pool(16ch) + xform W3 -> Hc ----------------
__global__ __launch_bounds__(256)
void pxformL1_k(const float* __restrict__ f2, const int* __restrict__ offsN,
                const int* __restrict__ oclist, const int* __restrict__ ocount,
                const float* __restrict__ W3, float* __restrict__ h) {
    __shared__ float sW[19 * 32];
    __shared__ float nf[8][16];
    for (int i = threadIdx.x; i < 19 * 32; i += 256) sW[i] = W3[i];
    int gid = blockIdx.x * 256 + threadIdx.x;
    int j = gid >> 5, ch = gid & 31;
    int lj = threadIdx.x >> 5;                   // 8 js per block
    bool valid = j < *ocount;
    int d = valid ? oclist[j] : 0;
    if (valid && ch < 16) {
        float m = 0.f;                           // f2 >= 0 (post-relu)
        int n0 = offsN[d], n1 = offsN[d + 1];
        for (int n = n0; n < n1; ++n) m = fmaxf(m, f2[(size_t)n * 16 + ch]);
        nf[lj][ch] = m;
    }
    __syncthreads();
    if (!valid) return;
    float px = (float)(d >> 12), py = (float)((d >> 6) & 63), pz = (float)(d & 63);
    float s = px * sW[16 * 32 + ch] + py * sW[17 * 32 + ch] + pz * sW[18 * 32 + ch];
    #pragma unroll
    for (int k = 0; k < 16; ++k) s += nf[lj][k] * sW[k * 32 + ch];
    h[(size_t)j * 32 + ch] = s;
}

template<int CI>
__global__ __launch_bounds__(256)
void xformL1_k(const float* __restrict__ fin, const float* __restrict__ W,
               const int* __restrict__ oclist, const int* __restrict__ ocount,
               float* __restrict__ h) {
    __shared__ float sW[(CI + 3) * 32];
    for (int i = threadIdx.x; i < (CI + 3) * 32; i += 256) sW[i] = W[i];
    __syncthreads();
    int gid = blockIdx.x * 256 + threadIdx.x;
    int j = gid >> 5, ch = gid & 31;
    if (j >= *ocount) return;
    int d = oclist[j];
    const float* f = fin + (size_t)j * CI;
    float px = (float)(d >> 12), py = (float)((d >> 6) & 63), pz = (float)(d & 63);
    float s = px * sW[CI * 32 + ch] + py * sW[(CI + 1) * 32 + ch] + pz * sW[(CI + 2) * 32 + ch];
    #pragma unroll
    for (int k = 0; k < CI; ++k) s += f[k] * sW[k * 32 + ch];
    h[(size_t)j * 32 + ch] = s;
}

// flat gather over occupied dst cells: one contiguous edge range per cell
__global__ __launch_bounds__(256)
void gatherL1_k(const float* __restrict__ h, const float* __restrict__ Wpos,
                const int* __restrict__ offsN, const int* __restrict__ offs0,
                const int* __restrict__ csrc0,
                const int* __restrict__ oclist, const int* __restrict__ ocount,
                float* __restrict__ g) {
    __shared__ float sW[96];
    for (int i = threadIdx.x; i < 96; i += 256) sW[i] = Wpos[i];
    __syncthreads();
    int gid = blockIdx.x * 256 + threadIdx.x;
    int j = gid >> 5, ch = gid & 31;
    if (j >= *ocount) return;
    int d = oclist[j];
    float px = (float)(d >> 12), py = (float)((d >> 6) & 63), pz = (float)(d & 63);
    float c = px * sW[ch] + py * sW[32 + ch] + pz * sW[64 + ch];
    float self = h[(size_t)j * 32 + ch];
    float m0 = fmaxf(c, self), m1 = m0, m2 = m0, m3 = m0;   // self-loop
    int e0 = offs0[offsN[d]], e1 = offs0[offsN[d + 1]];
    int t = e0;
    for (; t + 4 <= e1; t += 4) {
        int s0 = csrc0[t], s1 = csrc0[t + 1], s2 = csrc0[t + 2], s3 = csrc0[t + 3];
        m0 = fmaxf(m0, h[(size_t)s0 * 32 + ch]);
        m1 = fmaxf(m1, h[(size_t)s1 * 32 + ch]);
        m2 = fmaxf(m2, h[(size_t)s2 * 32 + ch]);
        m3 = fmaxf(m3, h[(size_t)s3 * 32 + ch]);
    }
    for (; t < e1; ++t) m0 = fmaxf(m0, h[(size_t)csrc0[t] * 32 + ch]);
    float m = fmaxf(fmaxf(m0, m1), fmaxf(m2, m3));
    g[(size_t)j * 32 + ch] = m - c;
}

// ---------------- level 2 (block per 16^3 cell) ----------------
__global__ __launch_bounds__(256)
void pool2x_k(const float* __restrict__ Gc, const int* __restrict__ jmap,
              const float* __restrict__ W5, float* __restrict__ h5) {
    __shared__ float part[8][32];
    __shared__ float nf2row[32];
    int d2 = blockIdx.x, tid = threadIdx.x;
    int x2 = d2 >> 8, y2 = (d2 >> 4) & 15, z2 = d2 & 15;
    int ch = tid & 31, grp = tid >> 5;                 // 8 grps x 8 children
    float m = 0.f;
    #pragma unroll
    for (int cc = 0; cc < 8; ++cc) {
        int child = grp * 8 + cc;
        int i = child >> 4, jj = (child >> 2) & 3, k = child & 3;
        int d1 = ((x2 * 4 + i) * 64 + (y2 * 4 + jj)) * 64 + (z2 * 4 + k);
        int cj = jmap[d1];
        if (cj >= 0) m = fmaxf(m, Gc[(size_t)cj * 32 + ch]);
    }
    part[grp][ch] = m;
    __syncthreads();
    if (tid < 32) {
        float mm = part[0][tid];
        #pragma unroll
        for (int g = 1; g < 8; ++g) mm = fmaxf(mm, part[g][tid]);
        nf2row[tid] = mm;
    }
    __syncthreads();
    if (tid < 64) {
        float s = x2 * W5[32 * 64 + tid] + y2 * W5[33 * 64 + tid] + z2 * W5[34 * 64 + tid];
        #pragma unroll
        for (int k = 0; k < 32; ++k) s += nf2row[k] * W5[k * 64 + tid];
        h5[(size_t)d2 * 64 + tid] = s;
    }
}

// level-2 gconv via flat adjacency list (+ optional fused next xform). One block per d2.
template<bool FUSE, bool WRITE_G>
__global__ __launch_bounds__(256)
void gconvL2_k(const float* __restrict__ h, const float* __restrict__ Wpos,
               const int* __restrict__ l2off, const int* __restrict__ l2num,
               const int* __restrict__ l2src,
               const float* __restrict__ Wn,           // (64+3)x64, if FUSE
               float* __restrict__ gout, float* __restrict__ hnext) {
    __shared__ float red[4][64];
    __shared__ float grow[64];
    int d2 = blockIdx.x, tid = threadIdx.x;
    int x2 = d2 >> 8, y2 = (d2 >> 4) & 15, z2 = d2 & 15;
    int ch = tid & 63, grp = tid >> 6;                 // 4 waves split the list
    int n0 = l2off[d2], num = l2num[d2];
    int per = (num + 3) >> 2;
    int s = n0 + grp * per;
    int e = min(n0 + num, s + per);
    float m0 = -1e30f, m1 = -1e30f, m2 = -1e30f, m3 = -1e30f;
    int t = s;
    for (; t + 4 <= e; t += 4) {
        int s0 = l2src[t], s1 = l2src[t + 1], s2 = l2src[t + 2], s3 = l2src[t + 3];
        m0 = fmaxf(m0, h[(size_t)s0 * 64 + ch]);
        m1 = fmaxf(m1, h[(size_t)s1 * 64 + ch]);
        m2 = fmaxf(m2, h[(size_t)s2 * 64 + ch]);
        m3 = fmaxf(m3, h[(size_t)s3 * 64 + ch]);
    }
    for (; t < e; ++t) m0 = fmaxf(m0, h[(size_t)l2src[t] * 64 + ch]);
    red[grp][ch] = fmaxf(fmaxf(m0, m1), fmaxf(m2, m3));
    __syncthreads();
    if (grp == 0) {
        float mm = fmaxf(fmaxf(red[0][ch], red[1][ch]), fmaxf(red[2][ch], red[3][ch]));
        float c = x2 * Wpos[ch] + y2 * Wpos[64 + ch] + z2 * Wpos[128 + ch];
        mm = fmaxf(mm, fmaxf(c, h[(size_t)d2 * 64 + ch]));   // self-loop + empty
        float g = mm - c;
        if (WRITE_G) gout[(size_t)d2 * 64 + ch] = g;
        if (FUSE) grow[ch] = g;
    }
    if (FUSE) {
        __syncthreads();
        if (tid < 64) {
            float s2v = x2 * Wn[64 * 64 + tid] + y2 * Wn[65 * 64 + tid] + z2 * Wn[66 * 64 + tid];
            #pragma unroll
            for (int k = 0; k < 64; ++k) s2v += grow[k] * Wn[k * 64 + tid];
            hnext[(size_t)d2 * 64 + tid] = s2v;
        }
    }
}

// ---------------- output pool + linear ----------------
__global__ __launch_bounds__(256)
void outpool_k(const float* __restrict__ g7, float* __restrict__ xo) {
    int gid = blockIdx.x * 256 + threadIdx.x;
    if (gid >= 64 * 64) return;
    int oc = gid >> 6, ch = gid & 63;
    int cx = oc >> 4, cy = (oc >> 2) & 3, cz = oc & 3;
    float m = 0.f;
    for (int tc = 0; tc < 64; ++tc) {
        int i = tc >> 4, j = (tc >> 2) & 3, k = tc & 3;
        int d2 = ((cx * 4 + i) * 16 + (cy * 4 + j)) * 16 + (cz * 4 + k);
        m = fmaxf(m, g7[(size_t)d2 * 64 + ch]);
    }
    xo[(size_t)oc * 64 + ch] = m;
}

__global__ __launch_bounds__(64)
void linear_k(const float* __restrict__ xo, const float* __restrict__ Wl,
              const float* __restrict__ bl, float* __restrict__ out) {
    int j = blockIdx.x;
    float s = 0.f;
    for (int i = threadIdx.x; i < 4096; i += 64) s += xo[i] * Wl[(size_t)i * 100 + j];
    #pragma unroll
    for (int off = 32; off; off >>= 1) s += __shfl_down(s, off);
    if (threadIdx.x == 0) out[j] = s + bl[j];
}

extern "C" void kernel_launch(void* const* d_in, const int* in_sizes, int n_in,
                              void* d_out, int out_size, void* d_ws, size_t ws_size,
                              hipStream_t stream) {
    (void)in_sizes; (void)n_in; (void)out_size;
    const float* nodes = (const float*)d_in[0];
    const float* feats = (const float*)d_in[1];
    const int*   edges = (const int*)d_in[2];
    const int*   esrc  = edges;
    const int*   edst  = edges + NE;
    const float* W1 = (const float*)d_in[3];
    const float* W2 = (const float*)d_in[4];
    const float* W3 = (const float*)d_in[5];
    const float* W4 = (const float*)d_in[6];
    const float* W5 = (const float*)d_in[7];
    const float* W6 = (const float*)d_in[8];
    const float* W7 = (const float*)d_in[9];
    const float* Wl = (const float*)d_in[10];
    const float* bl = (const float*)d_in[11];
    float* out = (float*)d_out;

    char* ws = (char*)d_ws;
    size_t off = 0;
    auto alloc = [&](size_t bytes) { void* p = ws + off; off = (off + bytes + 255) & ~(size_t)255; return p; };
    // zero region: cntN + ocount + btot + l2cursor (one memset)
    int*   cntN    = (int*)alloc((size_t)C1 * 4);
    int*   ocount  = (int*)alloc(4);
    int*   btot    = (int*)alloc((size_t)NB * 4);
    int*   l2cursor= (int*)alloc(4);
    size_t zero_bytes = off;
    int*   bsum   = (int*)alloc(260 * 4);
    int*   bbase  = (int*)alloc((size_t)(NB + 1) * 4);
    int*   cursor = (int*)alloc((size_t)NB * 4);
    int*   cid    = (int*)alloc((size_t)NN * 4);
    int*   rank   = (int*)alloc((size_t)NN * 4);
    int*   nidx   = (int*)alloc((size_t)NN * 4);
    int*   offsN  = (int*)alloc((size_t)(C1 + 1) * 4);
    int*   offs0  = (int*)alloc((size_t)(NN + 1) * 4);
    int*   srcs0  = (int*)alloc((size_t)NE * 4);
    int*   csrc0  = (int*)alloc((size_t)NE * 4);
    int2*  ebuf   = (int2*)alloc((size_t)NE * 8);
    int*   oclist = (int*)alloc((size_t)NN * 4);
    int*   jmap   = (int*)alloc((size_t)C1 * 4);
    int*   cidP   = (int*)alloc((size_t)NN * 4);
    int*   jsrcP  = (int*)alloc((size_t)NN * 4);
    int*   l2off  = (int*)alloc((size_t)C2 * 4);
    int*   l2num  = (int*)alloc((size_t)C2 * 4);
    int*   l2srcA = (int*)alloc((size_t)NE * 4);
    float* pnodes = (float*)alloc((size_t)NN * 3 * 4);
    float* pfeat  = (float*)alloc((size_t)NN * 4);
    float* A      = (float*)alloc((size_t)NN * 48 * 4);   // h1,f1,h2,f2
    float* Hc     = (float*)alloc((size_t)NN * 32 * 4);
    float* Gc     = (float*)alloc((size_t)NN * 32 * 4);
    float* h5     = (float*)alloc((size_t)C2 * 64 * 4);
    float* h6     = (float*)alloc((size_t)C2 * 64 * 4);
    float* h7     = (float*)alloc((size_t)C2 * 64 * 4);
    float* g7     = (float*)alloc((size_t)C2 * 64 * 4);
    float* xo     = (float*)alloc((size_t)64 * 64 * 4);
    if (ws_size < off) return;

    float* h1 = A;                      // [NN][8]
    float* f1 = A + (size_t)NN * 8;
    float* h2 = A + (size_t)NN * 16;    // [NN][16]
    float* f2 = A + (size_t)NN * 32;

    hipMemsetAsync(cntN, 0, zero_bytes, stream);

    auto gr = [](long long n) { return (int)((n + 255) / 256); };
    const int nbC1 = (C1 + 2047) / 2048;   // 128
    const int gPA  = (NE + PA_EDGES - 1) / PA_EDGES;  // 196

    // ---- connectivity build (new-id space) ----
    cidhist_k<<<gr(NN), 256, 0, stream>>>(nodes, cid, cntN);
    oclist_k<<<C1 / 256, 256, 0, stream>>>(cntN, oclist, jmap, ocount);
    scan1_k<<<nbC1, 256, 0, stream>>>(cntN, C1, offsN, bsum);
    scan2_k<<<1, 256, 0, stream>>>(bsum, nbC1);
    scan3_k<<<gr(C1 + 1), 256, 0, stream>>>(offsN, C1, bsum, nbC1);
    nscatter_k<<<gr(NN), 256, 0, stream>>>(cid, offsN, cntN, rank, nidx);
    permute_k<<<gr(NN), 256, 0, stream>>>(nidx, nodes, feats, cid, jmap, pnodes, pfeat, cidP, jsrcP);
    bhist_k<<<gPA, 256, 0, stream>>>(edst, rank, btot);
    scanB_k<<<1, 256, 0, stream>>>(btot, bbase, cursor);
    passA_k<<<gPA, 256, 0, stream>>>(esrc, edst, rank, cursor, ebuf);
    passB_k<<<NB, 256, 0, stream>>>(ebuf, bbase, jsrcP, offs0, srcs0, csrc0);
    masklist_k<<<C2, 256, 0, stream>>>(offsN, offs0, csrc0, oclist, l2off, l2num, l2srcA, l2cursor);

    // ---- level 0 (new-id space) ----
    xform0_k<1, 8><<<gr((long long)NN * 8), 256, 0, stream>>>(pnodes, pfeat, W1, h1);
    gatherL0_k<8><<<gr((long long)NN * 8), 256, 0, stream>>>(pnodes, h1, W1 + 1 * 8, offs0, srcs0, f1);
    xform0_k<8, 16><<<gr((long long)NN * 16), 256, 0, stream>>>(pnodes, f1, W2, h2);
    gatherL0_k<16><<<gr((long long)NN * 16), 256, 0, stream>>>(pnodes, h2, W2 + 8 * 16, offs0, srcs0, f2);

    // ---- level 1 (compact occupied cells, flat edge ranges) ----
    pxformL1_k<<<gr((long long)NN * 32), 256, 0, stream>>>(f2, offsN, oclist, ocount, W3, Hc);
    gatherL1_k<<<gr((long long)NN * 32), 256, 0, stream>>>(Hc, W3 + 16 * 32, offsN, offs0, csrc0, oclist, ocount, Gc);
    xformL1_k<32><<<gr((long long)NN * 32), 256, 0, stream>>>(Gc, W4, oclist, ocount, Hc);
    gatherL1_k<<<gr((long long)NN * 32), 256, 0, stream>>>(Hc, W4 + 32 * 32, offsN, offs0, csrc0, oclist, ocount, Gc);

    // ---- level 2 (block per 16^3 cell, list-driven, fused) ----
    pool2x_k<<<C2, 256, 0, stream>>>(Gc, jmap, W5, h5);
    gconvL2_k<true,  false><<<C2, 256, 0, stream>>>(h5, W5 + 32 * 64, l2off, l2num, l2srcA, W6, nullptr, h6);
    gconvL2_k<true,  false><<<C2, 256, 0, stream>>>(h6, W6 + 64 * 64, l2off, l2num, l2srcA, W7, nullptr, h7);
    gconvL2_k<false, true ><<<C2, 256, 0, stream>>>(h7, W7 + 64 * 64, l2off, l2num, l2srcA, nullptr, g7, nullptr);

    outpool_k<<<16, 256, 0, stream>>>(g7, xo);
    linear_k<<<100, 64, 0, stream>>>(xo, Wl, bl, out);
}

// Round 11
// 543.810 us; speedup vs baseline: 44.5676x; 1.0300x over previous
//
#include <hip/hip_runtime.h>

#define NN 100000      // nodes
#define NE 1600000     // edges
#define C1 262144      // 64^3 cells
#define C2 4096        // 16^3 cells
#define BSH 7          // bucket shift (128 new-ids per bucket)
#define BSZ 128
#define NB 782         // ceil(NN/128)
#define PA_EDGES 8192
#define PA_IT (PA_EDGES / 256)
#define JMASK 0xFFFFF  // low 20 bits: compact j; bits 20..31: parent2(src cell)

__device__ __forceinline__ int parent2(int c) {   // 64^3 cell id -> 16^3 cell id
    return ((c >> 14) << 8) | (((c >> 8) & 15) << 4) | ((c >> 2) & 15);
}

// ---------------- cid of each node + node-per-cell histogram ----------------
__global__ __launch_bounds__(256)
void cidhist_k(const float* __restrict__ nodes, int* __restrict__ cid,
               int* __restrict__ cntN) {
    int i = blockIdx.x * 256 + threadIdx.x;
    if (i >= NN) return;
    int cx = min(max((int)floorf(nodes[3 * i]     * 0.25f), 0), 63);
    int cy = min(max((int)floorf(nodes[3 * i + 1] * 0.25f), 0), 63);
    int cz = min(max((int)floorf(nodes[3 * i + 2] * 0.25f), 0), 63);
    int c = (cx * 64 + cy) * 64 + cz;
    cid[i] = c;
    atomicAdd(&cntN[c], 1);
}

// ---------------- occupied-cell list + cell->compact-index map ----------------
__global__ __launch_bounds__(256)
void oclist_k(const int* __restrict__ cntN, int* __restrict__ oclist,
              int* __restrict__ jmap, int* __restrict__ ocount) {
    int c = blockIdx.x * 256 + threadIdx.x;     // grid covers C1 exactly
    bool occ = cntN[c] > 0;
    unsigned long long b = __ballot(occ);
    int lane = threadIdx.x & 63;
    int cnt = __popcll(b);
    int base = 0;
    if (cnt) {
        if (lane == 0) base = atomicAdd(ocount, cnt);
        base = __shfl(base, 0);
    }
    int pre = __popcll(b & ((1ull << lane) - 1));
    int j = occ ? base + pre : -1;
    jmap[c] = j;
    if (occ) oclist[j] = c;
}

// ---------------- cell scan (offsN over C1): 2048/block ----------------
__global__ __launch_bounds__(256)
void scan1_k(const int* __restrict__ cnt, int n, int* __restrict__ offs,
             int* __restrict__ bsum) {
    __shared__ int ws[4];
    int t = threadIdx.x, lane = t & 63, w = t >> 6;
    int base = blockIdx.x * 2048 + t * 8;
    int v[8]; int s = 0;
    #pragma unroll
    for (int i = 0; i < 8; ++i) { v[i] = (base + i < n) ? cnt[base + i] : 0; s += v[i]; }
    int sc = s;
    #pragma unroll
    for (int off = 1; off < 64; off <<= 1) { int o = __shfl_up(sc, off); if (lane >= off) sc += o; }
    if (lane == 63) ws[w] = sc;
    __syncthreads();
    int wbase = 0;
    for (int i = 0; i < w; ++i) wbase += ws[i];
    int run = wbase + sc - s;
    #pragma unroll
    for (int i = 0; i < 8; ++i) { if (base + i < n) offs[base + i] = run; run += v[i]; }
    if (t == 255) bsum[blockIdx.x] = wbase + sc;
}

__global__ __launch_bounds__(256)
void scan2_k(int* __restrict__ bsum, int nb) {   // one block, nb <= 256
    __shared__ int ws[4];
    int t = threadIdx.x, lane = t & 63, w = t >> 6;
    int v = (t < nb) ? bsum[t] : 0;
    int sc = v;
    #pragma unroll
    for (int off = 1; off < 64; off <<= 1) { int o = __shfl_up(sc, off); if (lane >= off) sc += o; }
    if (lane == 63) ws[w] = sc;
    __syncthreads();
    int wbase = 0;
    for (int i = 0; i < w; ++i) wbase += ws[i];
    if (t < nb) bsum[t] = wbase + sc - v;
    if (t == 255) bsum[nb] = ws[0] + ws[1] + ws[2] + ws[3];
}

__global__ __launch_bounds__(256)
void scan3_k(int* __restrict__ offs, int n, const int* __restrict__ bsum, int nb) {
    int i = blockIdx.x * 256 + threadIdx.x;
    if (i < n) offs[i] += bsum[i >> 11];
    else if (i == n) offs[n] = bsum[nb];
}

// ---------------- node scatter: rank (new id) + nidx (old id by new id) ----------------
__global__ __launch_bounds__(256)
void nscatter_k(const int* __restrict__ cid, const int* __restrict__ offsN,
                int* __restrict__ cntN, int* __restrict__ rank, int* __restrict__ nidx) {
    int i = blockIdx.x * 256 + threadIdx.x;
    if (i >= NN) return;
    int c = cid[i];
    int pos = offsN[c] + atomicAdd(&cntN[c], -1) - 1;
    rank[i] = pos;
    nidx[pos] = i;
}

// ---------------- permute node data into new-id order ----------------
__global__ __launch_bounds__(256)
void permute_k(const int* __restrict__ nidx, const float* __restrict__ nodes,
               const float* __restrict__ feats, const int* __restrict__ cid,
               const int* __restrict__ jmap,
               float* __restrict__ pnodes, float* __restrict__ pfeat,
               int* __restrict__ jsrcP) {
    int d = blockIdx.x * 256 + threadIdx.x;
    if (d >= NN) return;
    int i = nidx[d];
    pnodes[3 * d]     = nodes[3 * i];
    pnodes[3 * d + 1] = nodes[3 * i + 1];
    pnodes[3 * d + 2] = nodes[3 * i + 2];
    pfeat[d] = feats[i];
    int c = cid[i];
    unsigned packed = (unsigned)jmap[c] | ((unsigned)parent2(c) << 20);  // j | s2<<20
    jsrcP[d] = (int)packed;
}

// ---------------- bucket histogram over rank[dst] (LDS pre-aggregated) ----------------
__global__ __launch_bounds__(256)
void bhist_k(const int* __restrict__ edst, const int* __restrict__ rank,
             int* __restrict__ btot) {
    __shared__ int h[NB];
    int tid = threadIdx.x;
    for (int i = tid; i < NB; i += 256) h[i] = 0;
    __syncthreads();
    int base = blockIdx.x * PA_EDGES;
    for (int i = 0; i < PA_IT; ++i) {
        int e = base + i * 256 + tid;
        if (e < NE) atomicAdd(&h[rank[edst[e]] >> BSH], 1);
    }
    __syncthreads();
    for (int i = tid; i < NB; i += 256) if (h[i]) atomicAdd(&btot[i], h[i]);
}

// one block: exclusive scan of NB (<=1024) bucket totals -> bbase[NB+1]; copy to cursor
__global__ __launch_bounds__(256)
void scanB_k(const int* __restrict__ btot, int* __restrict__ bbase,
             int* __restrict__ cursor) {
    __shared__ int ws[4];
    int t = threadIdx.x, lane = t & 63, w = t >> 6;
    int i0 = 4 * t;
    int v[4]; int s = 0;
    #pragma unroll
    for (int q = 0; q < 4; ++q) { v[q] = (i0 + q < NB) ? btot[i0 + q] : 0; s += v[q]; }
    int sc = s;
    #pragma unroll
    for (int off = 1; off < 64; off <<= 1) { int o = __shfl_up(sc, off); if (lane >= off) sc += o; }
    if (lane == 63) ws[w] = sc;
    __syncthreads();
    int wb = 0;
    for (int q = 0; q < w; ++q) wb += ws[q];
    int run = wb + sc - s;
    #pragma unroll
    for (int q = 0; q < 4; ++q) {
        if (i0 + q <= NB) { bbase[i0 + q] = run; if (i0 + q < NB) cursor[i0 + q] = run; }
        run += v[q];
    }
}

// ---------------- pass A: partition (rank_src, rank_dst) pairs by dst bucket ----------------
__global__ __launch_bounds__(256)
void passA_k(const int* __restrict__ esrc, const int* __restrict__ edst,
             const int* __restrict__ rank, int* __restrict__ cursor,
             int2* __restrict__ ebuf) {
    __shared__ int hist[NB];
    __shared__ int lofs[NB + 1];
    __shared__ int gbase[NB];
    __shared__ int cnt2[NB];
    __shared__ int2 stage[PA_EDGES];             // 64KB
    __shared__ unsigned short sbid[PA_EDGES];    // 16KB
    __shared__ int ws[4];
    int tid = threadIdx.x, lane = tid & 63, w = tid >> 6;
    for (int i = tid; i < NB; i += 256) { hist[i] = 0; cnt2[i] = 0; }
    __syncthreads();
    int base = blockIdx.x * PA_EDGES;
    for (int i = 0; i < PA_IT; ++i) {
        int e = base + i * 256 + tid;
        if (e < NE) atomicAdd(&hist[rank[edst[e]] >> BSH], 1);
    }
    __syncthreads();
    // exclusive scan hist -> lofs (4 per thread)
    int i0 = 4 * tid;
    int v[4]; int s = 0;
    #pragma unroll
    for (int q = 0; q < 4; ++q) { v[q] = (i0 + q < NB) ? hist[i0 + q] : 0; s += v[q]; }
    int sc = s;
    #pragma unroll
    for (int off = 1; off < 64; off <<= 1) { int o = __shfl_up(sc, off); if (lane >= off) sc += o; }
    if (lane == 63) ws[w] = sc;
    __syncthreads();
    int wb = 0;
    for (int q = 0; q < w; ++q) wb += ws[q];
    int run = wb + sc - s;
    #pragma unroll
    for (int q = 0; q < 4; ++q) {
        if (i0 + q <= NB) lofs[i0 + q] = run;
        run += v[q];
    }
    __syncthreads();
    for (int b = tid; b < NB; b += 256) {
        int c = hist[b];
        gbase[b] = c ? atomicAdd(&cursor[b], c) : 0;
    }
    __syncthreads();
    for (int i = 0; i < PA_IT; ++i) {
        int e = base + i * 256 + tid;
        if (e < NE) {
            int rd = rank[edst[e]], rs = rank[esrc[e]];
            int b = rd >> BSH;
            int p = lofs[b] + atomicAdd(&cnt2[b], 1);
            stage[p] = make_int2(rs, rd);
            sbid[p] = (unsigned short)b;
        }
    }
    __syncthreads();
    int nval = min(PA_EDGES, NE - base);
    for (int k = tid; k < nval; k += 256) {
        int b = sbid[k];
        ebuf[gbase[b] + (k - lofs[b])] = stage[k];
    }
}

// ---------------- pass B: per-bucket final scatter; offs0 (new-id CSR); csrc fused ----------------
__global__ __launch_bounds__(256)
void passB_k(const int2* __restrict__ ebuf, const int* __restrict__ bbase,
             const int* __restrict__ jsrcP,
             int* __restrict__ offs0, int* __restrict__ srcs0, int* __restrict__ csrc0) {
    __shared__ int cnt[BSZ];
    __shared__ int pos[BSZ];
    __shared__ int ws[4];
    int b = blockIdx.x, tid = threadIdx.x, lane = tid & 63, w = tid >> 6;
    int d0 = b << BSH;
    int range = min(BSZ, NN - d0);
    if (tid < BSZ) cnt[tid] = 0;
    __syncthreads();
    int r0 = bbase[b], r1 = bbase[b + 1];
    for (int k = r0 + tid; k < r1; k += 256) atomicAdd(&cnt[ebuf[k].y & (BSZ - 1)], 1);
    __syncthreads();
    int v = (tid < BSZ) ? cnt[tid] : 0;
    int sc = v;
    #pragma unroll
    for (int off = 1; off < 64; off <<= 1) { int o = __shfl_up(sc, off); if (lane >= off) sc += o; }
    if (lane == 63) ws[w] = sc;
    __syncthreads();
    int wb = 0;
    for (int q = 0; q < w; ++q) wb += ws[q];
    int rel = wb + sc - v;                        // exclusive per-dst prefix
    if (tid < range) offs0[d0 + tid] = r0 + rel;
    if (tid == 0) offs0[min(d0 + BSZ, NN)] = r1;  // benign duplicate of next base
    if (tid < BSZ) pos[tid] = r0 + rel;
    __syncthreads();
    for (int k = r0 + tid; k < r1; k += 256) {
        int2 pr = ebuf[k];
        int di = pr.y & (BSZ - 1);
        int p = atomicAdd(&pos[di], 1);
        int rs = pr.x;
        srcs0[p] = rs;
        csrc0[p] = jsrcP[rs];                     // packed j | s2<<20
    }
}

// ---------------- level-2 adjacency list: LDS bitmap -> compact per-d2 src list ----------------
__global__ __launch_bounds__(256)
void masklist_k(const int* __restrict__ offsN, const int* __restrict__ offs0,
                const int* __restrict__ csrc0,
                int* __restrict__ l2off, int* __restrict__ l2num,
                int* __restrict__ l2src, int* __restrict__ l2cursor) {
    __shared__ unsigned long long words[64];
    __shared__ int wpre[64];
    __shared__ int sbase;
    int d2 = blockIdx.x, tid = threadIdx.x;
    if (tid < 64) words[tid] = 0;
    __syncthreads();
    int x2 = d2 >> 8, y2 = (d2 >> 4) & 15, z2 = d2 & 15;
    int child = tid >> 2, sub = tid & 3;         // 64 children x 4 threads
    int i = child >> 4, jj = (child >> 2) & 3, k = child & 3;
    int d1 = ((x2 * 4 + i) * 64 + (y2 * 4 + jj)) * 64 + (z2 * 4 + k);
    int e0 = offs0[offsN[d1]], e1 = offs0[offsN[d1 + 1]];
    for (int t = e0 + sub; t < e1; t += 4) {
        int s2 = (int)(((unsigned)csrc0[t]) >> 20);   // logical shift: packed parent2
        atomicOr(&words[s2 >> 6], 1ull << (s2 & 63));
    }
    __syncthreads();
    if (tid < 64) {                                // wave 0 only
        int pc = __popcll(words[tid]);
        int sc = pc;
        #pragma unroll
        for (int off = 1; off < 64; off <<= 1) {
            int o = __shfl_up(sc, off);
            if (tid >= off) sc += o;
        }
        wpre[tid] = sc - pc;                       // exclusive prefix
        if (tid == 63) {
            l2num[d2] = sc;
            int bb = atomicAdd(l2cursor, sc);
            l2off[d2] = bb;
            sbase = bb;
        }
    }
    __syncthreads();
    if (tid < 64) {
        unsigned long long wb = words[tid];
        int p = sbase + wpre[tid];
        while (wb) {
            int b = __builtin_ctzll(wb);
            wb &= wb - 1;
            l2src[p++] = (tid << 6) | b;
        }
    }
}

// ---------------- level 0: h = f @ W_f + pos @ W_p (new-id space) ----------------
template<int CI, int CO>
__global__ __launch_bounds__(256)
void xform0_k(const float* __restrict__ pnodes, const float* __restrict__ f,
              const float* __restrict__ W, float* __restrict__ h) {
    __shared__ float sW[(CI + 3) * CO];
    for (int i = threadIdx.x; i < (CI + 3) * CO; i += 256) sW[i] = W[i];
    __syncthreads();
    int gid = blockIdx.x * 256 + threadIdx.x;
    int i = gid / CO, ch = gid - i * CO;
    if (i >= NN) return;
    float s = pnodes[3 * i] * sW[CI * CO + ch] + pnodes[3 * i + 1] * sW[(CI + 1) * CO + ch]
            + pnodes[3 * i + 2] * sW[(CI + 2) * CO + ch];
    #pragma unroll
    for (int k = 0; k < CI; ++k) s += f[(size_t)i * CI + k] * sW[k * CO + ch];
    h[(size_t)i * CO + ch] = s;
}

// fused: gather over W1 (8ch) + xform W2 (8->16) -> h2. Block covers 32 dst nodes.
__global__ __launch_bounds__(256)
void gatherL0f_k(const float* __restrict__ pnodes, const float* __restrict__ h1,
                 const float* __restrict__ W1pos,       // 3x8
                 const float* __restrict__ W2,          // 11x16
                 const int* __restrict__ offs, const int* __restrict__ srcs,
                 float* __restrict__ h2) {
    __shared__ float sW1[24];
    __shared__ float sW2[176];
    __shared__ float f1s[32][8];
    int tid = threadIdx.x;
    if (tid < 24) sW1[tid] = W1pos[tid];
    if (tid < 176) sW2[tid] = W2[tid];
    __syncthreads();
    int gid = blockIdx.x * 256 + tid;
    int d = gid >> 3, ch = gid & 7;
    int dbase = blockIdx.x * 32;
    if (d < NN) {
        float c = pnodes[3 * d] * sW1[ch] + pnodes[3 * d + 1] * sW1[8 + ch] + pnodes[3 * d + 2] * sW1[16 + ch];
        float m0 = c, m1 = c, m2 = c, m3 = c;
        int e0 = offs[d], e1 = offs[d + 1];
        int t = e0;
        for (; t + 4 <= e1; t += 4) {
            int s0 = srcs[t], s1 = srcs[t + 1], s2 = srcs[t + 2], s3 = srcs[t + 3];
            m0 = fmaxf(m0, h1[(size_t)s0 * 8 + ch]);
            m1 = fmaxf(m1, h1[(size_t)s1 * 8 + ch]);
            m2 = fmaxf(m2, h1[(size_t)s2 * 8 + ch]);
            m3 = fmaxf(m3, h1[(size_t)s3 * 8 + ch]);
        }
        for (; t < e1; ++t) m0 = fmaxf(m0, h1[(size_t)srcs[t] * 8 + ch]);
        f1s[d - dbase][ch] = fmaxf(fmaxf(m0, m1), fmaxf(m2, m3)) - c;
    }
    __syncthreads();
    // epilogue: h2[d][ch2] for 32 d x 16 ch2 = 512 outputs, 2 per thread
    #pragma unroll
    for (int rep = 0; rep < 2; ++rep) {
        int dL = (tid >> 4) + rep * 16, ch2 = tid & 15;
        int dg = dbase + dL;
        if (dg < NN) {
            float s = pnodes[3 * dg] * sW2[128 + ch2] + pnodes[3 * dg + 1] * sW2[144 + ch2]
                    + pnodes[3 * dg + 2] * sW2[160 + ch2];
            #pragma unroll
            for (int k = 0; k < 8; ++k) s += f1s[dL][k] * sW2[k * 16 + ch2];
            h2[(size_t)dg * 16 + ch2] = s;
        }
    }
}

template<int CO>
__global__ __launch_bounds__(256)
void gatherL0_k(const float* __restrict__ pnodes, const float* __restrict__ h,
                const float* __restrict__ Wpos, const int* __restrict__ offs,
                const int* __restrict__ srcs, float* __restrict__ out) {
    __shared__ float sW[3 * CO];
    for (int i = threadIdx.x; i < 3 * CO; i += 256) sW[i] = Wpos[i];
    __syncthreads();
    int gid = blockIdx.x * 256 + threadIdx.x;
    int d = gid / CO, ch = gid - d * CO;
    if (d >= NN) return;
    float c = pnodes[3 * d] * sW[ch] + pnodes[3 * d + 1] * sW[CO + ch] + pnodes[3 * d + 2] * sW[2 * CO + ch];
    float m0 = c, m1 = c, m2 = c, m3 = c;        // no self-loop at level 0; empty -> 0
    int e0 = offs[d], e1 = offs[d + 1];
    int t = e0;
    for (; t + 4 <= e1; t += 4) {
        int s0 = srcs[t], s1 = srcs[t + 1], s2 = srcs[t + 2], s3 = srcs[t + 3];
        m0 = fmaxf(m0, h[(size_t)s0 * CO + ch]);
        m1 = fmaxf(m1, h[(size_t)s1 * CO + ch]);
        m2 = fmaxf(m2, h[(size_t)s2 * CO + ch]);
        m3 = fmaxf(m3, h[(size_t)s3 * CO + ch]);
    }
    for (; t < e1; ++t) m0 = fmaxf(m0, h[(size_t)srcs[t] * CO + ch]);
    float m = fmaxf(fmaxf(m0, m1), fmaxf(m2, m3));
    out[(size_t)d * CO + ch] = m - c;
}

// ---------------- level 1: fused pool(16ch) + xform W3 -> Hc ----------------
__global__ __launch_bounds__(256)
void pxformL1_k(const float* __restrict__ f2, const int* __restrict__ offsN,
                const int* __restrict__ oclist, const int* __restrict__ ocount,
                const float* __restrict__ W3, float* __restrict__ h) {
    __shared__ float sW[19 * 32];
    __shared__ float nf[8][16];
    for (int i = threadIdx.x; i < 19 * 32; i += 256) sW[i] = W3[i];
    int gid = blockIdx.x * 256 + threadIdx.x;
    int j = gid >> 5, ch = gid & 31;
    int lj = threadIdx.x >> 5;                   // 8 js per block
    bool valid = j < *ocount;
    int d = valid ? oclist[j] : 0;
    if (valid && ch < 16) {
        float m = 0.f;                           // f2 >= 0 (post-relu)
        int n0 = offsN[d], n1 = offsN[d + 1];
        for (int n = n0; n < n1; ++n) m = fmaxf(m, f2[(size_t)n * 16 + ch]);
        nf[lj][ch] = m;
    }
    __syncthreads();
    if (!valid) return;
    float px = (float)(d >> 12), py = (float)((d >> 6) & 63), pz = (float)(d & 63);
    float s = px * sW[16 * 32 + ch] + py * sW[17 * 32 + ch] + pz * sW[18 * 32 + ch];
    #pragma unroll
    for (int k = 0; k < 16; ++k) s += nf[lj][k] * sW[k * 32 + ch];
    h[(size_t)j * 32 + ch] = s;
}

// fused: gather over W3pos + xform W4 (32->32) -> hnext (MUST be a different buffer).
__global__ __launch_bounds__(256)
void gatherL1f_k(const float* __restrict__ h, const float* __restrict__ W3pos,
                 const float* __restrict__ W4,          // 35x32
                 const int* __restrict__ offsN, const int* __restrict__ offs0,
                 const int* __restrict__ csrc0,
                 const int* __restrict__ oclist, const int* __restrict__ ocount,
                 float* __restrict__ hnext) {
    __shared__ float sWp[96];
    __shared__ float sW4[35 * 32];
    __shared__ float gs[8][32];
    int tid = threadIdx.x;
    if (tid < 96) sWp[tid] = W3pos[tid];
    for (int i = tid; i < 35 * 32; i += 256) sW4[i] = W4[i];
    __syncthreads();
    int gid = blockIdx.x * 256 + tid;
    int j = gid >> 5, ch = gid & 31;
    int lj = tid >> 5;
    bool valid = j < *ocount;
    int d = 0;
    float px = 0, py = 0, pz = 0;
    if (valid) {
        d = oclist[j];
        px = (float)(d >> 12); py = (float)((d >> 6) & 63); pz = (float)(d & 63);
        float c = px * sWp[ch] + py * sWp[32 + ch] + pz * sWp[64 + ch];
        float self = h[(size_t)j * 32 + ch];
        float m0 = fmaxf(c, self), m1 = m0, m2 = m0, m3 = m0;   // self-loop
        int e0 = offs0[offsN[d]], e1 = offs0[offsN[d + 1]];
        int t = e0;
        for (; t + 4 <= e1; t += 4) {
            int s0 = csrc0[t] & JMASK, s1 = csrc0[t + 1] & JMASK;
            int s2 = csrc0[t + 2] & JMASK, s3 = csrc0[t + 3] & JMASK;
            m0 = fmaxf(m0, h[(size_t)s0 * 32 + ch]);
            m1 = fmaxf(m1, h[(size_t)s1 * 32 + ch]);
            m2 = fmaxf(m2, h[(size_t)s2 * 32 + ch]);
            m3 = fmaxf(m3, h[(size_t)s3 * 32 + ch]);
        }
        for (; t < e1; ++t) m0 = fmaxf(m0, h[(size_t)(csrc0[t] & JMASK) * 32 + ch]);
        gs[lj][ch] = fmaxf(fmaxf(m0, m1), fmaxf(m2, m3)) - c;
    }
    __syncthreads();
    if (!valid) return;
    float s = px * sW4[32 * 32 + ch] + py * sW4[33 * 32 + ch] + pz * sW4[34 * 32 + ch];
    #pragma unroll
    for (int k = 0; k < 32; ++k) s += gs[lj][k] * sW4[k * 32 + ch];
    hnext[(size_t)j * 32 + ch] = s;
}

// plain flat gather (final level-1 layer)
__global__ __launch_bounds__(256)
void gatherL1_k(const float* __restrict__ h, const float* __restrict__ Wpos,
                const int* __restrict__ offsN, const int* __restrict__ offs0,
                const int* __restrict__ csrc0,
                const int* __restrict__ oclist, const int* __restrict__ ocount,
                float* __restrict__ g) {
    __shared__ float sW[96];
    for (int i = threadIdx.x; i < 96; i += 256) sW[i] = Wpos[i];
    __syncthreads();
    int gid = blockIdx.x * 256 + threadIdx.x;
    int j = gid >> 5, ch = gid & 31;
    if (j >= *ocount) return;
    int d = oclist[j];
    float px = (float)(d >> 12), py = (float)((d >> 6) & 63), pz = (float)(d & 63);
    float c = px * sW[ch] + py * sW[32 + ch] + pz * sW[64 + ch];
    float self = h[(size_t)j * 32 + ch];
    float m0 = fmaxf(c, self), m1 = m0, m2 = m0, m3 = m0;   // self-loop
    int e0 = offs0[offsN[d]], e1 = offs0[offsN[d + 1]];
    int t = e0;
    for (; t + 4 <= e1; t += 4) {
        int s0 = csrc0[t] & JMASK, s1 = csrc0[t + 1] & JMASK;
        int s2 = csrc0[t + 2] & JMASK, s3 = csrc0[t + 3] & JMASK;
        m0 = fmaxf(m0, h[(size_t)s0 * 32 + ch]);
        m1 = fmaxf(m1, h[(size_t)s1 * 32 + ch]);
        m2 = fmaxf(m2, h[(size_t)s2 * 32 + ch]);
        m3 = fmaxf(m3, h[(size_t)s3 * 32 + ch]);
    }
    for (; t < e1; ++t) m0 = fmaxf(m0, h[(size_t)(csrc0[t] & JMASK) * 32 + ch]);
    float m = fmaxf(fmaxf(m0, m1), fmaxf(m2, m3));
    g[(size_t)j * 32 + ch] = m - c;
}

// ---------------- level 2 (block per 16^3 cell) ----------------
__global__ __launch_bounds__(256)
void pool2x_k(const float* __restrict__ Gc, const int* __restrict__ jmap,
              const float* __restrict__ W5, float* __restrict__ h5) {
    __shared__ float part[8][32];
    __shared__ float nf2row[32];
    int d2 = blockIdx.x, tid = threadIdx.x;
    int x2 = d2 >> 8, y2 = (d2 >> 4) & 15, z2 = d2 & 15;
    int ch = tid & 31, grp = tid >> 5;                 // 8 grps x 8 children
    float m = 0.f;
    #pragma unroll
    for (int cc = 0; cc < 8; ++cc) {
        int child = grp * 8 + cc;
        int i = child >> 4, jj = (child >> 2) & 3, k = child & 3;
        int d1 = ((x2 * 4 + i) * 64 + (y2 * 4 + jj)) * 64 + (z2 * 4 + k);
        int cj = jmap[d1];
        if (cj >= 0) m = fmaxf(m, Gc[(size_t)cj * 32 + ch]);
    }
    part[grp][ch] = m;
    __syncthreads();
    if (tid < 32) {
        float mm = part[0][tid];
        #pragma unroll
        for (int g = 1; g < 8; ++g) mm = fmaxf(mm, part[g][tid]);
        nf2row[tid] = mm;
    }
    __syncthreads();
    if (tid < 64) {
        float s = x2 * W5[32 * 64 + tid] + y2 * W5[33 * 64 + tid] + z2 * W5[34 * 64 + tid];
        #pragma unroll
        for (int k = 0; k < 32; ++k) s += nf2row[k] * W5[k * 64 + tid];
        h5[(size_t)d2 * 64 + tid] = s;
    }
}

// level-2 gconv via flat adjacency list (+ optional fused next xform). One block per d2.
template<bool FUSE, bool WRITE_G>
__global__ __launch_bounds__(256)
void gconvL2_k(const float* __restrict__ h, const float* __restrict__ Wpos,
               const int* __restrict__ l2off, const int* __restrict__ l2num,
               const int* __restrict__ l2src,
               const float* __restrict__ Wn,           // (64+3)x64, if FUSE
               float* __restrict__ gout, float* __restrict__ hnext) {
    __shared__ float red[4][64];
    __shared__ float grow[64];
    int d2 = blockIdx.x, tid = threadIdx.x;
    int x2 = d2 >> 8, y2 = (d2 >> 4) & 15, z2 = d2 & 15;
    int ch = tid & 63, grp = tid >> 6;                 // 4 waves split the list
    int n0 = l2off[d2], num = l2num[d2];
    int per = (num + 3) >> 2;
    int s = n0 + grp * per;
    int e = min(n0 + num, s + per);
    float m0 = -1e30f, m1 = -1e30f, m2 = -1e30f, m3 = -1e30f;
    int t = s;
    for (; t + 4 <= e; t += 4) {
        int s0 = l2src[t], s1 = l2src[t + 1], s2 = l2src[t + 2], s3 = l2src[t + 3];
        m0 = fmaxf(m0, h[(size_t)s0 * 64 + ch]);
        m1 = fmaxf(m1, h[(size_t)s1 * 64 + ch]);
        m2 = fmaxf(m2, h[(size_t)s2 * 64 + ch]);
        m3 = fmaxf(m3, h[(size_t)s3 * 64 + ch]);
    }
    for (; t < e; ++t) m0 = fmaxf(m0, h[(size_t)l2src[t] * 64 + ch]);
    red[grp][ch] = fmaxf(fmaxf(m0, m1), fmaxf(m2, m3));
    __syncthreads();
    if (grp == 0) {
        float mm = fmaxf(fmaxf(red[0][ch], red[1][ch]), fmaxf(red[2][ch], red[3][ch]));
        float c = x2 * Wpos[ch] + y2 * Wpos[64 + ch] + z2 * Wpos[128 + ch];
        mm = fmaxf(mm, fmaxf(c, h[(size_t)d2 * 64 + ch]));   // self-loop + empty
        float g = mm - c;
        if (WRITE_G) gout[(size_t)d2 * 64 + ch] = g;
        if (FUSE) grow[ch] = g;
    }
    if (FUSE) {
        __syncthreads();
        if (tid < 64) {
            float s2v = x2 * Wn[64 * 64 + tid] + y2 * Wn[65 * 64 + tid] + z2 * Wn[66 * 64 + tid];
            #pragma unroll
            for (int k = 0; k < 64; ++k) s2v += grow[k] * Wn[k * 64 + tid];
            hnext[(size_t)d2 * 64 + tid] = s2v;
        }
    }
}

// ---------------- output pool + linear ----------------
__global__ __launch_bounds__(256)
void outpool_k(const float* __restrict__ g7, float* __restrict__ xo) {
    int gid = blockIdx.x * 256 + threadIdx.x;
    if (gid >= 64 * 64) return;
    int oc = gid >> 6, ch = gid & 63;
    int cx = oc >> 4, cy = (oc >> 2) & 3, cz = oc & 3;
    float m = 0.f;
    for (int tc = 0; tc < 64; ++tc) {
        int i = tc >> 4, j = (tc >> 2) & 3, k = tc & 3;
        int d2 = ((cx * 4 + i) * 16 + (cy * 4 + j)) * 16 + (cz * 4 + k);
        m = fmaxf(m, g7[(size_t)d2 * 64 + ch]);
    }
    xo[(size_t)oc * 64 + ch] = m;
}

__global__ __launch_bounds__(64)
void linear_k(const float* __restrict__ xo, const float* __restrict__ Wl,
              const float* __restrict__ bl, float* __restrict__ out) {
    int j = blockIdx.x;
    float s = 0.f;
    for (int i = threadIdx.x; i < 4096; i += 64) s += xo[i] * Wl[(size_t)i * 100 + j];
    #pragma unroll
    for (int off = 32; off; off >>= 1) s += __shfl_down(s, off);
    if (threadIdx.x == 0) out[j] = s + bl[j];
}

extern "C" void kernel_launch(void* const* d_in, const int* in_sizes, int n_in,
                              void* d_out, int out_size, void* d_ws, size_t ws_size,
                              hipStream_t stream) {
    (void)in_sizes; (void)n_in; (void)out_size;
    const float* nodes = (const float*)d_in[0];
    const float* feats = (const float*)d_in[1];
    const int*   edges = (const int*)d_in[2];
    const int*   esrc  = edges;
    const int*   edst  = edges + NE;
    const float* W1 = (const float*)d_in[3];
    const float* W2 = (const float*)d_in[4];
    const float* W3 = (const float*)d_in[5];
    const float* W4 = (const float*)d_in[6];
    const float* W5 = (const float*)d_in[7];
    const float* W6 = (const float*)d_in[8];
    const float* W7 = (const float*)d_in[9];
    const float* Wl = (const float*)d_in[10];
    const float* bl = (const float*)d_in[11];
    float* out = (float*)d_out;

    char* ws = (char*)d_ws;
    size_t off = 0;
    auto alloc = [&](size_t bytes) { void* p = ws + off; off = (off + bytes + 255) & ~(size_t)255; return p; };
    // zero region: cntN + ocount + btot + l2cursor (one memset)
    int*   cntN    = (int*)alloc((size_t)C1 * 4);
    int*   ocount  = (int*)alloc(4);
    int*   btot    = (int*)alloc((size_t)NB * 4);
    int*   l2cursor= (int*)alloc(4);
    size_t zero_bytes = off;
    int*   bsum   = (int*)alloc(260 * 4);
    int*   bbase  = (int*)alloc((size_t)(NB + 1) * 4);
    int*   cursor = (int*)alloc((size_t)NB * 4);
    int*   cid    = (int*)alloc((size_t)NN * 4);
    int*   rank   = (int*)alloc((size_t)NN * 4);
    int*   nidx   = (int*)alloc((size_t)NN * 4);
    int*   offsN  = (int*)alloc((size_t)(C1 + 1) * 4);
    int*   offs0  = (int*)alloc((size_t)(NN + 1) * 4);
    int*   srcs0  = (int*)alloc((size_t)NE * 4);
    int*   csrc0  = (int*)alloc((size_t)NE * 4);
    int2*  ebuf   = (int2*)alloc((size_t)NE * 8);
    int*   oclist = (int*)alloc((size_t)NN * 4);
    int*   jmap   = (int*)alloc((size_t)C1 * 4);
    int*   jsrcP  = (int*)alloc((size_t)NN * 4);
    int*   l2off  = (int*)alloc((size_t)C2 * 4);
    int*   l2num  = (int*)alloc((size_t)C2 * 4);
    int*   l2srcA = (int*)alloc((size_t)NE * 4);
    float* pnodes = (float*)alloc((size_t)NN * 3 * 4);
    float* pfeat  = (float*)alloc((size_t)NN * 4);
    float* A      = (float*)alloc((size_t)NN * 48 * 4);   // h1, h2, f2
    float* Hc     = (float*)alloc((size_t)NN * 32 * 4);
    float* Gc     = (float*)alloc((size_t)NN * 32 * 4);
    float* h5     = (float*)alloc((size_t)C2 * 64 * 4);
    float* h6     = (float*)alloc((size_t)C2 * 64 * 4);
    float* h7     = (float*)alloc((size_t)C2 * 64 * 4);
    float* g7     = (float*)alloc((size_t)C2 * 64 * 4);
    float* xo     = (float*)alloc((size_t)64 * 64 * 4);
    if (ws_size < off) return;

    float* h1 = A;                      // [NN][8]
    float* h2 = A + (size_t)NN * 16;    // [NN][16]
    float* f2 = A + (size_t)NN * 32;    // [NN][16]

    hipMemsetAsync(cntN, 0, zero_bytes, stream);

    auto gr = [](long long n) { return (int)((n + 255) / 256); };
    const int nbC1 = (C1 + 2047) / 2048;   // 128
    const int gPA  = (NE + PA_EDGES - 1) / PA_EDGES;  // 196

    // ---- connectivity build (new-id space) ----
    cidhist_k<<<gr(NN), 256, 0, stream>>>(nodes, cid, cntN);
    oclist_k<<<C1 / 256, 256, 0, stream>>>(cntN, oclist, jmap, ocount);
    scan1_k<<<nbC1, 256, 0, stream>>>(cntN, C1, offsN, bsum);
    scan2_k<<<1, 256, 0, stream>>>(bsum, nbC1);
    scan3_k<<<gr(C1 + 1), 256, 0, stream>>>(offsN, C1, bsum, nbC1);
    nscatter_k<<<gr(NN), 256, 0, stream>>>(cid, offsN, cntN, rank, nidx);
    permute_k<<<gr(NN), 256, 0, stream>>>(nidx, nodes, feats, cid, jmap, pnodes, pfeat, jsrcP);
    bhist_k<<<gPA, 256, 0, stream>>>(edst, rank, btot);
    scanB_k<<<1, 256, 0, stream>>>(btot, bbase, cursor);
    passA_k<<<gPA, 256, 0, stream>>>(esrc, edst, rank, cursor, ebuf);
    passB_k<<<NB, 256, 0, stream>>>(ebuf, bbase, jsrcP, offs0, srcs0, csrc0);
    masklist_k<<<C2, 256, 0, stream>>>(offsN, offs0, csrc0, l2off, l2num, l2srcA, l2cursor);

    // ---- level 0 (new-id space) ----
    xform0_k<1, 8><<<gr((long long)NN * 8), 256, 0, stream>>>(pnodes, pfeat, W1, h1);
    gatherL0f_k<<<gr((long long)NN * 8), 256, 0, stream>>>(pnodes, h1, W1 + 1 * 8, W2, offs0, srcs0, h2);
    gatherL0_k<16><<<gr((long long)NN * 16), 256, 0, stream>>>(pnodes, h2, W2 + 8 * 16, offs0, srcs0, f2);

    // ---- level 1 (compact occupied cells, flat edge ranges; ping-pong Hc/Gc) ----
    pxformL1_k<<<gr((long long)NN * 32), 256, 0, stream>>>(f2, offsN, oclist, ocount, W3, Hc);
    gatherL1f_k<<<gr((long long)NN * 32), 256, 0, stream>>>(Hc, W3 + 16 * 32, W4, offsN, offs0, csrc0, oclist, ocount, Gc);
    gatherL1_k<<<gr((long long)NN * 32), 256, 0, stream>>>(Gc, W4 + 32 * 32, offsN, offs0, csrc0, oclist, ocount, Hc);

    // ---- level 2 (block per 16^3 cell, list-driven, fused) ----
    pool2x_k<<<C2, 256, 0, stream>>>(Hc, jmap, W5, h5);
    gconvL2_k<true,  false><<<C2, 256, 0, stream>>>(h5, W5 + 32 * 64, l2off, l2num, l2srcA, W6, nullptr, h6);
    gconvL2_k<true,  false><<<C2, 256, 0, stream>>>(h6, W6 + 64 * 64, l2off, l2num, l2srcA, W7, nullptr, h7);
    gconvL2_k<false, true ><<<C2, 256, 0, stream>>>(h7, W7 + 64 * 64, l2off, l2num, l2srcA, nullptr, g7, nullptr);

    outpool_k<<<16, 256, 0, stream>>>(g7, xo);
    linear_k<<<100, 64, 0, stream>>>(xo, Wl, bl, out);
}

// Round 12
// 465.216 us; speedup vs baseline: 52.0969x; 1.1689x over previous
//
#include <hip/hip_runtime.h>

#define NN 100000      // nodes
#define NE 1600000     // edges
#define C1 262144      // 64^3 cells
#define C2 4096        // 16^3 cells
#define BSH 7          // bucket shift (128 new-ids per bucket)
#define BSZ 128
#define NB 782         // ceil(NN/128)
#define PA_EDGES 8192
#define PA_IT (PA_EDGES / 256)
#define JMASK 0xFFFFF  // low 20 bits: compact j; bits 20..31: parent2(src cell)

__device__ __forceinline__ int parent2(int c) {   // 64^3 cell id -> 16^3 cell id
    return ((c >> 14) << 8) | (((c >> 8) & 15) << 4) | ((c >> 2) & 15);
}
__device__ __forceinline__ float4 max4(float4 a, float4 b) {
    return make_float4(fmaxf(a.x, b.x), fmaxf(a.y, b.y), fmaxf(a.z, b.z), fmaxf(a.w, b.w));
}
__device__ __forceinline__ float4 fma4(float s, float4 w, float4 acc) {
    return make_float4(s * w.x + acc.x, s * w.y + acc.y, s * w.z + acc.z, s * w.w + acc.w);
}

// ---------------- cid of each node + node-per-cell histogram ----------------
__global__ __launch_bounds__(256)
void cidhist_k(const float* __restrict__ nodes, int* __restrict__ cid,
               int* __restrict__ cntN) {
    int i = blockIdx.x * 256 + threadIdx.x;
    if (i >= NN) return;
    int cx = min(max((int)floorf(nodes[3 * i]     * 0.25f), 0), 63);
    int cy = min(max((int)floorf(nodes[3 * i + 1] * 0.25f), 0), 63);
    int cz = min(max((int)floorf(nodes[3 * i + 2] * 0.25f), 0), 63);
    int c = (cx * 64 + cy) * 64 + cz;
    cid[i] = c;
    atomicAdd(&cntN[c], 1);
}

// ---------------- occupied-cell list + cell->compact-index map ----------------
__global__ __launch_bounds__(256)
void oclist_k(const int* __restrict__ cntN, int* __restrict__ oclist,
              int* __restrict__ jmap, int* __restrict__ ocount) {
    int c = blockIdx.x * 256 + threadIdx.x;     // grid covers C1 exactly
    bool occ = cntN[c] > 0;
    unsigned long long b = __ballot(occ);
    int lane = threadIdx.x & 63;
    int cnt = __popcll(b);
    int base = 0;
    if (cnt) {
        if (lane == 0) base = atomicAdd(ocount, cnt);
        base = __shfl(base, 0);
    }
    int pre = __popcll(b & ((1ull << lane) - 1));
    int j = occ ? base + pre : -1;
    jmap[c] = j;
    if (occ) oclist[j] = c;
}

// ---------------- cell scan (offsN over C1): 2048/block ----------------
__global__ __launch_bounds__(256)
void scan1_k(const int* __restrict__ cnt, int n, int* __restrict__ offs,
             int* __restrict__ bsum) {
    __shared__ int ws[4];
    int t = threadIdx.x, lane = t & 63, w = t >> 6;
    int base = blockIdx.x * 2048 + t * 8;
    int v[8]; int s = 0;
    #pragma unroll
    for (int i = 0; i < 8; ++i) { v[i] = (base + i < n) ? cnt[base + i] : 0; s += v[i]; }
    int sc = s;
    #pragma unroll
    for (int off = 1; off < 64; off <<= 1) { int o = __shfl_up(sc, off); if (lane >= off) sc += o; }
    if (lane == 63) ws[w] = sc;
    __syncthreads();
    int wbase = 0;
    for (int i = 0; i < w; ++i) wbase += ws[i];
    int run = wbase + sc - s;
    #pragma unroll
    for (int i = 0; i < 8; ++i) { if (base + i < n) offs[base + i] = run; run += v[i]; }
    if (t == 255) bsum[blockIdx.x] = wbase + sc;
}

__global__ __launch_bounds__(256)
void scan2_k(int* __restrict__ bsum, int nb) {   // one block, nb <= 256
    __shared__ int ws[4];
    int t = threadIdx.x, lane = t & 63, w = t >> 6;
    int v = (t < nb) ? bsum[t] : 0;
    int sc = v;
    #pragma unroll
    for (int off = 1; off < 64; off <<= 1) { int o = __shfl_up(sc, off); if (lane >= off) sc += o; }
    if (lane == 63) ws[w] = sc;
    __syncthreads();
    int wbase = 0;
    for (int i = 0; i < w; ++i) wbase += ws[i];
    if (t < nb) bsum[t] = wbase + sc - v;
    if (t == 255) bsum[nb] = ws[0] + ws[1] + ws[2] + ws[3];
}

__global__ __launch_bounds__(256)
void scan3_k(int* __restrict__ offs, int n, const int* __restrict__ bsum, int nb) {
    int i = blockIdx.x * 256 + threadIdx.x;
    if (i < n) offs[i] += bsum[i >> 11];
    else if (i == n) offs[n] = bsum[nb];
}

// ---------------- node scatter: rank (new id) + nidx (old id by new id) ----------------
__global__ __launch_bounds__(256)
void nscatter_k(const int* __restrict__ cid, const int* __restrict__ offsN,
                int* __restrict__ cntN, int* __restrict__ rank, int* __restrict__ nidx) {
    int i = blockIdx.x * 256 + threadIdx.x;
    if (i >= NN) return;
    int c = cid[i];
    int pos = offsN[c] + atomicAdd(&cntN[c], -1) - 1;
    rank[i] = pos;
    nidx[pos] = i;
}

// ---------------- permute node data into new-id order ----------------
__global__ __launch_bounds__(256)
void permute_k(const int* __restrict__ nidx, const float* __restrict__ nodes,
               const float* __restrict__ feats, const int* __restrict__ cid,
               const int* __restrict__ jmap,
               float* __restrict__ pnodes, float* __restrict__ pfeat,
               int* __restrict__ jsrcP) {
    int d = blockIdx.x * 256 + threadIdx.x;
    if (d >= NN) return;
    int i = nidx[d];
    pnodes[3 * d]     = nodes[3 * i];
    pnodes[3 * d + 1] = nodes[3 * i + 1];
    pnodes[3 * d + 2] = nodes[3 * i + 2];
    pfeat[d] = feats[i];
    int c = cid[i];
    unsigned packed = (unsigned)jmap[c] | ((unsigned)parent2(c) << 20);  // j | s2<<20
    jsrcP[d] = (int)packed;
}

// ---------------- bucket histogram over rank[dst] (LDS pre-aggregated) ----------------
__global__ __launch_bounds__(256)
void bhist_k(const int* __restrict__ edst, const int* __restrict__ rank,
             int* __restrict__ btot) {
    __shared__ int h[NB];
    int tid = threadIdx.x;
    for (int i = tid; i < NB; i += 256) h[i] = 0;
    __syncthreads();
    int base = blockIdx.x * PA_EDGES;
    for (int i = 0; i < PA_IT; ++i) {
        int e = base + i * 256 + tid;
        if (e < NE) atomicAdd(&h[rank[edst[e]] >> BSH], 1);
    }
    __syncthreads();
    for (int i = tid; i < NB; i += 256) if (h[i]) atomicAdd(&btot[i], h[i]);
}

// one block: exclusive scan of NB (<=1024) bucket totals -> bbase[NB+1]; copy to cursor
__global__ __launch_bounds__(256)
void scanB_k(const int* __restrict__ btot, int* __restrict__ bbase,
             int* __restrict__ cursor) {
    __shared__ int ws[4];
    int t = threadIdx.x, lane = t & 63, w = t >> 6;
    int i0 = 4 * t;
    int v[4]; int s = 0;
    #pragma unroll
    for (int q = 0; q < 4; ++q) { v[q] = (i0 + q < NB) ? btot[i0 + q] : 0; s += v[q]; }
    int sc = s;
    #pragma unroll
    for (int off = 1; off < 64; off <<= 1) { int o = __shfl_up(sc, off); if (lane >= off) sc += o; }
    if (lane == 63) ws[w] = sc;
    __syncthreads();
    int wb = 0;
    for (int q = 0; q < w; ++q) wb += ws[q];
    int run = wb + sc - s;
    #pragma unroll
    for (int q = 0; q < 4; ++q) {
        if (i0 + q <= NB) { bbase[i0 + q] = run; if (i0 + q < NB) cursor[i0 + q] = run; }
        run += v[q];
    }
}

// ---------------- pass A: partition (rank_src, rank_dst) pairs by dst bucket ----------------
__global__ __launch_bounds__(256)
void passA_k(const int* __restrict__ esrc, const int* __restrict__ edst,
             const int* __restrict__ rank, int* __restrict__ cursor,
             int2* __restrict__ ebuf) {
    __shared__ int hist[NB];
    __shared__ int lofs[NB + 1];
    __shared__ int gbase[NB];
    __shared__ int cnt2[NB];
    __shared__ int2 stage[PA_EDGES];             // 64KB
    __shared__ unsigned short sbid[PA_EDGES];    // 16KB
    __shared__ int ws[4];
    int tid = threadIdx.x, lane = tid & 63, w = tid >> 6;
    for (int i = tid; i < NB; i += 256) { hist[i] = 0; cnt2[i] = 0; }
    __syncthreads();
    int base = blockIdx.x * PA_EDGES;
    for (int i = 0; i < PA_IT; ++i) {
        int e = base + i * 256 + tid;
        if (e < NE) atomicAdd(&hist[rank[edst[e]] >> BSH], 1);
    }
    __syncthreads();
    // exclusive scan hist -> lofs (4 per thread)
    int i0 = 4 * tid;
    int v[4]; int s = 0;
    #pragma unroll
    for (int q = 0; q < 4; ++q) { v[q] = (i0 + q < NB) ? hist[i0 + q] : 0; s += v[q]; }
    int sc = s;
    #pragma unroll
    for (int off = 1; off < 64; off <<= 1) { int o = __shfl_up(sc, off); if (lane >= off) sc += o; }
    if (lane == 63) ws[w] = sc;
    __syncthreads();
    int wb = 0;
    for (int q = 0; q < w; ++q) wb += ws[q];
    int run = wb + sc - s;
    #pragma unroll
    for (int q = 0; q < 4; ++q) {
        if (i0 + q <= NB) lofs[i0 + q] = run;
        run += v[q];
    }
    __syncthreads();
    for (int b = tid; b < NB; b += 256) {
        int c = hist[b];
        gbase[b] = c ? atomicAdd(&cursor[b], c) : 0;
    }
    __syncthreads();
    for (int i = 0; i < PA_IT; ++i) {
        int e = base + i * 256 + tid;
        if (e < NE) {
            int rd = rank[edst[e]], rs = rank[esrc[e]];
            int b = rd >> BSH;
            int p = lofs[b] + atomicAdd(&cnt2[b], 1);
            stage[p] = make_int2(rs, rd);
            sbid[p] = (unsigned short)b;
        }
    }
    __syncthreads();
    int nval = min(PA_EDGES, NE - base);
    for (int k = tid; k < nval; k += 256) {
        int b = sbid[k];
        ebuf[gbase[b] + (k - lofs[b])] = stage[k];
    }
}

// ---------------- pass B: per-bucket final scatter; offs0 (new-id CSR); csrc fused ----------------
__global__ __launch_bounds__(256)
void passB_k(const int2* __restrict__ ebuf, const int* __restrict__ bbase,
             const int* __restrict__ jsrcP,
             int* __restrict__ offs0, int* __restrict__ srcs0, int* __restrict__ csrc0) {
    __shared__ int cnt[BSZ];
    __shared__ int pos[BSZ];
    __shared__ int ws[4];
    int b = blockIdx.x, tid = threadIdx.x, lane = tid & 63, w = tid >> 6;
    int d0 = b << BSH;
    int range = min(BSZ, NN - d0);
    if (tid < BSZ) cnt[tid] = 0;
    __syncthreads();
    int r0 = bbase[b], r1 = bbase[b + 1];
    for (int k = r0 + tid; k < r1; k += 256) atomicAdd(&cnt[ebuf[k].y & (BSZ - 1)], 1);
    __syncthreads();
    int v = (tid < BSZ) ? cnt[tid] : 0;
    int sc = v;
    #pragma unroll
    for (int off = 1; off < 64; off <<= 1) { int o = __shfl_up(sc, off); if (lane >= off) sc += o; }
    if (lane == 63) ws[w] = sc;
    __syncthreads();
    int wb = 0;
    for (int q = 0; q < w; ++q) wb += ws[q];
    int rel = wb + sc - v;                        // exclusive per-dst prefix
    if (tid < range) offs0[d0 + tid] = r0 + rel;
    if (tid == 0) offs0[min(d0 + BSZ, NN)] = r1;  // benign duplicate of next base
    if (tid < BSZ) pos[tid] = r0 + rel;
    __syncthreads();
    for (int k = r0 + tid; k < r1; k += 256) {
        int2 pr = ebuf[k];
        int di = pr.y & (BSZ - 1);
        int p = atomicAdd(&pos[di], 1);
        int rs = pr.x;
        srcs0[p] = rs;
        csrc0[p] = jsrcP[rs];                     // packed j | s2<<20
    }
}

// ---------------- level-2 adjacency list: LDS bitmap -> compact per-d2 src list ----------------
__global__ __launch_bounds__(256)
void masklist_k(const int* __restrict__ offsN, const int* __restrict__ offs0,
                const int* __restrict__ csrc0,
                int* __restrict__ l2off, int* __restrict__ l2num,
                int* __restrict__ l2src, int* __restrict__ l2cursor) {
    __shared__ unsigned long long words[64];
    __shared__ int wpre[64];
    __shared__ int sbase;
    int d2 = blockIdx.x, tid = threadIdx.x;
    if (tid < 64) words[tid] = 0;
    __syncthreads();
    int x2 = d2 >> 8, y2 = (d2 >> 4) & 15, z2 = d2 & 15;
    int child = tid >> 2, sub = tid & 3;         // 64 children x 4 threads
    int i = child >> 4, jj = (child >> 2) & 3, k = child & 3;
    int d1 = ((x2 * 4 + i) * 64 + (y2 * 4 + jj)) * 64 + (z2 * 4 + k);
    int e0 = offs0[offsN[d1]], e1 = offs0[offsN[d1 + 1]];
    for (int t = e0 + sub; t < e1; t += 4) {
        int s2 = (int)(((unsigned)csrc0[t]) >> 20);   // logical shift: packed parent2
        atomicOr(&words[s2 >> 6], 1ull << (s2 & 63));
    }
    __syncthreads();
    if (tid < 64) {                                // wave 0 only
        int pc = __popcll(words[tid]);
        int sc = pc;
        #pragma unroll
        for (int off = 1; off < 64; off <<= 1) {
            int o = __shfl_up(sc, off);
            if (tid >= off) sc += o;
        }
        wpre[tid] = sc - pc;                       // exclusive prefix
        if (tid == 63) {
            l2num[d2] = sc;
            int bb = atomicAdd(l2cursor, sc);
            l2off[d2] = bb;
            sbase = bb;
        }
    }
    __syncthreads();
    if (tid < 64) {
        unsigned long long wb = words[tid];
        int p = sbase + wpre[tid];
        while (wb) {
            int b = __builtin_ctzll(wb);
            wb &= wb - 1;
            l2src[p++] = (tid << 6) | b;
        }
    }
}

// ---------------- level 0: h = f @ W_f + pos @ W_p (new-id space) ----------------
template<int CI, int CO>
__global__ __launch_bounds__(256)
void xform0_k(const float* __restrict__ pnodes, const float* __restrict__ f,
              const float* __restrict__ W, float* __restrict__ h) {
    __shared__ float sW[(CI + 3) * CO];
    for (int i = threadIdx.x; i < (CI + 3) * CO; i += 256) sW[i] = W[i];
    __syncthreads();
    int gid = blockIdx.x * 256 + threadIdx.x;
    int i = gid / CO, ch = gid - i * CO;
    if (i >= NN) return;
    float s = pnodes[3 * i] * sW[CI * CO + ch] + pnodes[3 * i + 1] * sW[(CI + 1) * CO + ch]
            + pnodes[3 * i + 2] * sW[(CI + 2) * CO + ch];
    #pragma unroll
    for (int k = 0; k < CI; ++k) s += f[(size_t)i * CI + k] * sW[k * CO + ch];
    h[(size_t)i * CO + ch] = s;
}

// fused: gather over W1 (8ch) + xform W2 (8->16) -> h2. Block covers 32 dst nodes.
__global__ __launch_bounds__(256)
void gatherL0f_k(const float* __restrict__ pnodes, const float* __restrict__ h1,
                 const float* __restrict__ W1pos,       // 3x8
                 const float* __restrict__ W2,          // 11x16
                 const int* __restrict__ offs, const int* __restrict__ srcs,
                 float* __restrict__ h2) {
    __shared__ float sW1[24];
    __shared__ float sW2[176];
    __shared__ float f1s[32][8];
    int tid = threadIdx.x;
    if (tid < 24) sW1[tid] = W1pos[tid];
    if (tid < 176) sW2[tid] = W2[tid];
    __syncthreads();
    int gid = blockIdx.x * 256 + tid;
    int d = gid >> 3, ch = gid & 7;
    int dbase = blockIdx.x * 32;
    if (d < NN) {
        float c = pnodes[3 * d] * sW1[ch] + pnodes[3 * d + 1] * sW1[8 + ch] + pnodes[3 * d + 2] * sW1[16 + ch];
        float m0 = c, m1 = c, m2 = c, m3 = c;
        int e0 = offs[d], e1 = offs[d + 1];
        int t = e0;
        for (; t + 4 <= e1; t += 4) {
            int s0 = srcs[t], s1 = srcs[t + 1], s2 = srcs[t + 2], s3 = srcs[t + 3];
            m0 = fmaxf(m0, h1[(size_t)s0 * 8 + ch]);
            m1 = fmaxf(m1, h1[(size_t)s1 * 8 + ch]);
            m2 = fmaxf(m2, h1[(size_t)s2 * 8 + ch]);
            m3 = fmaxf(m3, h1[(size_t)s3 * 8 + ch]);
        }
        for (; t < e1; ++t) m0 = fmaxf(m0, h1[(size_t)srcs[t] * 8 + ch]);
        f1s[d - dbase][ch] = fmaxf(fmaxf(m0, m1), fmaxf(m2, m3)) - c;
    }
    __syncthreads();
    // epilogue: h2[d][ch2] for 32 d x 16 ch2 = 512 outputs, 2 per thread
    #pragma unroll
    for (int rep = 0; rep < 2; ++rep) {
        int dL = (tid >> 4) + rep * 16, ch2 = tid & 15;
        int dg = dbase + dL;
        if (dg < NN) {
            float s = pnodes[3 * dg] * sW2[128 + ch2] + pnodes[3 * dg + 1] * sW2[144 + ch2]
                    + pnodes[3 * dg + 2] * sW2[160 + ch2];
            #pragma unroll
            for (int k = 0; k < 8; ++k) s += f1s[dL][k] * sW2[k * 16 + ch2];
            h2[(size_t)dg * 16 + ch2] = s;
        }
    }
}

// float4 gather, CO=16: 4 threads per dst node (channel quads)
__global__ __launch_bounds__(256)
void gatherL0v4_k(const float* __restrict__ pnodes, const float* __restrict__ h,
                  const float* __restrict__ Wpos,       // 3x16
                  const int* __restrict__ offs, const int* __restrict__ srcs,
                  float* __restrict__ out) {
    __shared__ float sW[48];
    int tid = threadIdx.x;
    if (tid < 48) sW[tid] = Wpos[tid];
    __syncthreads();
    int gid = blockIdx.x * 256 + tid;
    int d = gid >> 2, q = gid & 3;
    if (d >= NN) return;
    float px = pnodes[3 * d], py = pnodes[3 * d + 1], pz = pnodes[3 * d + 2];
    float4 w0 = *(const float4*)&sW[q * 4];
    float4 w1 = *(const float4*)&sW[16 + q * 4];
    float4 w2 = *(const float4*)&sW[32 + q * 4];
    float4 c = make_float4(px * w0.x + py * w1.x + pz * w2.x, px * w0.y + py * w1.y + pz * w2.y,
                           px * w0.z + py * w1.z + pz * w2.z, px * w0.w + py * w1.w + pz * w2.w);
    float4 m0 = c, m1 = c, m2 = c, m3 = c;       // no self-loop at level 0; empty -> 0
    int e0 = offs[d], e1 = offs[d + 1];
    int t = e0;
    for (; t + 4 <= e1; t += 4) {
        int s0 = srcs[t], s1 = srcs[t + 1], s2 = srcs[t + 2], s3 = srcs[t + 3];
        m0 = max4(m0, *(const float4*)&h[(size_t)s0 * 16 + q * 4]);
        m1 = max4(m1, *(const float4*)&h[(size_t)s1 * 16 + q * 4]);
        m2 = max4(m2, *(const float4*)&h[(size_t)s2 * 16 + q * 4]);
        m3 = max4(m3, *(const float4*)&h[(size_t)s3 * 16 + q * 4]);
    }
    for (; t < e1; ++t) m0 = max4(m0, *(const float4*)&h[(size_t)srcs[t] * 16 + q * 4]);
    float4 m = max4(max4(m0, m1), max4(m2, m3));
    *(float4*)&out[(size_t)d * 16 + q * 4] = make_float4(m.x - c.x, m.y - c.y, m.z - c.z, m.w - c.w);
}

// ---------------- level 1: fused pool(16ch) + xform W3 -> Hc ----------------
__global__ __launch_bounds__(256)
void pxformL1_k(const float* __restrict__ f2, const int* __restrict__ offsN,
                const int* __restrict__ oclist, const int* __restrict__ ocount,
                const float* __restrict__ W3, float* __restrict__ h) {
    __shared__ float sW[19 * 32];
    __shared__ float nf[8][16];
    for (int i = threadIdx.x; i < 19 * 32; i += 256) sW[i] = W3[i];
    int gid = blockIdx.x * 256 + threadIdx.x;
    int j = gid >> 5, ch = gid & 31;
    int lj = threadIdx.x >> 5;                   // 8 js per block
    bool valid = j < *ocount;
    int d = valid ? oclist[j] : 0;
    if (valid && ch < 16) {
        float m = 0.f;                           // f2 >= 0 (post-relu)
        int n0 = offsN[d], n1 = offsN[d + 1];
        for (int n = n0; n < n1; ++n) m = fmaxf(m, f2[(size_t)n * 16 + ch]);
        nf[lj][ch] = m;
    }
    __syncthreads();
    if (!valid) return;
    float px = (float)(d >> 12), py = (float)((d >> 6) & 63), pz = (float)(d & 63);
    float s = px * sW[16 * 32 + ch] + py * sW[17 * 32 + ch] + pz * sW[18 * 32 + ch];
    #pragma unroll
    for (int k = 0; k < 16; ++k) s += nf[lj][k] * sW[k * 32 + ch];
    h[(size_t)j * 32 + ch] = s;
}

// fused float4 gather(W3pos) + xform W4 (32->32) -> hnext (different buffer).
// 8 threads per j (channel quads); 32 j per block.
__global__ __launch_bounds__(256)
void gatherL1f_k(const float* __restrict__ h, const float* __restrict__ W3pos,
                 const float* __restrict__ W4,          // 35x32
                 const int* __restrict__ offsN, const int* __restrict__ offs0,
                 const int* __restrict__ csrc0,
                 const int* __restrict__ oclist, const int* __restrict__ ocount,
                 float* __restrict__ hnext) {
    __shared__ float sWp[96];
    __shared__ float sW4[35 * 32];
    __shared__ float gsT[32][33];                // [ch][lj], padded
    int tid = threadIdx.x;
    if (tid < 96) sWp[tid] = W3pos[tid];
    for (int i = tid; i < 35 * 32; i += 256) sW4[i] = W4[i];
    __syncthreads();
    int gid = blockIdx.x * 256 + tid;
    int j = gid >> 3, q = gid & 7;
    int lj = tid >> 3;
    bool valid = j < *ocount;
    int d = 0;
    float px = 0, py = 0, pz = 0;
    float4 c = make_float4(0, 0, 0, 0);
    if (valid) {
        d = oclist[j];
        px = (float)(d >> 12); py = (float)((d >> 6) & 63); pz = (float)(d & 63);
        float4 w0 = *(const float4*)&sWp[q * 4];
        float4 w1 = *(const float4*)&sWp[32 + q * 4];
        float4 w2 = *(const float4*)&sWp[64 + q * 4];
        c = make_float4(px * w0.x + py * w1.x + pz * w2.x, px * w0.y + py * w1.y + pz * w2.y,
                        px * w0.z + py * w1.z + pz * w2.z, px * w0.w + py * w1.w + pz * w2.w);
        float4 self = *(const float4*)&h[(size_t)j * 32 + q * 4];
        float4 m0 = max4(c, self), m1 = m0, m2 = m0, m3 = m0;   // self-loop
        int e0 = offs0[offsN[d]], e1 = offs0[offsN[d + 1]];
        int t = e0;
        for (; t + 4 <= e1; t += 4) {
            int s0 = csrc0[t] & JMASK, s1 = csrc0[t + 1] & JMASK;
            int s2 = csrc0[t + 2] & JMASK, s3 = csrc0[t + 3] & JMASK;
            m0 = max4(m0, *(const float4*)&h[(size_t)s0 * 32 + q * 4]);
            m1 = max4(m1, *(const float4*)&h[(size_t)s1 * 32 + q * 4]);
            m2 = max4(m2, *(const float4*)&h[(size_t)s2 * 32 + q * 4]);
            m3 = max4(m3, *(const float4*)&h[(size_t)s3 * 32 + q * 4]);
        }
        for (; t < e1; ++t) m0 = max4(m0, *(const float4*)&h[(size_t)(csrc0[t] & JMASK) * 32 + q * 4]);
        float4 m = max4(max4(m0, m1), max4(m2, m3));
        gsT[q * 4 + 0][lj] = m.x - c.x;
        gsT[q * 4 + 1][lj] = m.y - c.y;
        gsT[q * 4 + 2][lj] = m.z - c.z;
        gsT[q * 4 + 3][lj] = m.w - c.w;
    }
    __syncthreads();
    if (!valid) return;
    float4 s4;
    {
        float4 w0 = *(const float4*)&sW4[32 * 32 + q * 4];
        float4 w1 = *(const float4*)&sW4[33 * 32 + q * 4];
        float4 w2 = *(const float4*)&sW4[34 * 32 + q * 4];
        s4 = make_float4(px * w0.x + py * w1.x + pz * w2.x, px * w0.y + py * w1.y + pz * w2.y,
                         px * w0.z + py * w1.z + pz * w2.z, px * w0.w + py * w1.w + pz * w2.w);
    }
    #pragma unroll
    for (int k = 0; k < 32; ++k) {
        float g = gsT[k][lj];
        s4 = fma4(g, *(const float4*)&sW4[k * 32 + q * 4], s4);
    }
    *(float4*)&hnext[(size_t)j * 32 + q * 4] = s4;
}

// plain float4 flat gather (final level-1 layer)
__global__ __launch_bounds__(256)
void gatherL1_k(const float* __restrict__ h, const float* __restrict__ Wpos,
                const int* __restrict__ offsN, const int* __restrict__ offs0,
                const int* __restrict__ csrc0,
                const int* __restrict__ oclist, const int* __restrict__ ocount,
                float* __restrict__ g) {
    __shared__ float sW[96];
    int tid = threadIdx.x;
    if (tid < 96) sW[tid] = Wpos[tid];
    __syncthreads();
    int gid = blockIdx.x * 256 + tid;
    int j = gid >> 3, q = gid & 7;
    if (j >= *ocount) return;
    int d = oclist[j];
    float px = (float)(d >> 12), py = (float)((d >> 6) & 63), pz = (float)(d & 63);
    float4 w0 = *(const float4*)&sW[q * 4];
    float4 w1 = *(const float4*)&sW[32 + q * 4];
    float4 w2 = *(const float4*)&sW[64 + q * 4];
    float4 c = make_float4(px * w0.x + py * w1.x + pz * w2.x, px * w0.y + py * w1.y + pz * w2.y,
                           px * w0.z + py * w1.z + pz * w2.z, px * w0.w + py * w1.w + pz * w2.w);
    float4 self = *(const float4*)&h[(size_t)j * 32 + q * 4];
    float4 m0 = max4(c, self), m1 = m0, m2 = m0, m3 = m0;   // self-loop
    int e0 = offs0[offsN[d]], e1 = offs0[offsN[d + 1]];
    int t = e0;
    for (; t + 4 <= e1; t += 4) {
        int s0 = csrc0[t] & JMASK, s1 = csrc0[t + 1] & JMASK;
        int s2 = csrc0[t + 2] & JMASK, s3 = csrc0[t + 3] & JMASK;
        m0 = max4(m0, *(const float4*)&h[(size_t)s0 * 32 + q * 4]);
        m1 = max4(m1, *(const float4*)&h[(size_t)s1 * 32 + q * 4]);
        m2 = max4(m2, *(const float4*)&h[(size_t)s2 * 32 + q * 4]);
        m3 = max4(m3, *(const float4*)&h[(size_t)s3 * 32 + q * 4]);
    }
    for (; t < e1; ++t) m0 = max4(m0, *(const float4*)&h[(size_t)(csrc0[t] & JMASK) * 32 + q * 4]);
    float4 m = max4(max4(m0, m1), max4(m2, m3));
    *(float4*)&g[(size_t)j * 32 + q * 4] = make_float4(m.x - c.x, m.y - c.y, m.z - c.z, m.w - c.w);
}

// ---------------- level 2 (block per 16^3 cell) ----------------
__global__ __launch_bounds__(256)
void pool2x_k(const float* __restrict__ Gc, const int* __restrict__ jmap,
              const float* __restrict__ W5, float* __restrict__ h5) {
    __shared__ float part[8][32];
    __shared__ float nf2row[32];
    int d2 = blockIdx.x, tid = threadIdx.x;
    int x2 = d2 >> 8, y2 = (d2 >> 4) & 15, z2 = d2 & 15;
    int ch = tid & 31, grp = tid >> 5;                 // 8 grps x 8 children
    float m = 0.f;
    #pragma unroll
    for (int cc = 0; cc < 8; ++cc) {
        int child = grp * 8 + cc;
        int i = child >> 4, jj = (child >> 2) & 3, k = child & 3;
        int d1 = ((x2 * 4 + i) * 64 + (y2 * 4 + jj)) * 64 + (z2 * 4 + k);
        int cj = jmap[d1];
        if (cj >= 0) m = fmaxf(m, Gc[(size_t)cj * 32 + ch]);
    }
    part[grp][ch] = m;
    __syncthreads();
    if (tid < 32) {
        float mm = part[0][tid];
        #pragma unroll
        for (int g = 1; g < 8; ++g) mm = fmaxf(mm, part[g][tid]);
        nf2row[tid] = mm;
    }
    __syncthreads();
    if (tid < 64) {
        float s = x2 * W5[32 * 64 + tid] + y2 * W5[33 * 64 + tid] + z2 * W5[34 * 64 + tid];
        #pragma unroll
        for (int k = 0; k < 32; ++k) s += nf2row[k] * W5[k * 64 + tid];
        h5[(size_t)d2 * 64 + tid] = s;
    }
}

// level-2 gconv via flat adjacency list, float4 (+ optional fused next xform). One block per d2.
// 16 groups x 16 channel-quads.
template<bool FUSE, bool WRITE_G>
__global__ __launch_bounds__(256)
void gconvL2_k(const float* __restrict__ h, const float* __restrict__ Wpos,
               const int* __restrict__ l2off, const int* __restrict__ l2num,
               const int* __restrict__ l2src,
               const float* __restrict__ Wn,           // (64+3)x64, if FUSE
               float* __restrict__ gout, float* __restrict__ hnext) {
    __shared__ float red[16][64];
    __shared__ float grow[64];
    int d2 = blockIdx.x, tid = threadIdx.x;
    int x2 = d2 >> 8, y2 = (d2 >> 4) & 15, z2 = d2 & 15;
    int q = tid & 15, grp = tid >> 4;                  // 16 groups split the list
    int n0 = l2off[d2], num = l2num[d2];
    int per = (num + 15) >> 4;
    int s = n0 + grp * per;
    int e = min(n0 + num, s + per);
    float4 m0 = make_float4(-1e30f, -1e30f, -1e30f, -1e30f);
    float4 m1 = m0, m2 = m0, m3 = m0;
    int t = s;
    for (; t + 4 <= e; t += 4) {
        int s0 = l2src[t], s1 = l2src[t + 1], s2 = l2src[t + 2], s3 = l2src[t + 3];
        m0 = max4(m0, *(const float4*)&h[(size_t)s0 * 64 + q * 4]);
        m1 = max4(m1, *(const float4*)&h[(size_t)s1 * 64 + q * 4]);
        m2 = max4(m2, *(const float4*)&h[(size_t)s2 * 64 + q * 4]);
        m3 = max4(m3, *(const float4*)&h[(size_t)s3 * 64 + q * 4]);
    }
    for (; t < e; ++t) m0 = max4(m0, *(const float4*)&h[(size_t)l2src[t] * 64 + q * 4]);
    float4 m = max4(max4(m0, m1), max4(m2, m3));
    red[grp][q * 4 + 0] = m.x;
    red[grp][q * 4 + 1] = m.y;
    red[grp][q * 4 + 2] = m.z;
    red[grp][q * 4 + 3] = m.w;
    __syncthreads();
    if (tid < 64) {
        int ch = tid;
        float mm = red[0][ch];
        #pragma unroll
        for (int g = 1; g < 16; ++g) mm = fmaxf(mm, red[g][ch]);
        float c = x2 * Wpos[ch] + y2 * Wpos[64 + ch] + z2 * Wpos[128 + ch];
        mm = fmaxf(mm, fmaxf(c, h[(size_t)d2 * 64 + ch]));   // self-loop + empty
        float g = mm - c;
        if (WRITE_G) gout[(size_t)d2 * 64 + ch] = g;
        if (FUSE) grow[ch] = g;
    }
    if (FUSE) {
        __syncthreads();
        if (tid < 64) {
            float s2v = x2 * Wn[64 * 64 + tid] + y2 * Wn[65 * 64 + tid] + z2 * Wn[66 * 64 + tid];
            #pragma unroll
            for (int k = 0; k < 64; ++k) s2v += grow[k] * Wn[k * 64 + tid];
            hnext[(size_t)d2 * 64 + tid] = s2v;
        }
    }
}

// ---------------- output pool + linear ----------------
__global__ __launch_bounds__(256)
void outpool_k(const float* __restrict__ g7, float* __restrict__ xo) {
    int gid = blockIdx.x * 256 + threadIdx.x;
    if (gid >= 64 * 64) return;
    int oc = gid >> 6, ch = gid & 63;
    int cx = oc >> 4, cy = (oc >> 2) & 3, cz = oc & 3;
    float m = 0.f;
    for (int tc = 0; tc < 64; ++tc) {
        int i = tc >> 4, j = (tc >> 2) & 3, k = tc & 3;
        int d2 = ((cx * 4 + i) * 16 + (cy * 4 + j)) * 16 + (cz * 4 + k);
        m = fmaxf(m, g7[(size_t)d2 * 64 + ch]);
    }
    xo[(size_t)oc * 64 + ch] = m;
}

__global__ __launch_bounds__(64)
void linear_k(const float* __restrict__ xo, const float* __restrict__ Wl,
              const float* __restrict__ bl, float* __restrict__ out) {
    int j = blockIdx.x;
    float s = 0.f;
    for (int i = threadIdx.x; i < 4096; i += 64) s += xo[i] * Wl[(size_t)i * 100 + j];
    #pragma unroll
    for (int off = 32; off; off >>= 1) s += __shfl_down(s, off);
    if (threadIdx.x == 0) out[j] = s + bl[j];
}

extern "C" void kernel_launch(void* const* d_in, const int* in_sizes, int n_in,
                              void* d_out, int out_size, void* d_ws, size_t ws_size,
                              hipStream_t stream) {
    (void)in_sizes; (void)n_in; (void)out_size;
    const float* nodes = (const float*)d_in[0];
    const float* feats = (const float*)d_in[1];
    const int*   edges = (const int*)d_in[2];
    const int*   esrc  = edges;
    const int*   edst  = edges + NE;
    const float* W1 = (const float*)d_in[3];
    const float* W2 = (const float*)d_in[4];
    const float* W3 = (const float*)d_in[5];
    const float* W4 = (const float*)d_in[6];
    const float* W5 = (const float*)d_in[7];
    const float* W6 = (const float*)d_in[8];
    const float* W7 = (const float*)d_in[9];
    const float* Wl = (const float*)d_in[10];
    const float* bl = (const float*)d_in[11];
    float* out = (float*)d_out;

    char* ws = (char*)d_ws;
    size_t off = 0;
    auto alloc = [&](size_t bytes) { void* p = ws + off; off = (off + bytes + 255) & ~(size_t)255; return p; };
    // zero region: cntN + ocount + btot + l2cursor (one memset)
    int*   cntN    = (int*)alloc((size_t)C1 * 4);
    int*   ocount  = (int*)alloc(4);
    int*   btot    = (int*)alloc((size_t)NB * 4);
    int*   l2cursor= (int*)alloc(4);
    size_t zero_bytes = off;
    int*   bsum   = (int*)alloc(260 * 4);
    int*   bbase  = (int*)alloc((size_t)(NB + 1) * 4);
    int*   cursor = (int*)alloc((size_t)NB * 4);
    int*   cid    = (int*)alloc((size_t)NN * 4);
    int*   rank   = (int*)alloc((size_t)NN * 4);
    int*   nidx   = (int*)alloc((size_t)NN * 4);
    int*   offsN  = (int*)alloc((size_t)(C1 + 1) * 4);
    int*   offs0  = (int*)alloc((size_t)(NN + 1) * 4);
    int*   srcs0  = (int*)alloc((size_t)NE * 4);
    int*   csrc0  = (int*)alloc((size_t)NE * 4);
    int2*  ebuf   = (int2*)alloc((size_t)NE * 8);
    int*   oclist = (int*)alloc((size_t)NN * 4);
    int*   jmap   = (int*)alloc((size_t)C1 * 4);
    int*   jsrcP  = (int*)alloc((size_t)NN * 4);
    int*   l2off  = (int*)alloc((size_t)C2 * 4);
    int*   l2num  = (int*)alloc((size_t)C2 * 4);
    int*   l2srcA = (int*)alloc((size_t)NE * 4);
    float* pnodes = (float*)alloc((size_t)NN * 3 * 4);
    float* pfeat  = (float*)alloc((size_t)NN * 4);
    float* A      = (float*)alloc((size_t)NN * 48 * 4);   // h1, h2, f2
    float* Hc     = (float*)alloc((size_t)NN * 32 * 4);
    float* Gc     = (float*)alloc((size_t)NN * 32 * 4);
    float* h5     = (float*)alloc((size_t)C2 * 64 * 4);
    float* h6     = (float*)alloc((size_t)C2 * 64 * 4);
    float* h7     = (float*)alloc((size_t)C2 * 64 * 4);
    float* g7     = (float*)alloc((size_t)C2 * 64 * 4);
    float* xo     = (float*)alloc((size_t)64 * 64 * 4);
    if (ws_size < off) return;

    float* h1 = A;                      // [NN][8]
    float* h2 = A + (size_t)NN * 16;    // [NN][16]
    float* f2 = A + (size_t)NN * 32;    // [NN][16]

    hipMemsetAsync(cntN, 0, zero_bytes, stream);

    auto gr = [](long long n) { return (int)((n + 255) / 256); };
    const int nbC1 = (C1 + 2047) / 2048;   // 128
    const int gPA  = (NE + PA_EDGES - 1) / PA_EDGES;  // 196

    // ---- connectivity build (new-id space) ----
    cidhist_k<<<gr(NN), 256, 0, stream>>>(nodes, cid, cntN);
    oclist_k<<<C1 / 256, 256, 0, stream>>>(cntN, oclist, jmap, ocount);
    scan1_k<<<nbC1, 256, 0, stream>>>(cntN, C1, offsN, bsum);
    scan2_k<<<1, 256, 0, stream>>>(bsum, nbC1);
    scan3_k<<<gr(C1 + 1), 256, 0, stream>>>(offsN, C1, bsum, nbC1);
    nscatter_k<<<gr(NN), 256, 0, stream>>>(cid, offsN, cntN, rank, nidx);
    permute_k<<<gr(NN), 256, 0, stream>>>(nidx, nodes, feats, cid, jmap, pnodes, pfeat, jsrcP);
    bhist_k<<<gPA, 256, 0, stream>>>(edst, rank, btot);
    scanB_k<<<1, 256, 0, stream>>>(btot, bbase, cursor);
    passA_k<<<gPA, 256, 0, stream>>>(esrc, edst, rank, cursor, ebuf);
    passB_k<<<NB, 256, 0, stream>>>(ebuf, bbase, jsrcP, offs0, srcs0, csrc0);
    masklist_k<<<C2, 256, 0, stream>>>(offsN, offs0, csrc0, l2off, l2num, l2srcA, l2cursor);

    // ---- level 0 (new-id space) ----
    xform0_k<1, 8><<<gr((long long)NN * 8), 256, 0, stream>>>(pnodes, pfeat, W1, h1);
    gatherL0f_k<<<gr((long long)NN * 8), 256, 0, stream>>>(pnodes, h1, W1 + 1 * 8, W2, offs0, srcs0, h2);
    gatherL0v4_k<<<gr((long long)NN * 4), 256, 0, stream>>>(pnodes, h2, W2 + 8 * 16, offs0, srcs0, f2);

    // ---- level 1 (compact occupied cells, flat edge ranges; ping-pong Hc/Gc) ----
    pxformL1_k<<<gr((long long)NN * 32), 256, 0, stream>>>(f2, offsN, oclist, ocount, W3, Hc);
    gatherL1f_k<<<gr((long long)NN * 8), 256, 0, stream>>>(Hc, W3 + 16 * 32, W4, offsN, offs0, csrc0, oclist, ocount, Gc);
    gatherL1_k<<<gr((long long)NN * 8), 256, 0, stream>>>(Gc, W4 + 32 * 32, offsN, offs0, csrc0, oclist, ocount, Hc);

    // ---- level 2 (block per 16^3 cell, list-driven, fused) ----
    pool2x_k<<<C2, 256, 0, stream>>>(Hc, jmap, W5, h5);
    gconvL2_k<true,  false><<<C2, 256, 0, stream>>>(h5, W5 + 32 * 64, l2off, l2num, l2srcA, W6, nullptr, h6);
    gconvL2_k<true,  false><<<C2, 256, 0, stream>>>(h6, W6 + 64 * 64, l2off, l2num, l2srcA, W7, nullptr, h7);
    gconvL2_k<false, true ><<<C2, 256, 0, stream>>>(h7, W7 + 64 * 64, l2off, l2num, l2srcA, nullptr, g7, nullptr);

    outpool_k<<<16, 256, 0, stream>>>(g7, xo);
    linear_k<<<100, 64, 0, stream>>>(xo, Wl, bl, out);
}

// Round 13
// 462.751 us; speedup vs baseline: 52.3744x; 1.0053x over previous
//
#include <hip/hip_runtime.h>

#define NN 100000      // nodes
#define NE 1600000     // edges
#define C1 262144      // 64^3 cells (keyed as d2*64+child)
#define C2 4096        // 16^3 cells
#define BSH 7          // bucket shift (128 new-ids per bucket)
#define BSZ 128
#define NB 782         // ceil(NN/128)
#define PA_EDGES 8192
#define PA_IT (PA_EDGES / 256)
#define JMASK 0xFFFFF  // low 20 bits: compact j; bits 20..31: d2 of src cell

// cell key layout: key = d2*64 + child, d2 = (x>>2)*256+(y>>2)*16+(z>>2),
// child = (x&3)*16+(y&3)*4+(z&3)
__device__ __forceinline__ void key2xyz(int key, float& x, float& y, float& z) {
    int d2 = key >> 6, ch = key & 63;
    x = (float)((((d2 >> 8) & 15) << 2) | (ch >> 4));
    y = (float)((((d2 >> 4) & 15) << 2) | ((ch >> 2) & 3));
    z = (float)(((d2 & 15) << 2) | (ch & 3));
}
__device__ __forceinline__ float4 max4(float4 a, float4 b) {
    return make_float4(fmaxf(a.x, b.x), fmaxf(a.y, b.y), fmaxf(a.z, b.z), fmaxf(a.w, b.w));
}
__device__ __forceinline__ float4 fma4(float s, float4 w, float4 acc) {
    return make_float4(s * w.x + acc.x, s * w.y + acc.y, s * w.z + acc.z, s * w.w + acc.w);
}

// ---------------- cell key of each node + node-per-cell histogram ----------------
__global__ __launch_bounds__(256)
void cidhist_k(const float* __restrict__ nodes, int* __restrict__ cid,
               int* __restrict__ cntN) {
    int i = blockIdx.x * 256 + threadIdx.x;
    if (i >= NN) return;
    int cx = min(max((int)floorf(nodes[3 * i]     * 0.25f), 0), 63);
    int cy = min(max((int)floorf(nodes[3 * i + 1] * 0.25f), 0), 63);
    int cz = min(max((int)floorf(nodes[3 * i + 2] * 0.25f), 0), 63);
    int d2 = ((cx >> 2) * 16 + (cy >> 2)) * 16 + (cz >> 2);
    int ch = ((cx & 3) * 4 + (cy & 3)) * 4 + (cz & 3);
    int key = (d2 << 6) | ch;
    cid[i] = key;
    atomicAdd(&cntN[key], 1);
}

// ---------------- occupied-cell list + cell->compact-index map ----------------
__global__ __launch_bounds__(256)
void oclist_k(const int* __restrict__ cntN, int* __restrict__ oclist,
              int* __restrict__ jmap, int* __restrict__ ocount) {
    int c = blockIdx.x * 256 + threadIdx.x;     // grid covers C1 exactly (keys)
    bool occ = cntN[c] > 0;
    unsigned long long b = __ballot(occ);
    int lane = threadIdx.x & 63;
    int cnt = __popcll(b);
    int base = 0;
    if (cnt) {
        if (lane == 0) base = atomicAdd(ocount, cnt);
        base = __shfl(base, 0);
    }
    int pre = __popcll(b & ((1ull << lane) - 1));
    int j = occ ? base + pre : -1;
    jmap[c] = j;
    if (occ) oclist[j] = c;
}

// ---------------- cell scan (offsN over C1): 2048/block ----------------
__global__ __launch_bounds__(256)
void scan1_k(const int* __restrict__ cnt, int n, int* __restrict__ offs,
             int* __restrict__ bsum) {
    __shared__ int ws[4];
    int t = threadIdx.x, lane = t & 63, w = t >> 6;
    int base = blockIdx.x * 2048 + t * 8;
    int v[8]; int s = 0;
    #pragma unroll
    for (int i = 0; i < 8; ++i) { v[i] = (base + i < n) ? cnt[base + i] : 0; s += v[i]; }
    int sc = s;
    #pragma unroll
    for (int off = 1; off < 64; off <<= 1) { int o = __shfl_up(sc, off); if (lane >= off) sc += o; }
    if (lane == 63) ws[w] = sc;
    __syncthreads();
    int wbase = 0;
    for (int i = 0; i < w; ++i) wbase += ws[i];
    int run = wbase + sc - s;
    #pragma unroll
    for (int i = 0; i < 8; ++i) { if (base + i < n) offs[base + i] = run; run += v[i]; }
    if (t == 255) bsum[blockIdx.x] = wbase + sc;
}

__global__ __launch_bounds__(256)
void scan2_k(int* __restrict__ bsum, int nb) {   // one block, nb <= 256
    __shared__ int ws[4];
    int t = threadIdx.x, lane = t & 63, w = t >> 6;
    int v = (t < nb) ? bsum[t] : 0;
    int sc = v;
    #pragma unroll
    for (int off = 1; off < 64; off <<= 1) { int o = __shfl_up(sc, off); if (lane >= off) sc += o; }
    if (lane == 63) ws[w] = sc;
    __syncthreads();
    int wbase = 0;
    for (int i = 0; i < w; ++i) wbase += ws[i];
    if (t < nb) bsum[t] = wbase + sc - v;
    if (t == 255) bsum[nb] = ws[0] + ws[1] + ws[2] + ws[3];
}

__global__ __launch_bounds__(256)
void scan3_k(int* __restrict__ offs, int n, const int* __restrict__ bsum, int nb) {
    int i = blockIdx.x * 256 + threadIdx.x;
    if (i < n) offs[i] += bsum[i >> 11];
    else if (i == n) offs[n] = bsum[nb];
}

// ---------------- node scatter: rank (new id) + nidx (old id by new id) ----------------
__global__ __launch_bounds__(256)
void nscatter_k(const int* __restrict__ cid, const int* __restrict__ offsN,
                int* __restrict__ cntN, int* __restrict__ rank, int* __restrict__ nidx) {
    int i = blockIdx.x * 256 + threadIdx.x;
    if (i >= NN) return;
    int c = cid[i];
    int pos = offsN[c] + atomicAdd(&cntN[c], -1) - 1;
    rank[i] = pos;
    nidx[pos] = i;
}

// ---------------- permute node data into new-id order ----------------
__global__ __launch_bounds__(256)
void permute_k(const int* __restrict__ nidx, const float* __restrict__ nodes,
               const float* __restrict__ feats, const int* __restrict__ cid,
               const int* __restrict__ jmap,
               float* __restrict__ pnodes, float* __restrict__ pfeat,
               int* __restrict__ jsrcP) {
    int d = blockIdx.x * 256 + threadIdx.x;
    if (d >= NN) return;
    int i = nidx[d];
    pnodes[3 * d]     = nodes[3 * i];
    pnodes[3 * d + 1] = nodes[3 * i + 1];
    pnodes[3 * d + 2] = nodes[3 * i + 2];
    pfeat[d] = feats[i];
    int c = cid[i];
    unsigned packed = (unsigned)jmap[c] | (((unsigned)c >> 6) << 20);  // j | d2<<20
    jsrcP[d] = (int)packed;
}

// ---------------- bucket histogram over rank[dst] (LDS pre-aggregated) ----------------
__global__ __launch_bounds__(256)
void bhist_k(const int* __restrict__ edst, const int* __restrict__ rank,
             int* __restrict__ btot) {
    __shared__ int h[NB];
    int tid = threadIdx.x;
    for (int i = tid; i < NB; i += 256) h[i] = 0;
    __syncthreads();
    int base = blockIdx.x * PA_EDGES;
    for (int i = 0; i < PA_IT; ++i) {
        int e = base + i * 256 + tid;
        if (e < NE) atomicAdd(&h[rank[edst[e]] >> BSH], 1);
    }
    __syncthreads();
    for (int i = tid; i < NB; i += 256) if (h[i]) atomicAdd(&btot[i], h[i]);
}

// one block: exclusive scan of NB (<=1024) bucket totals -> bbase[NB+1]; copy to cursor
__global__ __launch_bounds__(256)
void scanB_k(const int* __restrict__ btot, int* __restrict__ bbase,
             int* __restrict__ cursor) {
    __shared__ int ws[4];
    int t = threadIdx.x, lane = t & 63, w = t >> 6;
    int i0 = 4 * t;
    int v[4]; int s = 0;
    #pragma unroll
    for (int q = 0; q < 4; ++q) { v[q] = (i0 + q < NB) ? btot[i0 + q] : 0; s += v[q]; }
    int sc = s;
    #pragma unroll
    for (int off = 1; off < 64; off <<= 1) { int o = __shfl_up(sc, off); if (lane >= off) sc += o; }
    if (lane == 63) ws[w] = sc;
    __syncthreads();
    int wb = 0;
    for (int q = 0; q < w; ++q) wb += ws[q];
    int run = wb + sc - s;
    #pragma unroll
    for (int q = 0; q < 4; ++q) {
        if (i0 + q <= NB) { bbase[i0 + q] = run; if (i0 + q < NB) cursor[i0 + q] = run; }
        run += v[q];
    }
}

// ---------------- pass A: partition (rank_src, rank_dst) pairs by dst bucket ----------------
__global__ __launch_bounds__(256)
void passA_k(const int* __restrict__ esrc, const int* __restrict__ edst,
             const int* __restrict__ rank, int* __restrict__ cursor,
             int2* __restrict__ ebuf) {
    __shared__ int hist[NB];
    __shared__ int lofs[NB + 1];
    __shared__ int gbase[NB];
    __shared__ int cnt2[NB];
    __shared__ int2 stage[PA_EDGES];             // 64KB
    __shared__ unsigned short sbid[PA_EDGES];    // 16KB
    __shared__ int ws[4];
    int tid = threadIdx.x, lane = tid & 63, w = tid >> 6;
    for (int i = tid; i < NB; i += 256) { hist[i] = 0; cnt2[i] = 0; }
    __syncthreads();
    int base = blockIdx.x * PA_EDGES;
    for (int i = 0; i < PA_IT; ++i) {
        int e = base + i * 256 + tid;
        if (e < NE) atomicAdd(&hist[rank[edst[e]] >> BSH], 1);
    }
    __syncthreads();
    // exclusive scan hist -> lofs (4 per thread)
    int i0 = 4 * tid;
    int v[4]; int s = 0;
    #pragma unroll
    for (int q = 0; q < 4; ++q) { v[q] = (i0 + q < NB) ? hist[i0 + q] : 0; s += v[q]; }
    int sc = s;
    #pragma unroll
    for (int off = 1; off < 64; off <<= 1) { int o = __shfl_up(sc, off); if (lane >= off) sc += o; }
    if (lane == 63) ws[w] = sc;
    __syncthreads();
    int wb = 0;
    for (int q = 0; q < w; ++q) wb += ws[q];
    int run = wb + sc - s;
    #pragma unroll
    for (int q = 0; q < 4; ++q) {
        if (i0 + q <= NB) lofs[i0 + q] = run;
        run += v[q];
    }
    __syncthreads();
    for (int b = tid; b < NB; b += 256) {
        int c = hist[b];
        gbase[b] = c ? atomicAdd(&cursor[b], c) : 0;
    }
    __syncthreads();
    for (int i = 0; i < PA_IT; ++i) {
        int e = base + i * 256 + tid;
        if (e < NE) {
            int rd = rank[edst[e]], rs = rank[esrc[e]];
            int b = rd >> BSH;
            int p = lofs[b] + atomicAdd(&cnt2[b], 1);
            stage[p] = make_int2(rs, rd);
            sbid[p] = (unsigned short)b;
        }
    }
    __syncthreads();
    int nval = min(PA_EDGES, NE - base);
    for (int k = tid; k < nval; k += 256) {
        int b = sbid[k];
        ebuf[gbase[b] + (k - lofs[b])] = stage[k];
    }
}

// ---------------- pass B: per-bucket final scatter; offs0 (new-id CSR); csrc fused ----------------
__global__ __launch_bounds__(256)
void passB_k(const int2* __restrict__ ebuf, const int* __restrict__ bbase,
             const int* __restrict__ jsrcP,
             int* __restrict__ offs0, int* __restrict__ srcs0, int* __restrict__ csrc0) {
    __shared__ int cnt[BSZ];
    __shared__ int pos[BSZ];
    __shared__ int ws[4];
    int b = blockIdx.x, tid = threadIdx.x, lane = tid & 63, w = tid >> 6;
    int d0 = b << BSH;
    int range = min(BSZ, NN - d0);
    if (tid < BSZ) cnt[tid] = 0;
    __syncthreads();
    int r0 = bbase[b], r1 = bbase[b + 1];
    for (int k = r0 + tid; k < r1; k += 256) atomicAdd(&cnt[ebuf[k].y & (BSZ - 1)], 1);
    __syncthreads();
    int v = (tid < BSZ) ? cnt[tid] : 0;
    int sc = v;
    #pragma unroll
    for (int off = 1; off < 64; off <<= 1) { int o = __shfl_up(sc, off); if (lane >= off) sc += o; }
    if (lane == 63) ws[w] = sc;
    __syncthreads();
    int wb = 0;
    for (int q = 0; q < w; ++q) wb += ws[q];
    int rel = wb + sc - v;                        // exclusive per-dst prefix
    if (tid < range) offs0[d0 + tid] = r0 + rel;
    if (tid == 0) offs0[min(d0 + BSZ, NN)] = r1;  // benign duplicate of next base
    if (tid < BSZ) pos[tid] = r0 + rel;
    __syncthreads();
    for (int k = r0 + tid; k < r1; k += 256) {
        int2 pr = ebuf[k];
        int di = pr.y & (BSZ - 1);
        int p = atomicAdd(&pos[di], 1);
        int rs = pr.x;
        srcs0[p] = rs;
        csrc0[p] = jsrcP[rs];                     // packed j | d2<<20
    }
}

// ---------------- level-2 adjacency list: contiguous edge slice -> LDS bitmap -> list ----------------
__global__ __launch_bounds__(256)
void masklist_k(const int* __restrict__ offsN, const int* __restrict__ offs0,
                const int* __restrict__ csrc0,
                int* __restrict__ l2off, int* __restrict__ l2num,
                int* __restrict__ l2src, int* __restrict__ l2cursor) {
    __shared__ unsigned long long words[64];
    __shared__ int wpre[64];
    __shared__ int sbase;
    int d2 = blockIdx.x, tid = threadIdx.x;
    if (tid < 64) words[tid] = 0;
    __syncthreads();
    // all edges of d2's 64 child cells are one contiguous range (key ordering)
    int e0 = offs0[offsN[d2 << 6]];
    int e1 = offs0[offsN[(d2 + 1) << 6]];
    for (int t = e0 + tid; t < e1; t += 256) {
        int s2 = (int)(((unsigned)csrc0[t]) >> 20);
        atomicOr(&words[s2 >> 6], 1ull << (s2 & 63));
    }
    __syncthreads();
    if (tid < 64) {                                // wave 0 only
        int pc = __popcll(words[tid]);
        int sc = pc;
        #pragma unroll
        for (int off = 1; off < 64; off <<= 1) {
            int o = __shfl_up(sc, off);
            if (tid >= off) sc += o;
        }
        wpre[tid] = sc - pc;                       // exclusive prefix
        if (tid == 63) {
            l2num[d2] = sc;
            int bb = atomicAdd(l2cursor, sc);
            l2off[d2] = bb;
            sbase = bb;
        }
    }
    __syncthreads();
    if (tid < 64) {
        unsigned long long wb = words[tid];
        int p = sbase + wpre[tid];
        while (wb) {
            int b = __builtin_ctzll(wb);
            wb &= wb - 1;
            l2src[p++] = (tid << 6) | b;
        }
    }
}

// ---------------- level 0: h = f @ W_f + pos @ W_p (new-id space) ----------------
template<int CI, int CO>
__global__ __launch_bounds__(256)
void xform0_k(const float* __restrict__ pnodes, const float* __restrict__ f,
              const float* __restrict__ W, float* __restrict__ h) {
    __shared__ float sW[(CI + 3) * CO];
    for (int i = threadIdx.x; i < (CI + 3) * CO; i += 256) sW[i] = W[i];
    __syncthreads();
    int gid = blockIdx.x * 256 + threadIdx.x;
    int i = gid / CO, ch = gid - i * CO;
    if (i >= NN) return;
    float s = pnodes[3 * i] * sW[CI * CO + ch] + pnodes[3 * i + 1] * sW[(CI + 1) * CO + ch]
            + pnodes[3 * i + 2] * sW[(CI + 2) * CO + ch];
    #pragma unroll
    for (int k = 0; k < CI; ++k) s += f[(size_t)i * CI + k] * sW[k * CO + ch];
    h[(size_t)i * CO + ch] = s;
}

// fused: gather over W1 (8ch) + xform W2 (8->16) -> h2. Block covers 32 dst nodes.
__global__ __launch_bounds__(256)
void gatherL0f_k(const float* __restrict__ pnodes, const float* __restrict__ h1,
                 const float* __restrict__ W1pos,       // 3x8
                 const float* __restrict__ W2,          // 11x16
                 const int* __restrict__ offs, const int* __restrict__ srcs,
                 float* __restrict__ h2) {
    __shared__ float sW1[24];
    __shared__ float sW2[176];
    __shared__ float f1s[32][8];
    int tid = threadIdx.x;
    if (tid < 24) sW1[tid] = W1pos[tid];
    if (tid < 176) sW2[tid] = W2[tid];
    __syncthreads();
    int gid = blockIdx.x * 256 + tid;
    int d = gid >> 3, ch = gid & 7;
    int dbase = blockIdx.x * 32;
    if (d < NN) {
        float c = pnodes[3 * d] * sW1[ch] + pnodes[3 * d + 1] * sW1[8 + ch] + pnodes[3 * d + 2] * sW1[16 + ch];
        float m0 = c, m1 = c, m2 = c, m3 = c;
        int e0 = offs[d], e1 = offs[d + 1];
        int t = e0;
        for (; t + 4 <= e1; t += 4) {
            int s0 = srcs[t], s1 = srcs[t + 1], s2 = srcs[t + 2], s3 = srcs[t + 3];
            m0 = fmaxf(m0, h1[(size_t)s0 * 8 + ch]);
            m1 = fmaxf(m1, h1[(size_t)s1 * 8 + ch]);
            m2 = fmaxf(m2, h1[(size_t)s2 * 8 + ch]);
            m3 = fmaxf(m3, h1[(size_t)s3 * 8 + ch]);
        }
        for (; t < e1; ++t) m0 = fmaxf(m0, h1[(size_t)srcs[t] * 8 + ch]);
        f1s[d - dbase][ch] = fmaxf(fmaxf(m0, m1), fmaxf(m2, m3)) - c;
    }
    __syncthreads();
    // epilogue: h2[d][ch2] for 32 d x 16 ch2 = 512 outputs, 2 per thread
    #pragma unroll
    for (int rep = 0; rep < 2; ++rep) {
        int dL = (tid >> 4) + rep * 16, ch2 = tid & 15;
        int dg = dbase + dL;
        if (dg < NN) {
            float s = pnodes[3 * dg] * sW2[128 + ch2] + pnodes[3 * dg + 1] * sW2[144 + ch2]
                    + pnodes[3 * dg + 2] * sW2[160 + ch2];
            #pragma unroll
            for (int k = 0; k < 8; ++k) s += f1s[dL][k] * sW2[k * 16 + ch2];
            h2[(size_t)dg * 16 + ch2] = s;
        }
    }
}

// float4 gather, CO=16: 4 threads per dst node (channel quads)
__global__ __launch_bounds__(256)
void gatherL0v4_k(const float* __restrict__ pnodes, const float* __restrict__ h,
                  const float* __restrict__ Wpos,       // 3x16
                  const int* __restrict__ offs, const int* __restrict__ srcs,
                  float* __restrict__ out) {
    __shared__ float sW[48];
    int tid = threadIdx.x;
    if (tid < 48) sW[tid] = Wpos[tid];
    __syncthreads();
    int gid = blockIdx.x * 256 + tid;
    int d = gid >> 2, q = gid & 3;
    if (d >= NN) return;
    float px = pnodes[3 * d], py = pnodes[3 * d + 1], pz = pnodes[3 * d + 2];
    float4 w0 = *(const float4*)&sW[q * 4];
    float4 w1 = *(const float4*)&sW[16 + q * 4];
    float4 w2 = *(const float4*)&sW[32 + q * 4];
    float4 c = make_float4(px * w0.x + py * w1.x + pz * w2.x, px * w0.y + py * w1.y + pz * w2.y,
                           px * w0.z + py * w1.z + pz * w2.z, px * w0.w + py * w1.w + pz * w2.w);
    float4 m0 = c, m1 = c, m2 = c, m3 = c;       // no self-loop at level 0; empty -> 0
    int e0 = offs[d], e1 = offs[d + 1];
    int t = e0;
    for (; t + 4 <= e1; t += 4) {
        int s0 = srcs[t], s1 = srcs[t + 1], s2 = srcs[t + 2], s3 = srcs[t + 3];
        m0 = max4(m0, *(const float4*)&h[(size_t)s0 * 16 + q * 4]);
        m1 = max4(m1, *(const float4*)&h[(size_t)s1 * 16 + q * 4]);
        m2 = max4(m2, *(const float4*)&h[(size_t)s2 * 16 + q * 4]);
        m3 = max4(m3, *(const float4*)&h[(size_t)s3 * 16 + q * 4]);
    }
    for (; t < e1; ++t) m0 = max4(m0, *(const float4*)&h[(size_t)srcs[t] * 16 + q * 4]);
    float4 m = max4(max4(m0, m1), max4(m2, m3));
    *(float4*)&out[(size_t)d * 16 + q * 4] = make_float4(m.x - c.x, m.y - c.y, m.z - c.z, m.w - c.w);
}

// ---------------- level 1: fused pool(16ch) + xform W3 -> Hc ----------------
__global__ __launch_bounds__(256)
void pxformL1_k(const float* __restrict__ f2, const int* __restrict__ offsN,
                const int* __restrict__ oclist, const int* __restrict__ ocount,
                const float* __restrict__ W3, float* __restrict__ h) {
    __shared__ float sW[19 * 32];
    __shared__ float nf[8][16];
    for (int i = threadIdx.x; i < 19 * 32; i += 256) sW[i] = W3[i];
    int gid = blockIdx.x * 256 + threadIdx.x;
    int j = gid >> 5, ch = gid & 31;
    int lj = threadIdx.x >> 5;                   // 8 js per block
    bool valid = j < *ocount;
    int d = valid ? oclist[j] : 0;
    if (valid && ch < 16) {
        float m = 0.f;                           // f2 >= 0 (post-relu)
        int n0 = offsN[d], n1 = offsN[d + 1];
        for (int n = n0; n < n1; ++n) m = fmaxf(m, f2[(size_t)n * 16 + ch]);
        nf[lj][ch] = m;
    }
    __syncthreads();
    if (!valid) return;
    float px, py, pz;
    key2xyz(d, px, py, pz);
    float s = px * sW[16 * 32 + ch] + py * sW[17 * 32 + ch] + pz * sW[18 * 32 + ch];
    #pragma unroll
    for (int k = 0; k < 16; ++k) s += nf[lj][k] * sW[k * 32 + ch];
    h[(size_t)j * 32 + ch] = s;
}

// fused float4 gather(W3pos) + xform W4 (32->32) -> hnext (different buffer).
__global__ __launch_bounds__(256)
void gatherL1f_k(const float* __restrict__ h, const float* __restrict__ W3pos,
                 const float* __restrict__ W4,          // 35x32
                 const int* __restrict__ offsN, const int* __restrict__ offs0,
                 const int* __restrict__ csrc0,
                 const int* __restrict__ oclist, const int* __restrict__ ocount,
                 float* __restrict__ hnext) {
    __shared__ float sWp[96];
    __shared__ float sW4[35 * 32];
    __shared__ float gsT[32][33];                // [ch][lj], padded
    int tid = threadIdx.x;
    if (tid < 96) sWp[tid] = W3pos[tid];
    for (int i = tid; i < 35 * 32; i += 256) sW4[i] = W4[i];
    __syncthreads();
    int gid = blockIdx.x * 256 + tid;
    int j = gid >> 3, q = gid & 7;
    int lj = tid >> 3;
    bool valid = j < *ocount;
    float px = 0, py = 0, pz = 0;
    if (valid) {
        int d = oclist[j];
        key2xyz(d, px, py, pz);
        float4 w0 = *(const float4*)&sWp[q * 4];
        float4 w1 = *(const float4*)&sWp[32 + q * 4];
        float4 w2 = *(const float4*)&sWp[64 + q * 4];
        float4 c = make_float4(px * w0.x + py * w1.x + pz * w2.x, px * w0.y + py * w1.y + pz * w2.y,
                               px * w0.z + py * w1.z + pz * w2.z, px * w0.w + py * w1.w + pz * w2.w);
        float4 self = *(const float4*)&h[(size_t)j * 32 + q * 4];
        float4 m0 = max4(c, self), m1 = m0, m2 = m0, m3 = m0;   // self-loop
        int e0 = offs0[offsN[d]], e1 = offs0[offsN[d + 1]];
        int t = e0;
        for (; t + 4 <= e1; t += 4) {
            int s0 = csrc0[t] & JMASK, s1 = csrc0[t + 1] & JMASK;
            int s2 = csrc0[t + 2] & JMASK, s3 = csrc0[t + 3] & JMASK;
            m0 = max4(m0, *(const float4*)&h[(size_t)s0 * 32 + q * 4]);
            m1 = max4(m1, *(const float4*)&h[(size_t)s1 * 32 + q * 4]);
            m2 = max4(m2, *(const float4*)&h[(size_t)s2 * 32 + q * 4]);
            m3 = max4(m3, *(const float4*)&h[(size_t)s3 * 32 + q * 4]);
        }
        for (; t < e1; ++t) m0 = max4(m0, *(const float4*)&h[(size_t)(csrc0[t] & JMASK) * 32 + q * 4]);
        float4 m = max4(max4(m0, m1), max4(m2, m3));
        gsT[q * 4 + 0][lj] = m.x - c.x;
        gsT[q * 4 + 1][lj] = m.y - c.y;
        gsT[q * 4 + 2][lj] = m.z - c.z;
        gsT[q * 4 + 3][lj] = m.w - c.w;
    }
    __syncthreads();
    if (!valid) return;
    float4 s4;
    {
        float4 w0 = *(const float4*)&sW4[32 * 32 + q * 4];
        float4 w1 = *(const float4*)&sW4[33 * 32 + q * 4];
        float4 w2 = *(const float4*)&sW4[34 * 32 + q * 4];
        s4 = make_float4(px * w0.x + py * w1.x + pz * w2.x, px * w0.y + py * w1.y + pz * w2.y,
                         px * w0.z + py * w1.z + pz * w2.z, px * w0.w + py * w1.w + pz * w2.w);
    }
    #pragma unroll
    for (int k = 0; k < 32; ++k) {
        float g = gsT[k][lj];
        s4 = fma4(g, *(const float4*)&sW4[k * 32 + q * 4], s4);
    }
    *(float4*)&hnext[(size_t)j * 32 + q * 4] = s4;
}

// plain float4 flat gather (final level-1 layer)
__global__ __launch_bounds__(256)
void gatherL1_k(const float* __restrict__ h, const float* __restrict__ Wpos,
                const int* __restrict__ offsN, const int* __restrict__ offs0,
                const int* __restrict__ csrc0,
                const int* __restrict__ oclist, const int* __restrict__ ocount,
                float* __restrict__ g) {
    __shared__ float sW[96];
    int tid = threadIdx.x;
    if (tid < 96) sW[tid] = Wpos[tid];
    __syncthreads();
    int gid = blockIdx.x * 256 + tid;
    int j = gid >> 3, q = gid & 7;
    if (j >= *ocount) return;
    int d = oclist[j];
    float px, py, pz;
    key2xyz(d, px, py, pz);
    float4 w0 = *(const float4*)&sW[q * 4];
    float4 w1 = *(const float4*)&sW[32 + q * 4];
    float4 w2 = *(const float4*)&sW[64 + q * 4];
    float4 c = make_float4(px * w0.x + py * w1.x + pz * w2.x, px * w0.y + py * w1.y + pz * w2.y,
                           px * w0.z + py * w1.z + pz * w2.z, px * w0.w + py * w1.w + pz * w2.w);
    float4 self = *(const float4*)&h[(size_t)j * 32 + q * 4];
    float4 m0 = max4(c, self), m1 = m0, m2 = m0, m3 = m0;   // self-loop
    int e0 = offs0[offsN[d]], e1 = offs0[offsN[d + 1]];
    int t = e0;
    for (; t + 4 <= e1; t += 4) {
        int s0 = csrc0[t] & JMASK, s1 = csrc0[t + 1] & JMASK;
        int s2 = csrc0[t + 2] & JMASK, s3 = csrc0[t + 3] & JMASK;
        m0 = max4(m0, *(const float4*)&h[(size_t)s0 * 32 + q * 4]);
        m1 = max4(m1, *(const float4*)&h[(size_t)s1 * 32 + q * 4]);
        m2 = max4(m2, *(const float4*)&h[(size_t)s2 * 32 + q * 4]);
        m3 = max4(m3, *(const float4*)&h[(size_t)s3 * 32 + q * 4]);
    }
    for (; t < e1; ++t) m0 = max4(m0, *(const float4*)&h[(size_t)(csrc0[t] & JMASK) * 32 + q * 4]);
    float4 m = max4(max4(m0, m1), max4(m2, m3));
    *(float4*)&g[(size_t)j * 32 + q * 4] = make_float4(m.x - c.x, m.y - c.y, m.z - c.z, m.w - c.w);
}

// ---------------- level 2 (block per 16^3 cell) ----------------
// children of d2 are the contiguous key range [d2*64, d2*64+64)
__global__ __launch_bounds__(256)
void pool2x_k(const float* __restrict__ Gc, const int* __restrict__ jmap,
              const float* __restrict__ W5, float* __restrict__ h5) {
    __shared__ float part[8][32];
    __shared__ float nf2row[32];
    int d2 = blockIdx.x, tid = threadIdx.x;
    int x2 = d2 >> 8, y2 = (d2 >> 4) & 15, z2 = d2 & 15;
    int ch = tid & 31, grp = tid >> 5;                 // 8 grps x 8 children
    float m = 0.f;
    #pragma unroll
    for (int cc = 0; cc < 8; ++cc) {
        int cj = jmap[(d2 << 6) | (grp * 8 + cc)];
        if (cj >= 0) m = fmaxf(m, Gc[(size_t)cj * 32 + ch]);
    }
    part[grp][ch] = m;
    __syncthreads();
    if (tid < 32) {
        float mm = part[0][tid];
        #pragma unroll
        for (int g = 1; g < 8; ++g) mm = fmaxf(mm, part[g][tid]);
        nf2row[tid] = mm;
    }
    __syncthreads();
    if (tid < 64) {
        float s = x2 * W5[32 * 64 + tid] + y2 * W5[33 * 64 + tid] + z2 * W5[34 * 64 + tid];
        #pragma unroll
        for (int k = 0; k < 32; ++k) s += nf2row[k] * W5[k * 64 + tid];
        h5[(size_t)d2 * 64 + tid] = s;
    }
}

// level-2 gconv via flat adjacency list, float4 (+ optional fused next xform). One block per d2.
template<bool FUSE, bool WRITE_G>
__global__ __launch_bounds__(256)
void gconvL2_k(const float* __restrict__ h, const float* __restrict__ Wpos,
               const int* __restrict__ l2off, const int* __restrict__ l2num,
               const int* __restrict__ l2src,
               const float* __restrict__ Wn,           // (64+3)x64, if FUSE
               float* __restrict__ gout, float* __restrict__ hnext) {
    __shared__ float red[16][64];
    __shared__ float grow[64];
    int d2 = blockIdx.x, tid = threadIdx.x;
    int x2 = d2 >> 8, y2 = (d2 >> 4) & 15, z2 = d2 & 15;
    int q = tid & 15, grp = tid >> 4;                  // 16 groups split the list
    int n0 = l2off[d2], num = l2num[d2];
    int per = (num + 15) >> 4;
    int s = n0 + grp * per;
    int e = min(n0 + num, s + per);
    float4 m0 = make_float4(-1e30f, -1e30f, -1e30f, -1e30f);
    float4 m1 = m0, m2 = m0, m3 = m0;
    int t = s;
    for (; t + 4 <= e; t += 4) {
        int s0 = l2src[t], s1 = l2src[t + 1], s2 = l2src[t + 2], s3 = l2src[t + 3];
        m0 = max4(m0, *(const float4*)&h[(size_t)s0 * 64 + q * 4]);
        m1 = max4(m1, *(const float4*)&h[(size_t)s1 * 64 + q * 4]);
        m2 = max4(m2, *(const float4*)&h[(size_t)s2 * 64 + q * 4]);
        m3 = max4(m3, *(const float4*)&h[(size_t)s3 * 64 + q * 4]);
    }
    for (; t < e; ++t) m0 = max4(m0, *(const float4*)&h[(size_t)l2src[t] * 64 + q * 4]);
    float4 m = max4(max4(m0, m1), max4(m2, m3));
    red[grp][q * 4 + 0] = m.x;
    red[grp][q * 4 + 1] = m.y;
    red[grp][q * 4 + 2] = m.z;
    red[grp][q * 4 + 3] = m.w;
    __syncthreads();
    if (tid < 64) {
        int ch = tid;
        float mm = red[0][ch];
        #pragma unroll
        for (int g = 1; g < 16; ++g) mm = fmaxf(mm, red[g][ch]);
        float c = x2 * Wpos[ch] + y2 * Wpos[64 + ch] + z2 * Wpos[128 + ch];
        mm = fmaxf(mm, fmaxf(c, h[(size_t)d2 * 64 + ch]));   // self-loop + empty
        float g = mm - c;
        if (WRITE_G) gout[(size_t)d2 * 64 + ch] = g;
        if (FUSE) grow[ch] = g;
    }
    if (FUSE) {
        __syncthreads();
        if (tid < 64) {
            float s2v = x2 * Wn[64 * 64 + tid] + y2 * Wn[65 * 64 + tid] + z2 * Wn[66 * 64 + tid];
            #pragma unroll
            for (int k = 0; k < 64; ++k) s2v += grow[k] * Wn[k * 64 + tid];
            hnext[(size_t)d2 * 64 + tid] = s2v;
        }
    }
}

// ---------------- output pool + linear ----------------
__global__ __launch_bounds__(256)
void outpool_k(const float* __restrict__ g7, float* __restrict__ xo) {
    int gid = blockIdx.x * 256 + threadIdx.x;
    if (gid >= 64 * 64) return;
    int oc = gid >> 6, ch = gid & 63;
    int cx = oc >> 4, cy = (oc >> 2) & 3, cz = oc & 3;
    float m = 0.f;
    for (int tc = 0; tc < 64; ++tc) {
        int i = tc >> 4, j = (tc >> 2) & 3, k = tc & 3;
        int d2 = ((cx * 4 + i) * 16 + (cy * 4 + j)) * 16 + (cz * 4 + k);
        m = fmaxf(m, g7[(size_t)d2 * 64 + ch]);
    }
    xo[(size_t)oc * 64 + ch] = m;
}

__global__ __launch_bounds__(64)
void linear_k(const float* __restrict__ xo, const float* __restrict__ Wl,
              const float* __restrict__ bl, float* __restrict__ out) {
    int j = blockIdx.x;
    float s = 0.f;
    for (int i = threadIdx.x; i < 4096; i += 64) s += xo[i] * Wl[(size_t)i * 100 + j];
    #pragma unroll
    for (int off = 32; off; off >>= 1) s += __shfl_down(s, off);
    if (threadIdx.x == 0) out[j] = s + bl[j];
}

extern "C" void kernel_launch(void* const* d_in, const int* in_sizes, int n_in,
                              void* d_out, int out_size, void* d_ws, size_t ws_size,
                              hipStream_t stream) {
    (void)in_sizes; (void)n_in; (void)out_size;
    const float* nodes = (const float*)d_in[0];
    const float* feats = (const float*)d_in[1];
    const int*   edges = (const int*)d_in[2];
    const int*   esrc  = edges;
    const int*   edst  = edges + NE;
    const float* W1 = (const float*)d_in[3];
    const float* W2 = (const float*)d_in[4];
    const float* W3 = (const float*)d_in[5];
    const float* W4 = (const float*)d_in[6];
    const float* W5 = (const float*)d_in[7];
    const float* W6 = (const float*)d_in[8];
    const float* W7 = (const float*)d_in[9];
    const float* Wl = (const float*)d_in[10];
    const float* bl = (const float*)d_in[11];
    float* out = (float*)d_out;

    char* ws = (char*)d_ws;
    size_t off = 0;
    auto alloc = [&](size_t bytes) { void* p = ws + off; off = (off + bytes + 255) & ~(size_t)255; return p; };
    // zero region: cntN + ocount + btot + l2cursor (one memset)
    int*   cntN    = (int*)alloc((size_t)C1 * 4);
    int*   ocount  = (int*)alloc(4);
    int*   btot    = (int*)alloc((size_t)NB * 4);
    int*   l2cursor= (int*)alloc(4);
    size_t zero_bytes = off;
    int*   bsum   = (int*)alloc(260 * 4);
    int*   bbase  = (int*)alloc((size_t)(NB + 1) * 4);
    int*   cursor = (int*)alloc((size_t)NB * 4);
    int*   cid    = (int*)alloc((size_t)NN * 4);
    int*   rank   = (int*)alloc((size_t)NN * 4);
    int*   nidx   = (int*)alloc((size_t)NN * 4);
    int*   offsN  = (int*)alloc((size_t)(C1 + 1) * 4);
    int*   offs0  = (int*)alloc((size_t)(NN + 1) * 4);
    int*   srcs0  = (int*)alloc((size_t)NE * 4);
    int*   csrc0  = (int*)alloc((size_t)NE * 4);
    int2*  ebuf   = (int2*)alloc((size_t)NE * 8);
    int*   oclist = (int*)alloc((size_t)NN * 4);
    int*   jmap   = (int*)alloc((size_t)C1 * 4);
    int*   jsrcP  = (int*)alloc((size_t)NN * 4);
    int*   l2off  = (int*)alloc((size_t)C2 * 4);
    int*   l2num  = (int*)alloc((size_t)C2 * 4);
    int*   l2srcA = (int*)alloc((size_t)NE * 4);
    float* pnodes = (float*)alloc((size_t)NN * 3 * 4);
    float* pfeat  = (float*)alloc((size_t)NN * 4);
    float* A      = (float*)alloc((size_t)NN * 48 * 4);   // h1, h2, f2
    float* Hc     = (float*)alloc((size_t)NN * 32 * 4);
    float* Gc     = (float*)alloc((size_t)NN * 32 * 4);
    float* h5     = (float*)alloc((size_t)C2 * 64 * 4);
    float* h6     = (float*)alloc((size_t)C2 * 64 * 4);
    float* h7     = (float*)alloc((size_t)C2 * 64 * 4);
    float* g7     = (float*)alloc((size_t)C2 * 64 * 4);
    float* xo     = (float*)alloc((size_t)64 * 64 * 4);
    if (ws_size < off) return;

    float* h1 = A;                      // [NN][8]
    float* h2 = A + (size_t)NN * 16;    // [NN][16]
    float* f2 = A + (size_t)NN * 32;    // [NN][16]

    hipMemsetAsync(cntN, 0, zero_bytes, stream);

    auto gr = [](long long n) { return (int)((n + 255) / 256); };
    const int nbC1 = (C1 + 2047) / 2048;   // 128
    const int gPA  = (NE + PA_EDGES - 1) / PA_EDGES;  // 196

    // ---- connectivity build (key space) ----
    cidhist_k<<<gr(NN), 256, 0, stream>>>(nodes, cid, cntN);
    oclist_k<<<C1 / 256, 256, 0, stream>>>(cntN, oclist, jmap, ocount);
    scan1_k<<<nbC1, 256, 0, stream>>>(cntN, C1, offsN, bsum);
    scan2_k<<<1, 256, 0, stream>>>(bsum, nbC1);
    scan3_k<<<gr(C1 + 1), 256, 0, stream>>>(offsN, C1, bsum, nbC1);
    nscatter_k<<<gr(NN), 256, 0, stream>>>(cid, offsN, cntN, rank, nidx);
    permute_k<<<gr(NN), 256, 0, stream>>>(nidx, nodes, feats, cid, jmap, pnodes, pfeat, jsrcP);
    bhist_k<<<gPA, 256, 0, stream>>>(edst, rank, btot);
    scanB_k<<<1, 256, 0, stream>>>(btot, bbase, cursor);
    passA_k<<<gPA, 256, 0, stream>>>(esrc, edst, rank, cursor, ebuf);
    passB_k<<<NB, 256, 0, stream>>>(ebuf, bbase, jsrcP, offs0, srcs0, csrc0);
    masklist_k<<<C2, 256, 0, stream>>>(offsN, offs0, csrc0, l2off, l2num, l2srcA, l2cursor);

    // ---- level 0 (rank space) ----
    xform0_k<1, 8><<<gr((long long)NN * 8), 256, 0, stream>>>(pnodes, pfeat, W1, h1);
    gatherL0f_k<<<gr((long long)NN * 8), 256, 0, stream>>>(pnodes, h1, W1 + 1 * 8, W2, offs0, srcs0, h2);
    gatherL0v4_k<<<gr((long long)NN * 4), 256, 0, stream>>>(pnodes, h2, W2 + 8 * 16, offs0, srcs0, f2);

    // ---- level 1 (compact occupied cells, flat edge ranges; ping-pong Hc/Gc) ----
    pxformL1_k<<<gr((long long)NN * 32), 256, 0, stream>>>(f2, offsN, oclist, ocount, W3, Hc);
    gatherL1f_k<<<gr((long long)NN * 8), 256, 0, stream>>>(Hc, W3 + 16 * 32, W4, offsN, offs0, csrc0, oclist, ocount, Gc);
    gatherL1_k<<<gr((long long)NN * 8), 256, 0, stream>>>(Gc, W4 + 32 * 32, offsN, offs0, csrc0, oclist, ocount, Hc);

    // ---- level 2 (block per 16^3 cell, list-driven, fused) ----
    pool2x_k<<<C2, 256, 0, stream>>>(Hc, jmap, W5, h5);
    gconvL2_k<true,  false><<<C2, 256, 0, stream>>>(h5, W5 + 32 * 64, l2off, l2num, l2srcA, W6, nullptr, h6);
    gconvL2_k<true,  false><<<C2, 256, 0, stream>>>(h6, W6 + 64 * 64, l2off, l2num, l2srcA, W7, nullptr, h7);
    gconvL2_k<false, true ><<<C2, 256, 0, stream>>>(h7, W7 + 64 * 64, l2off, l2num, l2srcA, nullptr, g7, nullptr);

    outpool_k<<<16, 256, 0, stream>>>(g7, xo);
    linear_k<<<100, 64, 0, stream>>>(xo, Wl, bl, out);
}

// Round 14
// 430.898 us; speedup vs baseline: 56.2461x; 1.0739x over previous
//
#include <hip/hip_runtime.h>

#define NN 100000      // nodes
#define NE 1600000     // edges
#define C1 262144      // 64^3 cells (keyed as d2*64+child)
#define C2 4096        // 16^3 cells
#define BSH 7          // bucket shift (128 new-ids per bucket)
#define BSZ 128
#define NB 782         // ceil(NN/128)
#define PA_EDGES 8192
#define PA_IT (PA_EDGES / 256)
#define JMASK 0xFFFFF  // low 20 bits: compact j; bits 20..31: d2 of src cell

// cell key layout: key = d2*64 + child, d2 = (x>>2)*256+(y>>2)*16+(z>>2),
// child = (x&3)*16+(y&3)*4+(z&3)
__device__ __forceinline__ void key2xyz(int key, float& x, float& y, float& z) {
    int d2 = key >> 6, ch = key & 63;
    x = (float)((((d2 >> 8) & 15) << 2) | (ch >> 4));
    y = (float)((((d2 >> 4) & 15) << 2) | ((ch >> 2) & 3));
    z = (float)(((d2 & 15) << 2) | (ch & 3));
}
__device__ __forceinline__ float4 max4(float4 a, float4 b) {
    return make_float4(fmaxf(a.x, b.x), fmaxf(a.y, b.y), fmaxf(a.z, b.z), fmaxf(a.w, b.w));
}
__device__ __forceinline__ float4 fma4(float s, float4 w, float4 acc) {
    return make_float4(s * w.x + acc.x, s * w.y + acc.y, s * w.z + acc.z, s * w.w + acc.w);
}

// ---------------- cell key of each node + node-per-cell histogram ----------------
__global__ __launch_bounds__(256)
void cidhist_k(const float* __restrict__ nodes, int* __restrict__ cid,
               int* __restrict__ cntN) {
    int i = blockIdx.x * 256 + threadIdx.x;
    if (i >= NN) return;
    int cx = min(max((int)floorf(nodes[3 * i]     * 0.25f), 0), 63);
    int cy = min(max((int)floorf(nodes[3 * i + 1] * 0.25f), 0), 63);
    int cz = min(max((int)floorf(nodes[3 * i + 2] * 0.25f), 0), 63);
    int d2 = ((cx >> 2) * 16 + (cy >> 2)) * 16 + (cz >> 2);
    int ch = ((cx & 3) * 4 + (cy & 3)) * 4 + (cz & 3);
    int key = (d2 << 6) | ch;
    cid[i] = key;
    atomicAdd(&cntN[key], 1);
}

// ---------------- occupied-cell list + cell->compact-index map ----------------
__global__ __launch_bounds__(256)
void oclist_k(const int* __restrict__ cntN, int* __restrict__ oclist,
              int* __restrict__ jmap, int* __restrict__ ocount) {
    int c = blockIdx.x * 256 + threadIdx.x;     // grid covers C1 exactly (keys)
    bool occ = cntN[c] > 0;
    unsigned long long b = __ballot(occ);
    int lane = threadIdx.x & 63;
    int cnt = __popcll(b);
    int base = 0;
    if (cnt) {
        if (lane == 0) base = atomicAdd(ocount, cnt);
        base = __shfl(base, 0);
    }
    int pre = __popcll(b & ((1ull << lane) - 1));
    int j = occ ? base + pre : -1;
    jmap[c] = j;
    if (occ) oclist[j] = c;
}

// ---------------- generic exclusive scan: 2048/block ----------------
__global__ __launch_bounds__(256)
void scan1_k(const int* __restrict__ cnt, int n, int* __restrict__ offs,
             int* __restrict__ bsum) {
    __shared__ int ws[4];
    int t = threadIdx.x, lane = t & 63, w = t >> 6;
    int base = blockIdx.x * 2048 + t * 8;
    int v[8]; int s = 0;
    #pragma unroll
    for (int i = 0; i < 8; ++i) { v[i] = (base + i < n) ? cnt[base + i] : 0; s += v[i]; }
    int sc = s;
    #pragma unroll
    for (int off = 1; off < 64; off <<= 1) { int o = __shfl_up(sc, off); if (lane >= off) sc += o; }
    if (lane == 63) ws[w] = sc;
    __syncthreads();
    int wbase = 0;
    for (int i = 0; i < w; ++i) wbase += ws[i];
    int run = wbase + sc - s;
    #pragma unroll
    for (int i = 0; i < 8; ++i) { if (base + i < n) offs[base + i] = run; run += v[i]; }
    if (t == 255) bsum[blockIdx.x] = wbase + sc;
}

__global__ __launch_bounds__(256)
void scan2_k(int* __restrict__ bsum, int nb) {   // one block, nb <= 256
    __shared__ int ws[4];
    int t = threadIdx.x, lane = t & 63, w = t >> 6;
    int v = (t < nb) ? bsum[t] : 0;
    int sc = v;
    #pragma unroll
    for (int off = 1; off < 64; off <<= 1) { int o = __shfl_up(sc, off); if (lane >= off) sc += o; }
    if (lane == 63) ws[w] = sc;
    __syncthreads();
    int wbase = 0;
    for (int i = 0; i < w; ++i) wbase += ws[i];
    if (t < nb) bsum[t] = wbase + sc - v;
    if (t == 255) bsum[nb] = ws[0] + ws[1] + ws[2] + ws[3];
}

__global__ __launch_bounds__(256)
void scan3_k(int* __restrict__ offs, int n, const int* __restrict__ bsum, int nb) {
    int i = blockIdx.x * 256 + threadIdx.x;
    if (i < n) offs[i] += bsum[i >> 11];
    else if (i == n) offs[n] = bsum[nb];
}

// ---------------- node scatter: rank (new id) + nidx (old id by new id) ----------------
__global__ __launch_bounds__(256)
void nscatter_k(const int* __restrict__ cid, const int* __restrict__ offsN,
                int* __restrict__ cntN, int* __restrict__ rank, int* __restrict__ nidx) {
    int i = blockIdx.x * 256 + threadIdx.x;
    if (i >= NN) return;
    int c = cid[i];
    int pos = offsN[c] + atomicAdd(&cntN[c], -1) - 1;
    rank[i] = pos;
    nidx[pos] = i;
}

// ---------------- permute node data into new-id order ----------------
__global__ __launch_bounds__(256)
void permute_k(const int* __restrict__ nidx, const float* __restrict__ nodes,
               const float* __restrict__ feats, const int* __restrict__ cid,
               const int* __restrict__ jmap,
               float* __restrict__ pnodes, float* __restrict__ pfeat,
               int* __restrict__ jsrcP) {
    int d = blockIdx.x * 256 + threadIdx.x;
    if (d >= NN) return;
    int i = nidx[d];
    pnodes[3 * d]     = nodes[3 * i];
    pnodes[3 * d + 1] = nodes[3 * i + 1];
    pnodes[3 * d + 2] = nodes[3 * i + 2];
    pfeat[d] = feats[i];
    int c = cid[i];
    unsigned packed = (unsigned)jmap[c] | (((unsigned)c >> 6) << 20);  // j | d2<<20
    jsrcP[d] = (int)packed;
}

// ---------------- bucket histogram over rank[dst] (LDS pre-aggregated) ----------------
__global__ __launch_bounds__(256)
void bhist_k(const int* __restrict__ edst, const int* __restrict__ rank,
             int* __restrict__ btot) {
    __shared__ int h[NB];
    int tid = threadIdx.x;
    for (int i = tid; i < NB; i += 256) h[i] = 0;
    __syncthreads();
    int base = blockIdx.x * PA_EDGES;
    for (int i = 0; i < PA_IT; ++i) {
        int e = base + i * 256 + tid;
        if (e < NE) atomicAdd(&h[rank[edst[e]] >> BSH], 1);
    }
    __syncthreads();
    for (int i = tid; i < NB; i += 256) if (h[i]) atomicAdd(&btot[i], h[i]);
}

// one block: exclusive scan of NB (<=1024) bucket totals -> bbase[NB+1]; copy to cursor
__global__ __launch_bounds__(256)
void scanB_k(const int* __restrict__ btot, int* __restrict__ bbase,
             int* __restrict__ cursor) {
    __shared__ int ws[4];
    int t = threadIdx.x, lane = t & 63, w = t >> 6;
    int i0 = 4 * t;
    int v[4]; int s = 0;
    #pragma unroll
    for (int q = 0; q < 4; ++q) { v[q] = (i0 + q < NB) ? btot[i0 + q] : 0; s += v[q]; }
    int sc = s;
    #pragma unroll
    for (int off = 1; off < 64; off <<= 1) { int o = __shfl_up(sc, off); if (lane >= off) sc += o; }
    if (lane == 63) ws[w] = sc;
    __syncthreads();
    int wb = 0;
    for (int q = 0; q < w; ++q) wb += ws[q];
    int run = wb + sc - s;
    #pragma unroll
    for (int q = 0; q < 4; ++q) {
        if (i0 + q <= NB) { bbase[i0 + q] = run; if (i0 + q < NB) cursor[i0 + q] = run; }
        run += v[q];
    }
}

// ---------------- pass A: partition (rank_src, rank_dst) pairs by dst bucket ----------------
__global__ __launch_bounds__(256)
void passA_k(const int* __restrict__ esrc, const int* __restrict__ edst,
             const int* __restrict__ rank, int* __restrict__ cursor,
             int2* __restrict__ ebuf) {
    __shared__ int hist[NB];
    __shared__ int lofs[NB + 1];
    __shared__ int gbase[NB];
    __shared__ int cnt2[NB];
    __shared__ int2 stage[PA_EDGES];             // 64KB
    __shared__ unsigned short sbid[PA_EDGES];    // 16KB
    __shared__ int ws[4];
    int tid = threadIdx.x, lane = tid & 63, w = tid >> 6;
    for (int i = tid; i < NB; i += 256) { hist[i] = 0; cnt2[i] = 0; }
    __syncthreads();
    int base = blockIdx.x * PA_EDGES;
    for (int i = 0; i < PA_IT; ++i) {
        int e = base + i * 256 + tid;
        if (e < NE) atomicAdd(&hist[rank[edst[e]] >> BSH], 1);
    }
    __syncthreads();
    // exclusive scan hist -> lofs (4 per thread)
    int i0 = 4 * tid;
    int v[4]; int s = 0;
    #pragma unroll
    for (int q = 0; q < 4; ++q) { v[q] = (i0 + q < NB) ? hist[i0 + q] : 0; s += v[q]; }
    int sc = s;
    #pragma unroll
    for (int off = 1; off < 64; off <<= 1) { int o = __shfl_up(sc, off); if (lane >= off) sc += o; }
    if (lane == 63) ws[w] = sc;
    __syncthreads();
    int wb = 0;
    for (int q = 0; q < w; ++q) wb += ws[q];
    int run = wb + sc - s;
    #pragma unroll
    for (int q = 0; q < 4; ++q) {
        if (i0 + q <= NB) lofs[i0 + q] = run;
        run += v[q];
    }
    __syncthreads();
    for (int b = tid; b < NB; b += 256) {
        int c = hist[b];
        gbase[b] = c ? atomicAdd(&cursor[b], c) : 0;
    }
    __syncthreads();
    for (int i = 0; i < PA_IT; ++i) {
        int e = base + i * 256 + tid;
        if (e < NE) {
            int rd = rank[edst[e]], rs = rank[esrc[e]];
            int b = rd >> BSH;
            int p = lofs[b] + atomicAdd(&cnt2[b], 1);
            stage[p] = make_int2(rs, rd);
            sbid[p] = (unsigned short)b;
        }
    }
    __syncthreads();
    int nval = min(PA_EDGES, NE - base);
    for (int k = tid; k < nval; k += 256) {
        int b = sbid[k];
        ebuf[gbase[b] + (k - lofs[b])] = stage[k];
    }
}

// ---------------- pass B: per-bucket final scatter; offs0 (new-id CSR); csrc fused ----------------
__global__ __launch_bounds__(256)
void passB_k(const int2* __restrict__ ebuf, const int* __restrict__ bbase,
             const int* __restrict__ jsrcP,
             int* __restrict__ offs0, int* __restrict__ srcs0, int* __restrict__ csrc0) {
    __shared__ int cnt[BSZ];
    __shared__ int pos[BSZ];
    __shared__ int ws[4];
    int b = blockIdx.x, tid = threadIdx.x, lane = tid & 63, w = tid >> 6;
    int d0 = b << BSH;
    int range = min(BSZ, NN - d0);
    if (tid < BSZ) cnt[tid] = 0;
    __syncthreads();
    int r0 = bbase[b], r1 = bbase[b + 1];
    for (int k = r0 + tid; k < r1; k += 256) atomicAdd(&cnt[ebuf[k].y & (BSZ - 1)], 1);
    __syncthreads();
    int v = (tid < BSZ) ? cnt[tid] : 0;
    int sc = v;
    #pragma unroll
    for (int off = 1; off < 64; off <<= 1) { int o = __shfl_up(sc, off); if (lane >= off) sc += o; }
    if (lane == 63) ws[w] = sc;
    __syncthreads();
    int wb = 0;
    for (int q = 0; q < w; ++q) wb += ws[q];
    int rel = wb + sc - v;                        // exclusive per-dst prefix
    if (tid < range) offs0[d0 + tid] = r0 + rel;
    if (tid == 0) offs0[min(d0 + BSZ, NN)] = r1;  // benign duplicate of next base
    if (tid < BSZ) pos[tid] = r0 + rel;
    __syncthreads();
    for (int k = r0 + tid; k < r1; k += 256) {
        int2 pr = ebuf[k];
        int di = pr.y & (BSZ - 1);
        int p = atomicAdd(&pos[di], 1);
        int rs = pr.x;
        srcs0[p] = rs;
        csrc0[p] = jsrcP[rs];                     // packed j | d2<<20
    }
}

// ---------------- level-2 bitmap: contiguous edge slice -> LDS bitmap -> global ----------------
__global__ __launch_bounds__(256)
void mask_k(const int* __restrict__ offsN, const int* __restrict__ offs0,
            const int* __restrict__ csrc0,
            unsigned long long* __restrict__ mask, int* __restrict__ l2num) {
    __shared__ unsigned long long words[64];
    int d2 = blockIdx.x, tid = threadIdx.x;
    if (tid < 64) words[tid] = 0;
    __syncthreads();
    // all edges of d2's 64 child cells are one contiguous range (key ordering)
    int e0 = offs0[offsN[d2 << 6]];
    int e1 = offs0[offsN[(d2 + 1) << 6]];
    for (int t = e0 + tid; t < e1; t += 256) {
        int s2 = (int)(((unsigned)csrc0[t]) >> 20);
        atomicOr(&words[s2 >> 6], 1ull << (s2 & 63));
    }
    __syncthreads();
    if (tid < 64) {                                // wave 0 only
        unsigned long long wv = words[tid];
        mask[(size_t)d2 * 64 + tid] = wv;
        int pc = __popcll(wv);
        int sc = pc;
        #pragma unroll
        for (int off = 1; off < 64; off <<= 1) {
            int o = __shfl_up(sc, off);
            if (tid >= off) sc += o;
        }
        if (tid == 63) l2num[d2] = sc;
    }
}

// ---------------- emit compact per-d2 src list at deterministic offsets ----------------
__global__ __launch_bounds__(64)
void emit_k(const unsigned long long* __restrict__ mask, const int* __restrict__ l2off,
            int* __restrict__ l2src) {
    int d2 = blockIdx.x, tid = threadIdx.x;      // 64 threads
    unsigned long long wv = mask[(size_t)d2 * 64 + tid];
    int pc = __popcll(wv);
    int sc = pc;
    #pragma unroll
    for (int off = 1; off < 64; off <<= 1) {
        int o = __shfl_up(sc, off);
        if (tid >= off) sc += o;
    }
    int p = l2off[d2] + sc - pc;                 // exclusive prefix within d2
    while (wv) {
        int b = __builtin_ctzll(wv);
        wv &= wv - 1;
        l2src[p++] = (tid << 6) | b;
    }
}

// ---------------- level 0: h = f @ W_f + pos @ W_p (new-id space) ----------------
template<int CI, int CO>
__global__ __launch_bounds__(256)
void xform0_k(const float* __restrict__ pnodes, const float* __restrict__ f,
              const float* __restrict__ W, float* __restrict__ h) {
    __shared__ float sW[(CI + 3) * CO];
    for (int i = threadIdx.x; i < (CI + 3) * CO; i += 256) sW[i] = W[i];
    __syncthreads();
    int gid = blockIdx.x * 256 + threadIdx.x;
    int i = gid / CO, ch = gid - i * CO;
    if (i >= NN) return;
    float s = pnodes[3 * i] * sW[CI * CO + ch] + pnodes[3 * i + 1] * sW[(CI + 1) * CO + ch]
            + pnodes[3 * i + 2] * sW[(CI + 2) * CO + ch];
    #pragma unroll
    for (int k = 0; k < CI; ++k) s += f[(size_t)i * CI + k] * sW[k * CO + ch];
    h[(size_t)i * CO + ch] = s;
}

// fused: gather over W1 (8ch) + xform W2 (8->16) -> h2. Block covers 32 dst nodes.
__global__ __launch_bounds__(256)
void gatherL0f_k(const float* __restrict__ pnodes, const float* __restrict__ h1,
                 const float* __restrict__ W1pos,       // 3x8
                 const float* __restrict__ W2,          // 11x16
                 const int* __restrict__ offs, const int* __restrict__ srcs,
                 float* __restrict__ h2) {
    __shared__ float sW1[24];
    __shared__ float sW2[176];
    __shared__ float f1s[32][8];
    int tid = threadIdx.x;
    if (tid < 24) sW1[tid] = W1pos[tid];
    if (tid < 176) sW2[tid] = W2[tid];
    __syncthreads();
    int gid = blockIdx.x * 256 + tid;
    int d = gid >> 3, ch = gid & 7;
    int dbase = blockIdx.x * 32;
    if (d < NN) {
        float c = pnodes[3 * d] * sW1[ch] + pnodes[3 * d + 1] * sW1[8 + ch] + pnodes[3 * d + 2] * sW1[16 + ch];
        float m0 = c, m1 = c, m2 = c, m3 = c;
        int e0 = offs[d], e1 = offs[d + 1];
        int t = e0;
        for (; t + 4 <= e1; t += 4) {
            int s0 = srcs[t], s1 = srcs[t + 1], s2 = srcs[t + 2], s3 = srcs[t + 3];
            m0 = fmaxf(m0, h1[(size_t)s0 * 8 + ch]);
            m1 = fmaxf(m1, h1[(size_t)s1 * 8 + ch]);
            m2 = fmaxf(m2, h1[(size_t)s2 * 8 + ch]);
            m3 = fmaxf(m3, h1[(size_t)s3 * 8 + ch]);
        }
        for (; t < e1; ++t) m0 = fmaxf(m0, h1[(size_t)srcs[t] * 8 + ch]);
        f1s[d - dbase][ch] = fmaxf(fmaxf(m0, m1), fmaxf(m2, m3)) - c;
    }
    __syncthreads();
    // epilogue: h2[d][ch2] for 32 d x 16 ch2 = 512 outputs, 2 per thread
    #pragma unroll
    for (int rep = 0; rep < 2; ++rep) {
        int dL = (tid >> 4) + rep * 16, ch2 = tid & 15;
        int dg = dbase + dL;
        if (dg < NN) {
            float s = pnodes[3 * dg] * sW2[128 + ch2] + pnodes[3 * dg + 1] * sW2[144 + ch2]
                    + pnodes[3 * dg + 2] * sW2[160 + ch2];
            #pragma unroll
            for (int k = 0; k < 8; ++k) s += f1s[dL][k] * sW2[k * 16 + ch2];
            h2[(size_t)dg * 16 + ch2] = s;
        }
    }
}

// float4 gather, CO=16: 4 threads per dst node (channel quads)
__global__ __launch_bounds__(256)
void gatherL0v4_k(const float* __restrict__ pnodes, const float* __restrict__ h,
                  const float* __restrict__ Wpos,       // 3x16
                  const int* __restrict__ offs, const int* __restrict__ srcs,
                  float* __restrict__ out) {
    __shared__ float sW[48];
    int tid = threadIdx.x;
    if (tid < 48) sW[tid] = Wpos[tid];
    __syncthreads();
    int gid = blockIdx.x * 256 + tid;
    int d = gid >> 2, q = gid & 3;
    if (d >= NN) return;
    float px = pnodes[3 * d], py = pnodes[3 * d + 1], pz = pnodes[3 * d + 2];
    float4 w0 = *(const float4*)&sW[q * 4];
    float4 w1 = *(const float4*)&sW[16 + q * 4];
    float4 w2 = *(const float4*)&sW[32 + q * 4];
    float4 c = make_float4(px * w0.x + py * w1.x + pz * w2.x, px * w0.y + py * w1.y + pz * w2.y,
                           px * w0.z + py * w1.z + pz * w2.z, px * w0.w + py * w1.w + pz * w2.w);
    float4 m0 = c, m1 = c, m2 = c, m3 = c;       // no self-loop at level 0; empty -> 0
    int e0 = offs[d], e1 = offs[d + 1];
    int t = e0;
    for (; t + 4 <= e1; t += 4) {
        int s0 = srcs[t], s1 = srcs[t + 1], s2 = srcs[t + 2], s3 = srcs[t + 3];
        m0 = max4(m0, *(const float4*)&h[(size_t)s0 * 16 + q * 4]);
        m1 = max4(m1, *(const float4*)&h[(size_t)s1 * 16 + q * 4]);
        m2 = max4(m2, *(const float4*)&h[(size_t)s2 * 16 + q * 4]);
        m3 = max4(m3, *(const float4*)&h[(size_t)s3 * 16 + q * 4]);
    }
    for (; t < e1; ++t) m0 = max4(m0, *(const float4*)&h[(size_t)srcs[t] * 16 + q * 4]);
    float4 m = max4(max4(m0, m1), max4(m2, m3));
    *(float4*)&out[(size_t)d * 16 + q * 4] = make_float4(m.x - c.x, m.y - c.y, m.z - c.z, m.w - c.w);
}

// ---------------- level 1: fused pool(16ch) + xform W3 -> Hc ----------------
__global__ __launch_bounds__(256)
void pxformL1_k(const float* __restrict__ f2, const int* __restrict__ offsN,
                const int* __restrict__ oclist, const int* __restrict__ ocount,
                const float* __restrict__ W3, float* __restrict__ h) {
    __shared__ float sW[19 * 32];
    __shared__ float nf[8][16];
    for (int i = threadIdx.x; i < 19 * 32; i += 256) sW[i] = W3[i];
    int gid = blockIdx.x * 256 + threadIdx.x;
    int j = gid >> 5, ch = gid & 31;
    int lj = threadIdx.x >> 5;                   // 8 js per block
    bool valid = j < *ocount;
    int d = valid ? oclist[j] : 0;
    if (valid && ch < 16) {
        float m = 0.f;                           // f2 >= 0 (post-relu)
        int n0 = offsN[d], n1 = offsN[d + 1];
        for (int n = n0; n < n1; ++n) m = fmaxf(m, f2[(size_t)n * 16 + ch]);
        nf[lj][ch] = m;
    }
    __syncthreads();
    if (!valid) return;
    float px, py, pz;
    key2xyz(d, px, py, pz);
    float s = px * sW[16 * 32 + ch] + py * sW[17 * 32 + ch] + pz * sW[18 * 32 + ch];
    #pragma unroll
    for (int k = 0; k < 16; ++k) s += nf[lj][k] * sW[k * 32 + ch];
    h[(size_t)j * 32 + ch] = s;
}

// fused float4 gather(W3pos) + xform W4 (32->32) -> hnext (different buffer).
__global__ __launch_bounds__(256)
void gatherL1f_k(const float* __restrict__ h, const float* __restrict__ W3pos,
                 const float* __restrict__ W4,          // 35x32
                 const int* __restrict__ offsN, const int* __restrict__ offs0,
                 const int* __restrict__ csrc0,
                 const int* __restrict__ oclist, const int* __restrict__ ocount,
                 float* __restrict__ hnext) {
    __shared__ float sWp[96];
    __shared__ float sW4[35 * 32];
    __shared__ float gsT[32][33];                // [ch][lj], padded
    int tid = threadIdx.x;
    if (tid < 96) sWp[tid] = W3pos[tid];
    for (int i = tid; i < 35 * 32; i += 256) sW4[i] = W4[i];
    __syncthreads();
    int gid = blockIdx.x * 256 + tid;
    int j = gid >> 3, q = gid & 7;
    int lj = tid >> 3;
    bool valid = j < *ocount;
    float px = 0, py = 0, pz = 0;
    if (valid) {
        int d = oclist[j];
        key2xyz(d, px, py, pz);
        float4 w0 = *(const float4*)&sWp[q * 4];
        float4 w1 = *(const float4*)&sWp[32 + q * 4];
        float4 w2 = *(const float4*)&sWp[64 + q * 4];
        float4 c = make_float4(px * w0.x + py * w1.x + pz * w2.x, px * w0.y + py * w1.y + pz * w2.y,
                               px * w0.z + py * w1.z + pz * w2.z, px * w0.w + py * w1.w + pz * w2.w);
        float4 self = *(const float4*)&h[(size_t)j * 32 + q * 4];
        float4 m0 = max4(c, self), m1 = m0, m2 = m0, m3 = m0;   // self-loop
        int e0 = offs0[offsN[d]], e1 = offs0[offsN[d + 1]];
        int t = e0;
        for (; t + 4 <= e1; t += 4) {
            int s0 = csrc0[t] & JMASK, s1 = csrc0[t + 1] & JMASK;
            int s2 = csrc0[t + 2] & JMASK, s3 = csrc0[t + 3] & JMASK;
            m0 = max4(m0, *(const float4*)&h[(size_t)s0 * 32 + q * 4]);
            m1 = max4(m1, *(const float4*)&h[(size_t)s1 * 32 + q * 4]);
            m2 = max4(m2, *(const float4*)&h[(size_t)s2 * 32 + q * 4]);
            m3 = max4(m3, *(const float4*)&h[(size_t)s3 * 32 + q * 4]);
        }
        for (; t < e1; ++t) m0 = max4(m0, *(const float4*)&h[(size_t)(csrc0[t] & JMASK) * 32 + q * 4]);
        float4 m = max4(max4(m0, m1), max4(m2, m3));
        gsT[q * 4 + 0][lj] = m.x - c.x;
        gsT[q * 4 + 1][lj] = m.y - c.y;
        gsT[q * 4 + 2][lj] = m.z - c.z;
        gsT[q * 4 + 3][lj] = m.w - c.w;
    }
    __syncthreads();
    if (!valid) return;
    float4 s4;
    {
        float4 w0 = *(const float4*)&sW4[32 * 32 + q * 4];
        float4 w1 = *(const float4*)&sW4[33 * 32 + q * 4];
        float4 w2 = *(const float4*)&sW4[34 * 32 + q * 4];
        s4 = make_float4(px * w0.x + py * w1.x + pz * w2.x, px * w0.y + py * w1.y + pz * w2.y,
                         px * w0.z + py * w1.z + pz * w2.z, px * w0.w + py * w1.w + pz * w2.w);
    }
    #pragma unroll
    for (int k = 0; k < 32; ++k) {
        float g = gsT[k][lj];
        s4 = fma4(g, *(const float4*)&sW4[k * 32 + q * 4], s4);
    }
    *(float4*)&hnext[(size_t)j * 32 + q * 4] = s4;
}

// plain float4 flat gather (final level-1 layer)
__global__ __launch_bounds__(256)
void gatherL1_k(const float* __restrict__ h, const float* __restrict__ Wpos,
                const int* __restrict__ offsN, const int* __restrict__ offs0,
                const int* __restrict__ csrc0,
                const int* __restrict__ oclist, const int* __restrict__ ocount,
                float* __restrict__ g) {
    __shared__ float sW[96];
    int tid = threadIdx.x;
    if (tid < 96) sW[tid] = Wpos[tid];
    __syncthreads();
    int gid = blockIdx.x * 256 + tid;
    int j = gid >> 3, q = gid & 7;
    if (j >= *ocount) return;
    int d = oclist[j];
    float px, py, pz;
    key2xyz(d, px, py, pz);
    float4 w0 = *(const float4*)&sW[q * 4];
    float4 w1 = *(const float4*)&sW[32 + q * 4];
    float4 w2 = *(const float4*)&sW[64 + q * 4];
    float4 c = make_float4(px * w0.x + py * w1.x + pz * w2.x, px * w0.y + py * w1.y + pz * w2.y,
                           px * w0.z + py * w1.z + pz * w2.z, px * w0.w + py * w1.w + pz * w2.w);
    float4 self = *(const float4*)&h[(size_t)j * 32 + q * 4];
    float4 m0 = max4(c, self), m1 = m0, m2 = m0, m3 = m0;   // self-loop
    int e0 = offs0[offsN[d]], e1 = offs0[offsN[d + 1]];
    int t = e0;
    for (; t + 4 <= e1; t += 4) {
        int s0 = csrc0[t] & JMASK, s1 = csrc0[t + 1] & JMASK;
        int s2 = csrc0[t + 2] & JMASK, s3 = csrc0[t + 3] & JMASK;
        m0 = max4(m0, *(const float4*)&h[(size_t)s0 * 32 + q * 4]);
        m1 = max4(m1, *(const float4*)&h[(size_t)s1 * 32 + q * 4]);
        m2 = max4(m2, *(const float4*)&h[(size_t)s2 * 32 + q * 4]);
        m3 = max4(m3, *(const float4*)&h[(size_t)s3 * 32 + q * 4]);
    }
    for (; t < e1; ++t) m0 = max4(m0, *(const float4*)&h[(size_t)(csrc0[t] & JMASK) * 32 + q * 4]);
    float4 m = max4(max4(m0, m1), max4(m2, m3));
    *(float4*)&g[(size_t)j * 32 + q * 4] = make_float4(m.x - c.x, m.y - c.y, m.z - c.z, m.w - c.w);
}

// ---------------- level 2 (block per 16^3 cell) ----------------
// children of d2 are the contiguous key range [d2*64, d2*64+64)
__global__ __launch_bounds__(256)
void pool2x_k(const float* __restrict__ Gc, const int* __restrict__ jmap,
              const float* __restrict__ W5, float* __restrict__ h5) {
    __shared__ float part[8][32];
    __shared__ float nf2row[32];
    int d2 = blockIdx.x, tid = threadIdx.x;
    int x2 = d2 >> 8, y2 = (d2 >> 4) & 15, z2 = d2 & 15;
    int ch = tid & 31, grp = tid >> 5;                 // 8 grps x 8 children
    float m = 0.f;
    #pragma unroll
    for (int cc = 0; cc < 8; ++cc) {
        int cj = jmap[(d2 << 6) | (grp * 8 + cc)];
        if (cj >= 0) m = fmaxf(m, Gc[(size_t)cj * 32 + ch]);
    }
    part[grp][ch] = m;
    __syncthreads();
    if (tid < 32) {
        float mm = part[0][tid];
        #pragma unroll
        for (int g = 1; g < 8; ++g) mm = fmaxf(mm, part[g][tid]);
        nf2row[tid] = mm;
    }
    __syncthreads();
    if (tid < 64) {
        float s = x2 * W5[32 * 64 + tid] + y2 * W5[33 * 64 + tid] + z2 * W5[34 * 64 + tid];
        #pragma unroll
        for (int k = 0; k < 32; ++k) s += nf2row[k] * W5[k * 64 + tid];
        h5[(size_t)d2 * 64 + tid] = s;
    }
}

// level-2 gconv via flat adjacency list, float4 (+ optional fused next xform). One block per d2.
template<bool FUSE, bool WRITE_G>
__global__ __launch_bounds__(256)
void gconvL2_k(const float* __restrict__ h, const float* __restrict__ Wpos,
               const int* __restrict__ l2off, const int* __restrict__ l2src,
               const float* __restrict__ Wn,           // (64+3)x64, if FUSE
               float* __restrict__ gout, float* __restrict__ hnext) {
    __shared__ float red[16][64];
    __shared__ float grow[64];
    int d2 = blockIdx.x, tid = threadIdx.x;
    int x2 = d2 >> 8, y2 = (d2 >> 4) & 15, z2 = d2 & 15;
    int q = tid & 15, grp = tid >> 4;                  // 16 groups split the list
    int n0 = l2off[d2], num = l2off[d2 + 1] - n0;
    int per = (num + 15) >> 4;
    int s = n0 + grp * per;
    int e = min(n0 + num, s + per);
    float4 m0 = make_float4(-1e30f, -1e30f, -1e30f, -1e30f);
    float4 m1 = m0, m2 = m0, m3 = m0;
    int t = s;
    for (; t + 4 <= e; t += 4) {
        int s0 = l2src[t], s1 = l2src[t + 1], s2 = l2src[t + 2], s3 = l2src[t + 3];
        m0 = max4(m0, *(const float4*)&h[(size_t)s0 * 64 + q * 4]);
        m1 = max4(m1, *(const float4*)&h[(size_t)s1 * 64 + q * 4]);
        m2 = max4(m2, *(const float4*)&h[(size_t)s2 * 64 + q * 4]);
        m3 = max4(m3, *(const float4*)&h[(size_t)s3 * 64 + q * 4]);
    }
    for (; t < e; ++t) m0 = max4(m0, *(const float4*)&h[(size_t)l2src[t] * 64 + q * 4]);
    float4 m = max4(max4(m0, m1), max4(m2, m3));
    red[grp][q * 4 + 0] = m.x;
    red[grp][q * 4 + 1] = m.y;
    red[grp][q * 4 + 2] = m.z;
    red[grp][q * 4 + 3] = m.w;
    __syncthreads();
    if (tid < 64) {
        int ch = tid;
        float mm = red[0][ch];
        #pragma unroll
        for (int g = 1; g < 16; ++g) mm = fmaxf(mm, red[g][ch]);
        float c = x2 * Wpos[ch] + y2 * Wpos[64 + ch] + z2 * Wpos[128 + ch];
        mm = fmaxf(mm, fmaxf(c, h[(size_t)d2 * 64 + ch]));   // self-loop + empty
        float g = mm - c;
        if (WRITE_G) gout[(size_t)d2 * 64 + ch] = g;
        if (FUSE) grow[ch] = g;
    }
    if (FUSE) {
        __syncthreads();
        if (tid < 64) {
            float s2v = x2 * Wn[64 * 64 + tid] + y2 * Wn[65 * 64 + tid] + z2 * Wn[66 * 64 + tid];
            #pragma unroll
            for (int k = 0; k < 64; ++k) s2v += grow[k] * Wn[k * 64 + tid];
            hnext[(size_t)d2 * 64 + tid] = s2v;
        }
    }
}

// ---------------- output pool + linear ----------------
__global__ __launch_bounds__(256)
void outpool_k(const float* __restrict__ g7, float* __restrict__ xo) {
    int gid = blockIdx.x * 256 + threadIdx.x;
    if (gid >= 64 * 64) return;
    int oc = gid >> 6, ch = gid & 63;
    int cx = oc >> 4, cy = (oc >> 2) & 3, cz = oc & 3;
    float m = 0.f;
    for (int tc = 0; tc < 64; ++tc) {
        int i = tc >> 4, j = (tc >> 2) & 3, k = tc & 3;
        int d2 = ((cx * 4 + i) * 16 + (cy * 4 + j)) * 16 + (cz * 4 + k);
        m = fmaxf(m, g7[(size_t)d2 * 64 + ch]);
    }
    xo[(size_t)oc * 64 + ch] = m;
}

__global__ __launch_bounds__(64)
void linear_k(const float* __restrict__ xo, const float* __restrict__ Wl,
              const float* __restrict__ bl, float* __restrict__ out) {
    int j = blockIdx.x;
    float s = 0.f;
    for (int i = threadIdx.x; i < 4096; i += 64) s += xo[i] * Wl[(size_t)i * 100 + j];
    #pragma unroll
    for (int off = 32; off; off >>= 1) s += __shfl_down(s, off);
    if (threadIdx.x == 0) out[j] = s + bl[j];
}

extern "C" void kernel_launch(void* const* d_in, const int* in_sizes, int n_in,
                              void* d_out, int out_size, void* d_ws, size_t ws_size,
                              hipStream_t stream) {
    (void)in_sizes; (void)n_in; (void)out_size;
    const float* nodes = (const float*)d_in[0];
    const float* feats = (const float*)d_in[1];
    const int*   edges = (const int*)d_in[2];
    const int*   esrc  = edges;
    const int*   edst  = edges + NE;
    const float* W1 = (const float*)d_in[3];
    const float* W2 = (const float*)d_in[4];
    const float* W3 = (const float*)d_in[5];
    const float* W4 = (const float*)d_in[6];
    const float* W5 = (const float*)d_in[7];
    const float* W6 = (const float*)d_in[8];
    const float* W7 = (const float*)d_in[9];
    const float* Wl = (const float*)d_in[10];
    const float* bl = (const float*)d_in[11];
    float* out = (float*)d_out;

    char* ws = (char*)d_ws;
    size_t off = 0;
    auto alloc = [&](size_t bytes) { void* p = ws + off; off = (off + bytes + 255) & ~(size_t)255; return p; };
    // zero region: cntN + ocount + btot (one memset)
    int*   cntN    = (int*)alloc((size_t)C1 * 4);
    int*   ocount  = (int*)alloc(4);
    int*   btot    = (int*)alloc((size_t)NB * 4);
    size_t zero_bytes = off;
    int*   bsum   = (int*)alloc(260 * 4);
    int*   bbase  = (int*)alloc((size_t)(NB + 1) * 4);
    int*   cursor = (int*)alloc((size_t)NB * 4);
    int*   cid    = (int*)alloc((size_t)NN * 4);
    int*   rank   = (int*)alloc((size_t)NN * 4);
    int*   nidx   = (int*)alloc((size_t)NN * 4);
    int*   offsN  = (int*)alloc((size_t)(C1 + 1) * 4);
    int*   offs0  = (int*)alloc((size_t)(NN + 1) * 4);
    int*   srcs0  = (int*)alloc((size_t)NE * 4);
    int*   csrc0  = (int*)alloc((size_t)NE * 4);
    int2*  ebuf   = (int2*)alloc((size_t)NE * 8);
    int*   oclist = (int*)alloc((size_t)NN * 4);
    int*   jmap   = (int*)alloc((size_t)C1 * 4);
    int*   jsrcP  = (int*)alloc((size_t)NN * 4);
    unsigned long long* mask = (unsigned long long*)alloc((size_t)C2 * 64 * 8);  // 2MB
    int*   l2num  = (int*)alloc((size_t)C2 * 4);
    int*   l2off  = (int*)alloc((size_t)(C2 + 1) * 4);
    int*   l2srcA = (int*)alloc((size_t)NE * 4);
    float* pnodes = (float*)alloc((size_t)NN * 3 * 4);
    float* pfeat  = (float*)alloc((size_t)NN * 4);
    float* A      = (float*)alloc((size_t)NN * 48 * 4);   // h1, h2, f2
    float* Hc     = (float*)alloc((size_t)NN * 32 * 4);
    float* Gc     = (float*)alloc((size_t)NN * 32 * 4);
    float* h5     = (float*)alloc((size_t)C2 * 64 * 4);
    float* h6     = (float*)alloc((size_t)C2 * 64 * 4);
    float* h7     = (float*)alloc((size_t)C2 * 64 * 4);
    float* g7     = (float*)alloc((size_t)C2 * 64 * 4);
    float* xo     = (float*)alloc((size_t)64 * 64 * 4);
    if (ws_size < off) return;

    float* h1 = A;                      // [NN][8]
    float* h2 = A + (size_t)NN * 16;    // [NN][16]
    float* f2 = A + (size_t)NN * 32;    // [NN][16]

    hipMemsetAsync(cntN, 0, zero_bytes, stream);

    auto gr = [](long long n) { return (int)((n + 255) / 256); };
    const int nbC1 = (C1 + 2047) / 2048;   // 128
    const int nbC2 = (C2 + 2047) / 2048;   // 2
    const int gPA  = (NE + PA_EDGES - 1) / PA_EDGES;  // 196

    // ---- connectivity build (key space) ----
    cidhist_k<<<gr(NN), 256, 0, stream>>>(nodes, cid, cntN);
    oclist_k<<<C1 / 256, 256, 0, stream>>>(cntN, oclist, jmap, ocount);
    scan1_k<<<nbC1, 256, 0, stream>>>(cntN, C1, offsN, bsum);
    scan2_k<<<1, 256, 0, stream>>>(bsum, nbC1);
    scan3_k<<<gr(C1 + 1), 256, 0, stream>>>(offsN, C1, bsum, nbC1);
    nscatter_k<<<gr(NN), 256, 0, stream>>>(cid, offsN, cntN, rank, nidx);
    permute_k<<<gr(NN), 256, 0, stream>>>(nidx, nodes, feats, cid, jmap, pnodes, pfeat, jsrcP);
    bhist_k<<<gPA, 256, 0, stream>>>(edst, rank, btot);
    scanB_k<<<1, 256, 0, stream>>>(btot, bbase, cursor);
    passA_k<<<gPA, 256, 0, stream>>>(esrc, edst, rank, cursor, ebuf);
    passB_k<<<NB, 256, 0, stream>>>(ebuf, bbase, jsrcP, offs0, srcs0, csrc0);
    // level-2 adjacency: bitmap -> scan -> deterministic emit (no global cursor)
    mask_k<<<C2, 256, 0, stream>>>(offsN, offs0, csrc0, mask, l2num);
    scan1_k<<<nbC2, 256, 0, stream>>>(l2num, C2, l2off, bsum);
    scan2_k<<<1, 256, 0, stream>>>(bsum, nbC2);
    scan3_k<<<gr(C2 + 1), 256, 0, stream>>>(l2off, C2, bsum, nbC2);
    emit_k<<<C2, 64, 0, stream>>>(mask, l2off, l2srcA);

    // ---- level 0 (rank space) ----
    xform0_k<1, 8><<<gr((long long)NN * 8), 256, 0, stream>>>(pnodes, pfeat, W1, h1);
    gatherL0f_k<<<gr((long long)NN * 8), 256, 0, stream>>>(pnodes, h1, W1 + 1 * 8, W2, offs0, srcs0, h2);
    gatherL0v4_k<<<gr((long long)NN * 4), 256, 0, stream>>>(pnodes, h2, W2 + 8 * 16, offs0, srcs0, f2);

    // ---- level 1 (compact occupied cells, flat edge ranges; ping-pong Hc/Gc) ----
    pxformL1_k<<<gr((long long)NN * 32), 256, 0, stream>>>(f2, offsN, oclist, ocount, W3, Hc);
    gatherL1f_k<<<gr((long long)NN * 8), 256, 0, stream>>>(Hc, W3 + 16 * 32, W4, offsN, offs0, csrc0, oclist, ocount, Gc);
    gatherL1_k<<<gr((long long)NN * 8), 256, 0, stream>>>(Gc, W4 + 32 * 32, offsN, offs0, csrc0, oclist, ocount, Hc);

    // ---- level 2 (block per 16^3 cell, list-driven, fused) ----
    pool2x_k<<<C2, 256, 0, stream>>>(Hc, jmap, W5, h5);
    gconvL2_k<true,  false><<<C2, 256, 0, stream>>>(h5, W5 + 32 * 64, l2off, l2srcA, W6, nullptr, h6);
    gconvL2_k<true,  false><<<C2, 256, 0, stream>>>(h6, W6 + 64 * 64, l2off, l2srcA, W7, nullptr, h7);
    gconvL2_k<false, true ><<<C2, 256, 0, stream>>>(h7, W7 + 64 * 64, l2off, l2srcA, nullptr, g7, nullptr);

    outpool_k<<<16, 256, 0, stream>>>(g7, xo);
    linear_k<<<100, 64, 0, stream>>>(xo, Wl, bl, out);
}

// Round 15
// 393.780 us; speedup vs baseline: 61.5478x; 1.0943x over previous
//
#include <hip/hip_runtime.h>

#define NN 100000      // nodes
#define NE 1600000     // edges
#define C1 262144      // 64^3 cells (keyed as d2*64+child)
#define C2 4096        // 16^3 cells
#define BSH 7          // bucket shift (128 new-ids per bucket)
#define BSZ 128
#define NB 782         // ceil(NN/128)
#define PA_EDGES 8192
#define PA_IT (PA_EDGES / 256)
#define JMASK 0xFFFFF  // low 20 bits: compact j; bits 20..31: d2 of src cell

// cell key layout: key = d2*64 + child, d2 = (x>>2)*256+(y>>2)*16+(z>>2),
// child = (x&3)*16+(y&3)*4+(z&3)
__device__ __forceinline__ void key2xyz(int key, float& x, float& y, float& z) {
    int d2 = key >> 6, ch = key & 63;
    x = (float)((((d2 >> 8) & 15) << 2) | (ch >> 4));
    y = (float)((((d2 >> 4) & 15) << 2) | ((ch >> 2) & 3));
    z = (float)(((d2 & 15) << 2) | (ch & 3));
}
__device__ __forceinline__ float4 max4(float4 a, float4 b) {
    return make_float4(fmaxf(a.x, b.x), fmaxf(a.y, b.y), fmaxf(a.z, b.z), fmaxf(a.w, b.w));
}
__device__ __forceinline__ float4 fma4(float s, float4 w, float4 acc) {
    return make_float4(s * w.x + acc.x, s * w.y + acc.y, s * w.z + acc.z, s * w.w + acc.w);
}

// ---------------- cell key of each node + node-per-cell histogram ----------------
__global__ __launch_bounds__(256)
void cidhist_k(const float* __restrict__ nodes, int* __restrict__ cid,
               int* __restrict__ cntN) {
    int i = blockIdx.x * 256 + threadIdx.x;
    if (i >= NN) return;
    int cx = min(max((int)floorf(nodes[3 * i]     * 0.25f), 0), 63);
    int cy = min(max((int)floorf(nodes[3 * i + 1] * 0.25f), 0), 63);
    int cz = min(max((int)floorf(nodes[3 * i + 2] * 0.25f), 0), 63);
    int d2 = ((cx >> 2) * 16 + (cy >> 2)) * 16 + (cz >> 2);
    int ch = ((cx & 3) * 4 + (cy & 3)) * 4 + (cz & 3);
    int key = (d2 << 6) | ch;
    cid[i] = key;
    atomicAdd(&cntN[key], 1);
}

// ---------------- generic exclusive scan: 2048/block. MODE 0: cnt[i]; MODE 1: cnt[i]>0 ----------------
template<int MODE>
__global__ __launch_bounds__(256)
void scan1_k(const int* __restrict__ cnt, int n, int* __restrict__ offs,
             int* __restrict__ bsum) {
    __shared__ int ws[4];
    int t = threadIdx.x, lane = t & 63, w = t >> 6;
    int base = blockIdx.x * 2048 + t * 8;
    int v[8]; int s = 0;
    #pragma unroll
    for (int i = 0; i < 8; ++i) {
        int raw = (base + i < n) ? cnt[base + i] : 0;
        v[i] = (MODE == 1) ? (raw > 0 ? 1 : 0) : raw;
        s += v[i];
    }
    int sc = s;
    #pragma unroll
    for (int off = 1; off < 64; off <<= 1) { int o = __shfl_up(sc, off); if (lane >= off) sc += o; }
    if (lane == 63) ws[w] = sc;
    __syncthreads();
    int wbase = 0;
    for (int i = 0; i < w; ++i) wbase += ws[i];
    int run = wbase + sc - s;
    #pragma unroll
    for (int i = 0; i < 8; ++i) { if (base + i < n) offs[base + i] = run; run += v[i]; }
    if (t == 255) bsum[blockIdx.x] = wbase + sc;
}

__global__ __launch_bounds__(256)
void scan2_k(int* __restrict__ bsum, int nb) {   // one block, nb <= 256
    __shared__ int ws[4];
    int t = threadIdx.x, lane = t & 63, w = t >> 6;
    int v = (t < nb) ? bsum[t] : 0;
    int sc = v;
    #pragma unroll
    for (int off = 1; off < 64; off <<= 1) { int o = __shfl_up(sc, off); if (lane >= off) sc += o; }
    if (lane == 63) ws[w] = sc;
    __syncthreads();
    int wbase = 0;
    for (int i = 0; i < w; ++i) wbase += ws[i];
    if (t < nb) bsum[t] = wbase + sc - v;
    if (t == 255) bsum[nb] = ws[0] + ws[1] + ws[2] + ws[3];
}

__global__ __launch_bounds__(256)
void scan3_k(int* __restrict__ offs, int n, const int* __restrict__ bsum, int nb) {
    int i = blockIdx.x * 256 + threadIdx.x;
    if (i < n) offs[i] += bsum[i >> 11];
    else if (i == n) offs[n] = bsum[nb];
}

// ---------------- occupied-cell compaction from offsOcc (deterministic, atomic-free) ----------------
__global__ __launch_bounds__(256)
void jlist_k(const int* __restrict__ offsOcc, int* __restrict__ jmap,
             int* __restrict__ oclist, int* __restrict__ ocount) {
    int c = blockIdx.x * 256 + threadIdx.x;
    if (c == 0) *ocount = offsOcc[C1];
    if (c >= C1) return;
    int pre = offsOcc[c];
    bool occ = offsOcc[c + 1] > pre;
    jmap[c] = occ ? pre : -1;
    if (occ) oclist[pre] = c;
}

// ---------------- node scatter: rank (new id) + nidx (old id by new id) ----------------
__global__ __launch_bounds__(256)
void nscatter_k(const int* __restrict__ cid, const int* __restrict__ offsN,
                int* __restrict__ cntN, int* __restrict__ rank, int* __restrict__ nidx) {
    int i = blockIdx.x * 256 + threadIdx.x;
    if (i >= NN) return;
    int c = cid[i];
    int pos = offsN[c] + atomicAdd(&cntN[c], -1) - 1;
    rank[i] = pos;
    nidx[pos] = i;
}

// ---------------- permute node data into new-id order ----------------
__global__ __launch_bounds__(256)
void permute_k(const int* __restrict__ nidx, const float* __restrict__ nodes,
               const float* __restrict__ feats, const int* __restrict__ cid,
               const int* __restrict__ jmap,
               float* __restrict__ pnodes, float* __restrict__ pfeat,
               int* __restrict__ jsrcP) {
    int d = blockIdx.x * 256 + threadIdx.x;
    if (d >= NN) return;
    int i = nidx[d];
    pnodes[3 * d]     = nodes[3 * i];
    pnodes[3 * d + 1] = nodes[3 * i + 1];
    pnodes[3 * d + 2] = nodes[3 * i + 2];
    pfeat[d] = feats[i];
    int c = cid[i];
    unsigned packed = (unsigned)jmap[c] | (((unsigned)c >> 6) << 20);  // j | d2<<20
    jsrcP[d] = (int)packed;
}

// ---------------- bucket histogram over rank[dst] (LDS pre-aggregated) ----------------
__global__ __launch_bounds__(256)
void bhist_k(const int* __restrict__ edst, const int* __restrict__ rank,
             int* __restrict__ btot) {
    __shared__ int h[NB];
    int tid = threadIdx.x;
    for (int i = tid; i < NB; i += 256) h[i] = 0;
    __syncthreads();
    int base = blockIdx.x * PA_EDGES;
    for (int i = 0; i < PA_IT; ++i) {
        int e = base + i * 256 + tid;
        if (e < NE) atomicAdd(&h[rank[edst[e]] >> BSH], 1);
    }
    __syncthreads();
    for (int i = tid; i < NB; i += 256) if (h[i]) atomicAdd(&btot[i], h[i]);
}

// one block: exclusive scan of NB (<=1024) bucket totals -> bbase[NB+1]; copy to cursor
__global__ __launch_bounds__(256)
void scanB_k(const int* __restrict__ btot, int* __restrict__ bbase,
             int* __restrict__ cursor) {
    __shared__ int ws[4];
    int t = threadIdx.x, lane = t & 63, w = t >> 6;
    int i0 = 4 * t;
    int v[4]; int s = 0;
    #pragma unroll
    for (int q = 0; q < 4; ++q) { v[q] = (i0 + q < NB) ? btot[i0 + q] : 0; s += v[q]; }
    int sc = s;
    #pragma unroll
    for (int off = 1; off < 64; off <<= 1) { int o = __shfl_up(sc, off); if (lane >= off) sc += o; }
    if (lane == 63) ws[w] = sc;
    __syncthreads();
    int wb = 0;
    for (int q = 0; q < w; ++q) wb += ws[q];
    int run = wb + sc - s;
    #pragma unroll
    for (int q = 0; q < 4; ++q) {
        if (i0 + q <= NB) { bbase[i0 + q] = run; if (i0 + q < NB) cursor[i0 + q] = run; }
        run += v[q];
    }
}

// ---------------- pass A: partition (rank_src, rank_dst) pairs by dst bucket ----------------
__global__ __launch_bounds__(256)
void passA_k(const int* __restrict__ esrc, const int* __restrict__ edst,
             const int* __restrict__ rank, int* __restrict__ cursor,
             int2* __restrict__ ebuf) {
    __shared__ int hist[NB];
    __shared__ int lofs[NB + 1];
    __shared__ int gbase[NB];
    __shared__ int cnt2[NB];
    __shared__ int2 stage[PA_EDGES];             // 64KB
    __shared__ unsigned short sbid[PA_EDGES];    // 16KB
    __shared__ int ws[4];
    int tid = threadIdx.x, lane = tid & 63, w = tid >> 6;
    for (int i = tid; i < NB; i += 256) { hist[i] = 0; cnt2[i] = 0; }
    __syncthreads();
    int base = blockIdx.x * PA_EDGES;
    for (int i = 0; i < PA_IT; ++i) {
        int e = base + i * 256 + tid;
        if (e < NE) atomicAdd(&hist[rank[edst[e]] >> BSH], 1);
    }
    __syncthreads();
    // exclusive scan hist -> lofs (4 per thread)
    int i0 = 4 * tid;
    int v[4]; int s = 0;
    #pragma unroll
    for (int q = 0; q < 4; ++q) { v[q] = (i0 + q < NB) ? hist[i0 + q] : 0; s += v[q]; }
    int sc = s;
    #pragma unroll
    for (int off = 1; off < 64; off <<= 1) { int o = __shfl_up(sc, off); if (lane >= off) sc += o; }
    if (lane == 63) ws[w] = sc;
    __syncthreads();
    int wb = 0;
    for (int q = 0; q < w; ++q) wb += ws[q];
    int run = wb + sc - s;
    #pragma unroll
    for (int q = 0; q < 4; ++q) {
        if (i0 + q <= NB) lofs[i0 + q] = run;
        run += v[q];
    }
    __syncthreads();
    for (int b = tid; b < NB; b += 256) {
        int c = hist[b];
        gbase[b] = c ? atomicAdd(&cursor[b], c) : 0;
    }
    __syncthreads();
    for (int i = 0; i < PA_IT; ++i) {
        int e = base + i * 256 + tid;
        if (e < NE) {
            int rd = rank[edst[e]], rs = rank[esrc[e]];
            int b = rd >> BSH;
            int p = lofs[b] + atomicAdd(&cnt2[b], 1);
            stage[p] = make_int2(rs, rd);
            sbid[p] = (unsigned short)b;
        }
    }
    __syncthreads();
    int nval = min(PA_EDGES, NE - base);
    for (int k = tid; k < nval; k += 256) {
        int b = sbid[k];
        ebuf[gbase[b] + (k - lofs[b])] = stage[k];
    }
}

// ---------------- pass B: per-bucket final scatter; offs0 (new-id CSR); csrc fused ----------------
__global__ __launch_bounds__(256)
void passB_k(const int2* __restrict__ ebuf, const int* __restrict__ bbase,
             const int* __restrict__ jsrcP,
             int* __restrict__ offs0, int* __restrict__ srcs0, int* __restrict__ csrc0) {
    __shared__ int cnt[BSZ];
    __shared__ int pos[BSZ];
    __shared__ int ws[4];
    int b = blockIdx.x, tid = threadIdx.x, lane = tid & 63, w = tid >> 6;
    int d0 = b << BSH;
    int range = min(BSZ, NN - d0);
    if (tid < BSZ) cnt[tid] = 0;
    __syncthreads();
    int r0 = bbase[b], r1 = bbase[b + 1];
    for (int k = r0 + tid; k < r1; k += 256) atomicAdd(&cnt[ebuf[k].y & (BSZ - 1)], 1);
    __syncthreads();
    int v = (tid < BSZ) ? cnt[tid] : 0;
    int sc = v;
    #pragma unroll
    for (int off = 1; off < 64; off <<= 1) { int o = __shfl_up(sc, off); if (lane >= off) sc += o; }
    if (lane == 63) ws[w] = sc;
    __syncthreads();
    int wb = 0;
    for (int q = 0; q < w; ++q) wb += ws[q];
    int rel = wb + sc - v;                        // exclusive per-dst prefix
    if (tid < range) offs0[d0 + tid] = r0 + rel;
    if (tid == 0) offs0[min(d0 + BSZ, NN)] = r1;  // benign duplicate of next base
    if (tid < BSZ) pos[tid] = r0 + rel;
    __syncthreads();
    for (int k = r0 + tid; k < r1; k += 256) {
        int2 pr = ebuf[k];
        int di = pr.y & (BSZ - 1);
        int p = atomicAdd(&pos[di], 1);
        int rs = pr.x;
        srcs0[p] = rs;
        csrc0[p] = jsrcP[rs];                     // packed j | d2<<20
    }
}

// ---------------- level-2 bitmap: contiguous edge slice -> LDS bitmap -> global ----------------
__global__ __launch_bounds__(256)
void mask_k(const int* __restrict__ offsN, const int* __restrict__ offs0,
            const int* __restrict__ csrc0,
            unsigned long long* __restrict__ mask, int* __restrict__ l2num) {
    __shared__ unsigned long long words[64];
    int d2 = blockIdx.x, tid = threadIdx.x;
    if (tid < 64) words[tid] = 0;
    __syncthreads();
    // all edges of d2's 64 child cells are one contiguous range (key ordering)
    int e0 = offs0[offsN[d2 << 6]];
    int e1 = offs0[offsN[(d2 + 1) << 6]];
    for (int t = e0 + tid; t < e1; t += 256) {
        int s2 = (int)(((unsigned)csrc0[t]) >> 20);
        atomicOr(&words[s2 >> 6], 1ull << (s2 & 63));
    }
    __syncthreads();
    if (tid < 64) {                                // wave 0 only
        unsigned long long wv = words[tid];
        mask[(size_t)d2 * 64 + tid] = wv;
        int pc = __popcll(wv);
        int sc = pc;
        #pragma unroll
        for (int off = 1; off < 64; off <<= 1) {
            int o = __shfl_up(sc, off);
            if (tid >= off) sc += o;
        }
        if (tid == 63) l2num[d2] = sc;
    }
}

// ---------------- emit compact per-d2 src list at deterministic offsets ----------------
__global__ __launch_bounds__(64)
void emit_k(const unsigned long long* __restrict__ mask, const int* __restrict__ l2off,
            int* __restrict__ l2src) {
    int d2 = blockIdx.x, tid = threadIdx.x;      // 64 threads
    unsigned long long wv = mask[(size_t)d2 * 64 + tid];
    int pc = __popcll(wv);
    int sc = pc;
    #pragma unroll
    for (int off = 1; off < 64; off <<= 1) {
        int o = __shfl_up(sc, off);
        if (tid >= off) sc += o;
    }
    int p = l2off[d2] + sc - pc;                 // exclusive prefix within d2
    while (wv) {
        int b = __builtin_ctzll(wv);
        wv &= wv - 1;
        l2src[p++] = (tid << 6) | b;
    }
}

// ---------------- level 0: h = f @ W_f + pos @ W_p (new-id space) ----------------
template<int CI, int CO>
__global__ __launch_bounds__(256)
void xform0_k(const float* __restrict__ pnodes, const float* __restrict__ f,
              const float* __restrict__ W, float* __restrict__ h) {
    __shared__ float sW[(CI + 3) * CO];
    for (int i = threadIdx.x; i < (CI + 3) * CO; i += 256) sW[i] = W[i];
    __syncthreads();
    int gid = blockIdx.x * 256 + threadIdx.x;
    int i = gid / CO, ch = gid - i * CO;
    if (i >= NN) return;
    float s = pnodes[3 * i] * sW[CI * CO + ch] + pnodes[3 * i + 1] * sW[(CI + 1) * CO + ch]
            + pnodes[3 * i + 2] * sW[(CI + 2) * CO + ch];
    #pragma unroll
    for (int k = 0; k < CI; ++k) s += f[(size_t)i * CI + k] * sW[k * CO + ch];
    h[(size_t)i * CO + ch] = s;
}

// fused: gather over W1 (8ch) + xform W2 (8->16) -> h2. Block covers 32 dst nodes.
__global__ __launch_bounds__(256)
void gatherL0f_k(const float* __restrict__ pnodes, const float* __restrict__ h1,
                 const float* __restrict__ W1pos,       // 3x8
                 const float* __restrict__ W2,          // 11x16
                 const int* __restrict__ offs, const int* __restrict__ srcs,
                 float* __restrict__ h2) {
    __shared__ float sW1[24];
    __shared__ float sW2[176];
    __shared__ float f1s[32][8];
    int tid = threadIdx.x;
    if (tid < 24) sW1[tid] = W1pos[tid];
    if (tid < 176) sW2[tid] = W2[tid];
    __syncthreads();
    int gid = blockIdx.x * 256 + tid;
    int d = gid >> 3, ch = gid & 7;
    int dbase = blockIdx.x * 32;
    if (d < NN) {
        float c = pnodes[3 * d] * sW1[ch] + pnodes[3 * d + 1] * sW1[8 + ch] + pnodes[3 * d + 2] * sW1[16 + ch];
        float m0 = c, m1 = c, m2 = c, m3 = c;
        int e0 = offs[d], e1 = offs[d + 1];
        int t = e0;
        for (; t + 4 <= e1; t += 4) {
            int s0 = srcs[t], s1 = srcs[t + 1], s2 = srcs[t + 2], s3 = srcs[t + 3];
            m0 = fmaxf(m0, h1[(size_t)s0 * 8 + ch]);
            m1 = fmaxf(m1, h1[(size_t)s1 * 8 + ch]);
            m2 = fmaxf(m2, h1[(size_t)s2 * 8 + ch]);
            m3 = fmaxf(m3, h1[(size_t)s3 * 8 + ch]);
        }
        for (; t < e1; ++t) m0 = fmaxf(m0, h1[(size_t)srcs[t] * 8 + ch]);
        f1s[d - dbase][ch] = fmaxf(fmaxf(m0, m1), fmaxf(m2, m3)) - c;
    }
    __syncthreads();
    // epilogue: h2[d][ch2] for 32 d x 16 ch2 = 512 outputs, 2 per thread
    #pragma unroll
    for (int rep = 0; rep < 2; ++rep) {
        int dL = (tid >> 4) + rep * 16, ch2 = tid & 15;
        int dg = dbase + dL;
        if (dg < NN) {
            float s = pnodes[3 * dg] * sW2[128 + ch2] + pnodes[3 * dg + 1] * sW2[144 + ch2]
                    + pnodes[3 * dg + 2] * sW2[160 + ch2];
            #pragma unroll
            for (int k = 0; k < 8; ++k) s += f1s[dL][k] * sW2[k * 16 + ch2];
            h2[(size_t)dg * 16 + ch2] = s;
        }
    }
}

// float4 gather, CO=16: 4 threads per dst node (channel quads)
__global__ __launch_bounds__(256)
void gatherL0v4_k(const float* __restrict__ pnodes, const float* __restrict__ h,
                  const float* __restrict__ Wpos,       // 3x16
                  const int* __restrict__ offs, const int* __restrict__ srcs,
                  float* __restrict__ out) {
    __shared__ float sW[48];
    int tid = threadIdx.x;
    if (tid < 48) sW[tid] = Wpos[tid];
    __syncthreads();
    int gid = blockIdx.x * 256 + tid;
    int d = gid >> 2, q = gid & 3;
    if (d >= NN) return;
    float px = pnodes[3 * d], py = pnodes[3 * d + 1], pz = pnodes[3 * d + 2];
    float4 w0 = *(const float4*)&sW[q * 4];
    float4 w1 = *(const float4*)&sW[16 + q * 4];
    float4 w2 = *(const float4*)&sW[32 + q * 4];
    float4 c = make_float4(px * w0.x + py * w1.x + pz * w2.x, px * w0.y + py * w1.y + pz * w2.y,
                           px * w0.z + py * w1.z + pz * w2.z, px * w0.w + py * w1.w + pz * w2.w);
    float4 m0 = c, m1 = c, m2 = c, m3 = c;       // no self-loop at level 0; empty -> 0
    int e0 = offs[d], e1 = offs[d + 1];
    int t = e0;
    for (; t + 4 <= e1; t += 4) {
        int s0 = srcs[t], s1 = srcs[t + 1], s2 = srcs[t + 2], s3 = srcs[t + 3];
        m0 = max4(m0, *(const float4*)&h[(size_t)s0 * 16 + q * 4]);
        m1 = max4(m1, *(const float4*)&h[(size_t)s1 * 16 + q * 4]);
        m2 = max4(m2, *(const float4*)&h[(size_t)s2 * 16 + q * 4]);
        m3 = max4(m3, *(const float4*)&h[(size_t)s3 * 16 + q * 4]);
    }
    for (; t < e1; ++t) m0 = max4(m0, *(const float4*)&h[(size_t)srcs[t] * 16 + q * 4]);
    float4 m = max4(max4(m0, m1), max4(m2, m3));
    *(float4*)&out[(size_t)d * 16 + q * 4] = make_float4(m.x - c.x, m.y - c.y, m.z - c.z, m.w - c.w);
}

// ---------------- level 1: fused pool(16ch) + xform W3 -> Hc ----------------
__global__ __launch_bounds__(256)
void pxformL1_k(const float* __restrict__ f2, const int* __restrict__ offsN,
                const int* __restrict__ oclist, const int* __restrict__ ocount,
                const float* __restrict__ W3, float* __restrict__ h) {
    __shared__ float sW[19 * 32];
    __shared__ float nf[8][16];
    for (int i = threadIdx.x; i < 19 * 32; i += 256) sW[i] = W3[i];
    int gid = blockIdx.x * 256 + threadIdx.x;
    int j = gid >> 5, ch = gid & 31;
    int lj = threadIdx.x >> 5;                   // 8 js per block
    bool valid = j < *ocount;
    int d = valid ? oclist[j] : 0;
    if (valid && ch < 16) {
        float m = 0.f;                           // f2 >= 0 (post-relu)
        int n0 = offsN[d], n1 = offsN[d + 1];
        for (int n = n0; n < n1; ++n) m = fmaxf(m, f2[(size_t)n * 16 + ch]);
        nf[lj][ch] = m;
    }
    __syncthreads();
    if (!valid) return;
    float px, py, pz;
    key2xyz(d, px, py, pz);
    float s = px * sW[16 * 32 + ch] + py * sW[17 * 32 + ch] + pz * sW[18 * 32 + ch];
    #pragma unroll
    for (int k = 0; k < 16; ++k) s += nf[lj][k] * sW[k * 32 + ch];
    h[(size_t)j * 32 + ch] = s;
}

// fused float4 gather(W3pos) + xform W4 (32->32) -> hnext (different buffer).
__global__ __launch_bounds__(256)
void gatherL1f_k(const float* __restrict__ h, const float* __restrict__ W3pos,
                 const float* __restrict__ W4,          // 35x32
                 const int* __restrict__ offsN, const int* __restrict__ offs0,
                 const int* __restrict__ csrc0,
                 const int* __restrict__ oclist, const int* __restrict__ ocount,
                 float* __restrict__ hnext) {
    __shared__ float sWp[96];
    __shared__ float sW4[35 * 32];
    __shared__ float gsT[32][33];                // [ch][lj], padded
    int tid = threadIdx.x;
    if (tid < 96) sWp[tid] = W3pos[tid];
    for (int i = tid; i < 35 * 32; i += 256) sW4[i] = W4[i];
    __syncthreads();
    int gid = blockIdx.x * 256 + tid;
    int j = gid >> 3, q = gid & 7;
    int lj = tid >> 3;
    bool valid = j < *ocount;
    float px = 0, py = 0, pz = 0;
    if (valid) {
        int d = oclist[j];
        key2xyz(d, px, py, pz);
        float4 w0 = *(const float4*)&sWp[q * 4];
        float4 w1 = *(const float4*)&sWp[32 + q * 4];
        float4 w2 = *(const float4*)&sWp[64 + q * 4];
        float4 c = make_float4(px * w0.x + py * w1.x + pz * w2.x, px * w0.y + py * w1.y + pz * w2.y,
                               px * w0.z + py * w1.z + pz * w2.z, px * w0.w + py * w1.w + pz * w2.w);
        float4 self = *(const float4*)&h[(size_t)j * 32 + q * 4];
        float4 m0 = max4(c, self), m1 = m0, m2 = m0, m3 = m0;   // self-loop
        int e0 = offs0[offsN[d]], e1 = offs0[offsN[d + 1]];
        int t = e0;
        for (; t + 4 <= e1; t += 4) {
            int s0 = csrc0[t] & JMASK, s1 = csrc0[t + 1] & JMASK;
            int s2 = csrc0[t + 2] & JMASK, s3 = csrc0[t + 3] & JMASK;
            m0 = max4(m0, *(const float4*)&h[(size_t)s0 * 32 + q * 4]);
            m1 = max4(m1, *(const float4*)&h[(size_t)s1 * 32 + q * 4]);
            m2 = max4(m2, *(const float4*)&h[(size_t)s2 * 32 + q * 4]);
            m3 = max4(m3, *(const float4*)&h[(size_t)s3 * 32 + q * 4]);
        }
        for (; t < e1; ++t) m0 = max4(m0, *(const float4*)&h[(size_t)(csrc0[t] & JMASK) * 32 + q * 4]);
        float4 m = max4(max4(m0, m1), max4(m2, m3));
        gsT[q * 4 + 0][lj] = m.x - c.x;
        gsT[q * 4 + 1][lj] = m.y - c.y;
        gsT[q * 4 + 2][lj] = m.z - c.z;
        gsT[q * 4 + 3][lj] = m.w - c.w;
    }
    __syncthreads();
    if (!valid) return;
    float4 s4;
    {
        float4 w0 = *(const float4*)&sW4[32 * 32 + q * 4];
        float4 w1 = *(const float4*)&sW4[33 * 32 + q * 4];
        float4 w2 = *(const float4*)&sW4[34 * 32 + q * 4];
        s4 = make_float4(px * w0.x + py * w1.x + pz * w2.x, px * w0.y + py * w1.y + pz * w2.y,
                         px * w0.z + py * w1.z + pz * w2.z, px * w0.w + py * w1.w + pz * w2.w);
    }
    #pragma unroll
    for (int k = 0; k < 32; ++k) {
        float g = gsT[k][lj];
        s4 = fma4(g, *(const float4*)&sW4[k * 32 + q * 4], s4);
    }
    *(float4*)&hnext[(size_t)j * 32 + q * 4] = s4;
}

// plain float4 flat gather (final level-1 layer)
__global__ __launch_bounds__(256)
void gatherL1_k(const float* __restrict__ h, const float* __restrict__ Wpos,
                const int* __restrict__ offsN, const int* __restrict__ offs0,
                const int* __restrict__ csrc0,
                const int* __restrict__ oclist, const int* __restrict__ ocount,
                float* __restrict__ g) {
    __shared__ float sW[96];
    int tid = threadIdx.x;
    if (tid < 96) sW[tid] = Wpos[tid];
    __syncthreads();
    int gid = blockIdx.x * 256 + tid;
    int j = gid >> 3, q = gid & 7;
    if (j >= *ocount) return;
    int d = oclist[j];
    float px, py, pz;
    key2xyz(d, px, py, pz);
    float4 w0 = *(const float4*)&sW[q * 4];
    float4 w1 = *(const float4*)&sW[32 + q * 4];
    float4 w2 = *(const float4*)&sW[64 + q * 4];
    float4 c = make_float4(px * w0.x + py * w1.x + pz * w2.x, px * w0.y + py * w1.y + pz * w2.y,
                           px * w0.z + py * w1.z + pz * w2.z, px * w0.w + py * w1.w + pz * w2.w);
    float4 self = *(const float4*)&h[(size_t)j * 32 + q * 4];
    float4 m0 = max4(c, self), m1 = m0, m2 = m0, m3 = m0;   // self-loop
    int e0 = offs0[offsN[d]], e1 = offs0[offsN[d + 1]];
    int t = e0;
    for (; t + 4 <= e1; t += 4) {
        int s0 = csrc0[t] & JMASK, s1 = csrc0[t + 1] & JMASK;
        int s2 = csrc0[t + 2] & JMASK, s3 = csrc0[t + 3] & JMASK;
        m0 = max4(m0, *(const float4*)&h[(size_t)s0 * 32 + q * 4]);
        m1 = max4(m1, *(const float4*)&h[(size_t)s1 * 32 + q * 4]);
        m2 = max4(m2, *(const float4*)&h[(size_t)s2 * 32 + q * 4]);
        m3 = max4(m3, *(const float4*)&h[(size_t)s3 * 32 + q * 4]);
    }
    for (; t < e1; ++t) m0 = max4(m0, *(const float4*)&h[(size_t)(csrc0[t] & JMASK) * 32 + q * 4]);
    float4 m = max4(max4(m0, m1), max4(m2, m3));
    *(float4*)&g[(size_t)j * 32 + q * 4] = make_float4(m.x - c.x, m.y - c.y, m.z - c.z, m.w - c.w);
}

// ---------------- level 2 (block per 16^3 cell) ----------------
// children of d2 are the contiguous key range [d2*64, d2*64+64)
__global__ __launch_bounds__(256)
void pool2x_k(const float* __restrict__ Gc, const int* __restrict__ jmap,
              const float* __restrict__ W5, float* __restrict__ h5) {
    __shared__ float part[8][32];
    __shared__ float nf2row[32];
    int d2 = blockIdx.x, tid = threadIdx.x;
    int x2 = d2 >> 8, y2 = (d2 >> 4) & 15, z2 = d2 & 15;
    int ch = tid & 31, grp = tid >> 5;                 // 8 grps x 8 children
    float m = 0.f;
    #pragma unroll
    for (int cc = 0; cc < 8; ++cc) {
        int cj = jmap[(d2 << 6) | (grp * 8 + cc)];
        if (cj >= 0) m = fmaxf(m, Gc[(size_t)cj * 32 + ch]);
    }
    part[grp][ch] = m;
    __syncthreads();
    if (tid < 32) {
        float mm = part[0][tid];
        #pragma unroll
        for (int g = 1; g < 8; ++g) mm = fmaxf(mm, part[g][tid]);
        nf2row[tid] = mm;
    }
    __syncthreads();
    if (tid < 64) {
        float s = x2 * W5[32 * 64 + tid] + y2 * W5[33 * 64 + tid] + z2 * W5[34 * 64 + tid];
        #pragma unroll
        for (int k = 0; k < 32; ++k) s += nf2row[k] * W5[k * 64 + tid];
        h5[(size_t)d2 * 64 + tid] = s;
    }
}

// level-2 gconv via flat adjacency list, float4 (+ optional fused next xform). One block per d2.
template<bool FUSE, bool WRITE_G>
__global__ __launch_bounds__(256)
void gconvL2_k(const float* __restrict__ h, const float* __restrict__ Wpos,
               const int* __restrict__ l2off, const int* __restrict__ l2src,
               const float* __restrict__ Wn,           // (64+3)x64, if FUSE
               float* __restrict__ gout, float* __restrict__ hnext) {
    __shared__ float red[16][64];
    __shared__ float grow[64];
    int d2 = blockIdx.x, tid = threadIdx.x;
    int x2 = d2 >> 8, y2 = (d2 >> 4) & 15, z2 = d2 & 15;
    int q = tid & 15, grp = tid >> 4;                  // 16 groups split the list
    int n0 = l2off[d2], num = l2off[d2 + 1] - n0;
    int per = (num + 15) >> 4;
    int s = n0 + grp * per;
    int e = min(n0 + num, s + per);
    float4 m0 = make_float4(-1e30f, -1e30f, -1e30f, -1e30f);
    float4 m1 = m0, m2 = m0, m3 = m0;
    int t = s;
    for (; t + 4 <= e; t += 4) {
        int s0 = l2src[t], s1 = l2src[t + 1], s2 = l2src[t + 2], s3 = l2src[t + 3];
        m0 = max4(m0, *(const float4*)&h[(size_t)s0 * 64 + q * 4]);
        m1 = max4(m1, *(const float4*)&h[(size_t)s1 * 64 + q * 4]);
        m2 = max4(m2, *(const float4*)&h[(size_t)s2 * 64 + q * 4]);
        m3 = max4(m3, *(const float4*)&h[(size_t)s3 * 64 + q * 4]);
    }
    for (; t < e; ++t) m0 = max4(m0, *(const float4*)&h[(size_t)l2src[t] * 64 + q * 4]);
    float4 m = max4(max4(m0, m1), max4(m2, m3));
    red[grp][q * 4 + 0] = m.x;
    red[grp][q * 4 + 1] = m.y;
    red[grp][q * 4 + 2] = m.z;
    red[grp][q * 4 + 3] = m.w;
    __syncthreads();
    if (tid < 64) {
        int ch = tid;
        float mm = red[0][ch];
        #pragma unroll
        for (int g = 1; g < 16; ++g) mm = fmaxf(mm, red[g][ch]);
        float c = x2 * Wpos[ch] + y2 * Wpos[64 + ch] + z2 * Wpos[128 + ch];
        mm = fmaxf(mm, fmaxf(c, h[(size_t)d2 * 64 + ch]));   // self-loop + empty
        float g = mm - c;
        if (WRITE_G) gout[(size_t)d2 * 64 + ch] = g;
        if (FUSE) grow[ch] = g;
    }
    if (FUSE) {
        __syncthreads();
        if (tid < 64) {
            float s2v = x2 * Wn[64 * 64 + tid] + y2 * Wn[65 * 64 + tid] + z2 * Wn[66 * 64 + tid];
            #pragma unroll
            for (int k = 0; k < 64; ++k) s2v += grow[k] * Wn[k * 64 + tid];
            hnext[(size_t)d2 * 64 + tid] = s2v;
        }
    }
}

// ---------------- output pool + linear ----------------
__global__ __launch_bounds__(256)
void outpool_k(const float* __restrict__ g7, float* __restrict__ xo) {
    int gid = blockIdx.x * 256 + threadIdx.x;
    if (gid >= 64 * 64) return;
    int oc = gid >> 6, ch = gid & 63;
    int cx = oc >> 4, cy = (oc >> 2) & 3, cz = oc & 3;
    float m = 0.f;
    for (int tc = 0; tc < 64; ++tc) {
        int i = tc >> 4, j = (tc >> 2) & 3, k = tc & 3;
        int d2 = ((cx * 4 + i) * 16 + (cy * 4 + j)) * 16 + (cz * 4 + k);
        m = fmaxf(m, g7[(size_t)d2 * 64 + ch]);
    }
    xo[(size_t)oc * 64 + ch] = m;
}

__global__ __launch_bounds__(64)
void linear_k(const float* __restrict__ xo, const float* __restrict__ Wl,
              const float* __restrict__ bl, float* __restrict__ out) {
    int j = blockIdx.x;
    float s = 0.f;
    for (int i = threadIdx.x; i < 4096; i += 64) s += xo[i] * Wl[(size_t)i * 100 + j];
    #pragma unroll
    for (int off = 32; off; off >>= 1) s += __shfl_down(s, off);
    if (threadIdx.x == 0) out[j] = s + bl[j];
}

extern "C" void kernel_launch(void* const* d_in, const int* in_sizes, int n_in,
                              void* d_out, int out_size, void* d_ws, size_t ws_size,
                              hipStream_t stream) {
    (void)in_sizes; (void)n_in; (void)out_size;
    const float* nodes = (const float*)d_in[0];
    const float* feats = (const float*)d_in[1];
    const int*   edges = (const int*)d_in[2];
    const int*   esrc  = edges;
    const int*   edst  = edges + NE;
    const float* W1 = (const float*)d_in[3];
    const float* W2 = (const float*)d_in[4];
    const float* W3 = (const float*)d_in[5];
    const float* W4 = (const float*)d_in[6];
    const float* W5 = (const float*)d_in[7];
    const float* W6 = (const float*)d_in[8];
    const float* W7 = (const float*)d_in[9];
    const float* Wl = (const float*)d_in[10];
    const float* bl = (const float*)d_in[11];
    float* out = (float*)d_out;

    char* ws = (char*)d_ws;
    size_t off = 0;
    auto alloc = [&](size_t bytes) { void* p = ws + off; off = (off + bytes + 255) & ~(size_t)255; return p; };
    // zero region: cntN + btot (one memset)
    int*   cntN    = (int*)alloc((size_t)C1 * 4);
    int*   btot    = (int*)alloc((size_t)NB * 4);
    size_t zero_bytes = off;
    int*   ocount  = (int*)alloc(4);
    int*   bsum   = (int*)alloc(260 * 4);
    int*   bbase  = (int*)alloc((size_t)(NB + 1) * 4);
    int*   cursor = (int*)alloc((size_t)NB * 4);
    int*   cid    = (int*)alloc((size_t)NN * 4);
    int*   rank   = (int*)alloc((size_t)NN * 4);
    int*   nidx   = (int*)alloc((size_t)NN * 4);
    int*   offsOcc= (int*)alloc((size_t)(C1 + 1) * 4);
    int*   offsN  = (int*)alloc((size_t)(C1 + 1) * 4);
    int*   offs0  = (int*)alloc((size_t)(NN + 1) * 4);
    int*   srcs0  = (int*)alloc((size_t)NE * 4);
    int*   csrc0  = (int*)alloc((size_t)NE * 4);
    int2*  ebuf   = (int2*)alloc((size_t)NE * 8);
    int*   oclist = (int*)alloc((size_t)NN * 4);
    int*   jmap   = (int*)alloc((size_t)C1 * 4);
    int*   jsrcP  = (int*)alloc((size_t)NN * 4);
    unsigned long long* mask = (unsigned long long*)alloc((size_t)C2 * 64 * 8);  // 2MB
    int*   l2num  = (int*)alloc((size_t)C2 * 4);
    int*   l2off  = (int*)alloc((size_t)(C2 + 1) * 4);
    int*   l2srcA = (int*)alloc((size_t)NE * 4);
    float* pnodes = (float*)alloc((size_t)NN * 3 * 4);
    float* pfeat  = (float*)alloc((size_t)NN * 4);
    float* A      = (float*)alloc((size_t)NN * 48 * 4);   // h1, h2, f2
    float* Hc     = (float*)alloc((size_t)NN * 32 * 4);
    float* Gc     = (float*)alloc((size_t)NN * 32 * 4);
    float* h5     = (float*)alloc((size_t)C2 * 64 * 4);
    float* h6     = (float*)alloc((size_t)C2 * 64 * 4);
    float* h7     = (float*)alloc((size_t)C2 * 64 * 4);
    float* g7     = (float*)alloc((size_t)C2 * 64 * 4);
    float* xo     = (float*)alloc((size_t)64 * 64 * 4);
    if (ws_size < off) return;

    float* h1 = A;                      // [NN][8]
    float* h2 = A + (size_t)NN * 16;    // [NN][16]
    float* f2 = A + (size_t)NN * 32;    // [NN][16]

    hipMemsetAsync(cntN, 0, zero_bytes, stream);

    auto gr = [](long long n) { return (int)((n + 255) / 256); };
    const int nbC1 = (C1 + 2047) / 2048;   // 128
    const int nbC2 = (C2 + 2047) / 2048;   // 2
    const int gPA  = (NE + PA_EDGES - 1) / PA_EDGES;  // 196

    // ---- connectivity build (key space, atomic-cursor-free) ----
    cidhist_k<<<gr(NN), 256, 0, stream>>>(nodes, cid, cntN);
    // occupancy compaction via boolean scan
    scan1_k<1><<<nbC1, 256, 0, stream>>>(cntN, C1, offsOcc, bsum);
    scan2_k<<<1, 256, 0, stream>>>(bsum, nbC1);
    scan3_k<<<gr(C1 + 1), 256, 0, stream>>>(offsOcc, C1, bsum, nbC1);
    jlist_k<<<gr(C1), 256, 0, stream>>>(offsOcc, jmap, oclist, ocount);
    // node CSR offsets
    scan1_k<0><<<nbC1, 256, 0, stream>>>(cntN, C1, offsN, bsum);
    scan2_k<<<1, 256, 0, stream>>>(bsum, nbC1);
    scan3_k<<<gr(C1 + 1), 256, 0, stream>>>(offsN, C1, bsum, nbC1);
    nscatter_k<<<gr(NN), 256, 0, stream>>>(cid, offsN, cntN, rank, nidx);
    permute_k<<<gr(NN), 256, 0, stream>>>(nidx, nodes, feats, cid, jmap, pnodes, pfeat, jsrcP);
    bhist_k<<<gPA, 256, 0, stream>>>(edst, rank, btot);
    scanB_k<<<1, 256, 0, stream>>>(btot, bbase, cursor);
    passA_k<<<gPA, 256, 0, stream>>>(esrc, edst, rank, cursor, ebuf);
    passB_k<<<NB, 256, 0, stream>>>(ebuf, bbase, jsrcP, offs0, srcs0, csrc0);
    // level-2 adjacency: bitmap -> scan -> deterministic emit
    mask_k<<<C2, 256, 0, stream>>>(offsN, offs0, csrc0, mask, l2num);
    scan1_k<0><<<nbC2, 256, 0, stream>>>(l2num, C2, l2off, bsum);
    scan2_k<<<1, 256, 0, stream>>>(bsum, nbC2);
    scan3_k<<<gr(C2 + 1), 256, 0, stream>>>(l2off, C2, bsum, nbC2);
    emit_k<<<C2, 64, 0, stream>>>(mask, l2off, l2srcA);

    // ---- level 0 (rank space) ----
    xform0_k<1, 8><<<gr((long long)NN * 8), 256, 0, stream>>>(pnodes, pfeat, W1, h1);
    gatherL0f_k<<<gr((long long)NN * 8), 256, 0, stream>>>(pnodes, h1, W1 + 1 * 8, W2, offs0, srcs0, h2);
    gatherL0v4_k<<<gr((long long)NN * 4), 256, 0, stream>>>(pnodes, h2, W2 + 8 * 16, offs0, srcs0, f2);

    // ---- level 1 (compact occupied cells, flat edge ranges; ping-pong Hc/Gc) ----
    pxformL1_k<<<gr((long long)NN * 32), 256, 0, stream>>>(f2, offsN, oclist, ocount, W3, Hc);
    gatherL1f_k<<<gr((long long)NN * 8), 256, 0, stream>>>(Hc, W3 + 16 * 32, W4, offsN, offs0, csrc0, oclist, ocount, Gc);
    gatherL1_k<<<gr((long long)NN * 8), 256, 0, stream>>>(Gc, W4 + 32 * 32, offsN, offs0, csrc0, oclist, ocount, Hc);

    // ---- level 2 (block per 16^3 cell, list-driven, fused) ----
    pool2x_k<<<C2, 256, 0, stream>>>(Hc, jmap, W5, h5);
    gconvL2_k<true,  false><<<C2, 256, 0, stream>>>(h5, W5 + 32 * 64, l2off, l2srcA, W6, nullptr, h6);
    gconvL2_k<true,  false><<<C2, 256, 0, stream>>>(h6, W6 + 64 * 64, l2off, l2srcA, W7, nullptr, h7);
    gconvL2_k<false, true ><<<C2, 256, 0, stream>>>(h7, W7 + 64 * 64, l2off, l2srcA, nullptr, g7, nullptr);

    outpool_k<<<16, 256, 0, stream>>>(g7, xo);
    linear_k<<<100, 64, 0, stream>>>(xo, Wl, bl, out);
}

// Round 16
// 390.056 us; speedup vs baseline: 62.1354x; 1.0095x over previous
//
#include <hip/hip_runtime.h>

#define NN 100000      // nodes
#define NE 1600000     // edges
#define C1 262144      // 64^3 cells (keyed as d2*64+child)
#define C2 4096        // 16^3 cells
#define BSH 7          // bucket shift (128 new-ids per bucket)
#define BSZ 128
#define NB 782         // ceil(NN/128)
#define PA_EDGES 8192
#define PA_IT (PA_EDGES / 256)
#define JMASK 0xFFFFF  // low 20 bits: compact j; bits 20..31: d2 of src cell
#define RMASK 0x1FFFF  // 17 bits: rank

// cell key layout: key = d2*64 + child, d2 = (x>>2)*256+(y>>2)*16+(z>>2),
// child = (x&3)*16+(y&3)*4+(z&3)
__device__ __forceinline__ void key2xyz(int key, float& x, float& y, float& z) {
    int d2 = key >> 6, ch = key & 63;
    x = (float)((((d2 >> 8) & 15) << 2) | (ch >> 4));
    y = (float)((((d2 >> 4) & 15) << 2) | ((ch >> 2) & 3));
    z = (float)(((d2 & 15) << 2) | (ch & 3));
}
__device__ __forceinline__ float4 max4(float4 a, float4 b) {
    return make_float4(fmaxf(a.x, b.x), fmaxf(a.y, b.y), fmaxf(a.z, b.z), fmaxf(a.w, b.w));
}
__device__ __forceinline__ float4 fma4(float s, float4 w, float4 acc) {
    return make_float4(s * w.x + acc.x, s * w.y + acc.y, s * w.z + acc.z, s * w.w + acc.w);
}

// ---------------- cell key of each node + node-per-cell histogram ----------------
__global__ __launch_bounds__(256)
void cidhist_k(const float* __restrict__ nodes, int* __restrict__ cid,
               int* __restrict__ cntN) {
    int i = blockIdx.x * 256 + threadIdx.x;
    if (i >= NN) return;
    int cx = min(max((int)floorf(nodes[3 * i]     * 0.25f), 0), 63);
    int cy = min(max((int)floorf(nodes[3 * i + 1] * 0.25f), 0), 63);
    int cz = min(max((int)floorf(nodes[3 * i + 2] * 0.25f), 0), 63);
    int d2 = ((cx >> 2) * 16 + (cy >> 2)) * 16 + (cz >> 2);
    int ch = ((cx & 3) * 4 + (cy & 3)) * 4 + (cz & 3);
    int key = (d2 << 6) | ch;
    cid[i] = key;
    atomicAdd(&cntN[key], 1);
}

// ---------------- generic exclusive scan: 2048/block. MODE 0: cnt[i]; MODE 1: cnt[i]>0 ----------------
template<int MODE>
__global__ __launch_bounds__(256)
void scan1_k(const int* __restrict__ cnt, int n, int* __restrict__ offs,
             int* __restrict__ bsum) {
    __shared__ int ws[4];
    int t = threadIdx.x, lane = t & 63, w = t >> 6;
    int base = blockIdx.x * 2048 + t * 8;
    int v[8]; int s = 0;
    #pragma unroll
    for (int i = 0; i < 8; ++i) {
        int raw = (base + i < n) ? cnt[base + i] : 0;
        v[i] = (MODE == 1) ? (raw > 0 ? 1 : 0) : raw;
        s += v[i];
    }
    int sc = s;
    #pragma unroll
    for (int off = 1; off < 64; off <<= 1) { int o = __shfl_up(sc, off); if (lane >= off) sc += o; }
    if (lane == 63) ws[w] = sc;
    __syncthreads();
    int wbase = 0;
    for (int i = 0; i < w; ++i) wbase += ws[i];
    int run = wbase + sc - s;
    #pragma unroll
    for (int i = 0; i < 8; ++i) { if (base + i < n) offs[base + i] = run; run += v[i]; }
    if (t == 255) bsum[blockIdx.x] = wbase + sc;
}

__global__ __launch_bounds__(256)
void scan2_k(int* __restrict__ bsum, int nb) {   // one block, nb <= 256
    __shared__ int ws[4];
    int t = threadIdx.x, lane = t & 63, w = t >> 6;
    int v = (t < nb) ? bsum[t] : 0;
    int sc = v;
    #pragma unroll
    for (int off = 1; off < 64; off <<= 1) { int o = __shfl_up(sc, off); if (lane >= off) sc += o; }
    if (lane == 63) ws[w] = sc;
    __syncthreads();
    int wbase = 0;
    for (int i = 0; i < w; ++i) wbase += ws[i];
    if (t < nb) bsum[t] = wbase + sc - v;
    if (t == 255) bsum[nb] = ws[0] + ws[1] + ws[2] + ws[3];
}

__global__ __launch_bounds__(256)
void scan3_k(int* __restrict__ offs, int n, const int* __restrict__ bsum, int nb) {
    int i = blockIdx.x * 256 + threadIdx.x;
    if (i < n) offs[i] += bsum[i >> 11];
    else if (i == n) offs[n] = bsum[nb];
}

// ---------------- occupied-cell compaction from offsOcc (deterministic, atomic-free) ----------------
__global__ __launch_bounds__(256)
void jlist_k(const int* __restrict__ offsOcc, int* __restrict__ jmap,
             int* __restrict__ oclist, int* __restrict__ ocount) {
    int c = blockIdx.x * 256 + threadIdx.x;
    if (c == 0) *ocount = offsOcc[C1];
    if (c >= C1) return;
    int pre = offsOcc[c];
    bool occ = offsOcc[c + 1] > pre;
    jmap[c] = occ ? pre : -1;
    if (occ) oclist[pre] = c;
}

// ---------------- node scatter: rank (new id) + nidx (old id by new id) ----------------
__global__ __launch_bounds__(256)
void nscatter_k(const int* __restrict__ cid, const int* __restrict__ offsN,
                int* __restrict__ cntN, int* __restrict__ rank, int* __restrict__ nidx) {
    int i = blockIdx.x * 256 + threadIdx.x;
    if (i >= NN) return;
    int c = cid[i];
    int pos = offsN[c] + atomicAdd(&cntN[c], -1) - 1;
    rank[i] = pos;
    nidx[pos] = i;
}

// ---------------- permute node data into new-id order ----------------
__global__ __launch_bounds__(256)
void permute_k(const int* __restrict__ nidx, const float* __restrict__ nodes,
               const float* __restrict__ feats, const int* __restrict__ cid,
               const int* __restrict__ jmap,
               float* __restrict__ pnodes, float* __restrict__ pfeat,
               int* __restrict__ jsrcP) {
    int d = blockIdx.x * 256 + threadIdx.x;
    if (d >= NN) return;
    int i = nidx[d];
    pnodes[3 * d]     = nodes[3 * i];
    pnodes[3 * d + 1] = nodes[3 * i + 1];
    pnodes[3 * d + 2] = nodes[3 * i + 2];
    pfeat[d] = feats[i];
    int c = cid[i];
    unsigned packed = (unsigned)jmap[c] | (((unsigned)c >> 6) << 20);  // j | d2<<20
    jsrcP[d] = (int)packed;
}

// ---------------- bucket histogram over rank[dst] (LDS pre-aggregated) ----------------
__global__ __launch_bounds__(256)
void bhist_k(const int* __restrict__ edst, const int* __restrict__ rank,
             int* __restrict__ btot) {
    __shared__ int h[NB];
    int tid = threadIdx.x;
    for (int i = tid; i < NB; i += 256) h[i] = 0;
    __syncthreads();
    int base = blockIdx.x * PA_EDGES;
    for (int i = 0; i < PA_IT; ++i) {
        int e = base + i * 256 + tid;
        if (e < NE) atomicAdd(&h[rank[edst[e]] >> BSH], 1);
    }
    __syncthreads();
    for (int i = tid; i < NB; i += 256) if (h[i]) atomicAdd(&btot[i], h[i]);
}

// one block: exclusive scan of NB (<=1024) bucket totals -> bbase[NB+1]; copy to cursor
__global__ __launch_bounds__(256)
void scanB_k(const int* __restrict__ btot, int* __restrict__ bbase,
             int* __restrict__ cursor) {
    __shared__ int ws[4];
    int t = threadIdx.x, lane = t & 63, w = t >> 6;
    int i0 = 4 * t;
    int v[4]; int s = 0;
    #pragma unroll
    for (int q = 0; q < 4; ++q) { v[q] = (i0 + q < NB) ? btot[i0 + q] : 0; s += v[q]; }
    int sc = s;
    #pragma unroll
    for (int off = 1; off < 64; off <<= 1) { int o = __shfl_up(sc, off); if (lane >= off) sc += o; }
    if (lane == 63) ws[w] = sc;
    __syncthreads();
    int wb = 0;
    for (int q = 0; q < w; ++q) wb += ws[q];
    int run = wb + sc - s;
    #pragma unroll
    for (int q = 0; q < 4; ++q) {
        if (i0 + q <= NB) { bbase[i0 + q] = run; if (i0 + q < NB) cursor[i0 + q] = run; }
        run += v[q];
    }
}

// ---------------- pass A: partition packed (rank_src | rd_low<<17) by dst bucket ----------------
__global__ __launch_bounds__(256)
void passA_k(const int* __restrict__ esrc, const int* __restrict__ edst,
             const int* __restrict__ rank, int* __restrict__ cursor,
             int* __restrict__ ebuf) {
    __shared__ int hist[NB];
    __shared__ int lofs[NB + 1];
    __shared__ int gbase[NB];
    __shared__ int cnt2[NB];
    __shared__ int stage[PA_EDGES];              // 32KB (packed)
    __shared__ unsigned short sbid[PA_EDGES];    // 16KB
    __shared__ int ws[4];
    int tid = threadIdx.x, lane = tid & 63, w = tid >> 6;
    for (int i = tid; i < NB; i += 256) { hist[i] = 0; cnt2[i] = 0; }
    __syncthreads();
    int base = blockIdx.x * PA_EDGES;
    for (int i = 0; i < PA_IT; ++i) {
        int e = base + i * 256 + tid;
        if (e < NE) atomicAdd(&hist[rank[edst[e]] >> BSH], 1);
    }
    __syncthreads();
    // exclusive scan hist -> lofs (4 per thread)
    int i0 = 4 * tid;
    int v[4]; int s = 0;
    #pragma unroll
    for (int q = 0; q < 4; ++q) { v[q] = (i0 + q < NB) ? hist[i0 + q] : 0; s += v[q]; }
    int sc = s;
    #pragma unroll
    for (int off = 1; off < 64; off <<= 1) { int o = __shfl_up(sc, off); if (lane >= off) sc += o; }
    if (lane == 63) ws[w] = sc;
    __syncthreads();
    int wb = 0;
    for (int q = 0; q < w; ++q) wb += ws[q];
    int run = wb + sc - s;
    #pragma unroll
    for (int q = 0; q < 4; ++q) {
        if (i0 + q <= NB) lofs[i0 + q] = run;
        run += v[q];
    }
    __syncthreads();
    for (int b = tid; b < NB; b += 256) {
        int c = hist[b];
        gbase[b] = c ? atomicAdd(&cursor[b], c) : 0;
    }
    __syncthreads();
    for (int i = 0; i < PA_IT; ++i) {
        int e = base + i * 256 + tid;
        if (e < NE) {
            int rd = rank[edst[e]], rs = rank[esrc[e]];
            int b = rd >> BSH;
            int p = lofs[b] + atomicAdd(&cnt2[b], 1);
            stage[p] = rs | ((rd & (BSZ - 1)) << 17);
            sbid[p] = (unsigned short)b;
        }
    }
    __syncthreads();
    int nval = min(PA_EDGES, NE - base);
    for (int k = tid; k < nval; k += 256) {
        int b = sbid[k];
        ebuf[gbase[b] + (k - lofs[b])] = stage[k];
    }
}

// ---------------- pass B: per-bucket final scatter; offs0 (new-id CSR); csrc fused ----------------
__global__ __launch_bounds__(256)
void passB_k(const int* __restrict__ ebuf, const int* __restrict__ bbase,
             const int* __restrict__ jsrcP,
             int* __restrict__ offs0, int* __restrict__ srcs0, int* __restrict__ csrc0) {
    __shared__ int cnt[BSZ];
    __shared__ int pos[BSZ];
    __shared__ int ws[4];
    int b = blockIdx.x, tid = threadIdx.x, lane = tid & 63, w = tid >> 6;
    int d0 = b << BSH;
    int range = min(BSZ, NN - d0);
    if (tid < BSZ) cnt[tid] = 0;
    __syncthreads();
    int r0 = bbase[b], r1 = bbase[b + 1];
    for (int k = r0 + tid; k < r1; k += 256) atomicAdd(&cnt[(ebuf[k] >> 17) & (BSZ - 1)], 1);
    __syncthreads();
    int v = (tid < BSZ) ? cnt[tid] : 0;
    int sc = v;
    #pragma unroll
    for (int off = 1; off < 64; off <<= 1) { int o = __shfl_up(sc, off); if (lane >= off) sc += o; }
    if (lane == 63) ws[w] = sc;
    __syncthreads();
    int wb = 0;
    for (int q = 0; q < w; ++q) wb += ws[q];
    int rel = wb + sc - v;                        // exclusive per-dst prefix
    if (tid < range) offs0[d0 + tid] = r0 + rel;
    if (tid == 0) offs0[min(d0 + BSZ, NN)] = r1;  // benign duplicate of next base
    if (tid < BSZ) pos[tid] = r0 + rel;
    __syncthreads();
    for (int k = r0 + tid; k < r1; k += 256) {
        int pk = ebuf[k];
        int di = (pk >> 17) & (BSZ - 1);
        int p = atomicAdd(&pos[di], 1);
        int rs = pk & RMASK;
        srcs0[p] = rs;
        csrc0[p] = jsrcP[rs];                     // packed j | d2<<20
    }
}

// ---------------- level-2 bitmap: contiguous edge slice -> LDS bitmap -> global ----------------
__global__ __launch_bounds__(256)
void mask_k(const int* __restrict__ offsN, const int* __restrict__ offs0,
            const int* __restrict__ csrc0,
            unsigned long long* __restrict__ mask, int* __restrict__ l2num) {
    __shared__ unsigned long long words[64];
    int d2 = blockIdx.x, tid = threadIdx.x;
    if (tid < 64) words[tid] = 0;
    __syncthreads();
    // all edges of d2's 64 child cells are one contiguous range (key ordering)
    int e0 = offs0[offsN[d2 << 6]];
    int e1 = offs0[offsN[(d2 + 1) << 6]];
    for (int t = e0 + tid; t < e1; t += 256) {
        int s2 = (int)(((unsigned)csrc0[t]) >> 20);
        atomicOr(&words[s2 >> 6], 1ull << (s2 & 63));
    }
    __syncthreads();
    if (tid < 64) {                                // wave 0 only
        unsigned long long wv = words[tid];
        mask[(size_t)d2 * 64 + tid] = wv;
        int pc = __popcll(wv);
        int sc = pc;
        #pragma unroll
        for (int off = 1; off < 64; off <<= 1) {
            int o = __shfl_up(sc, off);
            if (tid >= off) sc += o;
        }
        if (tid == 63) l2num[d2] = sc;
    }
}

// ---------------- emit compact per-d2 src list at deterministic offsets ----------------
__global__ __launch_bounds__(64)
void emit_k(const unsigned long long* __restrict__ mask, const int* __restrict__ l2off,
            int* __restrict__ l2src) {
    int d2 = blockIdx.x, tid = threadIdx.x;      // 64 threads
    unsigned long long wv = mask[(size_t)d2 * 64 + tid];
    int pc = __popcll(wv);
    int sc = pc;
    #pragma unroll
    for (int off = 1; off < 64; off <<= 1) {
        int o = __shfl_up(sc, off);
        if (tid >= off) sc += o;
    }
    int p = l2off[d2] + sc - pc;                 // exclusive prefix within d2
    while (wv) {
        int b = __builtin_ctzll(wv);
        wv &= wv - 1;
        l2src[p++] = (tid << 6) | b;
    }
}

// ---------------- level 0: h = f @ W_f + pos @ W_p (new-id space) ----------------
template<int CI, int CO>
__global__ __launch_bounds__(256)
void xform0_k(const float* __restrict__ pnodes, const float* __restrict__ f,
              const float* __restrict__ W, float* __restrict__ h) {
    __shared__ float sW[(CI + 3) * CO];
    for (int i = threadIdx.x; i < (CI + 3) * CO; i += 256) sW[i] = W[i];
    __syncthreads();
    int gid = blockIdx.x * 256 + threadIdx.x;
    int i = gid / CO, ch = gid - i * CO;
    if (i >= NN) return;
    float s = pnodes[3 * i] * sW[CI * CO + ch] + pnodes[3 * i + 1] * sW[(CI + 1) * CO + ch]
            + pnodes[3 * i + 2] * sW[(CI + 2) * CO + ch];
    #pragma unroll
    for (int k = 0; k < CI; ++k) s += f[(size_t)i * CI + k] * sW[k * CO + ch];
    h[(size_t)i * CO + ch] = s;
}

// fused: gather over W1 (8ch) + xform W2 (8->16) -> h2. Block covers 32 dst nodes.
__global__ __launch_bounds__(256)
void gatherL0f_k(const float* __restrict__ pnodes, const float* __restrict__ h1,
                 const float* __restrict__ W1pos,       // 3x8
                 const float* __restrict__ W2,          // 11x16
                 const int* __restrict__ offs, const int* __restrict__ srcs,
                 float* __restrict__ h2) {
    __shared__ float sW1[24];
    __shared__ float sW2[176];
    __shared__ float f1s[32][8];
    int tid = threadIdx.x;
    if (tid < 24) sW1[tid] = W1pos[tid];
    if (tid < 176) sW2[tid] = W2[tid];
    __syncthreads();
    int gid = blockIdx.x * 256 + tid;
    int d = gid >> 3, ch = gid & 7;
    int dbase = blockIdx.x * 32;
    if (d < NN) {
        float c = pnodes[3 * d] * sW1[ch] + pnodes[3 * d + 1] * sW1[8 + ch] + pnodes[3 * d + 2] * sW1[16 + ch];
        float m0 = c, m1 = c, m2 = c, m3 = c;
        int e0 = offs[d], e1 = offs[d + 1];
        int t = e0;
        for (; t + 4 <= e1; t += 4) {
            int s0 = srcs[t], s1 = srcs[t + 1], s2 = srcs[t + 2], s3 = srcs[t + 3];
            m0 = fmaxf(m0, h1[(size_t)s0 * 8 + ch]);
            m1 = fmaxf(m1, h1[(size_t)s1 * 8 + ch]);
            m2 = fmaxf(m2, h1[(size_t)s2 * 8 + ch]);
            m3 = fmaxf(m3, h1[(size_t)s3 * 8 + ch]);
        }
        for (; t < e1; ++t) m0 = fmaxf(m0, h1[(size_t)srcs[t] * 8 + ch]);
        f1s[d - dbase][ch] = fmaxf(fmaxf(m0, m1), fmaxf(m2, m3)) - c;
    }
    __syncthreads();
    // epilogue: h2[d][ch2] for 32 d x 16 ch2 = 512 outputs, 2 per thread
    #pragma unroll
    for (int rep = 0; rep < 2; ++rep) {
        int dL = (tid >> 4) + rep * 16, ch2 = tid & 15;
        int dg = dbase + dL;
        if (dg < NN) {
            float s = pnodes[3 * dg] * sW2[128 + ch2] + pnodes[3 * dg + 1] * sW2[144 + ch2]
                    + pnodes[3 * dg + 2] * sW2[160 + ch2];
            #pragma unroll
            for (int k = 0; k < 8; ++k) s += f1s[dL][k] * sW2[k * 16 + ch2];
            h2[(size_t)dg * 16 + ch2] = s;
        }
    }
}

// float4 gather, CO=16: 4 threads per dst node (channel quads)
__global__ __launch_bounds__(256)
void gatherL0v4_k(const float* __restrict__ pnodes, const float* __restrict__ h,
                  const float* __restrict__ Wpos,       // 3x16
                  const int* __restrict__ offs, const int* __restrict__ srcs,
                  float* __restrict__ out) {
    __shared__ float sW[48];
    int tid = threadIdx.x;
    if (tid < 48) sW[tid] = Wpos[tid];
    __syncthreads();
    int gid = blockIdx.x * 256 + tid;
    int d = gid >> 2, q = gid & 3;
    if (d >= NN) return;
    float px = pnodes[3 * d], py = pnodes[3 * d + 1], pz = pnodes[3 * d + 2];
    float4 w0 = *(const float4*)&sW[q * 4];
    float4 w1 = *(const float4*)&sW[16 + q * 4];
    float4 w2 = *(const float4*)&sW[32 + q * 4];
    float4 c = make_float4(px * w0.x + py * w1.x + pz * w2.x, px * w0.y + py * w1.y + pz * w2.y,
                           px * w0.z + py * w1.z + pz * w2.z, px * w0.w + py * w1.w + pz * w2.w);
    float4 m0 = c, m1 = c, m2 = c, m3 = c;       // no self-loop at level 0; empty -> 0
    int e0 = offs[d], e1 = offs[d + 1];
    int t = e0;
    for (; t + 4 <= e1; t += 4) {
        int s0 = srcs[t], s1 = srcs[t + 1], s2 = srcs[t + 2], s3 = srcs[t + 3];
        m0 = max4(m0, *(const float4*)&h[(size_t)s0 * 16 + q * 4]);
        m1 = max4(m1, *(const float4*)&h[(size_t)s1 * 16 + q * 4]);
        m2 = max4(m2, *(const float4*)&h[(size_t)s2 * 16 + q * 4]);
        m3 = max4(m3, *(const float4*)&h[(size_t)s3 * 16 + q * 4]);
    }
    for (; t < e1; ++t) m0 = max4(m0, *(const float4*)&h[(size_t)srcs[t] * 16 + q * 4]);
    float4 m = max4(max4(m0, m1), max4(m2, m3));
    *(float4*)&out[(size_t)d * 16 + q * 4] = make_float4(m.x - c.x, m.y - c.y, m.z - c.z, m.w - c.w);
}

// ---------------- level 1: fused pool(16ch) + xform W3 -> Hc ----------------
__global__ __launch_bounds__(256)
void pxformL1_k(const float* __restrict__ f2, const int* __restrict__ offsN,
                const int* __restrict__ oclist, const int* __restrict__ ocount,
                const float* __restrict__ W3, float* __restrict__ h) {
    __shared__ float sW[19 * 32];
    __shared__ float nf[8][16];
    for (int i = threadIdx.x; i < 19 * 32; i += 256) sW[i] = W3[i];
    int gid = blockIdx.x * 256 + threadIdx.x;
    int j = gid >> 5, ch = gid & 31;
    int lj = threadIdx.x >> 5;                   // 8 js per block
    bool valid = j < *ocount;
    int d = valid ? oclist[j] : 0;
    if (valid && ch < 16) {
        float m = 0.f;                           // f2 >= 0 (post-relu)
        int n0 = offsN[d], n1 = offsN[d + 1];
        for (int n = n0; n < n1; ++n) m = fmaxf(m, f2[(size_t)n * 16 + ch]);
        nf[lj][ch] = m;
    }
    __syncthreads();
    if (!valid) return;
    float px, py, pz;
    key2xyz(d, px, py, pz);
    float s = px * sW[16 * 32 + ch] + py * sW[17 * 32 + ch] + pz * sW[18 * 32 + ch];
    #pragma unroll
    for (int k = 0; k < 16; ++k) s += nf[lj][k] * sW[k * 32 + ch];
    h[(size_t)j * 32 + ch] = s;
}

// fused float4 gather(W3pos) + xform W4 (32->32) -> hnext (different buffer).
__global__ __launch_bounds__(256)
void gatherL1f_k(const float* __restrict__ h, const float* __restrict__ W3pos,
                 const float* __restrict__ W4,          // 35x32
                 const int* __restrict__ offsN, const int* __restrict__ offs0,
                 const int* __restrict__ csrc0,
                 const int* __restrict__ oclist, const int* __restrict__ ocount,
                 float* __restrict__ hnext) {
    __shared__ float sWp[96];
    __shared__ float sW4[35 * 32];
    __shared__ float gsT[32][33];                // [ch][lj], padded
    int tid = threadIdx.x;
    if (tid < 96) sWp[tid] = W3pos[tid];
    for (int i = tid; i < 35 * 32; i += 256) sW4[i] = W4[i];
    __syncthreads();
    int gid = blockIdx.x * 256 + tid;
    int j = gid >> 3, q = gid & 7;
    int lj = tid >> 3;
    bool valid = j < *ocount;
    float px = 0, py = 0, pz = 0;
    if (valid) {
        int d = oclist[j];
        key2xyz(d, px, py, pz);
        float4 w0 = *(const float4*)&sWp[q * 4];
        float4 w1 = *(const float4*)&sWp[32 + q * 4];
        float4 w2 = *(const float4*)&sWp[64 + q * 4];
        float4 c = make_float4(px * w0.x + py * w1.x + pz * w2.x, px * w0.y + py * w1.y + pz * w2.y,
                               px * w0.z + py * w1.z + pz * w2.z, px * w0.w + py * w1.w + pz * w2.w);
        float4 self = *(const float4*)&h[(size_t)j * 32 + q * 4];
        float4 m0 = max4(c, self), m1 = m0, m2 = m0, m3 = m0;   // self-loop
        int e0 = offs0[offsN[d]], e1 = offs0[offsN[d + 1]];
        int t = e0;
        for (; t + 4 <= e1; t += 4) {
            int s0 = csrc0[t] & JMASK, s1 = csrc0[t + 1] & JMASK;
            int s2 = csrc0[t + 2] & JMASK, s3 = csrc0[t + 3] & JMASK;
            m0 = max4(m0, *(const float4*)&h[(size_t)s0 * 32 + q * 4]);
            m1 = max4(m1, *(const float4*)&h[(size_t)s1 * 32 + q * 4]);
            m2 = max4(m2, *(const float4*)&h[(size_t)s2 * 32 + q * 4]);
            m3 = max4(m3, *(const float4*)&h[(size_t)s3 * 32 + q * 4]);
        }
        for (; t < e1; ++t) m0 = max4(m0, *(const float4*)&h[(size_t)(csrc0[t] & JMASK) * 32 + q * 4]);
        float4 m = max4(max4(m0, m1), max4(m2, m3));
        gsT[q * 4 + 0][lj] = m.x - c.x;
        gsT[q * 4 + 1][lj] = m.y - c.y;
        gsT[q * 4 + 2][lj] = m.z - c.z;
        gsT[q * 4 + 3][lj] = m.w - c.w;
    }
    __syncthreads();
    if (!valid) return;
    float4 s4;
    {
        float4 w0 = *(const float4*)&sW4[32 * 32 + q * 4];
        float4 w1 = *(const float4*)&sW4[33 * 32 + q * 4];
        float4 w2 = *(const float4*)&sW4[34 * 32 + q * 4];
        s4 = make_float4(px * w0.x + py * w1.x + pz * w2.x, px * w0.y + py * w1.y + pz * w2.y,
                         px * w0.z + py * w1.z + pz * w2.z, px * w0.w + py * w1.w + pz * w2.w);
    }
    #pragma unroll
    for (int k = 0; k < 32; ++k) {
        float g = gsT[k][lj];
        s4 = fma4(g, *(const float4*)&sW4[k * 32 + q * 4], s4);
    }
    *(float4*)&hnext[(size_t)j * 32 + q * 4] = s4;
}

// plain float4 flat gather (final level-1 layer)
__global__ __launch_bounds__(256)
void gatherL1_k(const float* __restrict__ h, const float* __restrict__ Wpos,
                const int* __restrict__ offsN, const int* __restrict__ offs0,
                const int* __restrict__ csrc0,
                const int* __restrict__ oclist, const int* __restrict__ ocount,
                float* __restrict__ g) {
    __shared__ float sW[96];
    int tid = threadIdx.x;
    if (tid < 96) sW[tid] = Wpos[tid];
    __syncthreads();
    int gid = blockIdx.x * 256 + tid;
    int j = gid >> 3, q = gid & 7;
    if (j >= *ocount) return;
    int d = oclist[j];
    float px, py, pz;
    key2xyz(d, px, py, pz);
    float4 w0 = *(const float4*)&sW[q * 4];
    float4 w1 = *(const float4*)&sW[32 + q * 4];
    float4 w2 = *(const float4*)&sW[64 + q * 4];
    float4 c = make_float4(px * w0.x + py * w1.x + pz * w2.x, px * w0.y + py * w1.y + pz * w2.y,
                           px * w0.z + py * w1.z + pz * w2.z, px * w0.w + py * w1.w + pz * w2.w);
    float4 self = *(const float4*)&h[(size_t)j * 32 + q * 4];
    float4 m0 = max4(c, self), m1 = m0, m2 = m0, m3 = m0;   // self-loop
    int e0 = offs0[offsN[d]], e1 = offs0[offsN[d + 1]];
    int t = e0;
    for (; t + 4 <= e1; t += 4) {
        int s0 = csrc0[t] & JMASK, s1 = csrc0[t + 1] & JMASK;
        int s2 = csrc0[t + 2] & JMASK, s3 = csrc0[t + 3] & JMASK;
        m0 = max4(m0, *(const float4*)&h[(size_t)s0 * 32 + q * 4]);
        m1 = max4(m1, *(const float4*)&h[(size_t)s1 * 32 + q * 4]);
        m2 = max4(m2, *(const float4*)&h[(size_t)s2 * 32 + q * 4]);
        m3 = max4(m3, *(const float4*)&h[(size_t)s3 * 32 + q * 4]);
    }
    for (; t < e1; ++t) m0 = max4(m0, *(const float4*)&h[(size_t)(csrc0[t] & JMASK) * 32 + q * 4]);
    float4 m = max4(max4(m0, m1), max4(m2, m3));
    *(float4*)&g[(size_t)j * 32 + q * 4] = make_float4(m.x - c.x, m.y - c.y, m.z - c.z, m.w - c.w);
}

// ---------------- level 2 (block per 16^3 cell) ----------------
// children of d2 are the contiguous key range [d2*64, d2*64+64)
__global__ __launch_bounds__(256)
void pool2x_k(const float* __restrict__ Gc, const int* __restrict__ jmap,
              const float* __restrict__ W5, float* __restrict__ h5) {
    __shared__ float part[8][32];
    __shared__ float nf2row[32];
    int d2 = blockIdx.x, tid = threadIdx.x;
    int x2 = d2 >> 8, y2 = (d2 >> 4) & 15, z2 = d2 & 15;
    int ch = tid & 31, grp = tid >> 5;                 // 8 grps x 8 children
    float m = 0.f;
    #pragma unroll
    for (int cc = 0; cc < 8; ++cc) {
        int cj = jmap[(d2 << 6) | (grp * 8 + cc)];
        if (cj >= 0) m = fmaxf(m, Gc[(size_t)cj * 32 + ch]);
    }
    part[grp][ch] = m;
    __syncthreads();
    if (tid < 32) {
        float mm = part[0][tid];
        #pragma unroll
        for (int g = 1; g < 8; ++g) mm = fmaxf(mm, part[g][tid]);
        nf2row[tid] = mm;
    }
    __syncthreads();
    if (tid < 64) {
        float s = x2 * W5[32 * 64 + tid] + y2 * W5[33 * 64 + tid] + z2 * W5[34 * 64 + tid];
        #pragma unroll
        for (int k = 0; k < 32; ++k) s += nf2row[k] * W5[k * 64 + tid];
        h5[(size_t)d2 * 64 + tid] = s;
    }
}

// level-2 gconv via flat adjacency list, float4 (+ optional fused next xform). One block per d2.
template<bool FUSE, bool WRITE_G>
__global__ __launch_bounds__(256)
void gconvL2_k(const float* __restrict__ h, const float* __restrict__ Wpos,
               const int* __restrict__ l2off, const int* __restrict__ l2src,
               const float* __restrict__ Wn,           // (64+3)x64, if FUSE
               float* __restrict__ gout, float* __restrict__ hnext) {
    __shared__ float red[16][64];
    __shared__ float grow[64];
    int d2 = blockIdx.x, tid = threadIdx.x;
    int x2 = d2 >> 8, y2 = (d2 >> 4) & 15, z2 = d2 & 15;
    int q = tid & 15, grp = tid >> 4;                  // 16 groups split the list
    int n0 = l2off[d2], num = l2off[d2 + 1] - n0;
    int per = (num + 15) >> 4;
    int s = n0 + grp * per;
    int e = min(n0 + num, s + per);
    float4 m0 = make_float4(-1e30f, -1e30f, -1e30f, -1e30f);
    float4 m1 = m0, m2 = m0, m3 = m0;
    int t = s;
    for (; t + 4 <= e; t += 4) {
        int s0 = l2src[t], s1 = l2src[t + 1], s2 = l2src[t + 2], s3 = l2src[t + 3];
        m0 = max4(m0, *(const float4*)&h[(size_t)s0 * 64 + q * 4]);
        m1 = max4(m1, *(const float4*)&h[(size_t)s1 * 64 + q * 4]);
        m2 = max4(m2, *(const float4*)&h[(size_t)s2 * 64 + q * 4]);
        m3 = max4(m3, *(const float4*)&h[(size_t)s3 * 64 + q * 4]);
    }
    for (; t < e; ++t) m0 = max4(m0, *(const float4*)&h[(size_t)l2src[t] * 64 + q * 4]);
    float4 m = max4(max4(m0, m1), max4(m2, m3));
    red[grp][q * 4 + 0] = m.x;
    red[grp][q * 4 + 1] = m.y;
    red[grp][q * 4 + 2] = m.z;
    red[grp][q * 4 + 3] = m.w;
    __syncthreads();
    if (tid < 64) {
        int ch = tid;
        float mm = red[0][ch];
        #pragma unroll
        for (int g = 1; g < 16; ++g) mm = fmaxf(mm, red[g][ch]);
        float c = x2 * Wpos[ch] + y2 * Wpos[64 + ch] + z2 * Wpos[128 + ch];
        mm = fmaxf(mm, fmaxf(c, h[(size_t)d2 * 64 + ch]));   // self-loop + empty
        float g = mm - c;
        if (WRITE_G) gout[(size_t)d2 * 64 + ch] = g;
        if (FUSE) grow[ch] = g;
    }
    if (FUSE) {
        __syncthreads();
        if (tid < 64) {
            float s2v = x2 * Wn[64 * 64 + tid] + y2 * Wn[65 * 64 + tid] + z2 * Wn[66 * 64 + tid];
            #pragma unroll
            for (int k = 0; k < 64; ++k) s2v += grow[k] * Wn[k * 64 + tid];
            hnext[(size_t)d2 * 64 + tid] = s2v;
        }
    }
}

// ---------------- output pool + linear ----------------
__global__ __launch_bounds__(256)
void outpool_k(const float* __restrict__ g7, float* __restrict__ xo) {
    int gid = blockIdx.x * 256 + threadIdx.x;
    if (gid >= 64 * 64) return;
    int oc = gid >> 6, ch = gid & 63;
    int cx = oc >> 4, cy = (oc >> 2) & 3, cz = oc & 3;
    float m = 0.f;
    for (int tc = 0; tc < 64; ++tc) {
        int i = tc >> 4, j = (tc >> 2) & 3, k = tc & 3;
        int d2 = ((cx * 4 + i) * 16 + (cy * 4 + j)) * 16 + (cz * 4 + k);
        m = fmaxf(m, g7[(size_t)d2 * 64 + ch]);
    }
    xo[(size_t)oc * 64 + ch] = m;
}

__global__ __launch_bounds__(64)
void linear_k(const float* __restrict__ xo, const float* __restrict__ Wl,
              const float* __restrict__ bl, float* __restrict__ out) {
    int j = blockIdx.x;
    float s = 0.f;
    for (int i = threadIdx.x; i < 4096; i += 64) s += xo[i] * Wl[(size_t)i * 100 + j];
    #pragma unroll
    for (int off = 32; off; off >>= 1) s += __shfl_down(s, off);
    if (threadIdx.x == 0) out[j] = s + bl[j];
}

extern "C" void kernel_launch(void* const* d_in, const int* in_sizes, int n_in,
                              void* d_out, int out_size, void* d_ws, size_t ws_size,
                              hipStream_t stream) {
    (void)in_sizes; (void)n_in; (void)out_size;
    const float* nodes = (const float*)d_in[0];
    const float* feats = (const float*)d_in[1];
    const int*   edges = (const int*)d_in[2];
    const int*   esrc  = edges;
    const int*   edst  = edges + NE;
    const float* W1 = (const float*)d_in[3];
    const float* W2 = (const float*)d_in[4];
    const float* W3 = (const float*)d_in[5];
    const float* W4 = (const float*)d_in[6];
    const float* W5 = (const float*)d_in[7];
    const float* W6 = (const float*)d_in[8];
    const float* W7 = (const float*)d_in[9];
    const float* Wl = (const float*)d_in[10];
    const float* bl = (const float*)d_in[11];
    float* out = (float*)d_out;

    char* ws = (char*)d_ws;
    size_t off = 0;
    auto alloc = [&](size_t bytes) { void* p = ws + off; off = (off + bytes + 255) & ~(size_t)255; return p; };
    // zero region: cntN + btot (one memset)
    int*   cntN    = (int*)alloc((size_t)C1 * 4);
    int*   btot    = (int*)alloc((size_t)NB * 4);
    size_t zero_bytes = off;
    int*   ocount  = (int*)alloc(4);
    int*   bsum   = (int*)alloc(260 * 4);
    int*   bbase  = (int*)alloc((size_t)(NB + 1) * 4);
    int*   cursor = (int*)alloc((size_t)NB * 4);
    int*   cid    = (int*)alloc((size_t)NN * 4);
    int*   rank   = (int*)alloc((size_t)NN * 4);
    int*   nidx   = (int*)alloc((size_t)NN * 4);
    int*   offsOcc= (int*)alloc((size_t)(C1 + 1) * 4);
    int*   offsN  = (int*)alloc((size_t)(C1 + 1) * 4);
    int*   offs0  = (int*)alloc((size_t)(NN + 1) * 4);
    int*   srcs0  = (int*)alloc((size_t)NE * 4);
    int*   csrc0  = (int*)alloc((size_t)NE * 4);
    int*   ebuf   = (int*)alloc((size_t)NE * 4);
    int*   oclist = (int*)alloc((size_t)NN * 4);
    int*   jmap   = (int*)alloc((size_t)C1 * 4);
    int*   jsrcP  = (int*)alloc((size_t)NN * 4);
    unsigned long long* mask = (unsigned long long*)alloc((size_t)C2 * 64 * 8);  // 2MB
    int*   l2num  = (int*)alloc((size_t)C2 * 4);
    int*   l2off  = (int*)alloc((size_t)(C2 + 1) * 4);
    int*   l2srcA = (int*)alloc((size_t)NE * 4);
    float* pnodes = (float*)alloc((size_t)NN * 3 * 4);
    float* pfeat  = (float*)alloc((size_t)NN * 4);
    float* A      = (float*)alloc((size_t)NN * 48 * 4);   // h1, h2, f2
    float* Hc     = (float*)alloc((size_t)NN * 32 * 4);
    float* Gc     = (float*)alloc((size_t)NN * 32 * 4);
    float* h5     = (float*)alloc((size_t)C2 * 64 * 4);
    float* h6     = (float*)alloc((size_t)C2 * 64 * 4);
    float* h7     = (float*)alloc((size_t)C2 * 64 * 4);
    float* g7     = (float*)alloc((size_t)C2 * 64 * 4);
    float* xo     = (float*)alloc((size_t)64 * 64 * 4);
    if (ws_size < off) return;

    float* h1 = A;                      // [NN][8]
    float* h2 = A + (size_t)NN * 16;    // [NN][16]
    float* f2 = A + (size_t)NN * 32;    // [NN][16]

    hipMemsetAsync(cntN, 0, zero_bytes, stream);

    auto gr = [](long long n) { return (int)((n + 255) / 256); };
    const int nbC1 = (C1 + 2047) / 2048;   // 128
    const int nbC2 = (C2 + 2047) / 2048;   // 2
    const int gPA  = (NE + PA_EDGES - 1) / PA_EDGES;  // 196

    // ---- connectivity build (key space, atomic-cursor-free) ----
    cidhist_k<<<gr(NN), 256, 0, stream>>>(nodes, cid, cntN);
    // occupancy compaction via boolean scan
    scan1_k<1><<<nbC1, 256, 0, stream>>>(cntN, C1, offsOcc, bsum);
    scan2_k<<<1, 256, 0, stream>>>(bsum, nbC1);
    scan3_k<<<gr(C1 + 1), 256, 0, stream>>>(offsOcc, C1, bsum, nbC1);
    jlist_k<<<gr(C1), 256, 0, stream>>>(offsOcc, jmap, oclist, ocount);
    // node CSR offsets
    scan1_k<0><<<nbC1, 256, 0, stream>>>(cntN, C1, offsN, bsum);
    scan2_k<<<1, 256, 0, stream>>>(bsum, nbC1);
    scan3_k<<<gr(C1 + 1), 256, 0, stream>>>(offsN, C1, bsum, nbC1);
    nscatter_k<<<gr(NN), 256, 0, stream>>>(cid, offsN, cntN, rank, nidx);
    permute_k<<<gr(NN), 256, 0, stream>>>(nidx, nodes, feats, cid, jmap, pnodes, pfeat, jsrcP);
    bhist_k<<<gPA, 256, 0, stream>>>(edst, rank, btot);
    scanB_k<<<1, 256, 0, stream>>>(btot, bbase, cursor);
    passA_k<<<gPA, 256, 0, stream>>>(esrc, edst, rank, cursor, ebuf);
    passB_k<<<NB, 256, 0, stream>>>(ebuf, bbase, jsrcP, offs0, srcs0, csrc0);
    // level-2 adjacency: bitmap -> scan -> deterministic emit
    mask_k<<<C2, 256, 0, stream>>>(offsN, offs0, csrc0, mask, l2num);
    scan1_k<0><<<nbC2, 256, 0, stream>>>(l2num, C2, l2off, bsum);
    scan2_k<<<1, 256, 0, stream>>>(bsum, nbC2);
    scan3_k<<<gr(C2 + 1), 256, 0, stream>>>(l2off, C2, bsum, nbC2);
    emit_k<<<C2, 64, 0, stream>>>(mask, l2off, l2srcA);

    // ---- level 0 (rank space) ----
    xform0_k<1, 8><<<gr((long long)NN * 8), 256, 0, stream>>>(pnodes, pfeat, W1, h1);
    gatherL0f_k<<<gr((long long)NN * 8), 256, 0, stream>>>(pnodes, h1, W1 + 1 * 8, W2, offs0, srcs0, h2);
    gatherL0v4_k<<<gr((long long)NN * 4), 256, 0, stream>>>(pnodes, h2, W2 + 8 * 16, offs0, srcs0, f2);

    // ---- level 1 (compact occupied cells, flat edge ranges; ping-pong Hc/Gc) ----
    pxformL1_k<<<gr((long long)NN * 32), 256, 0, stream>>>(f2, offsN, oclist, ocount, W3, Hc);
    gatherL1f_k<<<gr((long long)NN * 8), 256, 0, stream>>>(Hc, W3 + 16 * 32, W4, offsN, offs0, csrc0, oclist, ocount, Gc);
    gatherL1_k<<<gr((long long)NN * 8), 256, 0, stream>>>(Gc, W4 + 32 * 32, offsN, offs0, csrc0, oclist, ocount, Hc);

    // ---- level 2 (block per 16^3 cell, list-driven, fused) ----
    pool2x_k<<<C2, 256, 0, stream>>>(Hc, jmap, W5, h5);
    gconvL2_k<true,  false><<<C2, 256, 0, stream>>>(h5, W5 + 32 * 64, l2off, l2srcA, W6, nullptr, h6);
    gconvL2_k<true,  false><<<C2, 256, 0, stream>>>(h6, W6 + 64 * 64, l2off, l2srcA, W7, nullptr, h7);
    gconvL2_k<false, true ><<<C2, 256, 0, stream>>>(h7, W7 + 64 * 64, l2off, l2srcA, nullptr, g7, nullptr);

    outpool_k<<<16, 256, 0, stream>>>(g7, xo);
    linear_k<<<100, 64, 0, stream>>>(xo, Wl, bl, out);
}